// Round 2
// baseline (1025704.590 us; speedup 1.0000x reference)
//
#include <hip/hip_runtime.h>
#include <math.h>

#define ACT_NONE 0
#define ACT_LEAKY 1
#define ACT_TANH 2

static inline unsigned cdivu(long a, long b) { return (unsigned)((a + b - 1) / b); }

// ---------------------------------------------------------------------------
// Direct convolution, NCHW, fp32. Each thread computes TW=8 consecutive
// outputs along W for one (n, oc, yo). Register row-cache xr[] shares input
// loads across kx taps. Epilogue: bias, activation, optional residual add.
// res/y may alias (in-place residual): each thread reads res[i] before
// writing y[i] at the same element only -> safe. (No __restrict__ on those.)
// ---------------------------------------------------------------------------
template <int K, int S, int DIL>
__global__ __launch_bounds__(256) void conv2d_k(
    const float* __restrict__ x, const float* __restrict__ w,
    const float* __restrict__ bias, const float* res, float* y, int N, int Cin,
    int Hin, int Win, int Cout, int Hout, int Wout, int pad, int act) {
  constexpr int TW = 8;
  constexpr int XL = (TW - 1) * S + (K - 1) * DIL + 1;
  int wq = (Wout + TW - 1) / TW;
  long gid = (long)blockIdx.x * 256 + threadIdx.x;
  long total = (long)N * Cout * Hout * wq;
  if (gid >= total) return;
  int xg = (int)(gid % wq);
  long r = gid / wq;
  int yo = (int)(r % Hout);
  r /= Hout;
  int oc = (int)(r % Cout);
  int n = (int)(r / Cout);

  float bv = bias[oc];
  float acc[TW];
#pragma unroll
  for (int j = 0; j < TW; ++j) acc[j] = bv;

  int xo0 = xg * TW;
  int xi0 = xo0 * S - pad;
  const float* xn = x + (long)n * Cin * Hin * Win;
  const float* wb = w + (long)oc * Cin * K * K;

  for (int ic = 0; ic < Cin; ++ic) {
    const float* xc = xn + (long)ic * Hin * Win;
    const float* wc = wb + ic * (K * K);
#pragma unroll
    for (int ky = 0; ky < K; ++ky) {
      int yi = yo * S - pad + ky * DIL;
      if ((unsigned)yi < (unsigned)Hin) {
        const float* row = xc + (long)yi * Win;
        float xr[XL];
#pragma unroll
        for (int i2 = 0; i2 < XL; ++i2) {
          int xi = xi0 + i2;
          xr[i2] = ((unsigned)xi < (unsigned)Win) ? row[xi] : 0.f;
        }
#pragma unroll
        for (int kx = 0; kx < K; ++kx) {
          float wv = wc[ky * K + kx];
#pragma unroll
          for (int j = 0; j < TW; ++j)
            acc[j] = fmaf(wv, xr[j * S + kx * DIL], acc[j]);
        }
      }
    }
  }

  long obase = (((long)n * Cout + oc) * Hout + yo) * (long)Wout + xo0;
#pragma unroll
  for (int j = 0; j < TW; ++j) {
    if (xo0 + j < Wout) {
      float v = acc[j];
      if (act == ACT_LEAKY)
        v = v >= 0.f ? v : 0.2f * v;
      else if (act == ACT_TANH)
        v = tanhf(v);
      if (res) v += res[obase + j];
      y[obase + j] = v;
    }
  }
}

// ---------------------------------------------------------------------------
// Bilinear 2x upsample, align_corners=True. One thread per output element.
// ---------------------------------------------------------------------------
__global__ __launch_bounds__(256) void upsample2_ac(
    const float* __restrict__ x, float* __restrict__ y, int C, int H, int W) {
  int Ho = 2 * H, Wo = 2 * W;
  long total = (long)C * Ho * Wo;
  long gid = (long)blockIdx.x * 256 + threadIdx.x;
  if (gid >= total) return;
  int xo = (int)(gid % Wo);
  long r = gid / Wo;
  int yo = (int)(r % Ho);
  int c = (int)(r / Ho);
  float fy = (float)(yo * (H - 1)) / (float)(Ho - 1);
  float fx = (float)(xo * (W - 1)) / (float)(Wo - 1);
  int y0 = (int)fy;
  int y1 = min(y0 + 1, H - 1);
  float wy = fy - (float)y0;
  int x0 = (int)fx;
  int x1 = min(x0 + 1, W - 1);
  float wx = fx - (float)x0;
  const float* p = x + (long)c * H * W;
  float r0 = p[(long)y0 * W + x0] * (1.f - wx) + p[(long)y0 * W + x1] * wx;
  float r1 = p[(long)y1 * W + x0] * (1.f - wx) + p[(long)y1 * W + x1] * wx;
  y[gid] = r0 * (1.f - wy) + r1 * wy;
}

// ---------------------------------------------------------------------------
// Fused 1x1 QKV conv writing directly into per-group token layout.
// Thread -> (frame tt, group-channel c in [0,64), row y, x-quad xq).
// token n = (tt*oh + i)*ow + j ; feature d = (c*ph + yy)*pw + xx
// with i=y/ph, yy=y%ph, j=x/pw, xx=x%pw. x state: [16,256,30,160].
// ---------------------------------------------------------------------------
__global__ __launch_bounds__(256) void qkv_tokens(
    const float* __restrict__ x, const float* __restrict__ wq,
    const float* __restrict__ bq, const float* __restrict__ wk,
    const float* __restrict__ bk, const float* __restrict__ wv,
    const float* __restrict__ bv, float* __restrict__ tq,
    float* __restrict__ tk, float* __restrict__ tv, int co, int ph, int pw,
    int oh, int ow) {
  long gid = (long)blockIdx.x * 256 + threadIdx.x;
  if (gid >= 16L * 64 * 30 * 40) return;
  int xq = (int)(gid % 40);
  long r = gid / 40;
  int y = (int)(r % 30);
  r /= 30;
  int c = (int)(r % 64);
  int tt = (int)(r / 64);
  int oc = co + c;

  float aq[4], ak[4], av[4];
  float bqv = bq[oc], bkv = bk[oc], bvv = bv[oc];
#pragma unroll
  for (int e = 0; e < 4; ++e) {
    aq[e] = bqv;
    ak[e] = bkv;
    av[e] = bvv;
  }
  const float* xp = x + ((long)tt * 256 * 30 + y) * 160 + xq * 4;
  const float* wqp = wq + (long)oc * 256;
  const float* wkp = wk + (long)oc * 256;
  const float* wvp = wv + (long)oc * 256;
  for (int ic = 0; ic < 256; ++ic) {
    float4 xv = *(const float4*)(xp + (long)ic * 4800);
    float wqv = wqp[ic], wkv = wkp[ic], wvv = wvp[ic];
    aq[0] = fmaf(wqv, xv.x, aq[0]);
    aq[1] = fmaf(wqv, xv.y, aq[1]);
    aq[2] = fmaf(wqv, xv.z, aq[2]);
    aq[3] = fmaf(wqv, xv.w, aq[3]);
    ak[0] = fmaf(wkv, xv.x, ak[0]);
    ak[1] = fmaf(wkv, xv.y, ak[1]);
    ak[2] = fmaf(wkv, xv.z, ak[2]);
    ak[3] = fmaf(wkv, xv.w, ak[3]);
    av[0] = fmaf(wvv, xv.x, av[0]);
    av[1] = fmaf(wvv, xv.y, av[1]);
    av[2] = fmaf(wvv, xv.z, av[2]);
    av[3] = fmaf(wvv, xv.w, av[3]);
  }
  int i = y / ph, yy = y - i * ph;
  int Dd = 64 * ph * pw;
#pragma unroll
  for (int e = 0; e < 4; ++e) {
    int xcol = xq * 4 + e;
    int j = xcol / pw, xx = xcol - j * pw;
    long n = ((long)tt * oh + i) * ow + j;
    long d = ((long)c * ph + yy) * pw + xx;
    long idx = n * Dd + d;
    tq[idx] = aq[e];
    tk[idx] = ak[e];
    tv[idx] = av[e];
  }
}

// ---------------------------------------------------------------------------
// Tiled SGEMM, 64x64 tile, 256 threads, 4x4 microtile, K-chunks of 16.
// gemm_qk: C[M,N] = scale * A[M,K] * B[N,K]^T  (scores; K=Dd mult of 16)
// ---------------------------------------------------------------------------
__global__ __launch_bounds__(256) void gemm_qk(const float* __restrict__ A,
                                               const float* __restrict__ B,
                                               float* __restrict__ C, int M,
                                               int N, int K, float scale) {
  __shared__ float As[16][68];
  __shared__ float Bs[16][68];
  int t = threadIdx.x;
  int tx = t & 15, ty = t >> 4;
  int row0 = blockIdx.y * 64, col0 = blockIdx.x * 64;
  float acc[4][4];
#pragma unroll
  for (int i = 0; i < 4; ++i)
#pragma unroll
    for (int j = 0; j < 4; ++j) acc[i][j] = 0.f;

  int lr = t >> 2;
  int lk = (t & 3) * 4;
  for (int k0 = 0; k0 < K; k0 += 16) {
    {
      int gr = row0 + lr;
      float4 av = make_float4(0.f, 0.f, 0.f, 0.f);
      if (gr < M) av = *(const float4*)(A + (long)gr * K + k0 + lk);
      As[lk + 0][lr] = av.x;
      As[lk + 1][lr] = av.y;
      As[lk + 2][lr] = av.z;
      As[lk + 3][lr] = av.w;
    }
    {
      int gc = col0 + lr;
      float4 bv = make_float4(0.f, 0.f, 0.f, 0.f);
      if (gc < N) bv = *(const float4*)(B + (long)gc * K + k0 + lk);
      Bs[lk + 0][lr] = bv.x;
      Bs[lk + 1][lr] = bv.y;
      Bs[lk + 2][lr] = bv.z;
      Bs[lk + 3][lr] = bv.w;
    }
    __syncthreads();
#pragma unroll
    for (int kk = 0; kk < 16; ++kk) {
      float4 a4 = *(const float4*)(&As[kk][ty * 4]);
      float4 b4 = *(const float4*)(&Bs[kk][tx * 4]);
      float aa[4] = {a4.x, a4.y, a4.z, a4.w};
      float bb[4] = {b4.x, b4.y, b4.z, b4.w};
#pragma unroll
      for (int i = 0; i < 4; ++i)
#pragma unroll
        for (int j = 0; j < 4; ++j) acc[i][j] = fmaf(aa[i], bb[j], acc[i][j]);
    }
    __syncthreads();
  }
#pragma unroll
  for (int i = 0; i < 4; ++i) {
    int gr = row0 + ty * 4 + i;
    if (gr < M) {
#pragma unroll
      for (int j = 0; j < 4; ++j) {
        int gc = col0 + tx * 4 + j;
        if (gc < N) C[(long)gr * N + gc] = acc[i][j] * scale;
      }
    }
  }
}

// ---------------------------------------------------------------------------
// gemm_av_scatter: C[M,N] = A[M,K] * B[K,N]; row gr is token (n0+gr), col gc
// is feature d; epilogue scatters into spatial [16,256,30,160] at bufT.
// K = Ntok (mult of 16), N = Dd (mult of 16).
// ---------------------------------------------------------------------------
__global__ __launch_bounds__(256) void gemm_av_scatter(
    const float* __restrict__ A, const float* __restrict__ B,
    float* __restrict__ outb, int M, int N, int K, int n0, int co, int ph,
    int pw, int oh, int ow) {
  __shared__ float As[16][68];
  __shared__ float Bs[16][68];
  int t = threadIdx.x;
  int tx = t & 15, ty = t >> 4;
  int row0 = blockIdx.y * 64, col0 = blockIdx.x * 64;
  float acc[4][4];
#pragma unroll
  for (int i = 0; i < 4; ++i)
#pragma unroll
    for (int j = 0; j < 4; ++j) acc[i][j] = 0.f;

  int lr = t >> 2;
  int lk = (t & 3) * 4;
  int kr = t >> 4;
  int lc = (t & 15) * 4;
  for (int k0 = 0; k0 < K; k0 += 16) {
    {
      int gr = row0 + lr;
      float4 av = make_float4(0.f, 0.f, 0.f, 0.f);
      if (gr < M) av = *(const float4*)(A + (long)gr * K + k0 + lk);
      As[lk + 0][lr] = av.x;
      As[lk + 1][lr] = av.y;
      As[lk + 2][lr] = av.z;
      As[lk + 3][lr] = av.w;
    }
    {
      int gc = col0 + lc;
      float4 bv = make_float4(0.f, 0.f, 0.f, 0.f);
      if (gc < N) bv = *(const float4*)(B + (long)(k0 + kr) * N + gc);
      Bs[kr][lc + 0] = bv.x;
      Bs[kr][lc + 1] = bv.y;
      Bs[kr][lc + 2] = bv.z;
      Bs[kr][lc + 3] = bv.w;
    }
    __syncthreads();
#pragma unroll
    for (int kk = 0; kk < 16; ++kk) {
      float4 a4 = *(const float4*)(&As[kk][ty * 4]);
      float4 b4 = *(const float4*)(&Bs[kk][tx * 4]);
      float aa[4] = {a4.x, a4.y, a4.z, a4.w};
      float bb[4] = {b4.x, b4.y, b4.z, b4.w};
#pragma unroll
      for (int i = 0; i < 4; ++i)
#pragma unroll
        for (int j = 0; j < 4; ++j) acc[i][j] = fmaf(aa[i], bb[j], acc[i][j]);
    }
    __syncthreads();
  }
  int pp = ph * pw;
#pragma unroll
  for (int i = 0; i < 4; ++i) {
    int gr = row0 + ty * 4 + i;
    if (gr < M) {
      int n = n0 + gr;
      int j2 = n % ow;
      int r2 = n / ow;
      int i2 = r2 % oh;
      int tt = r2 / oh;
#pragma unroll
      for (int j = 0; j < 4; ++j) {
        int gc = col0 + tx * 4 + j;
        if (gc < N) {
          int c = gc / pp;
          int rr = gc - c * pp;
          int yy = rr / pw;
          int xx = rr - yy * pw;
          long dst = (((long)tt * 256 + co + c) * 30 + i2 * ph + yy) * 160 +
                     (long)j2 * pw + xx;
          outb[dst] = acc[i][j];
        }
      }
    }
  }
}

// ---------------------------------------------------------------------------
// Row softmax in place. One block (256 threads) per row; row length N.
// ---------------------------------------------------------------------------
__global__ __launch_bounds__(256) void softmax_rows(float* __restrict__ S,
                                                    int N) {
  int row = blockIdx.x;
  float* p = S + (long)row * N;
  __shared__ float red[256];
  int t = threadIdx.x;
  float m = -1e30f;
  for (int i = t; i < N; i += 256) m = fmaxf(m, p[i]);
  red[t] = m;
  __syncthreads();
  for (int s = 128; s > 0; s >>= 1) {
    if (t < s) red[t] = fmaxf(red[t], red[t + s]);
    __syncthreads();
  }
  m = red[0];
  __syncthreads();
  float sum = 0.f;
  for (int i = t; i < N; i += 256) {
    float e = __expf(p[i] - m);
    p[i] = e;
    sum += e;
  }
  red[t] = sum;
  __syncthreads();
  for (int s = 128; s > 0; s >>= 1) {
    if (t < s) red[t] += red[t + s];
    __syncthreads();
  }
  float inv = 1.f / red[0];
  __syncthreads();
  for (int i = t; i < N; i += 256) p[i] *= inv;
}

// ---------------------------------------------------------------------------
extern "C" void kernel_launch(void* const* d_in, const int* in_sizes, int n_in,
                              void* d_out, int out_size, void* d_ws,
                              size_t ws_size, hipStream_t stream) {
  const float* input = (const float*)d_in[0];
  const float* enc_w0 = (const float*)d_in[1];
  const float* enc_b0 = (const float*)d_in[2];
  const float* enc_w1 = (const float*)d_in[3];
  const float* enc_b1 = (const float*)d_in[4];
  const float* enc_w2 = (const float*)d_in[5];
  const float* enc_b2 = (const float*)d_in[6];
  const float* enc_w3 = (const float*)d_in[7];
  const float* enc_b3 = (const float*)d_in[8];
  const float* tq_w = (const float*)d_in[9];
  const float* tq_b = (const float*)d_in[10];
  const float* tk_w = (const float*)d_in[11];
  const float* tk_b = (const float*)d_in[12];
  const float* tv_w = (const float*)d_in[13];
  const float* tv_b = (const float*)d_in[14];
  const float* to_w = (const float*)d_in[15];
  const float* to_b = (const float*)d_in[16];
  const float* tf1_w = (const float*)d_in[17];
  const float* tf1_b = (const float*)d_in[18];
  const float* tf2_w = (const float*)d_in[19];
  const float* tf2_b = (const float*)d_in[20];
  const float* d0_w = (const float*)d_in[21];
  const float* d0_b = (const float*)d_in[22];
  const float* d1_w = (const float*)d_in[23];
  const float* d1_b = (const float*)d_in[24];
  const float* d2_w = (const float*)d_in[25];
  const float* d2_b = (const float*)d_in[26];
  const float* d3_w = (const float*)d_in[27];
  const float* d3_b = (const float*)d_in[28];
  float* out = (float*)d_out;

  const size_t F = (size_t)16 * 256 * 30 * 160;  // 19,660,800 fp32
  const size_t TN = (size_t)16 * 4800 * 64;      // 4,915,200 fp32
  const int SC_ROWS = 1280;
  float* ws = (float*)d_ws;
  float* x = ws;                                  // F
  float* bufT = x + F;                            // F
  float* qt = bufT + F;                           // TN
  float* kt = qt + TN;                            // TN
  float* vt = kt + TN;                            // TN
  float* sc = vt + TN;                            // SC_ROWS*5120
  size_t need_bytes = (2 * F + 3 * TN + (size_t)SC_ROWS * 5120) * sizeof(float);
  if (ws_size < need_bytes) return;  // fail loud (wrong answer) not crash

  // ---------------- encoder ----------------
  {
    long tot = 16L * 64 * 60 * 40;
    conv2d_k<3, 2, 1><<<cdivu(tot, 256), 256, 0, stream>>>(
        input, enc_w0, enc_b0, nullptr, bufT, 16, 3, 120, 640, 64, 60, 320, 1,
        ACT_LEAKY);
    conv2d_k<3, 1, 1><<<cdivu(tot, 256), 256, 0, stream>>>(
        bufT, enc_w1, enc_b1, nullptr, x, 16, 64, 60, 320, 64, 60, 320, 1,
        ACT_LEAKY);
  }
  {
    long tot = 16L * 128 * 30 * 20;
    conv2d_k<3, 2, 1><<<cdivu(tot, 256), 256, 0, stream>>>(
        x, enc_w2, enc_b2, nullptr, bufT, 16, 64, 60, 320, 128, 30, 160, 1,
        ACT_LEAKY);
  }
  {
    long tot = 16L * 256 * 30 * 20;
    conv2d_k<3, 1, 1><<<cdivu(tot, 256), 256, 0, stream>>>(
        bufT, enc_w3, enc_b3, nullptr, x, 16, 128, 30, 160, 256, 30, 160, 1,
        ACT_LEAKY);
  }

  static const int PWa[4] = {80, 32, 10, 5};
  static const int PHa[4] = {15, 6, 5, 3};

  // ---------------- transformer stack ----------------
  long totc = 16L * 256 * 30 * 20;
  for (int l = 0; l < 8; ++l) {
    for (int g = 0; g < 4; ++g) {
      int ph = PHa[g], pw = PWa[g];
      int oh = 30 / ph, ow = 160 / pw;
      int Ntok = 16 * oh * ow;
      int Dd = 64 * ph * pw;
      qkv_tokens<<<4800, 256, 0, stream>>>(
          x, tq_w + (size_t)l * 256 * 256, tq_b + l * 256,
          tk_w + (size_t)l * 256 * 256, tk_b + l * 256,
          tv_w + (size_t)l * 256 * 256, tv_b + l * 256, qt, kt, vt, g * 64, ph,
          pw, oh, ow);
      float scale = 1.0f / sqrtf((float)Dd);
      for (int r0 = 0; r0 < Ntok; r0 += SC_ROWS) {
        int rows = Ntok - r0 < SC_ROWS ? Ntok - r0 : SC_ROWS;
        dim3 g1(cdivu(Ntok, 64), cdivu(rows, 64));
        gemm_qk<<<g1, 256, 0, stream>>>(qt + (size_t)r0 * Dd, kt, sc, rows,
                                        Ntok, Dd, scale);
        softmax_rows<<<rows, 256, 0, stream>>>(sc, Ntok);
        dim3 g2(cdivu(Dd, 64), cdivu(rows, 64));
        gemm_av_scatter<<<g2, 256, 0, stream>>>(sc, vt, bufT, rows, Dd, Ntok,
                                                r0, g * 64, ph, pw, oh, ow);
      }
    }

    // out conv 3x3 + leaky + residual (in place into x)
    conv2d_k<3, 1, 1><<<cdivu(totc, 256), 256, 0, stream>>>(
        bufT, to_w + (size_t)l * 256 * 256 * 9, to_b + l * 256, x, x, 16, 256,
        30, 160, 256, 30, 160, 1, ACT_LEAKY);

    // feed-forward
    conv2d_k<3, 1, 2><<<cdivu(totc, 256), 256, 0, stream>>>(
        x, tf1_w + (size_t)l * 256 * 256 * 9, tf1_b + l * 256, nullptr, bufT,
        16, 256, 30, 160, 256, 30, 160, 2, ACT_LEAKY);
    conv2d_k<3, 1, 1><<<cdivu(totc, 256), 256, 0, stream>>>(
        bufT, tf2_w + (size_t)l * 256 * 256 * 9, tf2_b + l * 256, x, x, 16,
        256, 30, 160, 256, 30, 160, 1, ACT_LEAKY);
  }

  // ---------------- decoder (per frame; scratch reuses qt/kt/vt) ----------
  for (int f = 0; f < 16; ++f) {
    const float* xf = x + (size_t)f * 256 * 30 * 160;
    upsample2_ac<<<cdivu(256L * 60 * 320, 256), 256, 0, stream>>>(xf, qt, 256,
                                                                  30, 160);
    {
      long tot = 1L * 128 * 60 * 40;
      conv2d_k<3, 1, 1><<<cdivu(tot, 256), 256, 0, stream>>>(
          qt, d0_w, d0_b, nullptr, kt, 1, 256, 60, 320, 128, 60, 320, 1,
          ACT_LEAKY);
    }
    {
      long tot = 1L * 64 * 60 * 40;
      conv2d_k<3, 1, 1><<<cdivu(tot, 256), 256, 0, stream>>>(
          kt, d1_w, d1_b, nullptr, vt, 1, 128, 60, 320, 64, 60, 320, 1,
          ACT_LEAKY);
    }
    upsample2_ac<<<cdivu(64L * 120 * 640, 256), 256, 0, stream>>>(vt, qt, 64,
                                                                  60, 320);
    {
      long tot = 1L * 64 * 120 * 80;
      conv2d_k<3, 1, 1><<<cdivu(tot, 256), 256, 0, stream>>>(
          qt, d2_w, d2_b, nullptr, kt, 1, 64, 120, 640, 64, 120, 640, 1,
          ACT_LEAKY);
    }
    {
      long tot = 1L * 3 * 120 * 80;
      conv2d_k<3, 1, 1><<<cdivu(tot, 256), 256, 0, stream>>>(
          kt, d3_w, d3_b, nullptr, out + (size_t)f * 3 * 120 * 640, 1, 64, 120,
          640, 3, 120, 640, 1, ACT_TANH);
    }
  }
}

// Round 4
// 101369.427 us; speedup vs baseline: 10.1185x; 10.1185x over previous
//
#include <hip/hip_runtime.h>
#include <hip/hip_bf16.h>
#include <math.h>

#define ACT_NONE 0
#define ACT_LEAKY 1
#define ACT_TANH 2

typedef __attribute__((ext_vector_type(8))) short bf16x8;
typedef __attribute__((ext_vector_type(4))) float f32x4;
typedef unsigned short u16;

#define MFMA(a, b, c) __builtin_amdgcn_mfma_f32_16x16x32_bf16((bf16x8)(a), (bf16x8)(b), (c), 0, 0, 0)

static inline unsigned cdivu(long a, long b) { return (unsigned)((a + b - 1) / b); }

__device__ __forceinline__ u16 f2bf(float x) {
  union { __hip_bfloat16 h; u16 u; } cv;
  cv.h = __float2bfloat16(x);
  return cv.u;
}
__device__ __forceinline__ float bf2f(u16 b) {
  union { u16 u; __hip_bfloat16 h; } cv;
  cv.u = b;
  return __bfloat162float(cv.h);
}
__device__ __forceinline__ void splitw(float v, u16* ph, u16* pl) {
  u16 h = f2bf(v);
  *ph = h;
  *pl = f2bf(v - bf2f(h));
}

// ---------------------------------------------------------------------------
// Direct fp32 conv (enc0: Cin=3; d3: Cout=3+tanh). Optional CL hi/lo output.
// ---------------------------------------------------------------------------
template <int K, int S, int DIL>
__global__ __launch_bounds__(256) void conv2d_k(
    const float* __restrict__ x, const float* __restrict__ w,
    const float* __restrict__ bias, float* y, u16* clh, u16* cll, int WpO,
    int PoffO, long o_fstride, int N, int Cin, int Hin, int Win, int Cout,
    int Hout, int Wout, int pad, int act) {
  constexpr int TW = 8;
  constexpr int XL = (TW - 1) * S + (K - 1) * DIL + 1;
  int wq = (Wout + TW - 1) / TW;
  long gid = (long)blockIdx.x * 256 + threadIdx.x;
  long total = (long)N * Cout * Hout * wq;
  if (gid >= total) return;
  int xg = (int)(gid % wq);
  long r = gid / wq;
  int yo = (int)(r % Hout);
  r /= Hout;
  int oc = (int)(r % Cout);
  int n = (int)(r / Cout);

  float bv = bias[oc];
  float acc[TW];
#pragma unroll
  for (int j = 0; j < TW; ++j) acc[j] = bv;

  int xo0 = xg * TW;
  int xi0 = xo0 * S - pad;
  const float* xn = x + (long)n * Cin * Hin * Win;
  const float* wb = w + (long)oc * Cin * K * K;

  for (int ic = 0; ic < Cin; ++ic) {
    const float* xc = xn + (long)ic * Hin * Win;
    const float* wc = wb + ic * (K * K);
#pragma unroll
    for (int ky = 0; ky < K; ++ky) {
      int yi = yo * S - pad + ky * DIL;
      if ((unsigned)yi < (unsigned)Hin) {
        const float* row = xc + (long)yi * Win;
        float xr[XL];
#pragma unroll
        for (int i2 = 0; i2 < XL; ++i2) {
          int xi = xi0 + i2;
          xr[i2] = ((unsigned)xi < (unsigned)Win) ? row[xi] : 0.f;
        }
#pragma unroll
        for (int kx = 0; kx < K; ++kx) {
          float wv = wc[ky * K + kx];
#pragma unroll
          for (int j = 0; j < TW; ++j)
            acc[j] = fmaf(wv, xr[j * S + kx * DIL], acc[j]);
        }
      }
    }
  }

#pragma unroll
  for (int j = 0; j < TW; ++j) {
    if (xo0 + j < Wout) {
      float v = acc[j];
      if (act == ACT_LEAKY)
        v = v >= 0.f ? v : 0.2f * v;
      else if (act == ACT_TANH)
        v = tanhf(v);
      if (y) y[(((long)n * Cout + oc) * Hout + yo) * Wout + xo0 + j] = v;
      if (clh) {
        long off = (long)n * o_fstride +
                   ((long)(yo + PoffO) * WpO + (xo0 + j + PoffO)) * Cout + oc;
        splitw(v, &clh[off], &cll[off]);
      }
    }
  }
}

// ---------------------------------------------------------------------------
// MFMA implicit-GEMM conv. A: channels-last padded hi/lo bf16; B: Wt
// [taps][Cout][Cin] hi/lo. Tile 128 x (64*NWN). No LDS. Split-bf16 (3 MFMA).
// ---------------------------------------------------------------------------
template <int NWN>
__global__ __launch_bounds__(128 * NWN) void conv_gemm(
    const u16* __restrict__ Ah, const u16* __restrict__ Al,
    const u16* __restrict__ Bh, const u16* __restrict__ Bl,
    const float* __restrict__ bias, int Cin, int Cout, int Hout, int Wout,
    int Wp, int Poff, int S, int DIL, int pad, int taps, long a_fstride,
    int act, float* yout, long y_fstride, u16* Oh, u16* Ol, long o_fstride,
    int WpO, int PoffO, int useres) {
  int t = threadIdx.x;
  int lane = t & 63;
  int w = t >> 6;
  int wc = w % NWN, wr = w / NWN;
  int l15 = lane & 15, l16 = lane >> 4;
  int HW = Hout * Wout;
  int row0 = blockIdx.x * 128 + wr * 64;
  int col0 = blockIdx.y * (64 * NWN) + wc * 64;
  const u16* Afh = Ah + (long)blockIdx.z * a_fstride;
  const u16* Afl = Al + (long)blockIdx.z * a_fstride;

  long aoff[4];
#pragma unroll
  for (int m = 0; m < 4; ++m) {
    int s = row0 + m * 16 + l15;
    if (s >= HW) s = HW - 1;
    int yo = s / Wout, xo = s - yo * Wout;
    int yb = yo * S - pad + Poff, xb = xo * S - pad + Poff;
    aoff[m] = ((long)yb * Wp + xb) * Cin + l16 * 8;
  }
  long boff[4];
#pragma unroll
  for (int n = 0; n < 4; ++n)
    boff[n] = (long)(col0 + n * 16 + l15) * Cin + l16 * 8;

  f32x4 acc[4][4];
#pragma unroll
  for (int m = 0; m < 4; ++m)
#pragma unroll
    for (int n = 0; n < 4; ++n) acc[m][n] = (f32x4){0.f, 0.f, 0.f, 0.f};

  for (int tap = 0; tap < taps; ++tap) {
    int ky = tap / 3, kx = tap - ky * 3;
    long atap = ((long)ky * DIL * Wp + kx * DIL) * Cin;
    long btap = (long)tap * Cout * Cin;
    for (int ic0 = 0; ic0 < Cin; ic0 += 32) {
      bf16x8 ah[4], al[4], bh[4], bl[4];
#pragma unroll
      for (int m = 0; m < 4; ++m) {
        long o = aoff[m] + atap + ic0;
        ah[m] = *(const bf16x8*)(Afh + o);
        al[m] = *(const bf16x8*)(Afl + o);
      }
#pragma unroll
      for (int n = 0; n < 4; ++n) {
        long o = boff[n] + btap + ic0;
        bh[n] = *(const bf16x8*)(Bh + o);
        bl[n] = *(const bf16x8*)(Bl + o);
      }
#pragma unroll
      for (int m = 0; m < 4; ++m)
#pragma unroll
        for (int n = 0; n < 4; ++n) {
          acc[m][n] = MFMA(ah[m], bh[n], acc[m][n]);
          acc[m][n] = MFMA(ah[m], bl[n], acc[m][n]);
          acc[m][n] = MFMA(al[m], bh[n], acc[m][n]);
        }
    }
  }

  float* yf = yout ? yout + (long)blockIdx.z * y_fstride : nullptr;
  u16* Ofh = Oh ? Oh + (long)blockIdx.z * o_fstride : nullptr;
  u16* Ofl = Ol ? Ol + (long)blockIdx.z * o_fstride : nullptr;
#pragma unroll
  for (int m = 0; m < 4; ++m) {
#pragma unroll
    for (int r = 0; r < 4; ++r) {
      int s = row0 + m * 16 + l16 * 4 + r;
      if (s >= HW) continue;
      int yo = s / Wout, xo = s - yo * Wout;
      long clbase = 0;
      if (Ofh) clbase = ((long)(yo + PoffO) * WpO + (xo + PoffO)) * Cout;
#pragma unroll
      for (int n = 0; n < 4; ++n) {
        int oc = col0 + n * 16 + l15;
        float v = acc[m][n][r] + bias[oc];
        if (act == ACT_LEAKY) v = v >= 0.f ? v : 0.2f * v;
        if (Ofh) {
          long off = clbase + oc;
          if (useres) v += bf2f(Ofh[off]) + bf2f(Ofl[off]);
          splitw(v, &Ofh[off], &Ofl[off]);
        }
        if (yf) yf[((long)oc * Hout + yo) * Wout + xo] = v;
      }
    }
  }
}

// ---------------------------------------------------------------------------
// QKV 1x1 GEMM (tile 128x64, 128 thr) writing straight into token layout.
// mode 0=Q (scaled), 1=K, 2=V (transposed [d][n]).
// ---------------------------------------------------------------------------
__global__ __launch_bounds__(128) void qkv_gemm(
    const u16* __restrict__ Ah, const u16* __restrict__ Al, long a_fstride,
    int Wp, int Poff, const u16* __restrict__ Bh, const u16* __restrict__ Bl,
    const float* __restrict__ bias, const int* __restrict__ nmap,
    const int* __restrict__ dmap, int ohow, int Dd, int pp, int NtokPad,
    float scale, int mode, u16* __restrict__ tH, u16* __restrict__ tL) {
  int t = threadIdx.x;
  int lane = t & 63;
  int wr = t >> 6;
  int l15 = lane & 15, l16 = lane >> 4;
  int row0 = blockIdx.x * 128 + wr * 64;
  int frame = blockIdx.z;
  const u16* Afh = Ah + (long)frame * a_fstride;
  const u16* Afl = Al + (long)frame * a_fstride;

  long aoff[4];
#pragma unroll
  for (int m = 0; m < 4; ++m) {
    int s = row0 + m * 16 + l15;
    if (s >= 4800) s = 4799;
    int yo = s / 160, xo = s - yo * 160;
    aoff[m] = ((long)(yo + Poff) * Wp + (xo + Poff)) * 256 + l16 * 8;
  }
  long boff[4];
#pragma unroll
  for (int n = 0; n < 4; ++n) boff[n] = (long)(n * 16 + l15) * 256 + l16 * 8;

  f32x4 acc[4][4];
#pragma unroll
  for (int m = 0; m < 4; ++m)
#pragma unroll
    for (int n = 0; n < 4; ++n) acc[m][n] = (f32x4){0.f, 0.f, 0.f, 0.f};

  for (int ic0 = 0; ic0 < 256; ic0 += 32) {
    bf16x8 ah[4], al[4], bh[4], bl[4];
#pragma unroll
    for (int m = 0; m < 4; ++m) {
      long o = aoff[m] + ic0;
      ah[m] = *(const bf16x8*)(Afh + o);
      al[m] = *(const bf16x8*)(Afl + o);
    }
#pragma unroll
    for (int n = 0; n < 4; ++n) {
      long o = boff[n] + ic0;
      bh[n] = *(const bf16x8*)(Bh + o);
      bl[n] = *(const bf16x8*)(Bl + o);
    }
#pragma unroll
    for (int m = 0; m < 4; ++m)
#pragma unroll
      for (int n = 0; n < 4; ++n) {
        acc[m][n] = MFMA(ah[m], bh[n], acc[m][n]);
        acc[m][n] = MFMA(ah[m], bl[n], acc[m][n]);
        acc[m][n] = MFMA(al[m], bh[n], acc[m][n]);
      }
  }

#pragma unroll
  for (int m = 0; m < 4; ++m) {
#pragma unroll
    for (int r = 0; r < 4; ++r) {
      int s = row0 + m * 16 + l16 * 4 + r;
      if (s >= 4800) continue;
      int nm = nmap[s], dm = dmap[s];
      int ntok = frame * ohow + nm;
#pragma unroll
      for (int n = 0; n < 4; ++n) {
        int c = n * 16 + l15;
        float v = acc[m][n][r] + bias[c];
        if (mode == 0) v *= scale;
        int d = c * pp + dm;
        long off = (mode == 2) ? ((long)d * NtokPad + ntok)
                               : ((long)ntok * Dd + d);
        splitw(v, &tH[off], &tL[off]);
      }
    }
  }
}

// ---------------------------------------------------------------------------
// Attention GEMM (tile 128x128, 256 thr). mode 0: fp32 out (split-K via
// blockIdx.z), mode 1: CL scatter via LUTs.
// ---------------------------------------------------------------------------
__global__ __launch_bounds__(256) void attn_gemm(
    const u16* __restrict__ Ah, const u16* __restrict__ Al, int lda, int Mrows,
    const u16* __restrict__ Bh, const u16* __restrict__ Bl, int ldb,
    int Nclamp, int Kpart, int Nvalid, int mode, float* outf, int ldo,
    long partstride, u16* __restrict__ Oh, u16* __restrict__ Ol,
    const int* __restrict__ rowbase, const int* __restrict__ doff) {
  int t = threadIdx.x;
  int lane = t & 63;
  int w = t >> 6;
  int wc = w & 1, wr = w >> 1;
  int l15 = lane & 15, l16 = lane >> 4;
  int row0 = blockIdx.x * 128 + wr * 64;
  int col0 = blockIdx.y * 128 + wc * 64;
  int kbase = blockIdx.z * Kpart;
  if (outf) outf += (long)blockIdx.z * partstride;

  long aoff[4];
#pragma unroll
  for (int m = 0; m < 4; ++m) {
    int sr = row0 + m * 16 + l15;
    if (sr >= Mrows) sr = Mrows - 1;
    aoff[m] = (long)sr * lda + l16 * 8;
  }
  long boff[4];
#pragma unroll
  for (int n = 0; n < 4; ++n) {
    int c = col0 + n * 16 + l15;
    if (c >= Nclamp) c = Nclamp - 1;
    boff[n] = (long)c * ldb + l16 * 8;
  }

  f32x4 acc[4][4];
#pragma unroll
  for (int m = 0; m < 4; ++m)
#pragma unroll
    for (int n = 0; n < 4; ++n) acc[m][n] = (f32x4){0.f, 0.f, 0.f, 0.f};

  for (int k = kbase; k < kbase + Kpart; k += 32) {
    bf16x8 ah[4], al[4], bh[4], bl[4];
#pragma unroll
    for (int m = 0; m < 4; ++m) {
      ah[m] = *(const bf16x8*)(Ah + aoff[m] + k);
      al[m] = *(const bf16x8*)(Al + aoff[m] + k);
    }
#pragma unroll
    for (int n = 0; n < 4; ++n) {
      bh[n] = *(const bf16x8*)(Bh + boff[n] + k);
      bl[n] = *(const bf16x8*)(Bl + boff[n] + k);
    }
#pragma unroll
    for (int m = 0; m < 4; ++m)
#pragma unroll
      for (int n = 0; n < 4; ++n) {
        acc[m][n] = MFMA(ah[m], bh[n], acc[m][n]);
        acc[m][n] = MFMA(ah[m], bl[n], acc[m][n]);
        acc[m][n] = MFMA(al[m], bh[n], acc[m][n]);
      }
  }

#pragma unroll
  for (int m = 0; m < 4; ++m) {
#pragma unroll
    for (int r = 0; r < 4; ++r) {
      int sr = row0 + m * 16 + l16 * 4 + r;
      if (sr >= Mrows) continue;
#pragma unroll
      for (int n = 0; n < 4; ++n) {
        int c = col0 + n * 16 + l15;
        if (c >= Nvalid) continue;
        float v = acc[m][n][r];
        if (mode == 0) {
          outf[(long)sr * ldo + c] = v;
        } else {
          long off = (long)rowbase[sr] + doff[c];
          splitw(v, &Oh[off], &Ol[off]);
        }
      }
    }
  }
}

// ---------------------------------------------------------------------------
__global__ __launch_bounds__(256) void reduce_scatter(
    const float* __restrict__ parts, int nparts, long pstride, int rows, int N,
    int mode, float* outf, u16* __restrict__ Oh, u16* __restrict__ Ol,
    const int* __restrict__ rowbase, const int* __restrict__ doff) {
  long gid = (long)blockIdx.x * 256 + threadIdx.x;
  long tot = (long)rows * N;
  if (gid >= tot) return;
  float s = 0.f;
  for (int p = 0; p < nparts; ++p) s += parts[p * pstride + gid];
  if (mode == 0) {
    outf[gid] = s;
  } else {
    int r = (int)(gid / N), c = (int)(gid % N);
    long off = (long)rowbase[r] + doff[c];
    splitw(s, &Oh[off], &Ol[off]);
  }
}

// ---------------------------------------------------------------------------
__global__ __launch_bounds__(256) void softmax_p(const float* __restrict__ S,
                                                 int Ntok, int NtokPad,
                                                 u16* __restrict__ Ph,
                                                 u16* __restrict__ Pl) {
  int row = blockIdx.x;
  const float* p = S + (long)row * Ntok;
  u16* ph = Ph + (long)row * NtokPad;
  u16* pl = Pl + (long)row * NtokPad;
  __shared__ float red[256];
  int t = threadIdx.x;
  float m = -1e30f;
  for (int i = t; i < Ntok; i += 256) m = fmaxf(m, p[i]);
  red[t] = m;
  __syncthreads();
  for (int s = 128; s > 0; s >>= 1) {
    if (t < s) red[t] = fmaxf(red[t], red[t + s]);
    __syncthreads();
  }
  m = red[0];
  __syncthreads();
  float sum = 0.f;
  for (int i = t; i < Ntok; i += 256) sum += __expf(p[i] - m);
  red[t] = sum;
  __syncthreads();
  for (int s = 128; s > 0; s >>= 1) {
    if (t < s) red[t] += red[t + s];
    __syncthreads();
  }
  float inv = 1.f / red[0];
  for (int i = t; i < Ntok; i += 256) {
    float e = __expf(p[i] - m) * inv;
    splitw(e, &ph[i], &pl[i]);
  }
  for (int i = Ntok + t; i < NtokPad; i += 256) {
    ph[i] = 0;
    pl[i] = 0;
  }
}

// ---------------------------------------------------------------------------
__global__ __launch_bounds__(256) void wt_build(const float* __restrict__ w,
                                                int Cout, int Cin, int taps,
                                                u16* __restrict__ Wh,
                                                u16* __restrict__ Wl) {
  long gid = (long)blockIdx.x * 256 + threadIdx.x;
  long tot = (long)taps * Cout * Cin;
  if (gid >= tot) return;
  int ic = (int)(gid % Cin);
  long r = gid / Cin;
  int oc = (int)(r % Cout);
  int tap = (int)(r / Cout);
  float v = w[((long)oc * Cin + ic) * taps + tap];
  splitw(v, &Wh[gid], &Wl[gid]);
}

__global__ __launch_bounds__(256) void wt1x1_build(const float* __restrict__ w,
                                                   int co, u16* __restrict__ Wh,
                                                   u16* __restrict__ Wl) {
  int gid = blockIdx.x * 256 + threadIdx.x;
  if (gid >= 64 * 256) return;
  int ic = gid & 255, c = gid >> 8;
  float v = w[(long)(co + c) * 256 + ic];
  splitw(v, &Wh[gid], &Wl[gid]);
}

// ---------------------------------------------------------------------------
__global__ __launch_bounds__(256) void maps_build(int ph, int pw, int ow,
                                                  int* __restrict__ nmap,
                                                  int* __restrict__ dmap) {
  int s = blockIdx.x * 256 + threadIdx.x;
  if (s >= 4800) return;
  int y = s / 160, x = s - y * 160;
  int i = y / ph, yy = y - i * ph;
  int j = x / pw, xx = x - j * pw;
  nmap[s] = i * ow + j;
  dmap[s] = yy * pw + xx;
}

__global__ __launch_bounds__(256) void luts_build(int ph, int pw, int ohow,
                                                  int ow, int pp, int Ntok,
                                                  int Dd, int gbase,
                                                  int* __restrict__ rowbase,
                                                  int* __restrict__ doff) {
  int gid = blockIdx.x * 256 + threadIdx.x;
  if (gid < Ntok) {
    int tt = gid / ohow, rem = gid - tt * ohow;
    int i = rem / ow, j = rem - i * ow;
    rowbase[gid] =
        tt * (32 * 162 * 256) + ((i * ph + 1) * 162 + (j * pw + 1)) * 256;
  }
  if (gid < Dd) {
    int c = gid / pp, rr = gid - c * pp;
    int yy = rr / pw, xx = rr - yy * pw;
    doff[gid] = (yy * 162 + xx) * 256 + gbase + c;
  }
}

// ---------------------------------------------------------------------------
// Bilinear x2 upsample (align_corners) CL hi/lo -> CL hi/lo. Writes the FULL
// padded output (zeros in halo) so overlaid buffers are re-cleaned per frame.
// ---------------------------------------------------------------------------
__global__ __launch_bounds__(256) void up_cl2cl_pad(
    const u16* __restrict__ sh, const u16* __restrict__ sl,
    u16* __restrict__ oh, u16* __restrict__ ol, int C, int H, int W, int Wps,
    int Poffs, int Hp, int Wpo, int Poffo) {
  int Ho = 2 * H, Wo = 2 * W;
  long tot = (long)Hp * Wpo * C;
  long gid = (long)blockIdx.x * 256 + threadIdx.x;
  if (gid >= tot) return;
  int c = (int)(gid % C);
  long r = gid / C;
  int xp = (int)(r % Wpo);
  int yp = (int)(r / Wpo);
  int x = xp - Poffo, y = yp - Poffo;
  float v = 0.f;
  if ((unsigned)x < (unsigned)Wo && (unsigned)y < (unsigned)Ho) {
    float fy = (float)(y * (H - 1)) / (float)(Ho - 1);
    float fx = (float)(x * (W - 1)) / (float)(Wo - 1);
    int y0 = (int)fy, x0 = (int)fx;
    int y1 = min(y0 + 1, H - 1), x1 = min(x0 + 1, W - 1);
    float wy = fy - y0, wx = fx - x0;
    auto rd = [&](int cy, int cx) {
      long o = ((long)(cy + Poffs) * Wps + (cx + Poffs)) * C + c;
      return bf2f(sh[o]) + bf2f(sl[o]);
    };
    float r0 = rd(y0, x0) * (1.f - wx) + rd(y0, x1) * wx;
    float r1 = rd(y1, x0) * (1.f - wx) + rd(y1, x1) * wx;
    v = r0 * (1.f - wy) + r1 * wy;
  }
  splitw(v, &oh[gid], &ol[gid]);
}

// ---------------------------------------------------------------------------
extern "C" void kernel_launch(void* const* d_in, const int* in_sizes, int n_in,
                              void* d_out, int out_size, void* d_ws,
                              size_t ws_size, hipStream_t stream) {
  const float* input = (const float*)d_in[0];
  const float* enc_w0 = (const float*)d_in[1];
  const float* enc_b0 = (const float*)d_in[2];
  const float* enc_w1 = (const float*)d_in[3];
  const float* enc_b1 = (const float*)d_in[4];
  const float* enc_w2 = (const float*)d_in[5];
  const float* enc_b2 = (const float*)d_in[6];
  const float* enc_w3 = (const float*)d_in[7];
  const float* enc_b3 = (const float*)d_in[8];
  const float* tq_w = (const float*)d_in[9];
  const float* tq_b = (const float*)d_in[10];
  const float* tk_w = (const float*)d_in[11];
  const float* tk_b = (const float*)d_in[12];
  const float* tv_w = (const float*)d_in[13];
  const float* tv_b = (const float*)d_in[14];
  const float* to_w = (const float*)d_in[15];
  const float* to_b = (const float*)d_in[16];
  const float* tf1_w = (const float*)d_in[17];
  const float* tf1_b = (const float*)d_in[18];
  const float* tf2_w = (const float*)d_in[19];
  const float* tf2_b = (const float*)d_in[20];
  const float* d0_w = (const float*)d_in[21];
  const float* d0_b = (const float*)d_in[22];
  const float* d1_w = (const float*)d_in[23];
  const float* d1_b = (const float*)d_in[24];
  const float* d2_w = (const float*)d_in[25];
  const float* d2_b = (const float*)d_in[26];
  const float* d3_w = (const float*)d_in[27];
  const float* d3_b = (const float*)d_in[28];
  float* out = (float*)d_out;

  // -------- workspace layout --------
  unsigned char* wsb = (unsigned char*)d_ws;
  size_t off = 0;
  auto alloc = [&](size_t bytes) {
    void* p = wsb + off;
    off = (off + bytes + 255) & ~(size_t)255;
    return p;
  };
  const long XCL_E = 22839296L;   // 16*34*164*256
  const long XCL2_E = 21233664L;  // 16*32*162*256  (== 16*64*324*64)
  const long QT_E = 4915200L;
  const long VT_E = 5111808L;  // 12288*416 max
  u16* XCLh = (u16*)alloc(XCL_E * 2);
  u16* XCLl = (u16*)alloc(XCL_E * 2);
  u16* XCL2h = (u16*)alloc(XCL2_E * 2);
  u16* XCL2l = (u16*)alloc(XCL2_E * 2);
  unsigned char* tokbase = wsb + off;
  u16* qth = (u16*)alloc(QT_E * 2);
  u16* qtl = (u16*)alloc(QT_E * 2);
  u16* kth = (u16*)alloc(QT_E * 2);
  u16* ktl = (u16*)alloc(QT_E * 2);
  u16* vth = (u16*)alloc(VT_E * 2);
  u16* vtl = (u16*)alloc(VT_E * 2);
  float* scores = (float*)alloc(5242880);  // 256*5120*4 (also partials)
  u16* Ph = (u16*)alloc(256L * 5120 * 2);
  u16* Pl = (u16*)alloc(256L * 5120 * 2);
  int* nmapA = (int*)alloc(4 * 4800 * 4);
  int* dmapA = (int*)alloc(4 * 4800 * 4);
  int* rowbaseA = (int*)alloc(7120 * 4);
  int* doffA = (int*)alloc(93248 * 4);
  u16* qwh = (u16*)alloc(16384 * 2);
  u16* qwl = (u16*)alloc(16384 * 2);
  u16* kwh = (u16*)alloc(16384 * 2);
  u16* kwl = (u16*)alloc(16384 * 2);
  u16* vwh = (u16*)alloc(16384 * 2);
  u16* vwl = (u16*)alloc(16384 * 2);
  size_t need = off;
  if (ws_size < need) return;  // fail loud, not crash

  // trunk conv weights overlay the P region (disjoint lifetimes)
  u16* Wth = (u16*)Ph;
  u16* Wtl = Wth + 589824;

  // ---- decoder buffers (overlay token region; all offsets 256-aligned) ----
  // dec0in  [62][322][256] hi/lo @ 0        (rewritten fully per frame)
  // dec0out [62][322][128] hi/lo @ 20443136 (halo zero from initial memset)
  // dec1out [62][322][64]  hi/lo @ 30664704 (halo zero from initial memset)
  // dec2in  [122][642][64] hi/lo @ 35775488 (rewritten fully per frame)
  // dec2out fp32 NCHW [64][120][640] @ 0    (overlays dec0in; dead by then)
  u16* dec0inH = (u16*)(tokbase + 0);
  u16* dec0inL = (u16*)(tokbase + 10221568);
  u16* dec0outH = (u16*)(tokbase + 20443136);
  u16* dec0outL = (u16*)(tokbase + 25553920);
  u16* dec1outH = (u16*)(tokbase + 30664704);
  u16* dec1outL = (u16*)(tokbase + 33220096);
  u16* dec2inH = (u16*)(tokbase + 35775488);
  u16* dec2inL = (u16*)(tokbase + 45800960);
  float* dec2out = (float*)(tokbase + 0);

  const long FS_TR = 1427456;  // 34*164*256
  const long FS_T2 = 1327104;  // 32*162*256 == 64*324*64
  const long FS_E2 = 713728;   // 34*164*128

  static const int PWa[4] = {80, 32, 10, 5};
  static const int PHa[4] = {15, 6, 5, 3};
  static const int rbOff[4] = {0, 64, 464, 2000};
  static const int doOff[4] = {0, 76800, 89088, 92288};

  // -------- encoder --------
  hipMemsetAsync(XCLh, 0, XCL_E * 2, stream);
  hipMemsetAsync(XCLl, 0, XCL_E * 2, stream);
  hipMemsetAsync(XCL2h, 0, XCL2_E * 2, stream);
  hipMemsetAsync(XCL2l, 0, XCL2_E * 2, stream);
  hipMemsetAsync(vth, 0, VT_E * 2, stream);  // first-call NaN guard (pads)
  hipMemsetAsync(vtl, 0, VT_E * 2, stream);
  {  // enc0: fp32 direct -> CL [64][324][64] Poff2 in XCL2 space
    long tot = 16L * 64 * 60 * 40;
    conv2d_k<3, 2, 1><<<cdivu(tot, 256), 256, 0, stream>>>(
        input, enc_w0, enc_b0, nullptr, XCL2h, XCL2l, 324, 2, FS_T2, 16, 3,
        120, 640, 64, 60, 320, 1, ACT_LEAKY);
  }
  {  // enc1: 64->64, 60x320, out CL into XCL space (enc geom)
    wt_build<<<cdivu(9L * 64 * 64, 256), 256, 0, stream>>>(enc_w1, 64, 64, 9,
                                                           Wth, Wtl);
    conv_gemm<1><<<dim3(150, 1, 16), 128, 0, stream>>>(
        XCL2h, XCL2l, Wth, Wtl, enc_b1, 64, 64, 60, 320, 324, 2, 1, 1, 1, 9,
        FS_T2, ACT_LEAKY, nullptr, 0, XCLh, XCLl, FS_T2, 324, 2, 0);
  }
  hipMemsetAsync(XCL2h, 0, XCL2_E * 2, stream);
  hipMemsetAsync(XCL2l, 0, XCL2_E * 2, stream);
  {  // enc2: 64->128 stride2 -> CL [34][164][128] in XCL2 space
    wt_build<<<cdivu(9L * 128 * 64, 256), 256, 0, stream>>>(enc_w2, 128, 64, 9,
                                                            Wth, Wtl);
    conv_gemm<2><<<dim3(38, 1, 16), 256, 0, stream>>>(
        XCLh, XCLl, Wth, Wtl, enc_b2, 64, 128, 30, 160, 324, 2, 2, 1, 1, 9,
        FS_T2, ACT_LEAKY, nullptr, 0, XCL2h, XCL2l, FS_E2, 164, 2, 0);
  }
  hipMemsetAsync(XCLh, 0, XCL_E * 2, stream);
  hipMemsetAsync(XCLl, 0, XCL_E * 2, stream);
  {  // enc3: 128->256 -> trunk XCL [34][164][256]
    wt_build<<<cdivu(9L * 256 * 128, 256), 256, 0, stream>>>(enc_w3, 256, 128,
                                                             9, Wth, Wtl);
    conv_gemm<2><<<dim3(38, 2, 16), 256, 0, stream>>>(
        XCL2h, XCL2l, Wth, Wtl, enc_b3, 128, 256, 30, 160, 164, 2, 1, 1, 1, 9,
        FS_E2, ACT_LEAKY, nullptr, 0, XCLh, XCLl, FS_TR, 164, 2, 0);
  }
  hipMemsetAsync(XCL2h, 0, XCL2_E * 2, stream);
  hipMemsetAsync(XCL2l, 0, XCL2_E * 2, stream);

  // -------- token maps / scatter LUTs (static per call) --------
  for (int g = 0; g < 4; ++g) {
    int ph = PHa[g], pw = PWa[g];
    int ohh = 30 / ph, oww = 160 / pw;
    int Ntok = 16 * ohh * oww, Dd = 64 * ph * pw, pp = ph * pw;
    maps_build<<<19, 256, 0, stream>>>(ph, pw, oww, nmapA + g * 4800,
                                       dmapA + g * 4800);
    int mx = Ntok > Dd ? Ntok : Dd;
    luts_build<<<cdivu(mx, 256), 256, 0, stream>>>(
        ph, pw, ohh * oww, oww, pp, Ntok, Dd, g * 64, rowbaseA + rbOff[g],
        doffA + doOff[g]);
  }

  // -------- transformer stack --------
  for (int l = 0; l < 8; ++l) {
    for (int g = 0; g < 4; ++g) {
      int ph = PHa[g], pw = PWa[g];
      int ohh = 30 / ph, oww = 160 / pw;
      int ohow = ohh * oww;
      int Ntok = 16 * ohow, Dd = 64 * ph * pw, pp = ph * pw;
      int NtokPad = (Ntok + 31) & ~31;
      float scale = 1.0f / sqrtf((float)Dd);
      const int* nmap = nmapA + g * 4800;
      const int* dmap = dmapA + g * 4800;
      const int* rowbase = rowbaseA + rbOff[g];
      const int* doffp = doffA + doOff[g];

      wt1x1_build<<<64, 256, 0, stream>>>(tq_w + (long)l * 65536, g * 64, qwh,
                                          qwl);
      wt1x1_build<<<64, 256, 0, stream>>>(tk_w + (long)l * 65536, g * 64, kwh,
                                          kwl);
      wt1x1_build<<<64, 256, 0, stream>>>(tv_w + (long)l * 65536, g * 64, vwh,
                                          vwl);
      qkv_gemm<<<dim3(38, 1, 16), 128, 0, stream>>>(
          XCLh, XCLl, FS_TR, 164, 2, qwh, qwl, tq_b + l * 256 + g * 64, nmap,
          dmap, ohow, Dd, pp, NtokPad, scale, 0, qth, qtl);
      qkv_gemm<<<dim3(38, 1, 16), 128, 0, stream>>>(
          XCLh, XCLl, FS_TR, 164, 2, kwh, kwl, tk_b + l * 256 + g * 64, nmap,
          dmap, ohow, Dd, pp, NtokPad, 1.f, 1, kth, ktl);
      qkv_gemm<<<dim3(38, 1, 16), 128, 0, stream>>>(
          XCLh, XCLl, FS_TR, 164, 2, vwh, vwl, tv_b + l * 256 + g * 64, nmap,
          dmap, ohow, Dd, pp, NtokPad, 1.f, 2, vth, vtl);

      if (g == 0) {
        // QK split-K: 32 parts of K=2400 -> partials -> reduce -> softmax
        float* scoresR = scores + 32 * 4096;
        attn_gemm<<<dim3(1, 1, 32), 256, 0, stream>>>(
            qth, qtl, Dd, 64, kth, ktl, Dd, 64, 2400, 64, 0, scores, 64, 4096,
            nullptr, nullptr, nullptr, nullptr);
        reduce_scatter<<<16, 256, 0, stream>>>(scores, 32, 4096, 64, 64, 0,
                                               scoresR, nullptr, nullptr,
                                               nullptr, nullptr);
        softmax_p<<<64, 256, 0, stream>>>(scoresR, 64, 64, Ph, Pl);
        attn_gemm<<<dim3(1, 600, 1), 256, 0, stream>>>(
            Ph, Pl, 64, 64, vth, vtl, 64, Dd, 64, Dd, 1, nullptr, 0, 0, XCL2h,
            XCL2l, rowbase, doffp);
      } else {
        for (int r0 = 0; r0 < Ntok; r0 += 256) {
          int rows = Ntok - r0 < 256 ? Ntok - r0 : 256;
          attn_gemm<<<dim3(cdivu(rows, 128), cdivu(Ntok, 128), 1), 256, 0,
                      stream>>>(qth + (long)r0 * Dd, qtl + (long)r0 * Dd, Dd,
                                rows, kth, ktl, Dd, Ntok, Dd, Ntok, 0, scores,
                                Ntok, 0, nullptr, nullptr, nullptr, nullptr);
          softmax_p<<<rows, 256, 0, stream>>>(scores, Ntok, NtokPad, Ph, Pl);
          if (g == 3) {
            attn_gemm<<<dim3(2, 8, 4), 256, 0, stream>>>(
                Ph, Pl, NtokPad, rows, vth, vtl, NtokPad, Dd, 1280, Dd, 0,
                scores, 960, 245760, nullptr, nullptr, nullptr, nullptr);
            reduce_scatter<<<cdivu((long)rows * 960, 256), 256, 0, stream>>>(
                scores, 4, 245760, rows, 960, 1, nullptr, XCL2h, XCL2l,
                rowbase + r0, doffp);
          } else {
            attn_gemm<<<dim3(cdivu(rows, 128), Dd / 128, 1), 256, 0, stream>>>(
                Ph, Pl, NtokPad, rows, vth, vtl, NtokPad, Dd, NtokPad, Dd, 1,
                nullptr, 0, 0, XCL2h, XCL2l, rowbase + r0, doffp);
          }
        }
      }
    }

    // out-conv 3x3 + leaky + residual (in-place on XCL)
    wt_build<<<cdivu(9L * 256 * 256, 256), 256, 0, stream>>>(
        to_w + (long)l * 589824, 256, 256, 9, Wth, Wtl);
    conv_gemm<2><<<dim3(38, 2, 16), 256, 0, stream>>>(
        XCL2h, XCL2l, Wth, Wtl, to_b + l * 256, 256, 256, 30, 160, 162, 1, 1,
        1, 1, 9, FS_T2, ACT_LEAKY, nullptr, 0, XCLh, XCLl, FS_TR, 164, 2, 1);
    // ff1: dil2 pad2
    wt_build<<<cdivu(9L * 256 * 256, 256), 256, 0, stream>>>(
        tf1_w + (long)l * 589824, 256, 256, 9, Wth, Wtl);
    conv_gemm<2><<<dim3(38, 2, 16), 256, 0, stream>>>(
        XCLh, XCLl, Wth, Wtl, tf1_b + l * 256, 256, 256, 30, 160, 164, 2, 1, 2,
        2, 9, FS_TR, ACT_LEAKY, nullptr, 0, XCL2h, XCL2l, FS_T2, 162, 1, 0);
    // ff2 + residual (in-place on XCL)
    wt_build<<<cdivu(9L * 256 * 256, 256), 256, 0, stream>>>(
        tf2_w + (long)l * 589824, 256, 256, 9, Wth, Wtl);
    conv_gemm<2><<<dim3(38, 2, 16), 256, 0, stream>>>(
        XCL2h, XCL2l, Wth, Wtl, tf2_b + l * 256, 256, 256, 30, 160, 162, 1, 1,
        1, 1, 9, FS_T2, ACT_LEAKY, nullptr, 0, XCLh, XCLl, FS_TR, 164, 2, 1);
  }

  // -------- decoder (per frame; disjoint buffers, halos re-zeroed) --------
  hipMemsetAsync(tokbase, 0, 55826432, stream);
  wt_build<<<cdivu(9L * 128 * 256, 256), 256, 0, stream>>>(d0_w, 128, 256, 9,
                                                           Wth, Wtl);
  u16* W1h = Wtl + 589824;  // d1 weights parked after d0's (both fit in P rgn)
  u16* W1l = W1h + 73728;
  wt_build<<<cdivu(9L * 64 * 128, 256), 256, 0, stream>>>(d1_w, 64, 128, 9,
                                                          W1h, W1l);
  u16* W2h = W1l + 73728;
  u16* W2l = W2h + 36864;
  wt_build<<<cdivu(9L * 64 * 64, 256), 256, 0, stream>>>(d2_w, 64, 64, 9, W2h,
                                                         W2l);
  for (int f = 0; f < 16; ++f) {
    // upsample trunk 30x160 -> 60x320 CL [62][322][256], full-padded write
    up_cl2cl_pad<<<cdivu(62L * 322 * 256, 256), 256, 0, stream>>>(
        XCLh + (long)f * FS_TR, XCLl + (long)f * FS_TR, dec0inH, dec0inL, 256,
        30, 160, 164, 2, 62, 322, 1);
    // d0: 256->128, 60x320
    conv_gemm<2><<<dim3(150, 1, 1), 256, 0, stream>>>(
        dec0inH, dec0inL, Wth, Wtl, d0_b, 256, 128, 60, 320, 322, 1, 1, 1, 1,
        9, 0, ACT_LEAKY, nullptr, 0, dec0outH, dec0outL, 0, 322, 1, 0);
    // d1: 128->64, 60x320, CL out
    conv_gemm<1><<<dim3(150, 1, 1), 128, 0, stream>>>(
        dec0outH, dec0outL, W1h, W1l, d1_b, 128, 64, 60, 320, 322, 1, 1, 1, 1,
        9, 0, ACT_LEAKY, nullptr, 0, dec1outH, dec1outL, 0, 322, 1, 0);
    // upsample 60x320 -> 120x640 CL [122][642][64], full-padded write
    up_cl2cl_pad<<<cdivu(122L * 642 * 64, 256), 256, 0, stream>>>(
        dec1outH, dec1outL, dec2inH, dec2inL, 64, 60, 320, 322, 1, 122, 642,
        1);
    // d2: 64->64, 120x640, fp32 NCHW out (overlays dec0in; dead)
    conv_gemm<1><<<dim3(600, 1, 1), 128, 0, stream>>>(
        dec2inH, dec2inL, W2h, W2l, d2_b, 64, 64, 120, 640, 642, 1, 1, 1, 1, 9,
        0, ACT_LEAKY, dec2out, 0, nullptr, nullptr, 0, 0, 0, 0);
    // d3: 64->3 + tanh, fp32 direct
    {
      long tot = 1L * 3 * 120 * 80;
      conv2d_k<3, 1, 1><<<cdivu(tot, 256), 256, 0, stream>>>(
          dec2out, d3_w, d3_b, out + (long)f * 230400, nullptr, nullptr, 0, 0,
          0, 1, 64, 120, 640, 3, 120, 640, 1, ACT_TANH);
    }
  }
}

// Round 5
// 67801.154 us; speedup vs baseline: 15.1281x; 1.4951x over previous
//
#include <hip/hip_runtime.h>
#include <hip/hip_bf16.h>
#include <math.h>

#define ACT_NONE 0
#define ACT_LEAKY 1
#define ACT_TANH 2

typedef __attribute__((ext_vector_type(8))) short bf16x8;
typedef __attribute__((ext_vector_type(4))) float f32x4;
typedef unsigned short u16;

#define MFMA(a, b, c) __builtin_amdgcn_mfma_f32_16x16x32_bf16((bf16x8)(a), (bf16x8)(b), (c), 0, 0, 0)

static inline unsigned cdivu(long a, long b) { return (unsigned)((a + b - 1) / b); }

__device__ __forceinline__ u16 f2bf(float x) {
  union { __hip_bfloat16 h; u16 u; } cv;
  cv.h = __float2bfloat16(x);
  return cv.u;
}
__device__ __forceinline__ float bf2f(u16 b) {
  union { u16 u; __hip_bfloat16 h; } cv;
  cv.u = b;
  return __bfloat162float(cv.h);
}
__device__ __forceinline__ void splitw(float v, u16* ph, u16* pl) {
  u16 h = f2bf(v);
  *ph = h;
  *pl = f2bf(v - bf2f(h));
}
// async global->LDS, 16B per lane; dest must be wave-uniform base (+lane*16)
__device__ __forceinline__ void gload16(const void* g, void* l) {
  __builtin_amdgcn_global_load_lds(
      (const __attribute__((address_space(1))) unsigned int*)g,
      (__attribute__((address_space(3))) unsigned int*)l, 16, 0, 0);
}

// ---------------------------------------------------------------------------
// Direct fp32 conv (enc0: Cin=3; d3: Cout=3+tanh). Optional CL hi/lo output.
// ---------------------------------------------------------------------------
template <int K, int S, int DIL>
__global__ __launch_bounds__(256) void conv2d_k(
    const float* __restrict__ x, const float* __restrict__ w,
    const float* __restrict__ bias, float* y, u16* clh, u16* cll, int WpO,
    int PoffO, long o_fstride, int N, int Cin, int Hin, int Win, int Cout,
    int Hout, int Wout, int pad, int act) {
  constexpr int TW = 8;
  constexpr int XL = (TW - 1) * S + (K - 1) * DIL + 1;
  int wq = (Wout + TW - 1) / TW;
  long gid = (long)blockIdx.x * 256 + threadIdx.x;
  long total = (long)N * Cout * Hout * wq;
  if (gid >= total) return;
  int xg = (int)(gid % wq);
  long r = gid / wq;
  int yo = (int)(r % Hout);
  r /= Hout;
  int oc = (int)(r % Cout);
  int n = (int)(r / Cout);

  float bv = bias[oc];
  float acc[TW];
#pragma unroll
  for (int j = 0; j < TW; ++j) acc[j] = bv;

  int xo0 = xg * TW;
  int xi0 = xo0 * S - pad;
  const float* xn = x + (long)n * Cin * Hin * Win;
  const float* wb = w + (long)oc * Cin * K * K;

  for (int ic = 0; ic < Cin; ++ic) {
    const float* xc = xn + (long)ic * Hin * Win;
    const float* wc = wb + ic * (K * K);
#pragma unroll
    for (int ky = 0; ky < K; ++ky) {
      int yi = yo * S - pad + ky * DIL;
      if ((unsigned)yi < (unsigned)Hin) {
        const float* row = xc + (long)yi * Win;
        float xr[XL];
#pragma unroll
        for (int i2 = 0; i2 < XL; ++i2) {
          int xi = xi0 + i2;
          xr[i2] = ((unsigned)xi < (unsigned)Win) ? row[xi] : 0.f;
        }
#pragma unroll
        for (int kx = 0; kx < K; ++kx) {
          float wv = wc[ky * K + kx];
#pragma unroll
          for (int j = 0; j < TW; ++j)
            acc[j] = fmaf(wv, xr[j * S + kx * DIL], acc[j]);
        }
      }
    }
  }

#pragma unroll
  for (int j = 0; j < TW; ++j) {
    if (xo0 + j < Wout) {
      float v = acc[j];
      if (act == ACT_LEAKY)
        v = v >= 0.f ? v : 0.2f * v;
      else if (act == ACT_TANH)
        v = tanhf(v);
      if (y) y[(((long)n * Cout + oc) * Hout + yo) * Wout + xo0 + j] = v;
      if (clh) {
        long off = (long)n * o_fstride +
                   ((long)(yo + PoffO) * WpO + (xo0 + j + PoffO)) * Cout + oc;
        splitw(v, &clh[off], &cll[off]);
      }
    }
  }
}

// ---------------------------------------------------------------------------
// LDS-staged MFMA implicit-GEMM conv (m97 2-barrier structure).
// A: channels-last padded hi/lo bf16; B: Wt [taps][Cout][Cin] hi/lo.
// Tile (WM*64) x (WN*64), 256 thr / 4 waves, K-step 32 (one tap x 32ch).
// Staging: per-lane global source gathers -> linear LDS [row][32] hi/lo.
// ---------------------------------------------------------------------------
template <int WM, int WN>
__global__ __launch_bounds__(256) void conv_gemm_lds(
    const u16* __restrict__ Ah, const u16* __restrict__ Al,
    const u16* __restrict__ Bh, const u16* __restrict__ Bl,
    const float* __restrict__ bias, int Cin, int Cout, int Hout, int Wout,
    int Wp, int Poff, int S, int DIL, int pad, int taps, long a_fstride,
    int act, float* yout, long y_fstride, u16* Oh, u16* Ol, long o_fstride,
    int WpO, int PoffO, int useres) {
  constexpr int TM = WM * 64, TN = WN * 64;
  __shared__ u16 AsH[TM * 32], AsL[TM * 32], BsH[TN * 32], BsL[TN * 32];
  int t = threadIdx.x;
  int lane = t & 63;
  int w = t >> 6;
  int wr = w / WN, wc = w % WN;
  int l15 = lane & 15, l16 = lane >> 4;
  int HW = Hout * Wout;
  int row0 = blockIdx.x * TM;
  int col0 = blockIdx.y * TN;
  const u16* Afh = Ah + (long)blockIdx.z * a_fstride;
  const u16* Afl = Al + (long)blockIdx.z * a_fstride;

  // staging assignment: thread t stages 16B (8ch) of row rs+64c, chunk cs
  int rs = t >> 2;
  int cs = (t & 3) * 8;
  long abase[WM];
#pragma unroll
  for (int c = 0; c < WM; ++c) {
    int s = row0 + rs + 64 * c;
    if (s >= HW) s = HW - 1;
    int yo = s / Wout, xo = s - yo * Wout;
    int yb = yo * S - pad + Poff, xb = xo * S - pad + Poff;
    abase[c] = ((long)yb * Wp + xb) * Cin + cs;
  }
  long bbase[WN];
#pragma unroll
  for (int c = 0; c < WN; ++c)
    bbase[c] = (long)(col0 + rs + 64 * c) * Cin + cs;
  int ldst = w * 512;  // wave-uniform u16 offset inside a 64-row call region

  f32x4 acc[4][4];
#pragma unroll
  for (int m = 0; m < 4; ++m)
#pragma unroll
    for (int n = 0; n < 4; ++n) acc[m][n] = (f32x4){0.f, 0.f, 0.f, 0.f};

  for (int tap = 0; tap < taps; ++tap) {
    int ky = tap / 3, kx = tap - ky * 3;
    long atap = ((long)ky * DIL * Wp + kx * DIL) * Cin;
    long btap = (long)tap * Cout * Cin;
    for (int ic0 = 0; ic0 < Cin; ic0 += 32) {
#pragma unroll
      for (int c = 0; c < WM; ++c) {
        gload16(Afh + abase[c] + atap + ic0, AsH + c * 2048 + ldst);
        gload16(Afl + abase[c] + atap + ic0, AsL + c * 2048 + ldst);
      }
#pragma unroll
      for (int c = 0; c < WN; ++c) {
        gload16(Bh + bbase[c] + btap + ic0, BsH + c * 2048 + ldst);
        gload16(Bl + bbase[c] + btap + ic0, BsL + c * 2048 + ldst);
      }
      __syncthreads();
      bf16x8 ah[4], al[4], bh[4], bl[4];
#pragma unroll
      for (int m = 0; m < 4; ++m) {
        int rrow = wr * 64 + m * 16 + l15;
        ah[m] = *(const bf16x8*)(AsH + rrow * 32 + l16 * 8);
        al[m] = *(const bf16x8*)(AsL + rrow * 32 + l16 * 8);
      }
#pragma unroll
      for (int n = 0; n < 4; ++n) {
        int rcol = wc * 64 + n * 16 + l15;
        bh[n] = *(const bf16x8*)(BsH + rcol * 32 + l16 * 8);
        bl[n] = *(const bf16x8*)(BsL + rcol * 32 + l16 * 8);
      }
#pragma unroll
      for (int m = 0; m < 4; ++m)
#pragma unroll
        for (int n = 0; n < 4; ++n) {
          acc[m][n] = MFMA(ah[m], bh[n], acc[m][n]);
          acc[m][n] = MFMA(ah[m], bl[n], acc[m][n]);
          acc[m][n] = MFMA(al[m], bh[n], acc[m][n]);
        }
      __syncthreads();
    }
  }

  float* yf = yout ? yout + (long)blockIdx.z * y_fstride : nullptr;
  u16* Ofh = Oh ? Oh + (long)blockIdx.z * o_fstride : nullptr;
  u16* Ofl = Ol ? Ol + (long)blockIdx.z * o_fstride : nullptr;
#pragma unroll
  for (int m = 0; m < 4; ++m) {
#pragma unroll
    for (int r = 0; r < 4; ++r) {
      int s = row0 + wr * 64 + m * 16 + l16 * 4 + r;
      if (s >= HW) continue;
      int yo = s / Wout, xo = s - yo * Wout;
      long clbase = 0;
      if (Ofh) clbase = ((long)(yo + PoffO) * WpO + (xo + PoffO)) * Cout;
#pragma unroll
      for (int n = 0; n < 4; ++n) {
        int oc = col0 + wc * 64 + n * 16 + l15;
        float v = acc[m][n][r] + bias[oc];
        if (act == ACT_LEAKY) v = v >= 0.f ? v : 0.2f * v;
        if (Ofh) {
          long off = clbase + oc;
          if (useres) v += bf2f(Ofh[off]) + bf2f(Ofl[off]);
          splitw(v, &Ofh[off], &Ofl[off]);
        }
        if (yf) yf[((long)oc * Hout + yo) * Wout + xo] = v;
      }
    }
  }
}

// ---------------------------------------------------------------------------
// QKV 1x1 GEMM (tile 128x64, 128 thr) writing straight into token layout.
// mode 0=Q (scaled), 1=K, 2=V (transposed [d][n]).
// ---------------------------------------------------------------------------
__global__ __launch_bounds__(128) void qkv_gemm(
    const u16* __restrict__ Ah, const u16* __restrict__ Al, long a_fstride,
    int Wp, int Poff, const u16* __restrict__ Bh, const u16* __restrict__ Bl,
    const float* __restrict__ bias, const int* __restrict__ nmap,
    const int* __restrict__ dmap, int ohow, int Dd, int pp, int NtokPad,
    float scale, int mode, u16* __restrict__ tH, u16* __restrict__ tL) {
  int t = threadIdx.x;
  int lane = t & 63;
  int wr = t >> 6;
  int l15 = lane & 15, l16 = lane >> 4;
  int row0 = blockIdx.x * 128 + wr * 64;
  int frame = blockIdx.z;
  const u16* Afh = Ah + (long)frame * a_fstride;
  const u16* Afl = Al + (long)frame * a_fstride;

  long aoff[4];
#pragma unroll
  for (int m = 0; m < 4; ++m) {
    int s = row0 + m * 16 + l15;
    if (s >= 4800) s = 4799;
    int yo = s / 160, xo = s - yo * 160;
    aoff[m] = ((long)(yo + Poff) * Wp + (xo + Poff)) * 256 + l16 * 8;
  }
  long boff[4];
#pragma unroll
  for (int n = 0; n < 4; ++n) boff[n] = (long)(n * 16 + l15) * 256 + l16 * 8;

  f32x4 acc[4][4];
#pragma unroll
  for (int m = 0; m < 4; ++m)
#pragma unroll
    for (int n = 0; n < 4; ++n) acc[m][n] = (f32x4){0.f, 0.f, 0.f, 0.f};

  for (int ic0 = 0; ic0 < 256; ic0 += 32) {
    bf16x8 ah[4], al[4], bh[4], bl[4];
#pragma unroll
    for (int m = 0; m < 4; ++m) {
      long o = aoff[m] + ic0;
      ah[m] = *(const bf16x8*)(Afh + o);
      al[m] = *(const bf16x8*)(Afl + o);
    }
#pragma unroll
    for (int n = 0; n < 4; ++n) {
      long o = boff[n] + ic0;
      bh[n] = *(const bf16x8*)(Bh + o);
      bl[n] = *(const bf16x8*)(Bl + o);
    }
#pragma unroll
    for (int m = 0; m < 4; ++m)
#pragma unroll
      for (int n = 0; n < 4; ++n) {
        acc[m][n] = MFMA(ah[m], bh[n], acc[m][n]);
        acc[m][n] = MFMA(ah[m], bl[n], acc[m][n]);
        acc[m][n] = MFMA(al[m], bh[n], acc[m][n]);
      }
  }

#pragma unroll
  for (int m = 0; m < 4; ++m) {
#pragma unroll
    for (int r = 0; r < 4; ++r) {
      int s = row0 + m * 16 + l16 * 4 + r;
      if (s >= 4800) continue;
      int nm = nmap[s], dm = dmap[s];
      int ntok = frame * ohow + nm;
#pragma unroll
      for (int n = 0; n < 4; ++n) {
        int c = n * 16 + l15;
        float v = acc[m][n][r] + bias[c];
        if (mode == 0) v *= scale;
        int d = c * pp + dm;
        long off = (mode == 2) ? ((long)d * NtokPad + ntok)
                               : ((long)ntok * Dd + d);
        splitw(v, &tH[off], &tL[off]);
      }
    }
  }
}

// ---------------------------------------------------------------------------
// LDS-staged attention GEMM (tile 128x128, 256 thr). A [M][lda], B [N][ldb],
// both K-contiguous. mode 0: fp32 out (split-K via z), mode 1: CL scatter.
// ---------------------------------------------------------------------------
__global__ __launch_bounds__(256) void attn_gemm_lds(
    const u16* __restrict__ Ah, const u16* __restrict__ Al, int lda, int Mrows,
    const u16* __restrict__ Bh, const u16* __restrict__ Bl, int ldb,
    int Nclamp, int Kpart, int Nvalid, int mode, float* outf, int ldo,
    long partstride, u16* __restrict__ Oh, u16* __restrict__ Ol,
    const int* __restrict__ rowbase, const int* __restrict__ doff) {
  __shared__ u16 AsH[128 * 32], AsL[128 * 32], BsH[128 * 32], BsL[128 * 32];
  int t = threadIdx.x;
  int lane = t & 63;
  int w = t >> 6;
  int wc = w & 1, wr = w >> 1;
  int l15 = lane & 15, l16 = lane >> 4;
  int row0 = blockIdx.x * 128;
  int col0 = blockIdx.y * 128;
  int kbase = blockIdx.z * Kpart;
  if (outf) outf += (long)blockIdx.z * partstride;

  int rs = t >> 2;
  int cs = (t & 3) * 8;
  long abase[2], bbase[2];
#pragma unroll
  for (int c = 0; c < 2; ++c) {
    int sr = row0 + rs + 64 * c;
    if (sr >= Mrows) sr = Mrows - 1;
    abase[c] = (long)sr * lda + cs;
    int cc = col0 + rs + 64 * c;
    if (cc >= Nclamp) cc = Nclamp - 1;
    bbase[c] = (long)cc * ldb + cs;
  }
  int ldst = w * 512;

  f32x4 acc[4][4];
#pragma unroll
  for (int m = 0; m < 4; ++m)
#pragma unroll
    for (int n = 0; n < 4; ++n) acc[m][n] = (f32x4){0.f, 0.f, 0.f, 0.f};

  for (int k = kbase; k < kbase + Kpart; k += 32) {
#pragma unroll
    for (int c = 0; c < 2; ++c) {
      gload16(Ah + abase[c] + k, AsH + c * 2048 + ldst);
      gload16(Al + abase[c] + k, AsL + c * 2048 + ldst);
      gload16(Bh + bbase[c] + k, BsH + c * 2048 + ldst);
      gload16(Bl + bbase[c] + k, BsL + c * 2048 + ldst);
    }
    __syncthreads();
    bf16x8 ah[4], al[4], bh[4], bl[4];
#pragma unroll
    for (int m = 0; m < 4; ++m) {
      int rrow = wr * 64 + m * 16 + l15;
      ah[m] = *(const bf16x8*)(AsH + rrow * 32 + l16 * 8);
      al[m] = *(const bf16x8*)(AsL + rrow * 32 + l16 * 8);
    }
#pragma unroll
    for (int n = 0; n < 4; ++n) {
      int rcol = wc * 64 + n * 16 + l15;
      bh[n] = *(const bf16x8*)(BsH + rcol * 32 + l16 * 8);
      bl[n] = *(const bf16x8*)(BsL + rcol * 32 + l16 * 8);
    }
#pragma unroll
    for (int m = 0; m < 4; ++m)
#pragma unroll
      for (int n = 0; n < 4; ++n) {
        acc[m][n] = MFMA(ah[m], bh[n], acc[m][n]);
        acc[m][n] = MFMA(ah[m], bl[n], acc[m][n]);
        acc[m][n] = MFMA(al[m], bh[n], acc[m][n]);
      }
    __syncthreads();
  }

#pragma unroll
  for (int m = 0; m < 4; ++m) {
#pragma unroll
    for (int r = 0; r < 4; ++r) {
      int sr = row0 + wr * 64 + m * 16 + l16 * 4 + r;
      if (sr >= Mrows) continue;
#pragma unroll
      for (int n = 0; n < 4; ++n) {
        int c = col0 + wc * 64 + n * 16 + l15;
        if (c >= Nvalid) continue;
        float v = acc[m][n][r];
        if (mode == 0) {
          outf[(long)sr * ldo + c] = v;
        } else {
          long off = (long)rowbase[sr] + doff[c];
          splitw(v, &Oh[off], &Ol[off]);
        }
      }
    }
  }
}

// ---------------------------------------------------------------------------
__global__ __launch_bounds__(256) void reduce_scatter(
    const float* __restrict__ parts, int nparts, long pstride, int rows, int N,
    int mode, float* outf, u16* __restrict__ Oh, u16* __restrict__ Ol,
    const int* __restrict__ rowbase, const int* __restrict__ doff) {
  long gid = (long)blockIdx.x * 256 + threadIdx.x;
  long tot = (long)rows * N;
  if (gid >= tot) return;
  float s = 0.f;
  for (int p = 0; p < nparts; ++p) s += parts[p * pstride + gid];
  if (mode == 0) {
    outf[gid] = s;
  } else {
    int r = (int)(gid / N), c = (int)(gid % N);
    long off = (long)rowbase[r] + doff[c];
    splitw(s, &Oh[off], &Ol[off]);
  }
}

// ---------------------------------------------------------------------------
__global__ __launch_bounds__(256) void softmax_p(const float* __restrict__ S,
                                                 int Ntok, int NtokPad,
                                                 u16* __restrict__ Ph,
                                                 u16* __restrict__ Pl) {
  int row = blockIdx.x;
  const float* p = S + (long)row * Ntok;
  u16* ph = Ph + (long)row * NtokPad;
  u16* pl = Pl + (long)row * NtokPad;
  __shared__ float red[256];
  int t = threadIdx.x;
  float m = -1e30f;
  for (int i = t; i < Ntok; i += 256) m = fmaxf(m, p[i]);
  red[t] = m;
  __syncthreads();
  for (int s = 128; s > 0; s >>= 1) {
    if (t < s) red[t] = fmaxf(red[t], red[t + s]);
    __syncthreads();
  }
  m = red[0];
  __syncthreads();
  float sum = 0.f;
  for (int i = t; i < Ntok; i += 256) sum += __expf(p[i] - m);
  red[t] = sum;
  __syncthreads();
  for (int s = 128; s > 0; s >>= 1) {
    if (t < s) red[t] += red[t + s];
    __syncthreads();
  }
  float inv = 1.f / red[0];
  for (int i = t; i < Ntok; i += 256) {
    float e = __expf(p[i] - m) * inv;
    splitw(e, &ph[i], &pl[i]);
  }
  for (int i = Ntok + t; i < NtokPad; i += 256) {
    ph[i] = 0;
    pl[i] = 0;
  }
}

// ---------------------------------------------------------------------------
__global__ __launch_bounds__(256) void wt_build(const float* __restrict__ w,
                                                int Cout, int Cin, int taps,
                                                u16* __restrict__ Wh,
                                                u16* __restrict__ Wl) {
  long gid = (long)blockIdx.x * 256 + threadIdx.x;
  long tot = (long)taps * Cout * Cin;
  if (gid >= tot) return;
  int ic = (int)(gid % Cin);
  long r = gid / Cin;
  int oc = (int)(r % Cout);
  int tap = (int)(r / Cout);
  float v = w[((long)oc * Cin + ic) * taps + tap];
  splitw(v, &Wh[gid], &Wl[gid]);
}

__global__ __launch_bounds__(256) void wt1x1_build(const float* __restrict__ w,
                                                   int co, u16* __restrict__ Wh,
                                                   u16* __restrict__ Wl) {
  int gid = blockIdx.x * 256 + threadIdx.x;
  if (gid >= 64 * 256) return;
  int ic = gid & 255, c = gid >> 8;
  float v = w[(long)(co + c) * 256 + ic];
  splitw(v, &Wh[gid], &Wl[gid]);
}

// ---------------------------------------------------------------------------
__global__ __launch_bounds__(256) void maps_build(int ph, int pw, int ow,
                                                  int* __restrict__ nmap,
                                                  int* __restrict__ dmap) {
  int s = blockIdx.x * 256 + threadIdx.x;
  if (s >= 4800) return;
  int y = s / 160, x = s - y * 160;
  int i = y / ph, yy = y - i * ph;
  int j = x / pw, xx = x - j * pw;
  nmap[s] = i * ow + j;
  dmap[s] = yy * pw + xx;
}

__global__ __launch_bounds__(256) void luts_build(int ph, int pw, int ohow,
                                                  int ow, int pp, int Ntok,
                                                  int Dd, int gbase,
                                                  int* __restrict__ rowbase,
                                                  int* __restrict__ doff) {
  int gid = blockIdx.x * 256 + threadIdx.x;
  if (gid < Ntok) {
    int tt = gid / ohow, rem = gid - tt * ohow;
    int i = rem / ow, j = rem - i * ow;
    rowbase[gid] =
        tt * (32 * 162 * 256) + ((i * ph + 1) * 162 + (j * pw + 1)) * 256;
  }
  if (gid < Dd) {
    int c = gid / pp, rr = gid - c * pp;
    int yy = rr / pw, xx = rr - yy * pw;
    doff[gid] = (yy * 162 + xx) * 256 + gbase + c;
  }
}

// ---------------------------------------------------------------------------
// Bilinear x2 upsample (align_corners) CL hi/lo -> CL hi/lo. Writes the FULL
// padded output (zeros in halo) so overlaid buffers are re-cleaned per frame.
// ---------------------------------------------------------------------------
__global__ __launch_bounds__(256) void up_cl2cl_pad(
    const u16* __restrict__ sh, const u16* __restrict__ sl,
    u16* __restrict__ oh, u16* __restrict__ ol, int C, int H, int W, int Wps,
    int Poffs, int Hp, int Wpo, int Poffo) {
  int Ho = 2 * H, Wo = 2 * W;
  long tot = (long)Hp * Wpo * C;
  long gid = (long)blockIdx.x * 256 + threadIdx.x;
  if (gid >= tot) return;
  int c = (int)(gid % C);
  long r = gid / C;
  int xp = (int)(r % Wpo);
  int yp = (int)(r / Wpo);
  int x = xp - Poffo, y = yp - Poffo;
  float v = 0.f;
  if ((unsigned)x < (unsigned)Wo && (unsigned)y < (unsigned)Ho) {
    float fy = (float)(y * (H - 1)) / (float)(Ho - 1);
    float fx = (float)(x * (W - 1)) / (float)(Wo - 1);
    int y0 = (int)fy, x0 = (int)fx;
    int y1 = min(y0 + 1, H - 1), x1 = min(x0 + 1, W - 1);
    float wy = fy - y0, wx = fx - x0;
    auto rd = [&](int cy, int cx) {
      long o = ((long)(cy + Poffs) * Wps + (cx + Poffs)) * C + c;
      return bf2f(sh[o]) + bf2f(sl[o]);
    };
    float r0 = rd(y0, x0) * (1.f - wx) + rd(y0, x1) * wx;
    float r1 = rd(y1, x0) * (1.f - wx) + rd(y1, x1) * wx;
    v = r0 * (1.f - wy) + r1 * wy;
  }
  splitw(v, &oh[gid], &ol[gid]);
}

// ---------------------------------------------------------------------------
extern "C" void kernel_launch(void* const* d_in, const int* in_sizes, int n_in,
                              void* d_out, int out_size, void* d_ws,
                              size_t ws_size, hipStream_t stream) {
  const float* input = (const float*)d_in[0];
  const float* enc_w0 = (const float*)d_in[1];
  const float* enc_b0 = (const float*)d_in[2];
  const float* enc_w1 = (const float*)d_in[3];
  const float* enc_b1 = (const float*)d_in[4];
  const float* enc_w2 = (const float*)d_in[5];
  const float* enc_b2 = (const float*)d_in[6];
  const float* enc_w3 = (const float*)d_in[7];
  const float* enc_b3 = (const float*)d_in[8];
  const float* tq_w = (const float*)d_in[9];
  const float* tq_b = (const float*)d_in[10];
  const float* tk_w = (const float*)d_in[11];
  const float* tk_b = (const float*)d_in[12];
  const float* tv_w = (const float*)d_in[13];
  const float* tv_b = (const float*)d_in[14];
  const float* to_w = (const float*)d_in[15];
  const float* to_b = (const float*)d_in[16];
  const float* tf1_w = (const float*)d_in[17];
  const float* tf1_b = (const float*)d_in[18];
  const float* tf2_w = (const float*)d_in[19];
  const float* tf2_b = (const float*)d_in[20];
  const float* d0_w = (const float*)d_in[21];
  const float* d0_b = (const float*)d_in[22];
  const float* d1_w = (const float*)d_in[23];
  const float* d1_b = (const float*)d_in[24];
  const float* d2_w = (const float*)d_in[25];
  const float* d2_b = (const float*)d_in[26];
  const float* d3_w = (const float*)d_in[27];
  const float* d3_b = (const float*)d_in[28];
  float* out = (float*)d_out;

  // -------- workspace layout --------
  unsigned char* wsb = (unsigned char*)d_ws;
  size_t off = 0;
  auto alloc = [&](size_t bytes) {
    void* p = wsb + off;
    off = (off + bytes + 255) & ~(size_t)255;
    return p;
  };
  const long XCL_E = 22839296L;   // 16*34*164*256
  const long XCL2_E = 21233664L;  // 16*32*162*256  (== 16*64*324*64)
  const long QT_E = 4915200L;
  const long VT_E = 5111808L;  // 12288*416 max
  u16* XCLh = (u16*)alloc(XCL_E * 2);
  u16* XCLl = (u16*)alloc(XCL_E * 2);
  u16* XCL2h = (u16*)alloc(XCL2_E * 2);
  u16* XCL2l = (u16*)alloc(XCL2_E * 2);
  unsigned char* tokbase = wsb + off;
  u16* qth = (u16*)alloc(QT_E * 2);
  u16* qtl = (u16*)alloc(QT_E * 2);
  u16* kth = (u16*)alloc(QT_E * 2);
  u16* ktl = (u16*)alloc(QT_E * 2);
  u16* vth = (u16*)alloc(VT_E * 2);
  u16* vtl = (u16*)alloc(VT_E * 2);
  float* scores = (float*)alloc(5242880);  // 256*5120*4 (also partials)
  u16* Ph = (u16*)alloc(256L * 5120 * 2);
  u16* Pl = (u16*)alloc(256L * 5120 * 2);
  int* nmapA = (int*)alloc(4 * 4800 * 4);
  int* dmapA = (int*)alloc(4 * 4800 * 4);
  int* rowbaseA = (int*)alloc(7120 * 4);
  int* doffA = (int*)alloc(93248 * 4);
  u16* qwh = (u16*)alloc(16384 * 2);
  u16* qwl = (u16*)alloc(16384 * 2);
  u16* kwh = (u16*)alloc(16384 * 2);
  u16* kwl = (u16*)alloc(16384 * 2);
  u16* vwh = (u16*)alloc(16384 * 2);
  u16* vwl = (u16*)alloc(16384 * 2);
  size_t need = off;
  if (ws_size < need) return;  // fail loud, not crash

  // trunk conv weights overlay the P region (disjoint lifetimes)
  u16* Wth = (u16*)Ph;
  u16* Wtl = Wth + 589824;

  // ---- decoder buffers (overlay token region; all offsets 256-aligned) ----
  u16* dec0inH = (u16*)(tokbase + 0);
  u16* dec0inL = (u16*)(tokbase + 10221568);
  u16* dec0outH = (u16*)(tokbase + 20443136);
  u16* dec0outL = (u16*)(tokbase + 25553920);
  u16* dec1outH = (u16*)(tokbase + 30664704);
  u16* dec1outL = (u16*)(tokbase + 33220096);
  u16* dec2inH = (u16*)(tokbase + 35775488);
  u16* dec2inL = (u16*)(tokbase + 45800960);
  float* dec2out = (float*)(tokbase + 0);

  const long FS_TR = 1427456;  // 34*164*256
  const long FS_T2 = 1327104;  // 32*162*256 == 64*324*64
  const long FS_E2 = 713728;   // 34*164*128

  static const int PWa[4] = {80, 32, 10, 5};
  static const int PHa[4] = {15, 6, 5, 3};
  static const int rbOff[4] = {0, 64, 464, 2000};
  static const int doOff[4] = {0, 76800, 89088, 92288};

  // -------- encoder --------
  hipMemsetAsync(XCLh, 0, XCL_E * 2, stream);
  hipMemsetAsync(XCLl, 0, XCL_E * 2, stream);
  hipMemsetAsync(XCL2h, 0, XCL2_E * 2, stream);
  hipMemsetAsync(XCL2l, 0, XCL2_E * 2, stream);
  hipMemsetAsync(vth, 0, VT_E * 2, stream);  // first-call NaN guard (pads)
  hipMemsetAsync(vtl, 0, VT_E * 2, stream);
  {  // enc0: fp32 direct -> CL [64][324][64] Poff2 in XCL2 space
    long tot = 16L * 64 * 60 * 40;
    conv2d_k<3, 2, 1><<<cdivu(tot, 256), 256, 0, stream>>>(
        input, enc_w0, enc_b0, nullptr, XCL2h, XCL2l, 324, 2, FS_T2, 16, 3,
        120, 640, 64, 60, 320, 1, ACT_LEAKY);
  }
  {  // enc1: 64->64, 60x320 (tile 256x64)
    wt_build<<<cdivu(9L * 64 * 64, 256), 256, 0, stream>>>(enc_w1, 64, 64, 9,
                                                           Wth, Wtl);
    conv_gemm_lds<4, 1><<<dim3(75, 1, 16), 256, 0, stream>>>(
        XCL2h, XCL2l, Wth, Wtl, enc_b1, 64, 64, 60, 320, 324, 2, 1, 1, 1, 9,
        FS_T2, ACT_LEAKY, nullptr, 0, XCLh, XCLl, FS_T2, 324, 2, 0);
  }
  hipMemsetAsync(XCL2h, 0, XCL2_E * 2, stream);
  hipMemsetAsync(XCL2l, 0, XCL2_E * 2, stream);
  {  // enc2: 64->128 stride2 -> CL [34][164][128] in XCL2 space
    wt_build<<<cdivu(9L * 128 * 64, 256), 256, 0, stream>>>(enc_w2, 128, 64, 9,
                                                            Wth, Wtl);
    conv_gemm_lds<2, 2><<<dim3(38, 1, 16), 256, 0, stream>>>(
        XCLh, XCLl, Wth, Wtl, enc_b2, 64, 128, 30, 160, 324, 2, 2, 1, 1, 9,
        FS_T2, ACT_LEAKY, nullptr, 0, XCL2h, XCL2l, FS_E2, 164, 2, 0);
  }
  hipMemsetAsync(XCLh, 0, XCL_E * 2, stream);
  hipMemsetAsync(XCLl, 0, XCL_E * 2, stream);
  {  // enc3: 128->256 -> trunk XCL [34][164][256]
    wt_build<<<cdivu(9L * 256 * 128, 256), 256, 0, stream>>>(enc_w3, 256, 128,
                                                             9, Wth, Wtl);
    conv_gemm_lds<2, 2><<<dim3(38, 2, 16), 256, 0, stream>>>(
        XCL2h, XCL2l, Wth, Wtl, enc_b3, 128, 256, 30, 160, 164, 2, 1, 1, 1, 9,
        FS_E2, ACT_LEAKY, nullptr, 0, XCLh, XCLl, FS_TR, 164, 2, 0);
  }
  hipMemsetAsync(XCL2h, 0, XCL2_E * 2, stream);
  hipMemsetAsync(XCL2l, 0, XCL2_E * 2, stream);

  // -------- token maps / scatter LUTs (static per call) --------
  for (int g = 0; g < 4; ++g) {
    int ph = PHa[g], pw = PWa[g];
    int ohh = 30 / ph, oww = 160 / pw;
    int Ntok = 16 * ohh * oww, Dd = 64 * ph * pw, pp = ph * pw;
    maps_build<<<19, 256, 0, stream>>>(ph, pw, oww, nmapA + g * 4800,
                                       dmapA + g * 4800);
    int mx = Ntok > Dd ? Ntok : Dd;
    luts_build<<<cdivu(mx, 256), 256, 0, stream>>>(
        ph, pw, ohh * oww, oww, pp, Ntok, Dd, g * 64, rowbaseA + rbOff[g],
        doffA + doOff[g]);
  }

  // -------- transformer stack --------
  for (int l = 0; l < 8; ++l) {
    for (int g = 0; g < 4; ++g) {
      int ph = PHa[g], pw = PWa[g];
      int ohh = 30 / ph, oww = 160 / pw;
      int ohow = ohh * oww;
      int Ntok = 16 * ohow, Dd = 64 * ph * pw, pp = ph * pw;
      int NtokPad = (Ntok + 31) & ~31;
      float scale = 1.0f / sqrtf((float)Dd);
      const int* nmap = nmapA + g * 4800;
      const int* dmap = dmapA + g * 4800;
      const int* rowbase = rowbaseA + rbOff[g];
      const int* doffp = doffA + doOff[g];

      wt1x1_build<<<64, 256, 0, stream>>>(tq_w + (long)l * 65536, g * 64, qwh,
                                          qwl);
      wt1x1_build<<<64, 256, 0, stream>>>(tk_w + (long)l * 65536, g * 64, kwh,
                                          kwl);
      wt1x1_build<<<64, 256, 0, stream>>>(tv_w + (long)l * 65536, g * 64, vwh,
                                          vwl);
      qkv_gemm<<<dim3(38, 1, 16), 128, 0, stream>>>(
          XCLh, XCLl, FS_TR, 164, 2, qwh, qwl, tq_b + l * 256 + g * 64, nmap,
          dmap, ohow, Dd, pp, NtokPad, scale, 0, qth, qtl);
      qkv_gemm<<<dim3(38, 1, 16), 128, 0, stream>>>(
          XCLh, XCLl, FS_TR, 164, 2, kwh, kwl, tk_b + l * 256 + g * 64, nmap,
          dmap, ohow, Dd, pp, NtokPad, 1.f, 1, kth, ktl);
      qkv_gemm<<<dim3(38, 1, 16), 128, 0, stream>>>(
          XCLh, XCLl, FS_TR, 164, 2, vwh, vwl, tv_b + l * 256 + g * 64, nmap,
          dmap, ohow, Dd, pp, NtokPad, 1.f, 2, vth, vtl);

      if (g == 0) {
        // QK split-K: 32 parts of K=2400 -> partials -> reduce -> softmax
        float* scoresR = scores + 32 * 4096;
        attn_gemm_lds<<<dim3(1, 1, 32), 256, 0, stream>>>(
            qth, qtl, Dd, 64, kth, ktl, Dd, 64, 2400, 64, 0, scores, 64, 4096,
            nullptr, nullptr, nullptr, nullptr);
        reduce_scatter<<<16, 256, 0, stream>>>(scores, 32, 4096, 64, 64, 0,
                                               scoresR, nullptr, nullptr,
                                               nullptr, nullptr);
        softmax_p<<<64, 256, 0, stream>>>(scoresR, 64, 64, Ph, Pl);
        attn_gemm_lds<<<dim3(1, 600, 1), 256, 0, stream>>>(
            Ph, Pl, 64, 64, vth, vtl, 64, Dd, 64, Dd, 1, nullptr, 0, 0, XCL2h,
            XCL2l, rowbase, doffp);
      } else {
        for (int r0 = 0; r0 < Ntok; r0 += 256) {
          int rows = Ntok - r0 < 256 ? Ntok - r0 : 256;
          attn_gemm_lds<<<dim3(cdivu(rows, 128), cdivu(Ntok, 128), 1), 256, 0,
                          stream>>>(qth + (long)r0 * Dd, qtl + (long)r0 * Dd,
                                    Dd, rows, kth, ktl, Dd, Ntok, Dd, Ntok, 0,
                                    scores, Ntok, 0, nullptr, nullptr, nullptr,
                                    nullptr);
          softmax_p<<<rows, 256, 0, stream>>>(scores, Ntok, NtokPad, Ph, Pl);
          if (g == 3) {
            attn_gemm_lds<<<dim3(2, 8, 4), 256, 0, stream>>>(
                Ph, Pl, NtokPad, rows, vth, vtl, NtokPad, Dd, 1280, Dd, 0,
                scores, 960, 245760, nullptr, nullptr, nullptr, nullptr);
            reduce_scatter<<<cdivu((long)rows * 960, 256), 256, 0, stream>>>(
                scores, 4, 245760, rows, 960, 1, nullptr, XCL2h, XCL2l,
                rowbase + r0, doffp);
          } else {
            attn_gemm_lds<<<dim3(cdivu(rows, 128), Dd / 128, 1), 256, 0,
                            stream>>>(Ph, Pl, NtokPad, rows, vth, vtl, NtokPad,
                                      Dd, NtokPad, Dd, 1, nullptr, 0, 0, XCL2h,
                                      XCL2l, rowbase + r0, doffp);
          }
        }
      }
    }

    // out-conv 3x3 + leaky + residual (in-place on XCL)
    wt_build<<<cdivu(9L * 256 * 256, 256), 256, 0, stream>>>(
        to_w + (long)l * 589824, 256, 256, 9, Wth, Wtl);
    conv_gemm_lds<2, 2><<<dim3(38, 2, 16), 256, 0, stream>>>(
        XCL2h, XCL2l, Wth, Wtl, to_b + l * 256, 256, 256, 30, 160, 162, 1, 1,
        1, 1, 9, FS_T2, ACT_LEAKY, nullptr, 0, XCLh, XCLl, FS_TR, 164, 2, 1);
    // ff1: dil2 pad2
    wt_build<<<cdivu(9L * 256 * 256, 256), 256, 0, stream>>>(
        tf1_w + (long)l * 589824, 256, 256, 9, Wth, Wtl);
    conv_gemm_lds<2, 2><<<dim3(38, 2, 16), 256, 0, stream>>>(
        XCLh, XCLl, Wth, Wtl, tf1_b + l * 256, 256, 256, 30, 160, 164, 2, 1, 2,
        2, 9, FS_TR, ACT_LEAKY, nullptr, 0, XCL2h, XCL2l, FS_T2, 162, 1, 0);
    // ff2 + residual (in-place on XCL)
    wt_build<<<cdivu(9L * 256 * 256, 256), 256, 0, stream>>>(
        tf2_w + (long)l * 589824, 256, 256, 9, Wth, Wtl);
    conv_gemm_lds<2, 2><<<dim3(38, 2, 16), 256, 0, stream>>>(
        XCL2h, XCL2l, Wth, Wtl, tf2_b + l * 256, 256, 256, 30, 160, 162, 1, 1,
        1, 1, 9, FS_T2, ACT_LEAKY, nullptr, 0, XCLh, XCLl, FS_TR, 164, 2, 1);
  }

  // -------- decoder (per frame; disjoint buffers, halos re-zeroed) --------
  hipMemsetAsync(tokbase, 0, 55826432, stream);
  wt_build<<<cdivu(9L * 128 * 256, 256), 256, 0, stream>>>(d0_w, 128, 256, 9,
                                                           Wth, Wtl);
  u16* W1h = Wtl + 589824;
  u16* W1l = W1h + 73728;
  wt_build<<<cdivu(9L * 64 * 128, 256), 256, 0, stream>>>(d1_w, 64, 128, 9,
                                                          W1h, W1l);
  u16* W2h = W1l + 73728;
  u16* W2l = W2h + 36864;
  wt_build<<<cdivu(9L * 64 * 64, 256), 256, 0, stream>>>(d2_w, 64, 64, 9, W2h,
                                                         W2l);
  for (int f = 0; f < 16; ++f) {
    // upsample trunk 30x160 -> 60x320 CL [62][322][256], full-padded write
    up_cl2cl_pad<<<cdivu(62L * 322 * 256, 256), 256, 0, stream>>>(
        XCLh + (long)f * FS_TR, XCLl + (long)f * FS_TR, dec0inH, dec0inL, 256,
        30, 160, 164, 2, 62, 322, 1);
    // d0: 256->128, 60x320
    conv_gemm_lds<2, 2><<<dim3(150, 1, 1), 256, 0, stream>>>(
        dec0inH, dec0inL, Wth, Wtl, d0_b, 256, 128, 60, 320, 322, 1, 1, 1, 1,
        9, 0, ACT_LEAKY, nullptr, 0, dec0outH, dec0outL, 0, 322, 1, 0);
    // d1: 128->64, 60x320, CL out (tile 256x64)
    conv_gemm_lds<4, 1><<<dim3(75, 1, 1), 256, 0, stream>>>(
        dec0outH, dec0outL, W1h, W1l, d1_b, 128, 64, 60, 320, 322, 1, 1, 1, 1,
        9, 0, ACT_LEAKY, nullptr, 0, dec1outH, dec1outL, 0, 322, 1, 0);
    // upsample 60x320 -> 120x640 CL [122][642][64], full-padded write
    up_cl2cl_pad<<<cdivu(122L * 642 * 64, 256), 256, 0, stream>>>(
        dec1outH, dec1outL, dec2inH, dec2inL, 64, 60, 320, 322, 1, 122, 642,
        1);
    // d2: 64->64, 120x640, fp32 NCHW out (overlays dec0in; dead)
    conv_gemm_lds<4, 1><<<dim3(300, 1, 1), 256, 0, stream>>>(
        dec2inH, dec2inL, W2h, W2l, d2_b, 64, 64, 120, 640, 642, 1, 1, 1, 1, 9,
        0, ACT_LEAKY, dec2out, 0, nullptr, nullptr, 0, 0, 0, 0);
    // d3: 64->3 + tanh, fp32 direct
    {
      long tot = 1L * 3 * 120 * 80;
      conv2d_k<3, 1, 1><<<cdivu(tot, 256), 256, 0, stream>>>(
          dec2out, d3_w, d3_b, out + (long)f * 230400, nullptr, nullptr, 0, 0,
          0, 1, 64, 120, 640, 3, 120, 640, 1, ACT_TANH);
    }
  }
}

// Round 7
// 40097.507 us; speedup vs baseline: 25.5803x; 1.6909x over previous
//
#include <hip/hip_runtime.h>
#include <hip/hip_bf16.h>
#include <math.h>

#define ACT_NONE 0
#define ACT_LEAKY 1
#define ACT_TANH 2

typedef __attribute__((ext_vector_type(8))) short bf16x8;
typedef __attribute__((ext_vector_type(4))) float f32x4;
typedef unsigned short u16;

#define MFMA(a, b, c) __builtin_amdgcn_mfma_f32_16x16x32_bf16((bf16x8)(a), (bf16x8)(b), (c), 0, 0, 0)

static inline unsigned cdivu(long a, long b) { return (unsigned)((a + b - 1) / b); }

__device__ __forceinline__ u16 f2bf(float x) {
  union { __hip_bfloat16 h; u16 u; } cv;
  cv.h = __float2bfloat16(x);
  return cv.u;
}
__device__ __forceinline__ float bf2f(u16 b) {
  union { u16 u; __hip_bfloat16 h; } cv;
  cv.u = b;
  return __bfloat162float(cv.h);
}
__device__ __forceinline__ void splitw(float v, u16* ph, u16* pl) {
  u16 h = f2bf(v);
  *ph = h;
  *pl = f2bf(v - bf2f(h));
}
// async global->LDS, 16B per lane; dest must be wave-uniform base (+lane*16)
__device__ __forceinline__ void gload16(const void* g, void* l) {
  __builtin_amdgcn_global_load_lds(
      (const __attribute__((address_space(1))) unsigned int*)g,
      (__attribute__((address_space(3))) unsigned int*)l, 16, 0, 0);
}

// ---------------------------------------------------------------------------
// Direct fp32 conv (enc0: Cin=3; d3: Cout=3+tanh). Optional CL hi/lo output.
// ---------------------------------------------------------------------------
template <int K, int S, int DIL>
__global__ __launch_bounds__(256) void conv2d_k(
    const float* __restrict__ x, const float* __restrict__ w,
    const float* __restrict__ bias, float* y, u16* clh, u16* cll, int WpO,
    int PoffO, long o_fstride, int N, int Cin, int Hin, int Win, int Cout,
    int Hout, int Wout, int pad, int act) {
  constexpr int TW = 8;
  constexpr int XL = (TW - 1) * S + (K - 1) * DIL + 1;
  int wq = (Wout + TW - 1) / TW;
  long gid = (long)blockIdx.x * 256 + threadIdx.x;
  long total = (long)N * Cout * Hout * wq;
  if (gid >= total) return;
  int xg = (int)(gid % wq);
  long r = gid / wq;
  int yo = (int)(r % Hout);
  r /= Hout;
  int oc = (int)(r % Cout);
  int n = (int)(r / Cout);

  float bv = bias[oc];
  float acc[TW];
#pragma unroll
  for (int j = 0; j < TW; ++j) acc[j] = bv;

  int xo0 = xg * TW;
  int xi0 = xo0 * S - pad;
  const float* xn = x + (long)n * Cin * Hin * Win;
  const float* wb = w + (long)oc * Cin * K * K;

  for (int ic = 0; ic < Cin; ++ic) {
    const float* xc = xn + (long)ic * Hin * Win;
    const float* wc = wb + ic * (K * K);
#pragma unroll
    for (int ky = 0; ky < K; ++ky) {
      int yi = yo * S - pad + ky * DIL;
      if ((unsigned)yi < (unsigned)Hin) {
        const float* row = xc + (long)yi * Win;
        float xr[XL];
#pragma unroll
        for (int i2 = 0; i2 < XL; ++i2) {
          int xi = xi0 + i2;
          xr[i2] = ((unsigned)xi < (unsigned)Win) ? row[xi] : 0.f;
        }
#pragma unroll
        for (int kx = 0; kx < K; ++kx) {
          float wv = wc[ky * K + kx];
#pragma unroll
          for (int j = 0; j < TW; ++j)
            acc[j] = fmaf(wv, xr[j * S + kx * DIL], acc[j]);
        }
      }
    }
  }

#pragma unroll
  for (int j = 0; j < TW; ++j) {
    if (xo0 + j < Wout) {
      float v = acc[j];
      if (act == ACT_LEAKY)
        v = v >= 0.f ? v : 0.2f * v;
      else if (act == ACT_TANH)
        v = tanhf(v);
      if (y) y[(((long)n * Cout + oc) * Hout + yo) * Wout + xo0 + j] = v;
      if (clh) {
        long off = (long)n * o_fstride +
                   ((long)(yo + PoffO) * WpO + (xo0 + j + PoffO)) * Cout + oc;
        splitw(v, &clh[off], &cll[off]);
      }
    }
  }
}

// ---------------------------------------------------------------------------
// LDS-staged MFMA implicit-GEMM conv (m97 2-barrier structure).
// ---------------------------------------------------------------------------
template <int WM, int WN>
__global__ __launch_bounds__(256) void conv_gemm_lds(
    const u16* __restrict__ Ah, const u16* __restrict__ Al,
    const u16* __restrict__ Bh, const u16* __restrict__ Bl,
    const float* __restrict__ bias, int Cin, int Cout, int Hout, int Wout,
    int Wp, int Poff, int S, int DIL, int pad, int taps, long a_fstride,
    int act, float* yout, long y_fstride, u16* Oh, u16* Ol, long o_fstride,
    int WpO, int PoffO, int useres) {
  constexpr int TM = WM * 64, TN = WN * 64;
  __shared__ u16 AsH[TM * 32], AsL[TM * 32], BsH[TN * 32], BsL[TN * 32];
  int t = threadIdx.x;
  int lane = t & 63;
  int w = t >> 6;
  int wr = w / WN, wc = w % WN;
  int l15 = lane & 15, l16 = lane >> 4;
  int HW = Hout * Wout;
  int row0 = blockIdx.x * TM;
  int col0 = blockIdx.y * TN;
  const u16* Afh = Ah + (long)blockIdx.z * a_fstride;
  const u16* Afl = Al + (long)blockIdx.z * a_fstride;

  int rs = t >> 2;
  int cs = (t & 3) * 8;
  long abase[WM];
#pragma unroll
  for (int c = 0; c < WM; ++c) {
    int s = row0 + rs + 64 * c;
    if (s >= HW) s = HW - 1;
    int yo = s / Wout, xo = s - yo * Wout;
    int yb = yo * S - pad + Poff, xb = xo * S - pad + Poff;
    abase[c] = ((long)yb * Wp + xb) * Cin + cs;
  }
  long bbase[WN];
#pragma unroll
  for (int c = 0; c < WN; ++c)
    bbase[c] = (long)(col0 + rs + 64 * c) * Cin + cs;
  int ldst = w * 512;

  f32x4 acc[4][4];
#pragma unroll
  for (int m = 0; m < 4; ++m)
#pragma unroll
    for (int n = 0; n < 4; ++n) acc[m][n] = (f32x4){0.f, 0.f, 0.f, 0.f};

  for (int tap = 0; tap < taps; ++tap) {
    int ky = tap / 3, kx = tap - ky * 3;
    long atap = ((long)ky * DIL * Wp + kx * DIL) * Cin;
    long btap = (long)tap * Cout * Cin;
    for (int ic0 = 0; ic0 < Cin; ic0 += 32) {
#pragma unroll
      for (int c = 0; c < WM; ++c) {
        gload16(Afh + abase[c] + atap + ic0, AsH + c * 2048 + ldst);
        gload16(Afl + abase[c] + atap + ic0, AsL + c * 2048 + ldst);
      }
#pragma unroll
      for (int c = 0; c < WN; ++c) {
        gload16(Bh + bbase[c] + btap + ic0, BsH + c * 2048 + ldst);
        gload16(Bl + bbase[c] + btap + ic0, BsL + c * 2048 + ldst);
      }
      __syncthreads();
      bf16x8 ah[4], al[4], bh[4], bl[4];
#pragma unroll
      for (int m = 0; m < 4; ++m) {
        int rrow = wr * 64 + m * 16 + l15;
        ah[m] = *(const bf16x8*)(AsH + rrow * 32 + l16 * 8);
        al[m] = *(const bf16x8*)(AsL + rrow * 32 + l16 * 8);
      }
#pragma unroll
      for (int n = 0; n < 4; ++n) {
        int rcol = wc * 64 + n * 16 + l15;
        bh[n] = *(const bf16x8*)(BsH + rcol * 32 + l16 * 8);
        bl[n] = *(const bf16x8*)(BsL + rcol * 32 + l16 * 8);
      }
#pragma unroll
      for (int m = 0; m < 4; ++m)
#pragma unroll
        for (int n = 0; n < 4; ++n) {
          acc[m][n] = MFMA(ah[m], bh[n], acc[m][n]);
          acc[m][n] = MFMA(ah[m], bl[n], acc[m][n]);
          acc[m][n] = MFMA(al[m], bh[n], acc[m][n]);
        }
      __syncthreads();
    }
  }

  float* yf = yout ? yout + (long)blockIdx.z * y_fstride : nullptr;
  u16* Ofh = Oh ? Oh + (long)blockIdx.z * o_fstride : nullptr;
  u16* Ofl = Ol ? Ol + (long)blockIdx.z * o_fstride : nullptr;
#pragma unroll
  for (int m = 0; m < 4; ++m) {
#pragma unroll
    for (int r = 0; r < 4; ++r) {
      int s = row0 + wr * 64 + m * 16 + l16 * 4 + r;
      if (s >= HW) continue;
      int yo = s / Wout, xo = s - yo * Wout;
      long clbase = 0;
      if (Ofh) clbase = ((long)(yo + PoffO) * WpO + (xo + PoffO)) * Cout;
#pragma unroll
      for (int n = 0; n < 4; ++n) {
        int oc = col0 + wc * 64 + n * 16 + l15;
        float v = acc[m][n][r] + bias[oc];
        if (act == ACT_LEAKY) v = v >= 0.f ? v : 0.2f * v;
        if (Ofh) {
          long off = clbase + oc;
          if (useres) v += bf2f(Ofh[off]) + bf2f(Ofl[off]);
          splitw(v, &Ofh[off], &Ofl[off]);
        }
        if (yf) yf[((long)oc * Hout + yo) * Wout + xo] = v;
      }
    }
  }
}

// ---------------------------------------------------------------------------
// QKV 1x1 GEMM (tile 128x64, 128 thr) writing straight into token layout.
// mode 0=Q (scaled), 1=K, 2=V (transposed [d][n]).
// ---------------------------------------------------------------------------
__global__ __launch_bounds__(128) void qkv_gemm(
    const u16* __restrict__ Ah, const u16* __restrict__ Al, long a_fstride,
    int Wp, int Poff, const u16* __restrict__ Bh, const u16* __restrict__ Bl,
    const float* __restrict__ bias, const int* __restrict__ nmap,
    const int* __restrict__ dmap, int ohow, int Dd, int pp, int NtokPad,
    float scale, int mode, u16* __restrict__ tH, u16* __restrict__ tL) {
  int t = threadIdx.x;
  int lane = t & 63;
  int wr = t >> 6;
  int l15 = lane & 15, l16 = lane >> 4;
  int row0 = blockIdx.x * 128 + wr * 64;
  int frame = blockIdx.z;
  const u16* Afh = Ah + (long)frame * a_fstride;
  const u16* Afl = Al + (long)frame * a_fstride;

  long aoff[4];
#pragma unroll
  for (int m = 0; m < 4; ++m) {
    int s = row0 + m * 16 + l15;
    if (s >= 4800) s = 4799;
    int yo = s / 160, xo = s - yo * 160;
    aoff[m] = ((long)(yo + Poff) * Wp + (xo + Poff)) * 256 + l16 * 8;
  }
  long boff[4];
#pragma unroll
  for (int n = 0; n < 4; ++n) boff[n] = (long)(n * 16 + l15) * 256 + l16 * 8;

  f32x4 acc[4][4];
#pragma unroll
  for (int m = 0; m < 4; ++m)
#pragma unroll
    for (int n = 0; n < 4; ++n) acc[m][n] = (f32x4){0.f, 0.f, 0.f, 0.f};

  for (int ic0 = 0; ic0 < 256; ic0 += 32) {
    bf16x8 ah[4], al[4], bh[4], bl[4];
#pragma unroll
    for (int m = 0; m < 4; ++m) {
      long o = aoff[m] + ic0;
      ah[m] = *(const bf16x8*)(Afh + o);
      al[m] = *(const bf16x8*)(Afl + o);
    }
#pragma unroll
    for (int n = 0; n < 4; ++n) {
      long o = boff[n] + ic0;
      bh[n] = *(const bf16x8*)(Bh + o);
      bl[n] = *(const bf16x8*)(Bl + o);
    }
#pragma unroll
    for (int m = 0; m < 4; ++m)
#pragma unroll
      for (int n = 0; n < 4; ++n) {
        acc[m][n] = MFMA(ah[m], bh[n], acc[m][n]);
        acc[m][n] = MFMA(ah[m], bl[n], acc[m][n]);
        acc[m][n] = MFMA(al[m], bh[n], acc[m][n]);
      }
  }

#pragma unroll
  for (int m = 0; m < 4; ++m) {
#pragma unroll
    for (int r = 0; r < 4; ++r) {
      int s = row0 + m * 16 + l16 * 4 + r;
      if (s >= 4800) continue;
      int nm = nmap[s], dm = dmap[s];
      int ntok = frame * ohow + nm;
#pragma unroll
      for (int n = 0; n < 4; ++n) {
        int c = n * 16 + l15;
        float v = acc[m][n][r] + bias[c];
        if (mode == 0) v *= scale;
        int d = c * pp + dm;
        long off = (mode == 2) ? ((long)d * NtokPad + ntok)
                               : ((long)ntok * Dd + d);
        splitw(v, &tH[off], &tL[off]);
      }
    }
  }
}

// ---------------------------------------------------------------------------
// LDS-staged attention GEMM (tile 128x128, 256 thr).
// ---------------------------------------------------------------------------
__global__ __launch_bounds__(256) void attn_gemm_lds(
    const u16* __restrict__ Ah, const u16* __restrict__ Al, int lda, int Mrows,
    const u16* __restrict__ Bh, const u16* __restrict__ Bl, int ldb,
    int Nclamp, int Kpart, int Nvalid, int mode, float* outf, int ldo,
    long partstride, u16* __restrict__ Oh, u16* __restrict__ Ol,
    const int* __restrict__ rowbase, const int* __restrict__ doff) {
  __shared__ u16 AsH[128 * 32], AsL[128 * 32], BsH[128 * 32], BsL[128 * 32];
  int t = threadIdx.x;
  int lane = t & 63;
  int w = t >> 6;
  int wc = w & 1, wr = w >> 1;
  int l15 = lane & 15, l16 = lane >> 4;
  int row0 = blockIdx.x * 128;
  int col0 = blockIdx.y * 128;
  int kbase = blockIdx.z * Kpart;
  if (outf) outf += (long)blockIdx.z * partstride;

  int rs = t >> 2;
  int cs = (t & 3) * 8;
  long abase[2], bbase[2];
#pragma unroll
  for (int c = 0; c < 2; ++c) {
    int sr = row0 + rs + 64 * c;
    if (sr >= Mrows) sr = Mrows - 1;
    abase[c] = (long)sr * lda + cs;
    int cc = col0 + rs + 64 * c;
    if (cc >= Nclamp) cc = Nclamp - 1;
    bbase[c] = (long)cc * ldb + cs;
  }
  int ldst = w * 512;

  f32x4 acc[4][4];
#pragma unroll
  for (int m = 0; m < 4; ++m)
#pragma unroll
    for (int n = 0; n < 4; ++n) acc[m][n] = (f32x4){0.f, 0.f, 0.f, 0.f};

  for (int k = kbase; k < kbase + Kpart; k += 32) {
#pragma unroll
    for (int c = 0; c < 2; ++c) {
      gload16(Ah + abase[c] + k, AsH + c * 2048 + ldst);
      gload16(Al + abase[c] + k, AsL + c * 2048 + ldst);
      gload16(Bh + bbase[c] + k, BsH + c * 2048 + ldst);
      gload16(Bl + bbase[c] + k, BsL + c * 2048 + ldst);
    }
    __syncthreads();
    bf16x8 ah[4], al[4], bh[4], bl[4];
#pragma unroll
    for (int m = 0; m < 4; ++m) {
      int rrow = wr * 64 + m * 16 + l15;
      ah[m] = *(const bf16x8*)(AsH + rrow * 32 + l16 * 8);
      al[m] = *(const bf16x8*)(AsL + rrow * 32 + l16 * 8);
    }
#pragma unroll
    for (int n = 0; n < 4; ++n) {
      int rcol = wc * 64 + n * 16 + l15;
      bh[n] = *(const bf16x8*)(BsH + rcol * 32 + l16 * 8);
      bl[n] = *(const bf16x8*)(BsL + rcol * 32 + l16 * 8);
    }
#pragma unroll
    for (int m = 0; m < 4; ++m)
#pragma unroll
      for (int n = 0; n < 4; ++n) {
        acc[m][n] = MFMA(ah[m], bh[n], acc[m][n]);
        acc[m][n] = MFMA(ah[m], bl[n], acc[m][n]);
        acc[m][n] = MFMA(al[m], bh[n], acc[m][n]);
      }
    __syncthreads();
  }

#pragma unroll
  for (int m = 0; m < 4; ++m) {
#pragma unroll
    for (int r = 0; r < 4; ++r) {
      int sr = row0 + wr * 64 + m * 16 + l16 * 4 + r;
      if (sr >= Mrows) continue;
#pragma unroll
      for (int n = 0; n < 4; ++n) {
        int c = col0 + wc * 64 + n * 16 + l15;
        if (c >= Nvalid) continue;
        float v = acc[m][n][r];
        if (mode == 0) {
          outf[(long)sr * ldo + c] = v;
        } else {
          long off = (long)rowbase[sr] + doff[c];
          splitw(v, &Oh[off], &Ol[off]);
        }
      }
    }
  }
}

// ---------------------------------------------------------------------------
__global__ __launch_bounds__(256) void reduce_scatter(
    const float* __restrict__ parts, int nparts, long pstride, int rows, int N,
    int mode, float* outf, u16* __restrict__ Oh, u16* __restrict__ Ol,
    const int* __restrict__ rowbase, const int* __restrict__ doff) {
  long gid = (long)blockIdx.x * 256 + threadIdx.x;
  long tot = (long)rows * N;
  if (gid >= tot) return;
  float s = 0.f;
  for (int p = 0; p < nparts; ++p) s += parts[p * pstride + gid];
  if (mode == 0) {
    outf[gid] = s;
  } else {
    int r = (int)(gid / N), c = (int)(gid % N);
    long off = (long)rowbase[r] + doff[c];
    splitw(s, &Oh[off], &Ol[off]);
  }
}

// ---------------------------------------------------------------------------
__global__ __launch_bounds__(256) void softmax_p(const float* __restrict__ S,
                                                 int Ntok, int NtokPad,
                                                 u16* __restrict__ Ph,
                                                 u16* __restrict__ Pl) {
  int row = blockIdx.x;
  const float* p = S + (long)row * Ntok;
  u16* ph = Ph + (long)row * NtokPad;
  u16* pl = Pl + (long)row * NtokPad;
  __shared__ float red[256];
  int t = threadIdx.x;
  float m = -1e30f;
  for (int i = t; i < Ntok; i += 256) m = fmaxf(m, p[i]);
  red[t] = m;
  __syncthreads();
  for (int s = 128; s > 0; s >>= 1) {
    if (t < s) red[t] = fmaxf(red[t], red[t + s]);
    __syncthreads();
  }
  m = red[0];
  __syncthreads();
  float sum = 0.f;
  for (int i = t; i < Ntok; i += 256) sum += __expf(p[i] - m);
  red[t] = sum;
  __syncthreads();
  for (int s = 128; s > 0; s >>= 1) {
    if (t < s) red[t] += red[t + s];
    __syncthreads();
  }
  float inv = 1.f / red[0];
  for (int i = t; i < Ntok; i += 256) {
    float e = __expf(p[i] - m) * inv;
    splitw(e, &ph[i], &pl[i]);
  }
  for (int i = Ntok + t; i < NtokPad; i += 256) {
    ph[i] = 0;
    pl[i] = 0;
  }
}

// ---------------------------------------------------------------------------
__global__ __launch_bounds__(256) void wt_build(const float* __restrict__ w,
                                                int Cout, int Cin, int taps,
                                                u16* __restrict__ Wh,
                                                u16* __restrict__ Wl) {
  long gid = (long)blockIdx.x * 256 + threadIdx.x;
  long tot = (long)taps * Cout * Cin;
  if (gid >= tot) return;
  int ic = (int)(gid % Cin);
  long r = gid / Cin;
  int oc = (int)(r % Cout);
  int tap = (int)(r / Cout);
  float v = w[((long)oc * Cin + ic) * taps + tap];
  splitw(v, &Wh[gid], &Wl[gid]);
}

// fused q/k/v 1x1 weight split build (one group of 64 out-channels)
__global__ __launch_bounds__(256) void wtqkv_build(
    const float* __restrict__ wq, const float* __restrict__ wk,
    const float* __restrict__ wv, int co, u16* __restrict__ qh,
    u16* __restrict__ ql, u16* __restrict__ kh, u16* __restrict__ kl,
    u16* __restrict__ vh, u16* __restrict__ vl) {
  int gid = blockIdx.x * 256 + threadIdx.x;
  if (gid >= 64 * 256) return;
  int ic = gid & 255, c = gid >> 8;
  long src = (long)(co + c) * 256 + ic;
  splitw(wq[src], &qh[gid], &ql[gid]);
  splitw(wk[src], &kh[gid], &kl[gid]);
  splitw(wv[src], &vh[gid], &vl[gid]);
}

// ---------------------------------------------------------------------------
__global__ __launch_bounds__(256) void maps_build(int ph, int pw, int ow,
                                                  int* __restrict__ nmap,
                                                  int* __restrict__ dmap) {
  int s = blockIdx.x * 256 + threadIdx.x;
  if (s >= 4800) return;
  int y = s / 160, x = s - y * 160;
  int i = y / ph, yy = y - i * ph;
  int j = x / pw, xx = x - j * pw;
  nmap[s] = i * ow + j;
  dmap[s] = yy * pw + xx;
}

__global__ __launch_bounds__(256) void luts_build(int ph, int pw, int ohow,
                                                  int ow, int pp, int Ntok,
                                                  int Dd, int gbase,
                                                  int* __restrict__ rowbase,
                                                  int* __restrict__ doff) {
  int gid = blockIdx.x * 256 + threadIdx.x;
  if (gid < Ntok) {
    int tt = gid / ohow, rem = gid - tt * ohow;
    int i = rem / ow, j = rem - i * ow;
    rowbase[gid] =
        tt * (32 * 162 * 256) + ((i * ph + 1) * 162 + (j * pw + 1)) * 256;
  }
  if (gid < Dd) {
    int c = gid / pp, rr = gid - c * pp;
    int yy = rr / pw, xx = rr - yy * pw;
    doff[gid] = (yy * 162 + xx) * 256 + gbase + c;
  }
}

// ---------------------------------------------------------------------------
// Bilinear x2 upsample (align_corners) CL hi/lo -> CL hi/lo. Writes the FULL
// padded output (zeros in halo) so overlaid buffers are re-cleaned per frame.
// ---------------------------------------------------------------------------
__global__ __launch_bounds__(256) void up_cl2cl_pad(
    const u16* __restrict__ sh, const u16* __restrict__ sl,
    u16* __restrict__ oh, u16* __restrict__ ol, int C, int H, int W, int Wps,
    int Poffs, int Hp, int Wpo, int Poffo) {
  int Ho = 2 * H, Wo = 2 * W;
  long tot = (long)Hp * Wpo * C;
  long gid = (long)blockIdx.x * 256 + threadIdx.x;
  if (gid >= tot) return;
  int c = (int)(gid % C);
  long r = gid / C;
  int xp = (int)(r % Wpo);
  int yp = (int)(r / Wpo);
  int x = xp - Poffo, y = yp - Poffo;
  float v = 0.f;
  if ((unsigned)x < (unsigned)Wo && (unsigned)y < (unsigned)Ho) {
    float fy = (float)(y * (H - 1)) / (float)(Ho - 1);
    float fx = (float)(x * (W - 1)) / (float)(Wo - 1);
    int y0 = (int)fy, x0 = (int)fx;
    int y1 = min(y0 + 1, H - 1), x1 = min(x0 + 1, W - 1);
    float wy = fy - y0, wx = fx - x0;
    auto rd = [&](int cy, int cx) {
      long o = ((long)(cy + Poffs) * Wps + (cx + Poffs)) * C + c;
      return bf2f(sh[o]) + bf2f(sl[o]);
    };
    float r0 = rd(y0, x0) * (1.f - wx) + rd(y0, x1) * wx;
    float r1 = rd(y1, x0) * (1.f - wx) + rd(y1, x1) * wx;
    v = r0 * (1.f - wy) + r1 * wy;
  }
  splitw(v, &oh[gid], &ol[gid]);
}

// ---------------------------------------------------------------------------
extern "C" void kernel_launch(void* const* d_in, const int* in_sizes, int n_in,
                              void* d_out, int out_size, void* d_ws,
                              size_t ws_size, hipStream_t stream) {
  const float* input = (const float*)d_in[0];
  const float* enc_w0 = (const float*)d_in[1];
  const float* enc_b0 = (const float*)d_in[2];
  const float* enc_w1 = (const float*)d_in[3];
  const float* enc_b1 = (const float*)d_in[4];
  const float* enc_w2 = (const float*)d_in[5];
  const float* enc_b2 = (const float*)d_in[6];
  const float* enc_w3 = (const float*)d_in[7];
  const float* enc_b3 = (const float*)d_in[8];
  const float* tq_w = (const float*)d_in[9];
  const float* tq_b = (const float*)d_in[10];
  const float* tk_w = (const float*)d_in[11];
  const float* tk_b = (const float*)d_in[12];
  const float* tv_w = (const float*)d_in[13];
  const float* tv_b = (const float*)d_in[14];
  const float* to_w = (const float*)d_in[15];
  const float* to_b = (const float*)d_in[16];
  const float* tf1_w = (const float*)d_in[17];
  const float* tf1_b = (const float*)d_in[18];
  const float* tf2_w = (const float*)d_in[19];
  const float* tf2_b = (const float*)d_in[20];
  const float* d0_w = (const float*)d_in[21];
  const float* d0_b = (const float*)d_in[22];
  const float* d1_w = (const float*)d_in[23];
  const float* d1_b = (const float*)d_in[24];
  const float* d2_w = (const float*)d_in[25];
  const float* d2_b = (const float*)d_in[26];
  const float* d3_w = (const float*)d_in[27];
  const float* d3_b = (const float*)d_in[28];
  float* out = (float*)d_out;

  // -------- workspace layout --------
  unsigned char* wsb = (unsigned char*)d_ws;
  size_t off = 0;
  auto alloc = [&](size_t bytes) {
    void* p = wsb + off;
    off = (off + bytes + 255) & ~(size_t)255;
    return p;
  };
  const long XCL_E = 22839296L;   // 16*34*164*256
  const long XCL2_E = 21233664L;  // 16*32*162*256
  const long QT_E = 4915200L;
  const long VT_E = 5111808L;
  u16* XCLh = (u16*)alloc(XCL_E * 2);
  u16* XCLl = (u16*)alloc(XCL_E * 2);
  u16* XCL2h = (u16*)alloc(XCL2_E * 2);
  u16* XCL2l = (u16*)alloc(XCL2_E * 2);
  u16* qth = (u16*)alloc(QT_E * 2);
  u16* qtl = (u16*)alloc(QT_E * 2);
  u16* kth = (u16*)alloc(QT_E * 2);
  u16* ktl = (u16*)alloc(QT_E * 2);
  u16* vth = (u16*)alloc(VT_E * 2);
  u16* vtl = (u16*)alloc(VT_E * 2);
  int* nmapA = (int*)alloc(4 * 4800 * 4);
  int* dmapA = (int*)alloc(4 * 4800 * 4);
  int* rowbaseA = (int*)alloc(7120 * 4);
  int* doffA = (int*)alloc(93248 * 4);
  u16* qwh = (u16*)alloc(16384 * 2);
  u16* qwl = (u16*)alloc(16384 * 2);
  u16* kwh = (u16*)alloc(16384 * 2);
  u16* kwl = (u16*)alloc(16384 * 2);
  u16* vwh = (u16*)alloc(16384 * 2);
  u16* vwl = (u16*)alloc(16384 * 2);
  // adaptive scores/P region (allocated LAST). Per row: scores 5120*4 +
  // Ph 5120*2 + Pl 5120*2 = 40960 bytes. (Round-6 bug: counted only 20480.)
  size_t fixed_end = off;
  size_t avail = ws_size > fixed_end ? ws_size - fixed_end : 0;
  const size_t PERROW = 40960;
  int SC = 256;
  if (avail >= (size_t)1024 * PERROW + 4096) SC = 1024;
  else if (avail >= (size_t)512 * PERROW + 4096) SC = 512;
  float* scores = (float*)alloc((size_t)SC * 5120 * 4);
  u16* Ph = (u16*)alloc((size_t)SC * 5120 * 2);
  u16* Pl = (u16*)alloc((size_t)SC * 5120 * 2);
  size_t need = off;
  if (ws_size < need) return;  // fail loud, not crash (SC=256 == round-5 fit)

  // trunk conv weights overlay the P region (disjoint lifetimes)
  u16* Wth = (u16*)Ph;
  u16* Wtl = Wth + 589824;

  // ---- decoder buffers: overlay XCL2 + token region (dead in decoder) ----
  // 2-frame batched. dec2out overlays dec0in (dead after d0).
  unsigned char* decbase = (unsigned char*)XCL2h;
  u16* dec0inH = (u16*)(decbase + 0);
  u16* dec0inL = (u16*)(decbase + 20443136);
  u16* dec0outH = (u16*)(decbase + 40886272);
  u16* dec0outL = (u16*)(decbase + 51107840);
  u16* dec1outH = (u16*)(decbase + 61329408);
  u16* dec1outL = (u16*)(decbase + 66440192);
  u16* dec2inH = (u16*)(decbase + 71550976);
  u16* dec2inL = (u16*)(decbase + 91601920);
  float* dec2out = (float*)(decbase + 0);
  const long D0IN_FS = 5110784, D0OUT_FS = 2555392, D1OUT_FS = 1277696;
  const long D2IN_FS = 5012736, D2OUT_FS = 4915200;

  const long FS_TR = 1427456;  // 34*164*256
  const long FS_T2 = 1327104;  // 32*162*256 == 64*324*64
  const long FS_E2 = 713728;   // 34*164*128

  static const int PWa[4] = {80, 32, 10, 5};
  static const int PHa[4] = {15, 6, 5, 3};
  static const int rbOff[4] = {0, 64, 464, 2000};
  static const int doOff[4] = {0, 76800, 89088, 92288};

  // -------- encoder --------
  hipMemsetAsync(XCLh, 0, XCL_E * 2, stream);
  hipMemsetAsync(XCLl, 0, XCL_E * 2, stream);
  hipMemsetAsync(XCL2h, 0, XCL2_E * 2, stream);
  hipMemsetAsync(XCL2l, 0, XCL2_E * 2, stream);
  hipMemsetAsync(vth, 0, VT_E * 2, stream);  // pad-column zero guard
  hipMemsetAsync(vtl, 0, VT_E * 2, stream);
  {  // enc0: fp32 direct -> CL [64][324][64] Poff2 in XCL2 space
    long tot = 16L * 64 * 60 * 40;
    conv2d_k<3, 2, 1><<<cdivu(tot, 256), 256, 0, stream>>>(
        input, enc_w0, enc_b0, nullptr, XCL2h, XCL2l, 324, 2, FS_T2, 16, 3,
        120, 640, 64, 60, 320, 1, ACT_LEAKY);
  }
  {  // enc1: 64->64, 60x320 (tile 256x64)
    wt_build<<<cdivu(9L * 64 * 64, 256), 256, 0, stream>>>(enc_w1, 64, 64, 9,
                                                           Wth, Wtl);
    conv_gemm_lds<4, 1><<<dim3(75, 1, 16), 256, 0, stream>>>(
        XCL2h, XCL2l, Wth, Wtl, enc_b1, 64, 64, 60, 320, 324, 2, 1, 1, 1, 9,
        FS_T2, ACT_LEAKY, nullptr, 0, XCLh, XCLl, FS_T2, 324, 2, 0);
  }
  hipMemsetAsync(XCL2h, 0, XCL2_E * 2, stream);
  hipMemsetAsync(XCL2l, 0, XCL2_E * 2, stream);
  {  // enc2: 64->128 stride2 -> CL [34][164][128] in XCL2 space
    wt_build<<<cdivu(9L * 128 * 64, 256), 256, 0, stream>>>(enc_w2, 128, 64, 9,
                                                            Wth, Wtl);
    conv_gemm_lds<2, 2><<<dim3(38, 1, 16), 256, 0, stream>>>(
        XCLh, XCLl, Wth, Wtl, enc_b2, 64, 128, 30, 160, 324, 2, 2, 1, 1, 9,
        FS_T2, ACT_LEAKY, nullptr, 0, XCL2h, XCL2l, FS_E2, 164, 2, 0);
  }
  hipMemsetAsync(XCLh, 0, XCL_E * 2, stream);
  hipMemsetAsync(XCLl, 0, XCL_E * 2, stream);
  {  // enc3: 128->256 -> trunk XCL [34][164][256]
    wt_build<<<cdivu(9L * 256 * 128, 256), 256, 0, stream>>>(enc_w3, 256, 128,
                                                             9, Wth, Wtl);
    conv_gemm_lds<2, 2><<<dim3(38, 2, 16), 256, 0, stream>>>(
        XCL2h, XCL2l, Wth, Wtl, enc_b3, 128, 256, 30, 160, 164, 2, 1, 1, 1, 9,
        FS_E2, ACT_LEAKY, nullptr, 0, XCLh, XCLl, FS_TR, 164, 2, 0);
  }
  hipMemsetAsync(XCL2h, 0, XCL2_E * 2, stream);
  hipMemsetAsync(XCL2l, 0, XCL2_E * 2, stream);

  // -------- token maps / scatter LUTs --------
  for (int g = 0; g < 4; ++g) {
    int ph = PHa[g], pw = PWa[g];
    int ohh = 30 / ph, oww = 160 / pw;
    int Ntok = 16 * ohh * oww, Dd = 64 * ph * pw, pp = ph * pw;
    maps_build<<<19, 256, 0, stream>>>(ph, pw, oww, nmapA + g * 4800,
                                       dmapA + g * 4800);
    int mx = Ntok > Dd ? Ntok : Dd;
    luts_build<<<cdivu(mx, 256), 256, 0, stream>>>(
        ph, pw, ohh * oww, oww, pp, Ntok, Dd, g * 64, rowbaseA + rbOff[g],
        doffA + doOff[g]);
  }

  // -------- transformer stack --------
  for (int l = 0; l < 8; ++l) {
    for (int g = 0; g < 4; ++g) {
      int ph = PHa[g], pw = PWa[g];
      int ohh = 30 / ph, oww = 160 / pw;
      int ohow = ohh * oww;
      int Ntok = 16 * ohow, Dd = 64 * ph * pw, pp = ph * pw;
      int NtokPad = (Ntok + 31) & ~31;
      float scale = 1.0f / sqrtf((float)Dd);
      const int* nmap = nmapA + g * 4800;
      const int* dmap = dmapA + g * 4800;
      const int* rowbase = rowbaseA + rbOff[g];
      const int* doffp = doffA + doOff[g];

      wtqkv_build<<<64, 256, 0, stream>>>(
          tq_w + (long)l * 65536, tk_w + (long)l * 65536,
          tv_w + (long)l * 65536, g * 64, qwh, qwl, kwh, kwl, vwh, vwl);
      qkv_gemm<<<dim3(38, 1, 16), 128, 0, stream>>>(
          XCLh, XCLl, FS_TR, 164, 2, qwh, qwl, tq_b + l * 256 + g * 64, nmap,
          dmap, ohow, Dd, pp, NtokPad, scale, 0, qth, qtl);
      qkv_gemm<<<dim3(38, 1, 16), 128, 0, stream>>>(
          XCLh, XCLl, FS_TR, 164, 2, kwh, kwl, tk_b + l * 256 + g * 64, nmap,
          dmap, ohow, Dd, pp, NtokPad, 1.f, 1, kth, ktl);
      qkv_gemm<<<dim3(38, 1, 16), 128, 0, stream>>>(
          XCLh, XCLl, FS_TR, 164, 2, vwh, vwl, tv_b + l * 256 + g * 64, nmap,
          dmap, ohow, Dd, pp, NtokPad, 1.f, 2, vth, vtl);

      if (g == 0) {
        // QK split-K: 32 parts of K=2400 -> partials -> reduce -> softmax
        float* scoresR = scores + 32 * 4096;
        attn_gemm_lds<<<dim3(1, 1, 32), 256, 0, stream>>>(
            qth, qtl, Dd, 64, kth, ktl, Dd, 64, 2400, 64, 0, scores, 64, 4096,
            nullptr, nullptr, nullptr, nullptr);
        reduce_scatter<<<16, 256, 0, stream>>>(scores, 32, 4096, 64, 64, 0,
                                               scoresR, nullptr, nullptr,
                                               nullptr, nullptr);
        softmax_p<<<64, 256, 0, stream>>>(scoresR, 64, 64, Ph, Pl);
        attn_gemm_lds<<<dim3(1, 600, 1), 256, 0, stream>>>(
            Ph, Pl, 64, 64, vth, vtl, 64, Dd, 64, Dd, 1, nullptr, 0, 0, XCL2h,
            XCL2l, rowbase, doffp);
      } else {
        // chunk rows bounded by scores capacity: chunk*Ntok <= SC*5120
        long cap = ((long)SC * 5120 / Ntok) & ~127L;
        int chunk = (int)(cap < 128 ? 128 : cap);
        if (chunk > Ntok) chunk = Ntok;
        for (int r0 = 0; r0 < Ntok; r0 += chunk) {
          int rows = Ntok - r0 < chunk ? Ntok - r0 : chunk;
          attn_gemm_lds<<<dim3(cdivu(rows, 128), cdivu(Ntok, 128), 1), 256, 0,
                          stream>>>(qth + (long)r0 * Dd, qtl + (long)r0 * Dd,
                                    Dd, rows, kth, ktl, Dd, Ntok, Dd, Ntok, 0,
                                    scores, Ntok, 0, nullptr, nullptr, nullptr,
                                    nullptr);
          softmax_p<<<rows, 256, 0, stream>>>(scores, Ntok, NtokPad, Ph, Pl);
          if (g == 3) {
            attn_gemm_lds<<<dim3(cdivu(rows, 128), 8, 4), 256, 0, stream>>>(
                Ph, Pl, NtokPad, rows, vth, vtl, NtokPad, Dd, 1280, Dd, 0,
                scores, 960, (long)rows * 960, nullptr, nullptr, nullptr,
                nullptr);
            reduce_scatter<<<cdivu((long)rows * 960, 256), 256, 0, stream>>>(
                scores, 4, (long)rows * 960, rows, 960, 1, nullptr, XCL2h,
                XCL2l, rowbase + r0, doffp);
          } else {
            attn_gemm_lds<<<dim3(cdivu(rows, 128), Dd / 128, 1), 256, 0,
                            stream>>>(Ph, Pl, NtokPad, rows, vth, vtl, NtokPad,
                                      Dd, NtokPad, Dd, 1, nullptr, 0, 0, XCL2h,
                                      XCL2l, rowbase + r0, doffp);
          }
        }
      }
    }

    // out-conv 3x3 + leaky + residual (in-place on XCL)
    wt_build<<<cdivu(9L * 256 * 256, 256), 256, 0, stream>>>(
        to_w + (long)l * 589824, 256, 256, 9, Wth, Wtl);
    conv_gemm_lds<2, 2><<<dim3(38, 2, 16), 256, 0, stream>>>(
        XCL2h, XCL2l, Wth, Wtl, to_b + l * 256, 256, 256, 30, 160, 162, 1, 1,
        1, 1, 9, FS_T2, ACT_LEAKY, nullptr, 0, XCLh, XCLl, FS_TR, 164, 2, 1);
    // ff1: dil2 pad2
    wt_build<<<cdivu(9L * 256 * 256, 256), 256, 0, stream>>>(
        tf1_w + (long)l * 589824, 256, 256, 9, Wth, Wtl);
    conv_gemm_lds<2, 2><<<dim3(38, 2, 16), 256, 0, stream>>>(
        XCLh, XCLl, Wth, Wtl, tf1_b + l * 256, 256, 256, 30, 160, 164, 2, 1, 2,
        2, 9, FS_TR, ACT_LEAKY, nullptr, 0, XCL2h, XCL2l, FS_T2, 162, 1, 0);
    // ff2 + residual (in-place on XCL)
    wt_build<<<cdivu(9L * 256 * 256, 256), 256, 0, stream>>>(
        tf2_w + (long)l * 589824, 256, 256, 9, Wth, Wtl);
    conv_gemm_lds<2, 2><<<dim3(38, 2, 16), 256, 0, stream>>>(
        XCL2h, XCL2l, Wth, Wtl, tf2_b + l * 256, 256, 256, 30, 160, 162, 1, 1,
        1, 1, 9, FS_T2, ACT_LEAKY, nullptr, 0, XCLh, XCLl, FS_TR, 164, 2, 1);
  }

  // -------- decoder (2-frame groups; overlays XCL2+token region) --------
  hipMemsetAsync(decbase, 0, 111652864, stream);
  wt_build<<<cdivu(9L * 128 * 256, 256), 256, 0, stream>>>(d0_w, 128, 256, 9,
                                                           Wth, Wtl);
  u16* W1h = Wtl + 589824;
  u16* W1l = W1h + 73728;
  wt_build<<<cdivu(9L * 64 * 128, 256), 256, 0, stream>>>(d1_w, 64, 128, 9,
                                                          W1h, W1l);
  u16* W2h = W1l + 73728;
  u16* W2l = W2h + 36864;
  wt_build<<<cdivu(9L * 64 * 64, 256), 256, 0, stream>>>(d2_w, 64, 64, 9, W2h,
                                                         W2l);
  for (int f = 0; f < 16; f += 2) {
    for (int ff = 0; ff < 2; ++ff)
      up_cl2cl_pad<<<cdivu(62L * 322 * 256, 256), 256, 0, stream>>>(
          XCLh + (long)(f + ff) * FS_TR, XCLl + (long)(f + ff) * FS_TR,
          dec0inH + (long)ff * D0IN_FS, dec0inL + (long)ff * D0IN_FS, 256, 30,
          160, 164, 2, 62, 322, 1);
    conv_gemm_lds<2, 2><<<dim3(150, 1, 2), 256, 0, stream>>>(
        dec0inH, dec0inL, Wth, Wtl, d0_b, 256, 128, 60, 320, 322, 1, 1, 1, 1,
        9, D0IN_FS, ACT_LEAKY, nullptr, 0, dec0outH, dec0outL, D0OUT_FS, 322,
        1, 0);
    conv_gemm_lds<4, 1><<<dim3(75, 1, 2), 256, 0, stream>>>(
        dec0outH, dec0outL, W1h, W1l, d1_b, 128, 64, 60, 320, 322, 1, 1, 1, 1,
        9, D0OUT_FS, ACT_LEAKY, nullptr, 0, dec1outH, dec1outL, D1OUT_FS, 322,
        1, 0);
    for (int ff = 0; ff < 2; ++ff)
      up_cl2cl_pad<<<cdivu(122L * 642 * 64, 256), 256, 0, stream>>>(
          dec1outH + (long)ff * D1OUT_FS, dec1outL + (long)ff * D1OUT_FS,
          dec2inH + (long)ff * D2IN_FS, dec2inL + (long)ff * D2IN_FS, 64, 60,
          320, 322, 1, 122, 642, 1);
    conv_gemm_lds<4, 1><<<dim3(300, 1, 2), 256, 0, stream>>>(
        dec2inH, dec2inL, W2h, W2l, d2_b, 64, 64, 120, 640, 642, 1, 1, 1, 1, 9,
        D2IN_FS, ACT_LEAKY, dec2out, D2OUT_FS, nullptr, nullptr, 0, 0, 0, 0);
    {
      long tot = 2L * 3 * 120 * 80;
      conv2d_k<3, 1, 1><<<cdivu(tot, 256), 256, 0, stream>>>(
          dec2out, d3_w, d3_b, out + (long)f * 230400, nullptr, nullptr, 0, 0,
          0, 2, 64, 120, 640, 3, 120, 640, 1, ACT_TANH);
    }
  }
}

// Round 8
// 39918.906 us; speedup vs baseline: 25.6947x; 1.0045x over previous
//
#include <hip/hip_runtime.h>
#include <hip/hip_bf16.h>
#include <math.h>

#define ACT_NONE 0
#define ACT_LEAKY 1
#define ACT_TANH 2

typedef __attribute__((ext_vector_type(8))) short bf16x8;
typedef __attribute__((ext_vector_type(4))) float f32x4;
typedef unsigned short u16;

#define MFMA(a, b, c) __builtin_amdgcn_mfma_f32_16x16x32_bf16((bf16x8)(a), (bf16x8)(b), (c), 0, 0, 0)

static inline unsigned cdivu(long a, long b) { return (unsigned)((a + b - 1) / b); }

__device__ __forceinline__ u16 f2bf(float x) {
  union { __hip_bfloat16 h; u16 u; } cv;
  cv.h = __float2bfloat16(x);
  return cv.u;
}
__device__ __forceinline__ float bf2f(u16 b) {
  union { u16 u; __hip_bfloat16 h; } cv;
  cv.u = b;
  return __bfloat162float(cv.h);
}
__device__ __forceinline__ void splitw(float v, u16* ph, u16* pl) {
  u16 h = f2bf(v);
  *ph = h;
  *pl = f2bf(v - bf2f(h));
}
// async global->LDS, 16B per lane; dest must be wave-uniform base (+lane*16)
__device__ __forceinline__ void gload16(const void* g, void* l) {
  __builtin_amdgcn_global_load_lds(
      (const __attribute__((address_space(1))) unsigned int*)g,
      (__attribute__((address_space(3))) unsigned int*)l, 16, 0, 0);
}

// ---------------------------------------------------------------------------
// Direct fp32 conv (enc0: Cin=3; d3: Cout=3+tanh). Optional CL hi/lo output.
// ---------------------------------------------------------------------------
template <int K, int S, int DIL>
__global__ __launch_bounds__(256) void conv2d_k(
    const float* __restrict__ x, const float* __restrict__ w,
    const float* __restrict__ bias, float* y, u16* clh, u16* cll, int WpO,
    int PoffO, long o_fstride, int N, int Cin, int Hin, int Win, int Cout,
    int Hout, int Wout, int pad, int act) {
  constexpr int TW = 8;
  constexpr int XL = (TW - 1) * S + (K - 1) * DIL + 1;
  int wq = (Wout + TW - 1) / TW;
  long gid = (long)blockIdx.x * 256 + threadIdx.x;
  long total = (long)N * Cout * Hout * wq;
  if (gid >= total) return;
  int xg = (int)(gid % wq);
  long r = gid / wq;
  int yo = (int)(r % Hout);
  r /= Hout;
  int oc = (int)(r % Cout);
  int n = (int)(r / Cout);

  float bv = bias[oc];
  float acc[TW];
#pragma unroll
  for (int j = 0; j < TW; ++j) acc[j] = bv;

  int xo0 = xg * TW;
  int xi0 = xo0 * S - pad;
  const float* xn = x + (long)n * Cin * Hin * Win;
  const float* wb = w + (long)oc * Cin * K * K;

  for (int ic = 0; ic < Cin; ++ic) {
    const float* xc = xn + (long)ic * Hin * Win;
    const float* wc = wb + ic * (K * K);
#pragma unroll
    for (int ky = 0; ky < K; ++ky) {
      int yi = yo * S - pad + ky * DIL;
      if ((unsigned)yi < (unsigned)Hin) {
        const float* row = xc + (long)yi * Win;
        float xr[XL];
#pragma unroll
        for (int i2 = 0; i2 < XL; ++i2) {
          int xi = xi0 + i2;
          xr[i2] = ((unsigned)xi < (unsigned)Win) ? row[xi] : 0.f;
        }
#pragma unroll
        for (int kx = 0; kx < K; ++kx) {
          float wv = wc[ky * K + kx];
#pragma unroll
          for (int j = 0; j < TW; ++j)
            acc[j] = fmaf(wv, xr[j * S + kx * DIL], acc[j]);
        }
      }
    }
  }

#pragma unroll
  for (int j = 0; j < TW; ++j) {
    if (xo0 + j < Wout) {
      float v = acc[j];
      if (act == ACT_LEAKY)
        v = v >= 0.f ? v : 0.2f * v;
      else if (act == ACT_TANH)
        v = tanhf(v);
      if (y) y[(((long)n * Cout + oc) * Hout + yo) * Wout + xo0 + j] = v;
      if (clh) {
        long off = (long)n * o_fstride +
                   ((long)(yo + PoffO) * WpO + (xo0 + j + PoffO)) * Cout + oc;
        splitw(v, &clh[off], &cll[off]);
      }
    }
  }
}

// ---------------------------------------------------------------------------
// LDS-staged MFMA implicit-GEMM conv (m97 2-barrier structure).
// ---------------------------------------------------------------------------
template <int WM, int WN>
__global__ __launch_bounds__(256) void conv_gemm_lds(
    const u16* __restrict__ Ah, const u16* __restrict__ Al,
    const u16* __restrict__ Bh, const u16* __restrict__ Bl,
    const float* __restrict__ bias, int Cin, int Cout, int Hout, int Wout,
    int Wp, int Poff, int S, int DIL, int pad, int taps, long a_fstride,
    int act, float* yout, long y_fstride, u16* Oh, u16* Ol, long o_fstride,
    int WpO, int PoffO, int useres) {
  constexpr int TM = WM * 64, TN = WN * 64;
  __shared__ u16 AsH[TM * 32], AsL[TM * 32], BsH[TN * 32], BsL[TN * 32];
  int t = threadIdx.x;
  int lane = t & 63;
  int w = t >> 6;
  int wr = w / WN, wc = w % WN;
  int l15 = lane & 15, l16 = lane >> 4;
  int HW = Hout * Wout;
  int row0 = blockIdx.x * TM;
  int col0 = blockIdx.y * TN;
  const u16* Afh = Ah + (long)blockIdx.z * a_fstride;
  const u16* Afl = Al + (long)blockIdx.z * a_fstride;

  int rs = t >> 2;
  int cs = (t & 3) * 8;
  long abase[WM];
#pragma unroll
  for (int c = 0; c < WM; ++c) {
    int s = row0 + rs + 64 * c;
    if (s >= HW) s = HW - 1;
    int yo = s / Wout, xo = s - yo * Wout;
    int yb = yo * S - pad + Poff, xb = xo * S - pad + Poff;
    abase[c] = ((long)yb * Wp + xb) * Cin + cs;
  }
  long bbase[WN];
#pragma unroll
  for (int c = 0; c < WN; ++c)
    bbase[c] = (long)(col0 + rs + 64 * c) * Cin + cs;
  int ldst = w * 512;

  f32x4 acc[4][4];
#pragma unroll
  for (int m = 0; m < 4; ++m)
#pragma unroll
    for (int n = 0; n < 4; ++n) acc[m][n] = (f32x4){0.f, 0.f, 0.f, 0.f};

  for (int tap = 0; tap < taps; ++tap) {
    int ky = tap / 3, kx = tap - ky * 3;
    long atap = ((long)ky * DIL * Wp + kx * DIL) * Cin;
    long btap = (long)tap * Cout * Cin;
    for (int ic0 = 0; ic0 < Cin; ic0 += 32) {
#pragma unroll
      for (int c = 0; c < WM; ++c) {
        gload16(Afh + abase[c] + atap + ic0, AsH + c * 2048 + ldst);
        gload16(Afl + abase[c] + atap + ic0, AsL + c * 2048 + ldst);
      }
#pragma unroll
      for (int c = 0; c < WN; ++c) {
        gload16(Bh + bbase[c] + btap + ic0, BsH + c * 2048 + ldst);
        gload16(Bl + bbase[c] + btap + ic0, BsL + c * 2048 + ldst);
      }
      __syncthreads();
      bf16x8 ah[4], al[4], bh[4], bl[4];
#pragma unroll
      for (int m = 0; m < 4; ++m) {
        int rrow = wr * 64 + m * 16 + l15;
        ah[m] = *(const bf16x8*)(AsH + rrow * 32 + l16 * 8);
        al[m] = *(const bf16x8*)(AsL + rrow * 32 + l16 * 8);
      }
#pragma unroll
      for (int n = 0; n < 4; ++n) {
        int rcol = wc * 64 + n * 16 + l15;
        bh[n] = *(const bf16x8*)(BsH + rcol * 32 + l16 * 8);
        bl[n] = *(const bf16x8*)(BsL + rcol * 32 + l16 * 8);
      }
#pragma unroll
      for (int m = 0; m < 4; ++m)
#pragma unroll
        for (int n = 0; n < 4; ++n) {
          acc[m][n] = MFMA(ah[m], bh[n], acc[m][n]);
          acc[m][n] = MFMA(ah[m], bl[n], acc[m][n]);
          acc[m][n] = MFMA(al[m], bh[n], acc[m][n]);
        }
      __syncthreads();
    }
  }

  float* yf = yout ? yout + (long)blockIdx.z * y_fstride : nullptr;
  u16* Ofh = Oh ? Oh + (long)blockIdx.z * o_fstride : nullptr;
  u16* Ofl = Ol ? Ol + (long)blockIdx.z * o_fstride : nullptr;
#pragma unroll
  for (int m = 0; m < 4; ++m) {
#pragma unroll
    for (int r = 0; r < 4; ++r) {
      int s = row0 + wr * 64 + m * 16 + l16 * 4 + r;
      if (s >= HW) continue;
      int yo = s / Wout, xo = s - yo * Wout;
      long clbase = 0;
      if (Ofh) clbase = ((long)(yo + PoffO) * WpO + (xo + PoffO)) * Cout;
#pragma unroll
      for (int n = 0; n < 4; ++n) {
        int oc = col0 + wc * 64 + n * 16 + l15;
        float v = acc[m][n][r] + bias[oc];
        if (act == ACT_LEAKY) v = v >= 0.f ? v : 0.2f * v;
        if (Ofh) {
          long off = clbase + oc;
          if (useres) v += bf2f(Ofh[off]) + bf2f(Ofl[off]);
          splitw(v, &Ofh[off], &Ofl[off]);
        }
        if (yf) yf[((long)oc * Hout + yo) * Wout + xo] = v;
      }
    }
  }
}

// ---------------------------------------------------------------------------
// LDS-staged QKV 1x1 GEMM. Tile 256x64, 256 thr / 4 waves (wave w owns rows
// w*64..w*64+63, all 64 cols). Staging map cloned from conv_gemm_lds<4,1>.
// Epilogue scatters to token layout: mode 0=Q (scaled), 1=K, 2=V ([d][n]).
// ---------------------------------------------------------------------------
__global__ __launch_bounds__(256) void qkv_gemm_lds(
    const u16* __restrict__ Ah, const u16* __restrict__ Al, long a_fstride,
    int Wp, int Poff, const u16* __restrict__ Bh, const u16* __restrict__ Bl,
    const float* __restrict__ bias, const int* __restrict__ nmap,
    const int* __restrict__ dmap, int ohow, int Dd, int pp, int NtokPad,
    float scale, int mode, u16* __restrict__ tH, u16* __restrict__ tL) {
  __shared__ u16 AsH[256 * 32], AsL[256 * 32], BsH[64 * 32], BsL[64 * 32];
  int t = threadIdx.x;
  int lane = t & 63;
  int w = t >> 6;
  int l15 = lane & 15, l16 = lane >> 4;
  int row0 = blockIdx.x * 256;
  int frame = blockIdx.z;
  const u16* Afh = Ah + (long)frame * a_fstride;
  const u16* Afl = Al + (long)frame * a_fstride;

  int rs = t >> 2;
  int cs = (t & 3) * 8;
  long abase[4];
#pragma unroll
  for (int c = 0; c < 4; ++c) {
    int s = row0 + rs + 64 * c;
    if (s >= 4800) s = 4799;
    int yo = s / 160, xo = s - yo * 160;
    abase[c] = ((long)(yo + Poff) * Wp + (xo + Poff)) * 256 + cs;
  }
  long bbase = (long)rs * 256 + cs;  // weight row = out-channel
  int ldst = w * 512;

  f32x4 acc[4][4];
#pragma unroll
  for (int m = 0; m < 4; ++m)
#pragma unroll
    for (int n = 0; n < 4; ++n) acc[m][n] = (f32x4){0.f, 0.f, 0.f, 0.f};

  for (int ic0 = 0; ic0 < 256; ic0 += 32) {
#pragma unroll
    for (int c = 0; c < 4; ++c) {
      gload16(Afh + abase[c] + ic0, AsH + c * 2048 + ldst);
      gload16(Afl + abase[c] + ic0, AsL + c * 2048 + ldst);
    }
    gload16(Bh + bbase + ic0, BsH + ldst);
    gload16(Bl + bbase + ic0, BsL + ldst);
    __syncthreads();
    bf16x8 ah[4], al[4], bh[4], bl[4];
#pragma unroll
    for (int m = 0; m < 4; ++m) {
      int rrow = w * 64 + m * 16 + l15;
      ah[m] = *(const bf16x8*)(AsH + rrow * 32 + l16 * 8);
      al[m] = *(const bf16x8*)(AsL + rrow * 32 + l16 * 8);
    }
#pragma unroll
    for (int n = 0; n < 4; ++n) {
      int rcol = n * 16 + l15;
      bh[n] = *(const bf16x8*)(BsH + rcol * 32 + l16 * 8);
      bl[n] = *(const bf16x8*)(BsL + rcol * 32 + l16 * 8);
    }
#pragma unroll
    for (int m = 0; m < 4; ++m)
#pragma unroll
      for (int n = 0; n < 4; ++n) {
        acc[m][n] = MFMA(ah[m], bh[n], acc[m][n]);
        acc[m][n] = MFMA(ah[m], bl[n], acc[m][n]);
        acc[m][n] = MFMA(al[m], bh[n], acc[m][n]);
      }
    __syncthreads();
  }

#pragma unroll
  for (int m = 0; m < 4; ++m) {
#pragma unroll
    for (int r = 0; r < 4; ++r) {
      int s = row0 + w * 64 + m * 16 + l16 * 4 + r;
      if (s >= 4800) continue;
      int nm = nmap[s], dm = dmap[s];
      int ntok = frame * ohow + nm;
#pragma unroll
      for (int n = 0; n < 4; ++n) {
        int c = n * 16 + l15;
        float v = acc[m][n][r] + bias[c];
        if (mode == 0) v *= scale;
        int d = c * pp + dm;
        long off = (mode == 2) ? ((long)d * NtokPad + ntok)
                               : ((long)ntok * Dd + d);
        splitw(v, &tH[off], &tL[off]);
      }
    }
  }
}

// ---------------------------------------------------------------------------
// LDS-staged attention GEMM (tile 128x128, 256 thr).
// ---------------------------------------------------------------------------
__global__ __launch_bounds__(256) void attn_gemm_lds(
    const u16* __restrict__ Ah, const u16* __restrict__ Al, int lda, int Mrows,
    const u16* __restrict__ Bh, const u16* __restrict__ Bl, int ldb,
    int Nclamp, int Kpart, int Nvalid, int mode, float* outf, int ldo,
    long partstride, u16* __restrict__ Oh, u16* __restrict__ Ol,
    const int* __restrict__ rowbase, const int* __restrict__ doff) {
  __shared__ u16 AsH[128 * 32], AsL[128 * 32], BsH[128 * 32], BsL[128 * 32];
  int t = threadIdx.x;
  int lane = t & 63;
  int w = t >> 6;
  int wc = w & 1, wr = w >> 1;
  int l15 = lane & 15, l16 = lane >> 4;
  int row0 = blockIdx.x * 128;
  int col0 = blockIdx.y * 128;
  int kbase = blockIdx.z * Kpart;
  if (outf) outf += (long)blockIdx.z * partstride;

  int rs = t >> 2;
  int cs = (t & 3) * 8;
  long abase[2], bbase[2];
#pragma unroll
  for (int c = 0; c < 2; ++c) {
    int sr = row0 + rs + 64 * c;
    if (sr >= Mrows) sr = Mrows - 1;
    abase[c] = (long)sr * lda + cs;
    int cc = col0 + rs + 64 * c;
    if (cc >= Nclamp) cc = Nclamp - 1;
    bbase[c] = (long)cc * ldb + cs;
  }
  int ldst = w * 512;

  f32x4 acc[4][4];
#pragma unroll
  for (int m = 0; m < 4; ++m)
#pragma unroll
    for (int n = 0; n < 4; ++n) acc[m][n] = (f32x4){0.f, 0.f, 0.f, 0.f};

  for (int k = kbase; k < kbase + Kpart; k += 32) {
#pragma unroll
    for (int c = 0; c < 2; ++c) {
      gload16(Ah + abase[c] + k, AsH + c * 2048 + ldst);
      gload16(Al + abase[c] + k, AsL + c * 2048 + ldst);
      gload16(Bh + bbase[c] + k, BsH + c * 2048 + ldst);
      gload16(Bl + bbase[c] + k, BsL + c * 2048 + ldst);
    }
    __syncthreads();
    bf16x8 ah[4], al[4], bh[4], bl[4];
#pragma unroll
    for (int m = 0; m < 4; ++m) {
      int rrow = wr * 64 + m * 16 + l15;
      ah[m] = *(const bf16x8*)(AsH + rrow * 32 + l16 * 8);
      al[m] = *(const bf16x8*)(AsL + rrow * 32 + l16 * 8);
    }
#pragma unroll
    for (int n = 0; n < 4; ++n) {
      int rcol = wc * 64 + n * 16 + l15;
      bh[n] = *(const bf16x8*)(BsH + rcol * 32 + l16 * 8);
      bl[n] = *(const bf16x8*)(BsL + rcol * 32 + l16 * 8);
    }
#pragma unroll
    for (int m = 0; m < 4; ++m)
#pragma unroll
      for (int n = 0; n < 4; ++n) {
        acc[m][n] = MFMA(ah[m], bh[n], acc[m][n]);
        acc[m][n] = MFMA(ah[m], bl[n], acc[m][n]);
        acc[m][n] = MFMA(al[m], bh[n], acc[m][n]);
      }
    __syncthreads();
  }

#pragma unroll
  for (int m = 0; m < 4; ++m) {
#pragma unroll
    for (int r = 0; r < 4; ++r) {
      int sr = row0 + wr * 64 + m * 16 + l16 * 4 + r;
      if (sr >= Mrows) continue;
#pragma unroll
      for (int n = 0; n < 4; ++n) {
        int c = col0 + wc * 64 + n * 16 + l15;
        if (c >= Nvalid) continue;
        float v = acc[m][n][r];
        if (mode == 0) {
          outf[(long)sr * ldo + c] = v;
        } else {
          long off = (long)rowbase[sr] + doff[c];
          splitw(v, &Oh[off], &Ol[off]);
        }
      }
    }
  }
}

// ---------------------------------------------------------------------------
__global__ __launch_bounds__(256) void reduce_scatter(
    const float* __restrict__ parts, int nparts, long pstride, int rows, int N,
    int mode, float* outf, u16* __restrict__ Oh, u16* __restrict__ Ol,
    const int* __restrict__ rowbase, const int* __restrict__ doff) {
  long gid = (long)blockIdx.x * 256 + threadIdx.x;
  long tot = (long)rows * N;
  if (gid >= tot) return;
  float s = 0.f;
  for (int p = 0; p < nparts; ++p) s += parts[p * pstride + gid];
  if (mode == 0) {
    outf[gid] = s;
  } else {
    int r = (int)(gid / N), c = (int)(gid % N);
    long off = (long)rowbase[r] + doff[c];
    splitw(s, &Oh[off], &Ol[off]);
  }
}

// ---------------------------------------------------------------------------
__global__ __launch_bounds__(256) void softmax_p(const float* __restrict__ S,
                                                 int Ntok, int NtokPad,
                                                 u16* __restrict__ Ph,
                                                 u16* __restrict__ Pl) {
  int row = blockIdx.x;
  const float* p = S + (long)row * Ntok;
  u16* ph = Ph + (long)row * NtokPad;
  u16* pl = Pl + (long)row * NtokPad;
  __shared__ float red[256];
  int t = threadIdx.x;
  float m = -1e30f;
  for (int i = t; i < Ntok; i += 256) m = fmaxf(m, p[i]);
  red[t] = m;
  __syncthreads();
  for (int s = 128; s > 0; s >>= 1) {
    if (t < s) red[t] = fmaxf(red[t], red[t + s]);
    __syncthreads();
  }
  m = red[0];
  __syncthreads();
  float sum = 0.f;
  for (int i = t; i < Ntok; i += 256) sum += __expf(p[i] - m);
  red[t] = sum;
  __syncthreads();
  for (int s = 128; s > 0; s >>= 1) {
    if (t < s) red[t] += red[t + s];
    __syncthreads();
  }
  float inv = 1.f / red[0];
  for (int i = t; i < Ntok; i += 256) {
    float e = __expf(p[i] - m) * inv;
    splitw(e, &ph[i], &pl[i]);
  }
  for (int i = Ntok + t; i < NtokPad; i += 256) {
    ph[i] = 0;
    pl[i] = 0;
  }
}

// ---------------------------------------------------------------------------
__global__ __launch_bounds__(256) void wt_build(const float* __restrict__ w,
                                                int Cout, int Cin, int taps,
                                                u16* __restrict__ Wh,
                                                u16* __restrict__ Wl) {
  long gid = (long)blockIdx.x * 256 + threadIdx.x;
  long tot = (long)taps * Cout * Cin;
  if (gid >= tot) return;
  int ic = (int)(gid % Cin);
  long r = gid / Cin;
  int oc = (int)(r % Cout);
  int tap = (int)(r / Cout);
  float v = w[((long)oc * Cin + ic) * taps + tap];
  splitw(v, &Wh[gid], &Wl[gid]);
}

// fused q/k/v 1x1 weight split build (one group of 64 out-channels)
__global__ __launch_bounds__(256) void wtqkv_build(
    const float* __restrict__ wq, const float* __restrict__ wk,
    const float* __restrict__ wv, int co, u16* __restrict__ qh,
    u16* __restrict__ ql, u16* __restrict__ kh, u16* __restrict__ kl,
    u16* __restrict__ vh, u16* __restrict__ vl) {
  int gid = blockIdx.x * 256 + threadIdx.x;
  if (gid >= 64 * 256) return;
  int ic = gid & 255, c = gid >> 8;
  long src = (long)(co + c) * 256 + ic;
  splitw(wq[src], &qh[gid], &ql[gid]);
  splitw(wk[src], &kh[gid], &kl[gid]);
  splitw(wv[src], &vh[gid], &vl[gid]);
}

// ---------------------------------------------------------------------------
__global__ __launch_bounds__(256) void maps_build(int ph, int pw, int ow,
                                                  int* __restrict__ nmap,
                                                  int* __restrict__ dmap) {
  int s = blockIdx.x * 256 + threadIdx.x;
  if (s >= 4800) return;
  int y = s / 160, x = s - y * 160;
  int i = y / ph, yy = y - i * ph;
  int j = x / pw, xx = x - j * pw;
  nmap[s] = i * ow + j;
  dmap[s] = yy * pw + xx;
}

__global__ __launch_bounds__(256) void luts_build(int ph, int pw, int ohow,
                                                  int ow, int pp, int Ntok,
                                                  int Dd, int gbase,
                                                  int* __restrict__ rowbase,
                                                  int* __restrict__ doff) {
  int gid = blockIdx.x * 256 + threadIdx.x;
  if (gid < Ntok) {
    int tt = gid / ohow, rem = gid - tt * ohow;
    int i = rem / ow, j = rem - i * ow;
    rowbase[gid] =
        tt * (32 * 162 * 256) + ((i * ph + 1) * 162 + (j * pw + 1)) * 256;
  }
  if (gid < Dd) {
    int c = gid / pp, rr = gid - c * pp;
    int yy = rr / pw, xx = rr - yy * pw;
    doff[gid] = (yy * 162 + xx) * 256 + gbase + c;
  }
}

// ---------------------------------------------------------------------------
// Bilinear x2 upsample (align_corners) CL hi/lo -> CL hi/lo. Writes the FULL
// padded output (zeros in halo) so overlaid buffers are re-cleaned per frame.
// ---------------------------------------------------------------------------
__global__ __launch_bounds__(256) void up_cl2cl_pad(
    const u16* __restrict__ sh, const u16* __restrict__ sl,
    u16* __restrict__ oh, u16* __restrict__ ol, int C, int H, int W, int Wps,
    int Poffs, int Hp, int Wpo, int Poffo) {
  int Ho = 2 * H, Wo = 2 * W;
  long tot = (long)Hp * Wpo * C;
  long gid = (long)blockIdx.x * 256 + threadIdx.x;
  if (gid >= tot) return;
  int c = (int)(gid % C);
  long r = gid / C;
  int xp = (int)(r % Wpo);
  int yp = (int)(r / Wpo);
  int x = xp - Poffo, y = yp - Poffo;
  float v = 0.f;
  if ((unsigned)x < (unsigned)Wo && (unsigned)y < (unsigned)Ho) {
    float fy = (float)(y * (H - 1)) / (float)(Ho - 1);
    float fx = (float)(x * (W - 1)) / (float)(Wo - 1);
    int y0 = (int)fy, x0 = (int)fx;
    int y1 = min(y0 + 1, H - 1), x1 = min(x0 + 1, W - 1);
    float wy = fy - y0, wx = fx - x0;
    auto rd = [&](int cy, int cx) {
      long o = ((long)(cy + Poffs) * Wps + (cx + Poffs)) * C + c;
      return bf2f(sh[o]) + bf2f(sl[o]);
    };
    float r0 = rd(y0, x0) * (1.f - wx) + rd(y0, x1) * wx;
    float r1 = rd(y1, x0) * (1.f - wx) + rd(y1, x1) * wx;
    v = r0 * (1.f - wy) + r1 * wy;
  }
  splitw(v, &oh[gid], &ol[gid]);
}

// ---------------------------------------------------------------------------
extern "C" void kernel_launch(void* const* d_in, const int* in_sizes, int n_in,
                              void* d_out, int out_size, void* d_ws,
                              size_t ws_size, hipStream_t stream) {
  const float* input = (const float*)d_in[0];
  const float* enc_w0 = (const float*)d_in[1];
  const float* enc_b0 = (const float*)d_in[2];
  const float* enc_w1 = (const float*)d_in[3];
  const float* enc_b1 = (const float*)d_in[4];
  const float* enc_w2 = (const float*)d_in[5];
  const float* enc_b2 = (const float*)d_in[6];
  const float* enc_w3 = (const float*)d_in[7];
  const float* enc_b3 = (const float*)d_in[8];
  const float* tq_w = (const float*)d_in[9];
  const float* tq_b = (const float*)d_in[10];
  const float* tk_w = (const float*)d_in[11];
  const float* tk_b = (const float*)d_in[12];
  const float* tv_w = (const float*)d_in[13];
  const float* tv_b = (const float*)d_in[14];
  const float* to_w = (const float*)d_in[15];
  const float* to_b = (const float*)d_in[16];
  const float* tf1_w = (const float*)d_in[17];
  const float* tf1_b = (const float*)d_in[18];
  const float* tf2_w = (const float*)d_in[19];
  const float* tf2_b = (const float*)d_in[20];
  const float* d0_w = (const float*)d_in[21];
  const float* d0_b = (const float*)d_in[22];
  const float* d1_w = (const float*)d_in[23];
  const float* d1_b = (const float*)d_in[24];
  const float* d2_w = (const float*)d_in[25];
  const float* d2_b = (const float*)d_in[26];
  const float* d3_w = (const float*)d_in[27];
  const float* d3_b = (const float*)d_in[28];
  float* out = (float*)d_out;

  // -------- workspace layout --------
  unsigned char* wsb = (unsigned char*)d_ws;
  size_t off = 0;
  auto alloc = [&](size_t bytes) {
    void* p = wsb + off;
    off = (off + bytes + 255) & ~(size_t)255;
    return p;
  };
  const long XCL_E = 22839296L;   // 16*34*164*256
  const long XCL2_E = 21233664L;  // 16*32*162*256
  const long QT_E = 4915200L;
  const long VT_E = 5111808L;
  u16* XCLh = (u16*)alloc(XCL_E * 2);
  u16* XCLl = (u16*)alloc(XCL_E * 2);
  u16* XCL2h = (u16*)alloc(XCL2_E * 2);
  u16* XCL2l = (u16*)alloc(XCL2_E * 2);
  u16* qth = (u16*)alloc(QT_E * 2);
  u16* qtl = (u16*)alloc(QT_E * 2);
  u16* kth = (u16*)alloc(QT_E * 2);
  u16* ktl = (u16*)alloc(QT_E * 2);
  u16* vth = (u16*)alloc(VT_E * 2);
  u16* vtl = (u16*)alloc(VT_E * 2);
  int* nmapA = (int*)alloc(4 * 4800 * 4);
  int* dmapA = (int*)alloc(4 * 4800 * 4);
  int* rowbaseA = (int*)alloc(7120 * 4);
  int* doffA = (int*)alloc(93248 * 4);
  u16* qwh = (u16*)alloc(16384 * 2);
  u16* qwl = (u16*)alloc(16384 * 2);
  u16* kwh = (u16*)alloc(16384 * 2);
  u16* kwl = (u16*)alloc(16384 * 2);
  u16* vwh = (u16*)alloc(16384 * 2);
  u16* vwl = (u16*)alloc(16384 * 2);
  // adaptive scores/P region (allocated LAST). Per row: scores 5120*4 +
  // Ph 5120*2 + Pl 5120*2 = 40960 bytes.
  size_t fixed_end = off;
  size_t avail = ws_size > fixed_end ? ws_size - fixed_end : 0;
  const size_t PERROW = 40960;
  int SC = 256;
  if (avail >= (size_t)1024 * PERROW + 4096) SC = 1024;
  else if (avail >= (size_t)512 * PERROW + 4096) SC = 512;
  float* scores = (float*)alloc((size_t)SC * 5120 * 4);
  u16* Ph = (u16*)alloc((size_t)SC * 5120 * 2);
  u16* Pl = (u16*)alloc((size_t)SC * 5120 * 2);
  size_t need = off;
  if (ws_size < need) return;  // fail loud, not crash (SC=256 == round-5 fit)

  // trunk conv weights overlay the P region (disjoint lifetimes)
  u16* Wth = (u16*)Ph;
  u16* Wtl = Wth + 589824;

  // ---- decoder buffers: overlay XCL2 + token region (dead in decoder) ----
  // 2-frame batched. dec2out overlays dec0in (dead after d0).
  unsigned char* decbase = (unsigned char*)XCL2h;
  u16* dec0inH = (u16*)(decbase + 0);
  u16* dec0inL = (u16*)(decbase + 20443136);
  u16* dec0outH = (u16*)(decbase + 40886272);
  u16* dec0outL = (u16*)(decbase + 51107840);
  u16* dec1outH = (u16*)(decbase + 61329408);
  u16* dec1outL = (u16*)(decbase + 66440192);
  u16* dec2inH = (u16*)(decbase + 71550976);
  u16* dec2inL = (u16*)(decbase + 91601920);
  float* dec2out = (float*)(decbase + 0);
  const long D0IN_FS = 5110784, D0OUT_FS = 2555392, D1OUT_FS = 1277696;
  const long D2IN_FS = 5012736, D2OUT_FS = 4915200;

  const long FS_TR = 1427456;  // 34*164*256
  const long FS_T2 = 1327104;  // 32*162*256 == 64*324*64
  const long FS_E2 = 713728;   // 34*164*128

  static const int PWa[4] = {80, 32, 10, 5};
  static const int PHa[4] = {15, 6, 5, 3};
  static const int rbOff[4] = {0, 64, 464, 2000};
  static const int doOff[4] = {0, 76800, 89088, 92288};

  // -------- encoder --------
  hipMemsetAsync(XCLh, 0, XCL_E * 2, stream);
  hipMemsetAsync(XCLl, 0, XCL_E * 2, stream);
  hipMemsetAsync(XCL2h, 0, XCL2_E * 2, stream);
  hipMemsetAsync(XCL2l, 0, XCL2_E * 2, stream);
  hipMemsetAsync(vth, 0, VT_E * 2, stream);  // pad-column zero guard
  hipMemsetAsync(vtl, 0, VT_E * 2, stream);
  {  // enc0: fp32 direct -> CL [64][324][64] Poff2 in XCL2 space
    long tot = 16L * 64 * 60 * 40;
    conv2d_k<3, 2, 1><<<cdivu(tot, 256), 256, 0, stream>>>(
        input, enc_w0, enc_b0, nullptr, XCL2h, XCL2l, 324, 2, FS_T2, 16, 3,
        120, 640, 64, 60, 320, 1, ACT_LEAKY);
  }
  {  // enc1: 64->64, 60x320 (tile 256x64)
    wt_build<<<cdivu(9L * 64 * 64, 256), 256, 0, stream>>>(enc_w1, 64, 64, 9,
                                                           Wth, Wtl);
    conv_gemm_lds<4, 1><<<dim3(75, 1, 16), 256, 0, stream>>>(
        XCL2h, XCL2l, Wth, Wtl, enc_b1, 64, 64, 60, 320, 324, 2, 1, 1, 1, 9,
        FS_T2, ACT_LEAKY, nullptr, 0, XCLh, XCLl, FS_T2, 324, 2, 0);
  }
  hipMemsetAsync(XCL2h, 0, XCL2_E * 2, stream);
  hipMemsetAsync(XCL2l, 0, XCL2_E * 2, stream);
  {  // enc2: 64->128 stride2 -> CL [34][164][128] in XCL2 space
    wt_build<<<cdivu(9L * 128 * 64, 256), 256, 0, stream>>>(enc_w2, 128, 64, 9,
                                                            Wth, Wtl);
    conv_gemm_lds<2, 2><<<dim3(38, 1, 16), 256, 0, stream>>>(
        XCLh, XCLl, Wth, Wtl, enc_b2, 64, 128, 30, 160, 324, 2, 2, 1, 1, 9,
        FS_T2, ACT_LEAKY, nullptr, 0, XCL2h, XCL2l, FS_E2, 164, 2, 0);
  }
  hipMemsetAsync(XCLh, 0, XCL_E * 2, stream);
  hipMemsetAsync(XCLl, 0, XCL_E * 2, stream);
  {  // enc3: 128->256 -> trunk XCL [34][164][256]
    wt_build<<<cdivu(9L * 256 * 128, 256), 256, 0, stream>>>(enc_w3, 256, 128,
                                                             9, Wth, Wtl);
    conv_gemm_lds<2, 2><<<dim3(38, 2, 16), 256, 0, stream>>>(
        XCL2h, XCL2l, Wth, Wtl, enc_b3, 128, 256, 30, 160, 164, 2, 1, 1, 1, 9,
        FS_E2, ACT_LEAKY, nullptr, 0, XCLh, XCLl, FS_TR, 164, 2, 0);
  }
  hipMemsetAsync(XCL2h, 0, XCL2_E * 2, stream);
  hipMemsetAsync(XCL2l, 0, XCL2_E * 2, stream);

  // -------- token maps / scatter LUTs --------
  for (int g = 0; g < 4; ++g) {
    int ph = PHa[g], pw = PWa[g];
    int ohh = 30 / ph, oww = 160 / pw;
    int Ntok = 16 * ohh * oww, Dd = 64 * ph * pw, pp = ph * pw;
    maps_build<<<19, 256, 0, stream>>>(ph, pw, oww, nmapA + g * 4800,
                                       dmapA + g * 4800);
    int mx = Ntok > Dd ? Ntok : Dd;
    luts_build<<<cdivu(mx, 256), 256, 0, stream>>>(
        ph, pw, ohh * oww, oww, pp, Ntok, Dd, g * 64, rowbaseA + rbOff[g],
        doffA + doOff[g]);
  }

  // -------- transformer stack --------
  for (int l = 0; l < 8; ++l) {
    for (int g = 0; g < 4; ++g) {
      int ph = PHa[g], pw = PWa[g];
      int ohh = 30 / ph, oww = 160 / pw;
      int ohow = ohh * oww;
      int Ntok = 16 * ohow, Dd = 64 * ph * pw, pp = ph * pw;
      int NtokPad = (Ntok + 31) & ~31;
      float scale = 1.0f / sqrtf((float)Dd);
      const int* nmap = nmapA + g * 4800;
      const int* dmap = dmapA + g * 4800;
      const int* rowbase = rowbaseA + rbOff[g];
      const int* doffp = doffA + doOff[g];

      wtqkv_build<<<64, 256, 0, stream>>>(
          tq_w + (long)l * 65536, tk_w + (long)l * 65536,
          tv_w + (long)l * 65536, g * 64, qwh, qwl, kwh, kwl, vwh, vwl);
      qkv_gemm_lds<<<dim3(19, 1, 16), 256, 0, stream>>>(
          XCLh, XCLl, FS_TR, 164, 2, qwh, qwl, tq_b + l * 256 + g * 64, nmap,
          dmap, ohow, Dd, pp, NtokPad, scale, 0, qth, qtl);
      qkv_gemm_lds<<<dim3(19, 1, 16), 256, 0, stream>>>(
          XCLh, XCLl, FS_TR, 164, 2, kwh, kwl, tk_b + l * 256 + g * 64, nmap,
          dmap, ohow, Dd, pp, NtokPad, 1.f, 1, kth, ktl);
      qkv_gemm_lds<<<dim3(19, 1, 16), 256, 0, stream>>>(
          XCLh, XCLl, FS_TR, 164, 2, vwh, vwl, tv_b + l * 256 + g * 64, nmap,
          dmap, ohow, Dd, pp, NtokPad, 1.f, 2, vth, vtl);

      if (g == 0) {
        // QK split-K: 32 parts of K=2400 -> partials -> reduce -> softmax
        float* scoresR = scores + 32 * 4096;
        attn_gemm_lds<<<dim3(1, 1, 32), 256, 0, stream>>>(
            qth, qtl, Dd, 64, kth, ktl, Dd, 64, 2400, 64, 0, scores, 64, 4096,
            nullptr, nullptr, nullptr, nullptr);
        reduce_scatter<<<16, 256, 0, stream>>>(scores, 32, 4096, 64, 64, 0,
                                               scoresR, nullptr, nullptr,
                                               nullptr, nullptr);
        softmax_p<<<64, 256, 0, stream>>>(scoresR, 64, 64, Ph, Pl);
        attn_gemm_lds<<<dim3(1, 600, 1), 256, 0, stream>>>(
            Ph, Pl, 64, 64, vth, vtl, 64, Dd, 64, Dd, 1, nullptr, 0, 0, XCL2h,
            XCL2l, rowbase, doffp);
      } else {
        // chunk rows bounded by scores capacity: chunk*Ntok <= SC*5120
        long cap = ((long)SC * 5120 / Ntok) & ~127L;
        int chunk = (int)(cap < 128 ? 128 : cap);
        if (chunk > Ntok) chunk = Ntok;
        for (int r0 = 0; r0 < Ntok; r0 += chunk) {
          int rows = Ntok - r0 < chunk ? Ntok - r0 : chunk;
          attn_gemm_lds<<<dim3(cdivu(rows, 128), cdivu(Ntok, 128), 1), 256, 0,
                          stream>>>(qth + (long)r0 * Dd, qtl + (long)r0 * Dd,
                                    Dd, rows, kth, ktl, Dd, Ntok, Dd, Ntok, 0,
                                    scores, Ntok, 0, nullptr, nullptr, nullptr,
                                    nullptr);
          softmax_p<<<rows, 256, 0, stream>>>(scores, Ntok, NtokPad, Ph, Pl);
          if (g == 3) {
            attn_gemm_lds<<<dim3(cdivu(rows, 128), 8, 4), 256, 0, stream>>>(
                Ph, Pl, NtokPad, rows, vth, vtl, NtokPad, Dd, 1280, Dd, 0,
                scores, 960, (long)rows * 960, nullptr, nullptr, nullptr,
                nullptr);
            reduce_scatter<<<cdivu((long)rows * 960, 256), 256, 0, stream>>>(
                scores, 4, (long)rows * 960, rows, 960, 1, nullptr, XCL2h,
                XCL2l, rowbase + r0, doffp);
          } else {
            attn_gemm_lds<<<dim3(cdivu(rows, 128), Dd / 128, 1), 256, 0,
                            stream>>>(Ph, Pl, NtokPad, rows, vth, vtl, NtokPad,
                                      Dd, NtokPad, Dd, 1, nullptr, 0, 0, XCL2h,
                                      XCL2l, rowbase + r0, doffp);
          }
        }
      }
    }

    // out-conv 3x3 + leaky + residual (in-place on XCL)
    wt_build<<<cdivu(9L * 256 * 256, 256), 256, 0, stream>>>(
        to_w + (long)l * 589824, 256, 256, 9, Wth, Wtl);
    conv_gemm_lds<2, 2><<<dim3(38, 2, 16), 256, 0, stream>>>(
        XCL2h, XCL2l, Wth, Wtl, to_b + l * 256, 256, 256, 30, 160, 162, 1, 1,
        1, 1, 9, FS_T2, ACT_LEAKY, nullptr, 0, XCLh, XCLl, FS_TR, 164, 2, 1);
    // ff1: dil2 pad2
    wt_build<<<cdivu(9L * 256 * 256, 256), 256, 0, stream>>>(
        tf1_w + (long)l * 589824, 256, 256, 9, Wth, Wtl);
    conv_gemm_lds<2, 2><<<dim3(38, 2, 16), 256, 0, stream>>>(
        XCLh, XCLl, Wth, Wtl, tf1_b + l * 256, 256, 256, 30, 160, 164, 2, 1, 2,
        2, 9, FS_TR, ACT_LEAKY, nullptr, 0, XCL2h, XCL2l, FS_T2, 162, 1, 0);
    // ff2 + residual (in-place on XCL)
    wt_build<<<cdivu(9L * 256 * 256, 256), 256, 0, stream>>>(
        tf2_w + (long)l * 589824, 256, 256, 9, Wth, Wtl);
    conv_gemm_lds<2, 2><<<dim3(38, 2, 16), 256, 0, stream>>>(
        XCL2h, XCL2l, Wth, Wtl, tf2_b + l * 256, 256, 256, 30, 160, 162, 1, 1,
        1, 1, 9, FS_T2, ACT_LEAKY, nullptr, 0, XCLh, XCLl, FS_TR, 164, 2, 1);
  }

  // -------- decoder (2-frame groups; overlays XCL2+token region) --------
  hipMemsetAsync(decbase, 0, 111652864, stream);
  wt_build<<<cdivu(9L * 128 * 256, 256), 256, 0, stream>>>(d0_w, 128, 256, 9,
                                                           Wth, Wtl);
  u16* W1h = Wtl + 589824;
  u16* W1l = W1h + 73728;
  wt_build<<<cdivu(9L * 64 * 128, 256), 256, 0, stream>>>(d1_w, 64, 128, 9,
                                                          W1h, W1l);
  u16* W2h = W1l + 73728;
  u16* W2l = W2h + 36864;
  wt_build<<<cdivu(9L * 64 * 64, 256), 256, 0, stream>>>(d2_w, 64, 64, 9, W2h,
                                                         W2l);
  for (int f = 0; f < 16; f += 2) {
    for (int ff = 0; ff < 2; ++ff)
      up_cl2cl_pad<<<cdivu(62L * 322 * 256, 256), 256, 0, stream>>>(
          XCLh + (long)(f + ff) * FS_TR, XCLl + (long)(f + ff) * FS_TR,
          dec0inH + (long)ff * D0IN_FS, dec0inL + (long)ff * D0IN_FS, 256, 30,
          160, 164, 2, 62, 322, 1);
    conv_gemm_lds<2, 2><<<dim3(150, 1, 2), 256, 0, stream>>>(
        dec0inH, dec0inL, Wth, Wtl, d0_b, 256, 128, 60, 320, 322, 1, 1, 1, 1,
        9, D0IN_FS, ACT_LEAKY, nullptr, 0, dec0outH, dec0outL, D0OUT_FS, 322,
        1, 0);
    conv_gemm_lds<4, 1><<<dim3(75, 1, 2), 256, 0, stream>>>(
        dec0outH, dec0outL, W1h, W1l, d1_b, 128, 64, 60, 320, 322, 1, 1, 1, 1,
        9, D0OUT_FS, ACT_LEAKY, nullptr, 0, dec1outH, dec1outL, D1OUT_FS, 322,
        1, 0);
    for (int ff = 0; ff < 2; ++ff)
      up_cl2cl_pad<<<cdivu(122L * 642 * 64, 256), 256, 0, stream>>>(
          dec1outH + (long)ff * D1OUT_FS, dec1outL + (long)ff * D1OUT_FS,
          dec2inH + (long)ff * D2IN_FS, dec2inL + (long)ff * D2IN_FS, 64, 60,
          320, 322, 1, 122, 642, 1);
    conv_gemm_lds<4, 1><<<dim3(300, 1, 2), 256, 0, stream>>>(
        dec2inH, dec2inL, W2h, W2l, d2_b, 64, 64, 120, 640, 642, 1, 1, 1, 1, 9,
        D2IN_FS, ACT_LEAKY, dec2out, D2OUT_FS, nullptr, nullptr, 0, 0, 0, 0);
    {
      long tot = 2L * 3 * 120 * 80;
      conv2d_k<3, 1, 1><<<cdivu(tot, 256), 256, 0, stream>>>(
          dec2out, d3_w, d3_b, out + (long)f * 230400, nullptr, nullptr, 0, 0,
          0, 2, 64, 120, 640, 3, 120, 640, 1, ACT_TANH);
    }
  }
}

// Round 9
// 37997.430 us; speedup vs baseline: 26.9941x; 1.0506x over previous
//
#include <hip/hip_runtime.h>
#include <hip/hip_bf16.h>
#include <math.h>

#define ACT_NONE 0
#define ACT_LEAKY 1
#define ACT_TANH 2

typedef __attribute__((ext_vector_type(8))) short bf16x8;
typedef __attribute__((ext_vector_type(4))) float f32x4;
typedef unsigned short u16;

#define MFMA(a, b, c) __builtin_amdgcn_mfma_f32_16x16x32_bf16((bf16x8)(a), (bf16x8)(b), (c), 0, 0, 0)

static inline unsigned cdivu(long a, long b) { return (unsigned)((a + b - 1) / b); }

__device__ __forceinline__ u16 f2bf(float x) {
  union { __hip_bfloat16 h; u16 u; } cv;
  cv.h = __float2bfloat16(x);
  return cv.u;
}
__device__ __forceinline__ float bf2f(u16 b) {
  union { u16 u; __hip_bfloat16 h; } cv;
  cv.u = b;
  return __bfloat162float(cv.h);
}
__device__ __forceinline__ void splitw(float v, u16* ph, u16* pl) {
  u16 h = f2bf(v);
  *ph = h;
  *pl = f2bf(v - bf2f(h));
}
// async global->LDS, 16B per lane; dest must be wave-uniform base (+lane*16)
__device__ __forceinline__ void gload16(const void* g, void* l) {
  __builtin_amdgcn_global_load_lds(
      (const __attribute__((address_space(1))) unsigned int*)g,
      (__attribute__((address_space(3))) unsigned int*)l, 16, 0, 0);
}

// ---------------------------------------------------------------------------
// Direct fp32 conv (enc0: Cin=3; d3: Cout=3+tanh). Optional CL hi/lo output.
// ---------------------------------------------------------------------------
template <int K, int S, int DIL>
__global__ __launch_bounds__(256) void conv2d_k(
    const float* __restrict__ x, const float* __restrict__ w,
    const float* __restrict__ bias, float* y, u16* clh, u16* cll, int WpO,
    int PoffO, long o_fstride, int N, int Cin, int Hin, int Win, int Cout,
    int Hout, int Wout, int pad, int act) {
  constexpr int TW = 8;
  constexpr int XL = (TW - 1) * S + (K - 1) * DIL + 1;
  int wq = (Wout + TW - 1) / TW;
  long gid = (long)blockIdx.x * 256 + threadIdx.x;
  long total = (long)N * Cout * Hout * wq;
  if (gid >= total) return;
  int xg = (int)(gid % wq);
  long r = gid / wq;
  int yo = (int)(r % Hout);
  r /= Hout;
  int oc = (int)(r % Cout);
  int n = (int)(r / Cout);

  float bv = bias[oc];
  float acc[TW];
#pragma unroll
  for (int j = 0; j < TW; ++j) acc[j] = bv;

  int xo0 = xg * TW;
  int xi0 = xo0 * S - pad;
  const float* xn = x + (long)n * Cin * Hin * Win;
  const float* wb = w + (long)oc * Cin * K * K;

  for (int ic = 0; ic < Cin; ++ic) {
    const float* xc = xn + (long)ic * Hin * Win;
    const float* wc = wb + ic * (K * K);
#pragma unroll
    for (int ky = 0; ky < K; ++ky) {
      int yi = yo * S - pad + ky * DIL;
      if ((unsigned)yi < (unsigned)Hin) {
        const float* row = xc + (long)yi * Win;
        float xr[XL];
#pragma unroll
        for (int i2 = 0; i2 < XL; ++i2) {
          int xi = xi0 + i2;
          xr[i2] = ((unsigned)xi < (unsigned)Win) ? row[xi] : 0.f;
        }
#pragma unroll
        for (int kx = 0; kx < K; ++kx) {
          float wv = wc[ky * K + kx];
#pragma unroll
          for (int j = 0; j < TW; ++j)
            acc[j] = fmaf(wv, xr[j * S + kx * DIL], acc[j]);
        }
      }
    }
  }

#pragma unroll
  for (int j = 0; j < TW; ++j) {
    if (xo0 + j < Wout) {
      float v = acc[j];
      if (act == ACT_LEAKY)
        v = v >= 0.f ? v : 0.2f * v;
      else if (act == ACT_TANH)
        v = tanhf(v);
      if (y) y[(((long)n * Cout + oc) * Hout + yo) * Wout + xo0 + j] = v;
      if (clh) {
        long off = (long)n * o_fstride +
                   ((long)(yo + PoffO) * WpO + (xo0 + j + PoffO)) * Cout + oc;
        splitw(v, &clh[off], &cll[off]);
      }
    }
  }
}

// ---------------------------------------------------------------------------
// LDS-staged MFMA implicit-GEMM conv (m97 2-barrier structure).
// ---------------------------------------------------------------------------
template <int WM, int WN>
__global__ __launch_bounds__(256) void conv_gemm_lds(
    const u16* __restrict__ Ah, const u16* __restrict__ Al,
    const u16* __restrict__ Bh, const u16* __restrict__ Bl,
    const float* __restrict__ bias, int Cin, int Cout, int Hout, int Wout,
    int Wp, int Poff, int S, int DIL, int pad, int taps, long a_fstride,
    int act, float* yout, long y_fstride, u16* Oh, u16* Ol, long o_fstride,
    int WpO, int PoffO, int useres) {
  constexpr int TM = WM * 64, TN = WN * 64;
  __shared__ u16 AsH[TM * 32], AsL[TM * 32], BsH[TN * 32], BsL[TN * 32];
  int t = threadIdx.x;
  int lane = t & 63;
  int w = t >> 6;
  int wr = w / WN, wc = w % WN;
  int l15 = lane & 15, l16 = lane >> 4;
  int HW = Hout * Wout;
  int row0 = blockIdx.x * TM;
  int col0 = blockIdx.y * TN;
  const u16* Afh = Ah + (long)blockIdx.z * a_fstride;
  const u16* Afl = Al + (long)blockIdx.z * a_fstride;

  int rs = t >> 2;
  int cs = (t & 3) * 8;
  long abase[WM];
#pragma unroll
  for (int c = 0; c < WM; ++c) {
    int s = row0 + rs + 64 * c;
    if (s >= HW) s = HW - 1;
    int yo = s / Wout, xo = s - yo * Wout;
    int yb = yo * S - pad + Poff, xb = xo * S - pad + Poff;
    abase[c] = ((long)yb * Wp + xb) * Cin + cs;
  }
  long bbase[WN];
#pragma unroll
  for (int c = 0; c < WN; ++c)
    bbase[c] = (long)(col0 + rs + 64 * c) * Cin + cs;
  int ldst = w * 512;

  f32x4 acc[4][4];
#pragma unroll
  for (int m = 0; m < 4; ++m)
#pragma unroll
    for (int n = 0; n < 4; ++n) acc[m][n] = (f32x4){0.f, 0.f, 0.f, 0.f};

  for (int tap = 0; tap < taps; ++tap) {
    int ky = tap / 3, kx = tap - ky * 3;
    long atap = ((long)ky * DIL * Wp + kx * DIL) * Cin;
    long btap = (long)tap * Cout * Cin;
    for (int ic0 = 0; ic0 < Cin; ic0 += 32) {
#pragma unroll
      for (int c = 0; c < WM; ++c) {
        gload16(Afh + abase[c] + atap + ic0, AsH + c * 2048 + ldst);
        gload16(Afl + abase[c] + atap + ic0, AsL + c * 2048 + ldst);
      }
#pragma unroll
      for (int c = 0; c < WN; ++c) {
        gload16(Bh + bbase[c] + btap + ic0, BsH + c * 2048 + ldst);
        gload16(Bl + bbase[c] + btap + ic0, BsL + c * 2048 + ldst);
      }
      __syncthreads();
      bf16x8 ah[4], al[4], bh[4], bl[4];
#pragma unroll
      for (int m = 0; m < 4; ++m) {
        int rrow = wr * 64 + m * 16 + l15;
        ah[m] = *(const bf16x8*)(AsH + rrow * 32 + l16 * 8);
        al[m] = *(const bf16x8*)(AsL + rrow * 32 + l16 * 8);
      }
#pragma unroll
      for (int n = 0; n < 4; ++n) {
        int rcol = wc * 64 + n * 16 + l15;
        bh[n] = *(const bf16x8*)(BsH + rcol * 32 + l16 * 8);
        bl[n] = *(const bf16x8*)(BsL + rcol * 32 + l16 * 8);
      }
#pragma unroll
      for (int m = 0; m < 4; ++m)
#pragma unroll
        for (int n = 0; n < 4; ++n) {
          acc[m][n] = MFMA(ah[m], bh[n], acc[m][n]);
          acc[m][n] = MFMA(ah[m], bl[n], acc[m][n]);
          acc[m][n] = MFMA(al[m], bh[n], acc[m][n]);
        }
      __syncthreads();
    }
  }

  float* yf = yout ? yout + (long)blockIdx.z * y_fstride : nullptr;
  u16* Ofh = Oh ? Oh + (long)blockIdx.z * o_fstride : nullptr;
  u16* Ofl = Ol ? Ol + (long)blockIdx.z * o_fstride : nullptr;
#pragma unroll
  for (int m = 0; m < 4; ++m) {
#pragma unroll
    for (int r = 0; r < 4; ++r) {
      int s = row0 + wr * 64 + m * 16 + l16 * 4 + r;
      if (s >= HW) continue;
      int yo = s / Wout, xo = s - yo * Wout;
      long clbase = 0;
      if (Ofh) clbase = ((long)(yo + PoffO) * WpO + (xo + PoffO)) * Cout;
#pragma unroll
      for (int n = 0; n < 4; ++n) {
        int oc = col0 + wc * 64 + n * 16 + l15;
        float v = acc[m][n][r] + bias[oc];
        if (act == ACT_LEAKY) v = v >= 0.f ? v : 0.2f * v;
        if (Ofh) {
          long off = clbase + oc;
          if (useres) v += bf2f(Ofh[off]) + bf2f(Ofl[off]);
          splitw(v, &Ofh[off], &Ofl[off]);
        }
        if (yf) yf[((long)oc * Hout + yo) * Wout + xo] = v;
      }
    }
  }
}

// ---------------------------------------------------------------------------
// LDS-staged QKV 1x1 GEMM. Tile 256x64, 4 waves. Token-layout scatter.
// ---------------------------------------------------------------------------
__global__ __launch_bounds__(256) void qkv_gemm_lds(
    const u16* __restrict__ Ah, const u16* __restrict__ Al, long a_fstride,
    int Wp, int Poff, const u16* __restrict__ Bh, const u16* __restrict__ Bl,
    const float* __restrict__ bias, const int* __restrict__ nmap,
    const int* __restrict__ dmap, int ohow, int Dd, int pp, int NtokPad,
    float scale, int mode, u16* __restrict__ tH, u16* __restrict__ tL) {
  __shared__ u16 AsH[256 * 32], AsL[256 * 32], BsH[64 * 32], BsL[64 * 32];
  int t = threadIdx.x;
  int lane = t & 63;
  int w = t >> 6;
  int l15 = lane & 15, l16 = lane >> 4;
  int row0 = blockIdx.x * 256;
  int frame = blockIdx.z;
  const u16* Afh = Ah + (long)frame * a_fstride;
  const u16* Afl = Al + (long)frame * a_fstride;

  int rs = t >> 2;
  int cs = (t & 3) * 8;
  long abase[4];
#pragma unroll
  for (int c = 0; c < 4; ++c) {
    int s = row0 + rs + 64 * c;
    if (s >= 4800) s = 4799;
    int yo = s / 160, xo = s - yo * 160;
    abase[c] = ((long)(yo + Poff) * Wp + (xo + Poff)) * 256 + cs;
  }
  long bbase = (long)rs * 256 + cs;
  int ldst = w * 512;

  f32x4 acc[4][4];
#pragma unroll
  for (int m = 0; m < 4; ++m)
#pragma unroll
    for (int n = 0; n < 4; ++n) acc[m][n] = (f32x4){0.f, 0.f, 0.f, 0.f};

  for (int ic0 = 0; ic0 < 256; ic0 += 32) {
#pragma unroll
    for (int c = 0; c < 4; ++c) {
      gload16(Afh + abase[c] + ic0, AsH + c * 2048 + ldst);
      gload16(Afl + abase[c] + ic0, AsL + c * 2048 + ldst);
    }
    gload16(Bh + bbase + ic0, BsH + ldst);
    gload16(Bl + bbase + ic0, BsL + ldst);
    __syncthreads();
    bf16x8 ah[4], al[4], bh[4], bl[4];
#pragma unroll
    for (int m = 0; m < 4; ++m) {
      int rrow = w * 64 + m * 16 + l15;
      ah[m] = *(const bf16x8*)(AsH + rrow * 32 + l16 * 8);
      al[m] = *(const bf16x8*)(AsL + rrow * 32 + l16 * 8);
    }
#pragma unroll
    for (int n = 0; n < 4; ++n) {
      int rcol = n * 16 + l15;
      bh[n] = *(const bf16x8*)(BsH + rcol * 32 + l16 * 8);
      bl[n] = *(const bf16x8*)(BsL + rcol * 32 + l16 * 8);
    }
#pragma unroll
    for (int m = 0; m < 4; ++m)
#pragma unroll
      for (int n = 0; n < 4; ++n) {
        acc[m][n] = MFMA(ah[m], bh[n], acc[m][n]);
        acc[m][n] = MFMA(ah[m], bl[n], acc[m][n]);
        acc[m][n] = MFMA(al[m], bh[n], acc[m][n]);
      }
    __syncthreads();
  }

#pragma unroll
  for (int m = 0; m < 4; ++m) {
#pragma unroll
    for (int r = 0; r < 4; ++r) {
      int s = row0 + w * 64 + m * 16 + l16 * 4 + r;
      if (s >= 4800) continue;
      int nm = nmap[s], dm = dmap[s];
      int ntok = frame * ohow + nm;
#pragma unroll
      for (int n = 0; n < 4; ++n) {
        int c = n * 16 + l15;
        float v = acc[m][n][r] + bias[c];
        if (mode == 0) v *= scale;
        int d = c * pp + dm;
        long off = (mode == 2) ? ((long)d * NtokPad + ntok)
                               : ((long)ntok * Dd + d);
        splitw(v, &tH[off], &tL[off]);
      }
    }
  }
}

// ---------------------------------------------------------------------------
// LDS-staged attention GEMM (tile 128x128, 256 thr). Used for QK (A,B split
// bf16 u16 buffers). mode 0: fp32 out.
// ---------------------------------------------------------------------------
__global__ __launch_bounds__(256) void attn_gemm_lds(
    const u16* __restrict__ Ah, const u16* __restrict__ Al, int lda, int Mrows,
    const u16* __restrict__ Bh, const u16* __restrict__ Bl, int ldb,
    int Nclamp, int Kpart, int Nvalid, int mode, float* outf, int ldo,
    long partstride, u16* __restrict__ Oh, u16* __restrict__ Ol,
    const int* __restrict__ rowbase, const int* __restrict__ doff) {
  __shared__ u16 AsH[128 * 32], AsL[128 * 32], BsH[128 * 32], BsL[128 * 32];
  int t = threadIdx.x;
  int lane = t & 63;
  int w = t >> 6;
  int wc = w & 1, wr = w >> 1;
  int l15 = lane & 15, l16 = lane >> 4;
  int row0 = blockIdx.x * 128;
  int col0 = blockIdx.y * 128;
  int kbase = blockIdx.z * Kpart;
  if (outf) outf += (long)blockIdx.z * partstride;

  int rs = t >> 2;
  int cs = (t & 3) * 8;
  long abase[2], bbase[2];
#pragma unroll
  for (int c = 0; c < 2; ++c) {
    int sr = row0 + rs + 64 * c;
    if (sr >= Mrows) sr = Mrows - 1;
    abase[c] = (long)sr * lda + cs;
    int cc = col0 + rs + 64 * c;
    if (cc >= Nclamp) cc = Nclamp - 1;
    bbase[c] = (long)cc * ldb + cs;
  }
  int ldst = w * 512;

  f32x4 acc[4][4];
#pragma unroll
  for (int m = 0; m < 4; ++m)
#pragma unroll
    for (int n = 0; n < 4; ++n) acc[m][n] = (f32x4){0.f, 0.f, 0.f, 0.f};

  for (int k = kbase; k < kbase + Kpart; k += 32) {
#pragma unroll
    for (int c = 0; c < 2; ++c) {
      gload16(Ah + abase[c] + k, AsH + c * 2048 + ldst);
      gload16(Al + abase[c] + k, AsL + c * 2048 + ldst);
      gload16(Bh + bbase[c] + k, BsH + c * 2048 + ldst);
      gload16(Bl + bbase[c] + k, BsL + c * 2048 + ldst);
    }
    __syncthreads();
    bf16x8 ah[4], al[4], bh[4], bl[4];
#pragma unroll
    for (int m = 0; m < 4; ++m) {
      int rrow = wr * 64 + m * 16 + l15;
      ah[m] = *(const bf16x8*)(AsH + rrow * 32 + l16 * 8);
      al[m] = *(const bf16x8*)(AsL + rrow * 32 + l16 * 8);
    }
#pragma unroll
    for (int n = 0; n < 4; ++n) {
      int rcol = wc * 64 + n * 16 + l15;
      bh[n] = *(const bf16x8*)(BsH + rcol * 32 + l16 * 8);
      bl[n] = *(const bf16x8*)(BsL + rcol * 32 + l16 * 8);
    }
#pragma unroll
    for (int m = 0; m < 4; ++m)
#pragma unroll
      for (int n = 0; n < 4; ++n) {
        acc[m][n] = MFMA(ah[m], bh[n], acc[m][n]);
        acc[m][n] = MFMA(ah[m], bl[n], acc[m][n]);
        acc[m][n] = MFMA(al[m], bh[n], acc[m][n]);
      }
    __syncthreads();
  }

#pragma unroll
  for (int m = 0; m < 4; ++m) {
#pragma unroll
    for (int r = 0; r < 4; ++r) {
      int sr = row0 + wr * 64 + m * 16 + l16 * 4 + r;
      if (sr >= Mrows) continue;
#pragma unroll
      for (int n = 0; n < 4; ++n) {
        int c = col0 + wc * 64 + n * 16 + l15;
        if (c >= Nvalid) continue;
        float v = acc[m][n][r];
        if (mode == 0) {
          outf[(long)sr * ldo + c] = v;
        } else {
          long off = (long)rowbase[sr] + doff[c];
          splitw(v, &Oh[off], &Ol[off]);
        }
      }
    }
  }
}

// ---------------------------------------------------------------------------
// PV GEMM: A = fp32 P rows (in-place softmax output), split to hi/lo bf16
// ON THE FLY (bit-identical to splitw). B = split V. Tile 128x128.
// mode 0: fp32 partials (split-K via z); mode 1: CL scatter via LUTs.
// ---------------------------------------------------------------------------
__global__ __launch_bounds__(256) void attn_pv_lds(
    const float* __restrict__ P, int lda, int Mrows,
    const u16* __restrict__ Bh, const u16* __restrict__ Bl, int ldb,
    int Nclamp, int Kpart, int Nvalid, int mode, float* outf, int ldo,
    long partstride, u16* __restrict__ Oh, u16* __restrict__ Ol,
    const int* __restrict__ rowbase, const int* __restrict__ doff) {
  __shared__ float Asf[128 * 32];              // 16KB fp32 A tile
  __shared__ u16 BsH[128 * 32], BsL[128 * 32]; // 8+8KB
  int t = threadIdx.x;
  int lane = t & 63;
  int w = t >> 6;
  int wc = w & 1, wr = w >> 1;
  int l15 = lane & 15, l16 = lane >> 4;
  int row0 = blockIdx.x * 128;
  int col0 = blockIdx.y * 128;
  int kbase = blockIdx.z * Kpart;
  if (outf) outf += (long)blockIdx.z * partstride;

  // A staging: slot s = t + 256*j ; row = s>>3, 16B-chunk = s&7 (4 f32)
  int arow = t >> 3;
  int acol = (t & 7) * 4;
  long abase[4];
#pragma unroll
  for (int j = 0; j < 4; ++j) {
    int r = row0 + arow + 32 * j;
    if (r >= Mrows) r = Mrows - 1;
    abase[j] = (long)r * lda + acol;
  }
  // B staging as in attn_gemm_lds
  int rs = t >> 2;
  int cs = (t & 3) * 8;
  long bbase[2];
#pragma unroll
  for (int c = 0; c < 2; ++c) {
    int cc = col0 + rs + 64 * c;
    if (cc >= Nclamp) cc = Nclamp - 1;
    bbase[c] = (long)cc * ldb + cs;
  }
  int ldst = w * 512;  // u16 units for B

  f32x4 acc[4][4];
#pragma unroll
  for (int m = 0; m < 4; ++m)
#pragma unroll
    for (int n = 0; n < 4; ++n) acc[m][n] = (f32x4){0.f, 0.f, 0.f, 0.f};

  for (int k = kbase; k < kbase + Kpart; k += 32) {
#pragma unroll
    for (int j = 0; j < 4; ++j)
      gload16(P + abase[j] + k, Asf + (w * 64 + 256 * j) * 4);
#pragma unroll
    for (int c = 0; c < 2; ++c) {
      gload16(Bh + bbase[c] + k, BsH + c * 2048 + ldst);
      gload16(Bl + bbase[c] + k, BsL + c * 2048 + ldst);
    }
    __syncthreads();
    bf16x8 ah[4], al[4], bh[4], bl[4];
#pragma unroll
    for (int m = 0; m < 4; ++m) {
      int rrow = wr * 64 + m * 16 + l15;
      const float* ap = Asf + rrow * 32 + l16 * 8;
      f32x4 p0 = *(const f32x4*)(ap);
      f32x4 p1 = *(const f32x4*)(ap + 4);
#pragma unroll
      for (int e = 0; e < 4; ++e) {
        float f0 = p0[e], f1 = p1[e];
        u16 h0 = f2bf(f0), h1 = f2bf(f1);
        ah[m][e] = (short)h0;
        ah[m][4 + e] = (short)h1;
        al[m][e] = (short)f2bf(f0 - bf2f(h0));
        al[m][4 + e] = (short)f2bf(f1 - bf2f(h1));
      }
    }
#pragma unroll
    for (int n = 0; n < 4; ++n) {
      int rcol = wc * 64 + n * 16 + l15;
      bh[n] = *(const bf16x8*)(BsH + rcol * 32 + l16 * 8);
      bl[n] = *(const bf16x8*)(BsL + rcol * 32 + l16 * 8);
    }
#pragma unroll
    for (int m = 0; m < 4; ++m)
#pragma unroll
      for (int n = 0; n < 4; ++n) {
        acc[m][n] = MFMA(ah[m], bh[n], acc[m][n]);
        acc[m][n] = MFMA(ah[m], bl[n], acc[m][n]);
        acc[m][n] = MFMA(al[m], bh[n], acc[m][n]);
      }
    __syncthreads();
  }

#pragma unroll
  for (int m = 0; m < 4; ++m) {
#pragma unroll
    for (int r = 0; r < 4; ++r) {
      int sr = row0 + wr * 64 + m * 16 + l16 * 4 + r;
      if (sr >= Mrows) continue;
#pragma unroll
      for (int n = 0; n < 4; ++n) {
        int c = col0 + wc * 64 + n * 16 + l15;
        if (c >= Nvalid) continue;
        float v = acc[m][n][r];
        if (mode == 0) {
          outf[(long)sr * ldo + c] = v;
        } else {
          long off = (long)rowbase[sr] + doff[c];
          splitw(v, &Oh[off], &Ol[off]);
        }
      }
    }
  }
}

// ---------------------------------------------------------------------------
__global__ __launch_bounds__(256) void reduce_scatter(
    const float* __restrict__ parts, int nparts, long pstride, int rows, int N,
    int mode, float* outf, u16* __restrict__ Oh, u16* __restrict__ Ol,
    const int* __restrict__ rowbase, const int* __restrict__ doff) {
  long gid = (long)blockIdx.x * 256 + threadIdx.x;
  long tot = (long)rows * N;
  if (gid >= tot) return;
  float s = 0.f;
  for (int p = 0; p < nparts; ++p) s += parts[p * pstride + gid];
  if (mode == 0) {
    outf[gid] = s;
  } else {
    int r = (int)(gid / N), c = (int)(gid % N);
    long off = (long)rowbase[r] + doff[c];
    splitw(s, &Oh[off], &Ol[off]);
  }
}

// ---------------------------------------------------------------------------
// In-place row softmax: row stride NtokPad, valid length Ntok. Writes fp32
// probabilities in place; zeroes pad columns [Ntok, NtokPad).
// ---------------------------------------------------------------------------
__global__ __launch_bounds__(256) void softmax_ip(float* __restrict__ S,
                                                  int Ntok, int NtokPad) {
  int row = blockIdx.x;
  float* p = S + (long)row * NtokPad;
  __shared__ float red[256];
  int t = threadIdx.x;
  float m = -1e30f;
  for (int i = t; i < Ntok; i += 256) m = fmaxf(m, p[i]);
  red[t] = m;
  __syncthreads();
  for (int s = 128; s > 0; s >>= 1) {
    if (t < s) red[t] = fmaxf(red[t], red[t + s]);
    __syncthreads();
  }
  m = red[0];
  __syncthreads();
  float sum = 0.f;
  for (int i = t; i < Ntok; i += 256) sum += __expf(p[i] - m);
  red[t] = sum;
  __syncthreads();
  for (int s = 128; s > 0; s >>= 1) {
    if (t < s) red[t] += red[t + s];
    __syncthreads();
  }
  float inv = 1.f / red[0];
  __syncthreads();
  for (int i = t; i < Ntok; i += 256) p[i] = __expf(p[i] - m) * inv;
  for (int i = Ntok + t; i < NtokPad; i += 256) p[i] = 0.f;
}

// ---------------------------------------------------------------------------
__global__ __launch_bounds__(256) void wt_build(const float* __restrict__ w,
                                                int Cout, int Cin, int taps,
                                                u16* __restrict__ Wh,
                                                u16* __restrict__ Wl) {
  long gid = (long)blockIdx.x * 256 + threadIdx.x;
  long tot = (long)taps * Cout * Cin;
  if (gid >= tot) return;
  int ic = (int)(gid % Cin);
  long r = gid / Cin;
  int oc = (int)(r % Cout);
  int tap = (int)(r / Cout);
  float v = w[((long)oc * Cin + ic) * taps + tap];
  splitw(v, &Wh[gid], &Wl[gid]);
}

// fused q/k/v 1x1 weight split build (one group of 64 out-channels)
__global__ __launch_bounds__(256) void wtqkv_build(
    const float* __restrict__ wq, const float* __restrict__ wk,
    const float* __restrict__ wv, int co, u16* __restrict__ qh,
    u16* __restrict__ ql, u16* __restrict__ kh, u16* __restrict__ kl,
    u16* __restrict__ vh, u16* __restrict__ vl) {
  int gid = blockIdx.x * 256 + threadIdx.x;
  if (gid >= 64 * 256) return;
  int ic = gid & 255, c = gid >> 8;
  long src = (long)(co + c) * 256 + ic;
  splitw(wq[src], &qh[gid], &ql[gid]);
  splitw(wk[src], &kh[gid], &kl[gid]);
  splitw(wv[src], &vh[gid], &vl[gid]);
}

// ---------------------------------------------------------------------------
__global__ __launch_bounds__(256) void maps_build(int ph, int pw, int ow,
                                                  int* __restrict__ nmap,
                                                  int* __restrict__ dmap) {
  int s = blockIdx.x * 256 + threadIdx.x;
  if (s >= 4800) return;
  int y = s / 160, x = s - y * 160;
  int i = y / ph, yy = y - i * ph;
  int j = x / pw, xx = x - j * pw;
  nmap[s] = i * ow + j;
  dmap[s] = yy * pw + xx;
}

__global__ __launch_bounds__(256) void luts_build(int ph, int pw, int ohow,
                                                  int ow, int pp, int Ntok,
                                                  int Dd, int gbase,
                                                  int* __restrict__ rowbase,
                                                  int* __restrict__ doff) {
  int gid = blockIdx.x * 256 + threadIdx.x;
  if (gid < Ntok) {
    int tt = gid / ohow, rem = gid - tt * ohow;
    int i = rem / ow, j = rem - i * ow;
    rowbase[gid] =
        tt * (32 * 162 * 256) + ((i * ph + 1) * 162 + (j * pw + 1)) * 256;
  }
  if (gid < Dd) {
    int c = gid / pp, rr = gid - c * pp;
    int yy = rr / pw, xx = rr - yy * pw;
    doff[gid] = (yy * 162 + xx) * 256 + gbase + c;
  }
}

// ---------------------------------------------------------------------------
// Bilinear x2 upsample (align_corners) CL hi/lo -> CL hi/lo. Writes the FULL
// padded output (zeros in halo) so overlaid buffers are re-cleaned per frame.
// ---------------------------------------------------------------------------
__global__ __launch_bounds__(256) void up_cl2cl_pad(
    const u16* __restrict__ sh, const u16* __restrict__ sl,
    u16* __restrict__ oh, u16* __restrict__ ol, int C, int H, int W, int Wps,
    int Poffs, int Hp, int Wpo, int Poffo) {
  int Ho = 2 * H, Wo = 2 * W;
  long tot = (long)Hp * Wpo * C;
  long gid = (long)blockIdx.x * 256 + threadIdx.x;
  if (gid >= tot) return;
  int c = (int)(gid % C);
  long r = gid / C;
  int xp = (int)(r % Wpo);
  int yp = (int)(r / Wpo);
  int x = xp - Poffo, y = yp - Poffo;
  float v = 0.f;
  if ((unsigned)x < (unsigned)Wo && (unsigned)y < (unsigned)Ho) {
    float fy = (float)(y * (H - 1)) / (float)(Ho - 1);
    float fx = (float)(x * (W - 1)) / (float)(Wo - 1);
    int y0 = (int)fy, x0 = (int)fx;
    int y1 = min(y0 + 1, H - 1), x1 = min(x0 + 1, W - 1);
    float wy = fy - y0, wx = fx - x0;
    auto rd = [&](int cy, int cx) {
      long o = ((long)(cy + Poffs) * Wps + (cx + Poffs)) * C + c;
      return bf2f(sh[o]) + bf2f(sl[o]);
    };
    float r0 = rd(y0, x0) * (1.f - wx) + rd(y0, x1) * wx;
    float r1 = rd(y1, x0) * (1.f - wx) + rd(y1, x1) * wx;
    v = r0 * (1.f - wy) + r1 * wy;
  }
  splitw(v, &oh[gid], &ol[gid]);
}

// ---------------------------------------------------------------------------
extern "C" void kernel_launch(void* const* d_in, const int* in_sizes, int n_in,
                              void* d_out, int out_size, void* d_ws,
                              size_t ws_size, hipStream_t stream) {
  const float* input = (const float*)d_in[0];
  const float* enc_w0 = (const float*)d_in[1];
  const float* enc_b0 = (const float*)d_in[2];
  const float* enc_w1 = (const float*)d_in[3];
  const float* enc_b1 = (const float*)d_in[4];
  const float* enc_w2 = (const float*)d_in[5];
  const float* enc_b2 = (const float*)d_in[6];
  const float* enc_w3 = (const float*)d_in[7];
  const float* enc_b3 = (const float*)d_in[8];
  const float* tq_w = (const float*)d_in[9];
  const float* tq_b = (const float*)d_in[10];
  const float* tk_w = (const float*)d_in[11];
  const float* tk_b = (const float*)d_in[12];
  const float* tv_w = (const float*)d_in[13];
  const float* tv_b = (const float*)d_in[14];
  const float* to_w = (const float*)d_in[15];
  const float* to_b = (const float*)d_in[16];
  const float* tf1_w = (const float*)d_in[17];
  const float* tf1_b = (const float*)d_in[18];
  const float* tf2_w = (const float*)d_in[19];
  const float* tf2_b = (const float*)d_in[20];
  const float* d0_w = (const float*)d_in[21];
  const float* d0_b = (const float*)d_in[22];
  const float* d1_w = (const float*)d_in[23];
  const float* d1_b = (const float*)d_in[24];
  const float* d2_w = (const float*)d_in[25];
  const float* d2_b = (const float*)d_in[26];
  const float* d3_w = (const float*)d_in[27];
  const float* d3_b = (const float*)d_in[28];
  float* out = (float*)d_out;

  // -------- workspace layout --------
  unsigned char* wsb = (unsigned char*)d_ws;
  size_t off = 0;
  auto alloc = [&](size_t bytes) {
    void* p = wsb + off;
    off = (off + bytes + 255) & ~(size_t)255;
    return p;
  };
  const long XCL_E = 22839296L;   // 16*34*164*256
  const long XCL2_E = 21233664L;  // 16*32*162*256
  const long QT_E = 4915200L;
  const long VT_E = 5111808L;
  u16* XCLh = (u16*)alloc(XCL_E * 2);
  u16* XCLl = (u16*)alloc(XCL_E * 2);
  u16* XCL2h = (u16*)alloc(XCL2_E * 2);
  u16* XCL2l = (u16*)alloc(XCL2_E * 2);
  u16* qth = (u16*)alloc(QT_E * 2);
  u16* qtl = (u16*)alloc(QT_E * 2);
  u16* kth = (u16*)alloc(QT_E * 2);
  u16* ktl = (u16*)alloc(QT_E * 2);
  u16* vth = (u16*)alloc(VT_E * 2);
  u16* vtl = (u16*)alloc(VT_E * 2);
  int* nmapA = (int*)alloc(4 * 4800 * 4);
  int* dmapA = (int*)alloc(4 * 4800 * 4);
  int* rowbaseA = (int*)alloc(7120 * 4);
  int* doffA = (int*)alloc(93248 * 4);
  u16* qwh = (u16*)alloc(16384 * 2);
  u16* qwl = (u16*)alloc(16384 * 2);
  u16* kwh = (u16*)alloc(16384 * 2);
  u16* kwl = (u16*)alloc(16384 * 2);
  u16* vwh = (u16*)alloc(16384 * 2);
  u16* vwl = (u16*)alloc(16384 * 2);
  // scores region (allocated LAST): holds fp32 scores/P in place (+ g3
  // split-K partials). P no longer has separate bf16 hi/lo buffers.
  size_t fixed_end = off;
  size_t avail = ws_size > fixed_end ? ws_size - fixed_end : 0;
  size_t SCB = avail > 4096 ? avail - 4096 : 0;
  if (SCB > 104857600UL) SCB = 104857600UL;
  float* scores = (float*)alloc(SCB);
  size_t need = off;
  if (ws_size < need) return;        // fail loud, not crash
  long SCAPf = (long)(SCB / 4);
  if (SCAPf < 1400000) return;       // ~5.6 MB minimum (weights + g0)

  // trunk conv weights overlay the scores region (disjoint lifetimes)
  u16* Wth = (u16*)scores;
  u16* Wtl = Wth + 589824;

  // ---- decoder buffers: overlay XCL2 + token region (dead in decoder) ----
  unsigned char* decbase = (unsigned char*)XCL2h;
  u16* dec0inH = (u16*)(decbase + 0);
  u16* dec0inL = (u16*)(decbase + 20443136);
  u16* dec0outH = (u16*)(decbase + 40886272);
  u16* dec0outL = (u16*)(decbase + 51107840);
  u16* dec1outH = (u16*)(decbase + 61329408);
  u16* dec1outL = (u16*)(decbase + 66440192);
  u16* dec2inH = (u16*)(decbase + 71550976);
  u16* dec2inL = (u16*)(decbase + 91601920);
  float* dec2out = (float*)(decbase + 0);
  // decoder weights parked past the decoder buffers (region ends ~144.7MB)
  u16* Wd0h = (u16*)(decbase + 111652864);
  u16* Wd0l = Wd0h + 294912;
  u16* W1h = Wd0l + 294912;
  u16* W1l = W1h + 73728;
  u16* W2h = W1l + 73728;
  u16* W2l = W2h + 36864;
  const long D0IN_FS = 5110784, D0OUT_FS = 2555392, D1OUT_FS = 1277696;
  const long D2IN_FS = 5012736, D2OUT_FS = 4915200;

  const long FS_TR = 1427456;  // 34*164*256
  const long FS_T2 = 1327104;  // 32*162*256 == 64*324*64
  const long FS_E2 = 713728;   // 34*164*128

  static const int PWa[4] = {80, 32, 10, 5};
  static const int PHa[4] = {15, 6, 5, 3};
  static const int rbOff[4] = {0, 64, 464, 2000};
  static const int doOff[4] = {0, 76800, 89088, 92288};

  // -------- encoder --------
  hipMemsetAsync(XCLh, 0, XCL_E * 2, stream);
  hipMemsetAsync(XCLl, 0, XCL_E * 2, stream);
  hipMemsetAsync(XCL2h, 0, XCL2_E * 2, stream);
  hipMemsetAsync(XCL2l, 0, XCL2_E * 2, stream);
  hipMemsetAsync(vth, 0, VT_E * 2, stream);  // pad-column zero guard
  hipMemsetAsync(vtl, 0, VT_E * 2, stream);
  {  // enc0: fp32 direct -> CL [64][324][64] Poff2 in XCL2 space
    long tot = 16L * 64 * 60 * 40;
    conv2d_k<3, 2, 1><<<cdivu(tot, 256), 256, 0, stream>>>(
        input, enc_w0, enc_b0, nullptr, XCL2h, XCL2l, 324, 2, FS_T2, 16, 3,
        120, 640, 64, 60, 320, 1, ACT_LEAKY);
  }
  {  // enc1: 64->64, 60x320 (tile 256x64)
    wt_build<<<cdivu(9L * 64 * 64, 256), 256, 0, stream>>>(enc_w1, 64, 64, 9,
                                                           Wth, Wtl);
    conv_gemm_lds<4, 1><<<dim3(75, 1, 16), 256, 0, stream>>>(
        XCL2h, XCL2l, Wth, Wtl, enc_b1, 64, 64, 60, 320, 324, 2, 1, 1, 1, 9,
        FS_T2, ACT_LEAKY, nullptr, 0, XCLh, XCLl, FS_T2, 324, 2, 0);
  }
  hipMemsetAsync(XCL2h, 0, XCL2_E * 2, stream);
  hipMemsetAsync(XCL2l, 0, XCL2_E * 2, stream);
  {  // enc2: 64->128 stride2 -> CL [34][164][128] in XCL2 space
    wt_build<<<cdivu(9L * 128 * 64, 256), 256, 0, stream>>>(enc_w2, 128, 64, 9,
                                                            Wth, Wtl);
    conv_gemm_lds<2, 2><<<dim3(38, 1, 16), 256, 0, stream>>>(
        XCLh, XCLl, Wth, Wtl, enc_b2, 64, 128, 30, 160, 324, 2, 2, 1, 1, 9,
        FS_T2, ACT_LEAKY, nullptr, 0, XCL2h, XCL2l, FS_E2, 164, 2, 0);
  }
  hipMemsetAsync(XCLh, 0, XCL_E * 2, stream);
  hipMemsetAsync(XCLl, 0, XCL_E * 2, stream);
  {  // enc3: 128->256 -> trunk XCL [34][164][256]
    wt_build<<<cdivu(9L * 256 * 128, 256), 256, 0, stream>>>(enc_w3, 256, 128,
                                                             9, Wth, Wtl);
    conv_gemm_lds<2, 2><<<dim3(38, 2, 16), 256, 0, stream>>>(
        XCL2h, XCL2l, Wth, Wtl, enc_b3, 128, 256, 30, 160, 164, 2, 1, 1, 1, 9,
        FS_E2, ACT_LEAKY, nullptr, 0, XCLh, XCLl, FS_TR, 164, 2, 0);
  }
  hipMemsetAsync(XCL2h, 0, XCL2_E * 2, stream);
  hipMemsetAsync(XCL2l, 0, XCL2_E * 2, stream);

  // -------- token maps / scatter LUTs --------
  for (int g = 0; g < 4; ++g) {
    int ph = PHa[g], pw = PWa[g];
    int ohh = 30 / ph, oww = 160 / pw;
    int Ntok = 16 * ohh * oww, Dd = 64 * ph * pw, pp = ph * pw;
    maps_build<<<19, 256, 0, stream>>>(ph, pw, oww, nmapA + g * 4800,
                                       dmapA + g * 4800);
    int mx = Ntok > Dd ? Ntok : Dd;
    luts_build<<<cdivu(mx, 256), 256, 0, stream>>>(
        ph, pw, ohh * oww, oww, pp, Ntok, Dd, g * 64, rowbaseA + rbOff[g],
        doffA + doOff[g]);
  }

  // -------- transformer stack --------
  for (int l = 0; l < 8; ++l) {
    for (int g = 0; g < 4; ++g) {
      int ph = PHa[g], pw = PWa[g];
      int ohh = 30 / ph, oww = 160 / pw;
      int ohow = ohh * oww;
      int Ntok = 16 * ohow, Dd = 64 * ph * pw, pp = ph * pw;
      int NtokPad = (Ntok + 31) & ~31;
      float scale = 1.0f / sqrtf((float)Dd);
      const int* nmap = nmapA + g * 4800;
      const int* dmap = dmapA + g * 4800;
      const int* rowbase = rowbaseA + rbOff[g];
      const int* doffp = doffA + doOff[g];

      wtqkv_build<<<64, 256, 0, stream>>>(
          tq_w + (long)l * 65536, tk_w + (long)l * 65536,
          tv_w + (long)l * 65536, g * 64, qwh, qwl, kwh, kwl, vwh, vwl);
      qkv_gemm_lds<<<dim3(19, 1, 16), 256, 0, stream>>>(
          XCLh, XCLl, FS_TR, 164, 2, qwh, qwl, tq_b + l * 256 + g * 64, nmap,
          dmap, ohow, Dd, pp, NtokPad, scale, 0, qth, qtl);
      qkv_gemm_lds<<<dim3(19, 1, 16), 256, 0, stream>>>(
          XCLh, XCLl, FS_TR, 164, 2, kwh, kwl, tk_b + l * 256 + g * 64, nmap,
          dmap, ohow, Dd, pp, NtokPad, 1.f, 1, kth, ktl);
      qkv_gemm_lds<<<dim3(19, 1, 16), 256, 0, stream>>>(
          XCLh, XCLl, FS_TR, 164, 2, vwh, vwl, tv_b + l * 256 + g * 64, nmap,
          dmap, ohow, Dd, pp, NtokPad, 1.f, 2, vth, vtl);

      if (g == 0) {
        // QK split-K: 32 parts of K=2400 -> partials -> reduce -> softmax
        float* scoresR = scores + 131072;
        attn_gemm_lds<<<dim3(1, 1, 32), 256, 0, stream>>>(
            qth, qtl, Dd, 64, kth, ktl, Dd, 64, 2400, 64, 0, scores, 64, 4096,
            nullptr, nullptr, nullptr, nullptr);
        reduce_scatter<<<16, 256, 0, stream>>>(scores, 32, 4096, 64, 64, 0,
                                               scoresR, nullptr, nullptr,
                                               nullptr, nullptr);
        softmax_ip<<<64, 256, 0, stream>>>(scoresR, 64, 64);
        attn_pv_lds<<<dim3(1, 600, 1), 256, 0, stream>>>(
            scoresR, 64, 64, vth, vtl, 64, Dd, 64, Dd, 1, nullptr, 0, 0,
            XCL2h, XCL2l, rowbase, doffp);
      } else {
        // chunk rows bounded by scores capacity (P row = NtokPad f32;
        // g3 additionally needs 4*960 f32/row of split-K partials)
        long denom = (long)NtokPad + (g == 3 ? 3840 : 0);
        long cap = (SCAPf / denom) & ~127L;
        int chunk = (int)(cap < 128 ? 128 : cap);
        if (chunk > Ntok) chunk = Ntok;
        float* partials = scores + (long)chunk * NtokPad;
        for (int r0 = 0; r0 < Ntok; r0 += chunk) {
          int rows = Ntok - r0 < chunk ? Ntok - r0 : chunk;
          attn_gemm_lds<<<dim3(cdivu(rows, 128), cdivu(Ntok, 128), 1), 256, 0,
                          stream>>>(qth + (long)r0 * Dd, qtl + (long)r0 * Dd,
                                    Dd, rows, kth, ktl, Dd, Ntok, Dd, Ntok, 0,
                                    scores, NtokPad, 0, nullptr, nullptr,
                                    nullptr, nullptr);
          softmax_ip<<<rows, 256, 0, stream>>>(scores, Ntok, NtokPad);
          if (g == 3) {
            attn_pv_lds<<<dim3(cdivu(rows, 128), 8, 4), 256, 0, stream>>>(
                scores, NtokPad, rows, vth, vtl, NtokPad, Dd, 1280, Dd, 0,
                partials, 960, (long)rows * 960, nullptr, nullptr, nullptr,
                nullptr);
            reduce_scatter<<<cdivu((long)rows * 960, 256), 256, 0, stream>>>(
                partials, 4, (long)rows * 960, rows, 960, 1, nullptr, XCL2h,
                XCL2l, rowbase + r0, doffp);
          } else {
            attn_pv_lds<<<dim3(cdivu(rows, 128), Dd / 128, 1), 256, 0,
                          stream>>>(scores, NtokPad, rows, vth, vtl, NtokPad,
                                    Dd, NtokPad, Dd, 1, nullptr, 0, 0, XCL2h,
                                    XCL2l, rowbase + r0, doffp);
          }
        }
      }
    }

    // out-conv 3x3 + leaky + residual (in-place on XCL)
    wt_build<<<cdivu(9L * 256 * 256, 256), 256, 0, stream>>>(
        to_w + (long)l * 589824, 256, 256, 9, Wth, Wtl);
    conv_gemm_lds<2, 2><<<dim3(38, 2, 16), 256, 0, stream>>>(
        XCL2h, XCL2l, Wth, Wtl, to_b + l * 256, 256, 256, 30, 160, 162, 1, 1,
        1, 1, 9, FS_T2, ACT_LEAKY, nullptr, 0, XCLh, XCLl, FS_TR, 164, 2, 1);
    // ff1: dil2 pad2
    wt_build<<<cdivu(9L * 256 * 256, 256), 256, 0, stream>>>(
        tf1_w + (long)l * 589824, 256, 256, 9, Wth, Wtl);
    conv_gemm_lds<2, 2><<<dim3(38, 2, 16), 256, 0, stream>>>(
        XCLh, XCLl, Wth, Wtl, tf1_b + l * 256, 256, 256, 30, 160, 164, 2, 1, 2,
        2, 9, FS_TR, ACT_LEAKY, nullptr, 0, XCL2h, XCL2l, FS_T2, 162, 1, 0);
    // ff2 + residual (in-place on XCL)
    wt_build<<<cdivu(9L * 256 * 256, 256), 256, 0, stream>>>(
        tf2_w + (long)l * 589824, 256, 256, 9, Wth, Wtl);
    conv_gemm_lds<2, 2><<<dim3(38, 2, 16), 256, 0, stream>>>(
        XCL2h, XCL2l, Wth, Wtl, tf2_b + l * 256, 256, 256, 30, 160, 162, 1, 1,
        1, 1, 9, FS_T2, ACT_LEAKY, nullptr, 0, XCLh, XCLl, FS_TR, 164, 2, 1);
  }

  // -------- decoder (2-frame groups; overlays XCL2+token region) --------
  hipMemsetAsync(decbase, 0, 111652864, stream);
  wt_build<<<cdivu(9L * 128 * 256, 256), 256, 0, stream>>>(d0_w, 128, 256, 9,
                                                           Wd0h, Wd0l);
  wt_build<<<cdivu(9L * 64 * 128, 256), 256, 0, stream>>>(d1_w, 64, 128, 9,
                                                          W1h, W1l);
  wt_build<<<cdivu(9L * 64 * 64, 256), 256, 0, stream>>>(d2_w, 64, 64, 9, W2h,
                                                         W2l);
  for (int f = 0; f < 16; f += 2) {
    for (int ff = 0; ff < 2; ++ff)
      up_cl2cl_pad<<<cdivu(62L * 322 * 256, 256), 256, 0, stream>>>(
          XCLh + (long)(f + ff) * FS_TR, XCLl + (long)(f + ff) * FS_TR,
          dec0inH + (long)ff * D0IN_FS, dec0inL + (long)ff * D0IN_FS, 256, 30,
          160, 164, 2, 62, 322, 1);
    conv_gemm_lds<2, 2><<<dim3(150, 1, 2), 256, 0, stream>>>(
        dec0inH, dec0inL, Wd0h, Wd0l, d0_b, 256, 128, 60, 320, 322, 1, 1, 1, 1,
        9, D0IN_FS, ACT_LEAKY, nullptr, 0, dec0outH, dec0outL, D0OUT_FS, 322,
        1, 0);
    conv_gemm_lds<4, 1><<<dim3(75, 1, 2), 256, 0, stream>>>(
        dec0outH, dec0outL, W1h, W1l, d1_b, 128, 64, 60, 320, 322, 1, 1, 1, 1,
        9, D0OUT_FS, ACT_LEAKY, nullptr, 0, dec1outH, dec1outL, D1OUT_FS, 322,
        1, 0);
    for (int ff = 0; ff < 2; ++ff)
      up_cl2cl_pad<<<cdivu(122L * 642 * 64, 256), 256, 0, stream>>>(
          dec1outH + (long)ff * D1OUT_FS, dec1outL + (long)ff * D1OUT_FS,
          dec2inH + (long)ff * D2IN_FS, dec2inL + (long)ff * D2IN_FS, 64, 60,
          320, 322, 1, 122, 642, 1);
    conv_gemm_lds<4, 1><<<dim3(300, 1, 2), 256, 0, stream>>>(
        dec2inH, dec2inL, W2h, W2l, d2_b, 64, 64, 120, 640, 642, 1, 1, 1, 1, 9,
        D2IN_FS, ACT_LEAKY, dec2out, D2OUT_FS, nullptr, nullptr, 0, 0, 0, 0);
    {
      long tot = 2L * 3 * 120 * 80;
      conv2d_k<3, 1, 1><<<cdivu(tot, 256), 256, 0, stream>>>(
          dec2out, d3_w, d3_b, out + (long)f * 230400, nullptr, nullptr, 0, 0,
          0, 2, 64, 120, 640, 3, 120, 640, 1, ACT_TANH);
    }
  }
}

// Round 10
// 37690.918 us; speedup vs baseline: 27.2136x; 1.0081x over previous
//
#include <hip/hip_runtime.h>
#include <hip/hip_bf16.h>
#include <math.h>

#define ACT_NONE 0
#define ACT_LEAKY 1
#define ACT_TANH 2

typedef __attribute__((ext_vector_type(8))) short bf16x8;
typedef __attribute__((ext_vector_type(4))) float f32x4;
typedef unsigned short u16;

#define MFMA(a, b, c) __builtin_amdgcn_mfma_f32_16x16x32_bf16((bf16x8)(a), (bf16x8)(b), (c), 0, 0, 0)

static inline unsigned cdivu(long a, long b) { return (unsigned)((a + b - 1) / b); }

__device__ __forceinline__ u16 f2bf(float x) {
  union { __hip_bfloat16 h; u16 u; } cv;
  cv.h = __float2bfloat16(x);
  return cv.u;
}
__device__ __forceinline__ float bf2f(u16 b) {
  union { u16 u; __hip_bfloat16 h; } cv;
  cv.u = b;
  return __bfloat162float(cv.h);
}
__device__ __forceinline__ void splitw(float v, u16* ph, u16* pl) {
  u16 h = f2bf(v);
  *ph = h;
  *pl = f2bf(v - bf2f(h));
}
// async global->LDS, 16B per lane; dest must be wave-uniform base (+lane*16)
__device__ __forceinline__ void gload16(const void* g, void* l) {
  __builtin_amdgcn_global_load_lds(
      (const __attribute__((address_space(1))) unsigned int*)g,
      (__attribute__((address_space(3))) unsigned int*)l, 16, 0, 0);
}

// ---------------------------------------------------------------------------
// Direct fp32 conv (enc0: Cin=3; d3: Cout=3+tanh). Optional CL hi/lo output.
// ---------------------------------------------------------------------------
template <int K, int S, int DIL>
__global__ __launch_bounds__(256) void conv2d_k(
    const float* __restrict__ x, const float* __restrict__ w,
    const float* __restrict__ bias, float* y, u16* clh, u16* cll, int WpO,
    int PoffO, long o_fstride, int N, int Cin, int Hin, int Win, int Cout,
    int Hout, int Wout, int pad, int act) {
  constexpr int TW = 8;
  constexpr int XL = (TW - 1) * S + (K - 1) * DIL + 1;
  int wq = (Wout + TW - 1) / TW;
  long gid = (long)blockIdx.x * 256 + threadIdx.x;
  long total = (long)N * Cout * Hout * wq;
  if (gid >= total) return;
  int xg = (int)(gid % wq);
  long r = gid / wq;
  int yo = (int)(r % Hout);
  r /= Hout;
  int oc = (int)(r % Cout);
  int n = (int)(r / Cout);

  float bv = bias[oc];
  float acc[TW];
#pragma unroll
  for (int j = 0; j < TW; ++j) acc[j] = bv;

  int xo0 = xg * TW;
  int xi0 = xo0 * S - pad;
  const float* xn = x + (long)n * Cin * Hin * Win;
  const float* wb = w + (long)oc * Cin * K * K;

  for (int ic = 0; ic < Cin; ++ic) {
    const float* xc = xn + (long)ic * Hin * Win;
    const float* wc = wb + ic * (K * K);
#pragma unroll
    for (int ky = 0; ky < K; ++ky) {
      int yi = yo * S - pad + ky * DIL;
      if ((unsigned)yi < (unsigned)Hin) {
        const float* row = xc + (long)yi * Win;
        float xr[XL];
#pragma unroll
        for (int i2 = 0; i2 < XL; ++i2) {
          int xi = xi0 + i2;
          xr[i2] = ((unsigned)xi < (unsigned)Win) ? row[xi] : 0.f;
        }
#pragma unroll
        for (int kx = 0; kx < K; ++kx) {
          float wv = wc[ky * K + kx];
#pragma unroll
          for (int j = 0; j < TW; ++j)
            acc[j] = fmaf(wv, xr[j * S + kx * DIL], acc[j]);
        }
      }
    }
  }

#pragma unroll
  for (int j = 0; j < TW; ++j) {
    if (xo0 + j < Wout) {
      float v = acc[j];
      if (act == ACT_LEAKY)
        v = v >= 0.f ? v : 0.2f * v;
      else if (act == ACT_TANH)
        v = tanhf(v);
      if (y) y[(((long)n * Cout + oc) * Hout + yo) * Wout + xo0 + j] = v;
      if (clh) {
        long off = (long)n * o_fstride +
                   ((long)(yo + PoffO) * WpO + (xo0 + j + PoffO)) * Cout + oc;
        splitw(v, &clh[off], &cll[off]);
      }
    }
  }
}

// ---------------------------------------------------------------------------
// LDS-staged MFMA implicit-GEMM conv (m97 2-barrier structure).
// B fragments loaded per-n inside the loop (low VGPR -> higher occupancy).
// ---------------------------------------------------------------------------
template <int WM, int WN>
__global__ __launch_bounds__(256) void conv_gemm_lds(
    const u16* __restrict__ Ah, const u16* __restrict__ Al,
    const u16* __restrict__ Bh, const u16* __restrict__ Bl,
    const float* __restrict__ bias, int Cin, int Cout, int Hout, int Wout,
    int Wp, int Poff, int S, int DIL, int pad, int taps, long a_fstride,
    int act, float* yout, long y_fstride, u16* Oh, u16* Ol, long o_fstride,
    int WpO, int PoffO, int useres) {
  constexpr int TM = WM * 64, TN = WN * 64;
  __shared__ u16 AsH[TM * 32], AsL[TM * 32], BsH[TN * 32], BsL[TN * 32];
  int t = threadIdx.x;
  int lane = t & 63;
  int w = t >> 6;
  int wr = w / WN, wc = w % WN;
  int l15 = lane & 15, l16 = lane >> 4;
  int HW = Hout * Wout;
  int row0 = blockIdx.x * TM;
  int col0 = blockIdx.y * TN;
  const u16* Afh = Ah + (long)blockIdx.z * a_fstride;
  const u16* Afl = Al + (long)blockIdx.z * a_fstride;

  int rs = t >> 2;
  int cs = (t & 3) * 8;
  long abase[WM];
#pragma unroll
  for (int c = 0; c < WM; ++c) {
    int s = row0 + rs + 64 * c;
    if (s >= HW) s = HW - 1;
    int yo = s / Wout, xo = s - yo * Wout;
    int yb = yo * S - pad + Poff, xb = xo * S - pad + Poff;
    abase[c] = ((long)yb * Wp + xb) * Cin + cs;
  }
  long bbase[WN];
#pragma unroll
  for (int c = 0; c < WN; ++c)
    bbase[c] = (long)(col0 + rs + 64 * c) * Cin + cs;
  int ldst = w * 512;

  f32x4 acc[4][4];
#pragma unroll
  for (int m = 0; m < 4; ++m)
#pragma unroll
    for (int n = 0; n < 4; ++n) acc[m][n] = (f32x4){0.f, 0.f, 0.f, 0.f};

  for (int tap = 0; tap < taps; ++tap) {
    int ky = tap / 3, kx = tap - ky * 3;
    long atap = ((long)ky * DIL * Wp + kx * DIL) * Cin;
    long btap = (long)tap * Cout * Cin;
    for (int ic0 = 0; ic0 < Cin; ic0 += 32) {
#pragma unroll
      for (int c = 0; c < WM; ++c) {
        gload16(Afh + abase[c] + atap + ic0, AsH + c * 2048 + ldst);
        gload16(Afl + abase[c] + atap + ic0, AsL + c * 2048 + ldst);
      }
#pragma unroll
      for (int c = 0; c < WN; ++c) {
        gload16(Bh + bbase[c] + btap + ic0, BsH + c * 2048 + ldst);
        gload16(Bl + bbase[c] + btap + ic0, BsL + c * 2048 + ldst);
      }
      __syncthreads();
      bf16x8 ah[4], al[4];
#pragma unroll
      for (int m = 0; m < 4; ++m) {
        int rrow = wr * 64 + m * 16 + l15;
        ah[m] = *(const bf16x8*)(AsH + rrow * 32 + l16 * 8);
        al[m] = *(const bf16x8*)(AsL + rrow * 32 + l16 * 8);
      }
#pragma unroll
      for (int n = 0; n < 4; ++n) {
        int rcol = wc * 64 + n * 16 + l15;
        bf16x8 bh = *(const bf16x8*)(BsH + rcol * 32 + l16 * 8);
        bf16x8 bl = *(const bf16x8*)(BsL + rcol * 32 + l16 * 8);
#pragma unroll
        for (int m = 0; m < 4; ++m) {
          acc[m][n] = MFMA(ah[m], bh, acc[m][n]);
          acc[m][n] = MFMA(ah[m], bl, acc[m][n]);
          acc[m][n] = MFMA(al[m], bh, acc[m][n]);
        }
      }
      __syncthreads();
    }
  }

  float* yf = yout ? yout + (long)blockIdx.z * y_fstride : nullptr;
  u16* Ofh = Oh ? Oh + (long)blockIdx.z * o_fstride : nullptr;
  u16* Ofl = Ol ? Ol + (long)blockIdx.z * o_fstride : nullptr;
#pragma unroll
  for (int m = 0; m < 4; ++m) {
#pragma unroll
    for (int r = 0; r < 4; ++r) {
      int s = row0 + wr * 64 + m * 16 + l16 * 4 + r;
      if (s >= HW) continue;
      int yo = s / Wout, xo = s - yo * Wout;
      long clbase = 0;
      if (Ofh) clbase = ((long)(yo + PoffO) * WpO + (xo + PoffO)) * Cout;
#pragma unroll
      for (int n = 0; n < 4; ++n) {
        int oc = col0 + wc * 64 + n * 16 + l15;
        float v = acc[m][n][r] + bias[oc];
        if (act == ACT_LEAKY) v = v >= 0.f ? v : 0.2f * v;
        if (Ofh) {
          long off = clbase + oc;
          if (useres) v += bf2f(Ofh[off]) + bf2f(Ofl[off]);
          splitw(v, &Ofh[off], &Ofl[off]);
        }
        if (yf) yf[((long)oc * Hout + yo) * Wout + xo] = v;
      }
    }
  }
}

// ---------------------------------------------------------------------------
// LDS-staged QKV 1x1 GEMM. Tile 256x64, 4 waves. Token-layout scatter.
// ---------------------------------------------------------------------------
__global__ __launch_bounds__(256) void qkv_gemm_lds(
    const u16* __restrict__ Ah, const u16* __restrict__ Al, long a_fstride,
    int Wp, int Poff, const u16* __restrict__ Bh, const u16* __restrict__ Bl,
    const float* __restrict__ bias, const int* __restrict__ nmap,
    const int* __restrict__ dmap, int ohow, int Dd, int pp, int NtokPad,
    float scale, int mode, u16* __restrict__ tH, u16* __restrict__ tL) {
  __shared__ u16 AsH[256 * 32], AsL[256 * 32], BsH[64 * 32], BsL[64 * 32];
  int t = threadIdx.x;
  int lane = t & 63;
  int w = t >> 6;
  int l15 = lane & 15, l16 = lane >> 4;
  int row0 = blockIdx.x * 256;
  int frame = blockIdx.z;
  const u16* Afh = Ah + (long)frame * a_fstride;
  const u16* Afl = Al + (long)frame * a_fstride;

  int rs = t >> 2;
  int cs = (t & 3) * 8;
  long abase[4];
#pragma unroll
  for (int c = 0; c < 4; ++c) {
    int s = row0 + rs + 64 * c;
    if (s >= 4800) s = 4799;
    int yo = s / 160, xo = s - yo * 160;
    abase[c] = ((long)(yo + Poff) * Wp + (xo + Poff)) * 256 + cs;
  }
  long bbase = (long)rs * 256 + cs;
  int ldst = w * 512;

  f32x4 acc[4][4];
#pragma unroll
  for (int m = 0; m < 4; ++m)
#pragma unroll
    for (int n = 0; n < 4; ++n) acc[m][n] = (f32x4){0.f, 0.f, 0.f, 0.f};

  for (int ic0 = 0; ic0 < 256; ic0 += 32) {
#pragma unroll
    for (int c = 0; c < 4; ++c) {
      gload16(Afh + abase[c] + ic0, AsH + c * 2048 + ldst);
      gload16(Afl + abase[c] + ic0, AsL + c * 2048 + ldst);
    }
    gload16(Bh + bbase + ic0, BsH + ldst);
    gload16(Bl + bbase + ic0, BsL + ldst);
    __syncthreads();
    bf16x8 ah[4], al[4];
#pragma unroll
    for (int m = 0; m < 4; ++m) {
      int rrow = w * 64 + m * 16 + l15;
      ah[m] = *(const bf16x8*)(AsH + rrow * 32 + l16 * 8);
      al[m] = *(const bf16x8*)(AsL + rrow * 32 + l16 * 8);
    }
#pragma unroll
    for (int n = 0; n < 4; ++n) {
      int rcol = n * 16 + l15;
      bf16x8 bh = *(const bf16x8*)(BsH + rcol * 32 + l16 * 8);
      bf16x8 bl = *(const bf16x8*)(BsL + rcol * 32 + l16 * 8);
#pragma unroll
      for (int m = 0; m < 4; ++m) {
        acc[m][n] = MFMA(ah[m], bh, acc[m][n]);
        acc[m][n] = MFMA(ah[m], bl, acc[m][n]);
        acc[m][n] = MFMA(al[m], bh, acc[m][n]);
      }
    }
    __syncthreads();
  }

#pragma unroll
  for (int m = 0; m < 4; ++m) {
#pragma unroll
    for (int r = 0; r < 4; ++r) {
      int s = row0 + w * 64 + m * 16 + l16 * 4 + r;
      if (s >= 4800) continue;
      int nm = nmap[s], dm = dmap[s];
      int ntok = frame * ohow + nm;
#pragma unroll
      for (int n = 0; n < 4; ++n) {
        int c = n * 16 + l15;
        float v = acc[m][n][r] + bias[c];
        if (mode == 0) v *= scale;
        int d = c * pp + dm;
        long off = (mode == 2) ? ((long)d * NtokPad + ntok)
                               : ((long)ntok * Dd + d);
        splitw(v, &tH[off], &tL[off]);
      }
    }
  }
}

// ---------------------------------------------------------------------------
// LDS-staged attention GEMM (tile 128x128, 256 thr). Used for QK (A,B split
// bf16 u16 buffers). mode 0: fp32 out.
// ---------------------------------------------------------------------------
__global__ __launch_bounds__(256) void attn_gemm_lds(
    const u16* __restrict__ Ah, const u16* __restrict__ Al, int lda, int Mrows,
    const u16* __restrict__ Bh, const u16* __restrict__ Bl, int ldb,
    int Nclamp, int Kpart, int Nvalid, int mode, float* outf, int ldo,
    long partstride, u16* __restrict__ Oh, u16* __restrict__ Ol,
    const int* __restrict__ rowbase, const int* __restrict__ doff) {
  __shared__ u16 AsH[128 * 32], AsL[128 * 32], BsH[128 * 32], BsL[128 * 32];
  int t = threadIdx.x;
  int lane = t & 63;
  int w = t >> 6;
  int wc = w & 1, wr = w >> 1;
  int l15 = lane & 15, l16 = lane >> 4;
  int row0 = blockIdx.x * 128;
  int col0 = blockIdx.y * 128;
  int kbase = blockIdx.z * Kpart;
  if (outf) outf += (long)blockIdx.z * partstride;

  int rs = t >> 2;
  int cs = (t & 3) * 8;
  long abase[2], bbase[2];
#pragma unroll
  for (int c = 0; c < 2; ++c) {
    int sr = row0 + rs + 64 * c;
    if (sr >= Mrows) sr = Mrows - 1;
    abase[c] = (long)sr * lda + cs;
    int cc = col0 + rs + 64 * c;
    if (cc >= Nclamp) cc = Nclamp - 1;
    bbase[c] = (long)cc * ldb + cs;
  }
  int ldst = w * 512;

  f32x4 acc[4][4];
#pragma unroll
  for (int m = 0; m < 4; ++m)
#pragma unroll
    for (int n = 0; n < 4; ++n) acc[m][n] = (f32x4){0.f, 0.f, 0.f, 0.f};

  for (int k = kbase; k < kbase + Kpart; k += 32) {
#pragma unroll
    for (int c = 0; c < 2; ++c) {
      gload16(Ah + abase[c] + k, AsH + c * 2048 + ldst);
      gload16(Al + abase[c] + k, AsL + c * 2048 + ldst);
      gload16(Bh + bbase[c] + k, BsH + c * 2048 + ldst);
      gload16(Bl + bbase[c] + k, BsL + c * 2048 + ldst);
    }
    __syncthreads();
    bf16x8 ah[4], al[4];
#pragma unroll
    for (int m = 0; m < 4; ++m) {
      int rrow = wr * 64 + m * 16 + l15;
      ah[m] = *(const bf16x8*)(AsH + rrow * 32 + l16 * 8);
      al[m] = *(const bf16x8*)(AsL + rrow * 32 + l16 * 8);
    }
#pragma unroll
    for (int n = 0; n < 4; ++n) {
      int rcol = wc * 64 + n * 16 + l15;
      bf16x8 bh = *(const bf16x8*)(BsH + rcol * 32 + l16 * 8);
      bf16x8 bl = *(const bf16x8*)(BsL + rcol * 32 + l16 * 8);
#pragma unroll
      for (int m = 0; m < 4; ++m) {
        acc[m][n] = MFMA(ah[m], bh, acc[m][n]);
        acc[m][n] = MFMA(ah[m], bl, acc[m][n]);
        acc[m][n] = MFMA(al[m], bh, acc[m][n]);
      }
    }
    __syncthreads();
  }

#pragma unroll
  for (int m = 0; m < 4; ++m) {
#pragma unroll
    for (int r = 0; r < 4; ++r) {
      int sr = row0 + wr * 64 + m * 16 + l16 * 4 + r;
      if (sr >= Mrows) continue;
#pragma unroll
      for (int n = 0; n < 4; ++n) {
        int c = col0 + wc * 64 + n * 16 + l15;
        if (c >= Nvalid) continue;
        float v = acc[m][n][r];
        if (mode == 0) {
          outf[(long)sr * ldo + c] = v;
        } else {
          long off = (long)rowbase[sr] + doff[c];
          splitw(v, &Oh[off], &Ol[off]);
        }
      }
    }
  }
}

// ---------------------------------------------------------------------------
// PV GEMM: A = fp32 P rows (in-place softmax output), split to hi/lo bf16
// ON THE FLY (bit-identical to splitw). B = split V. Tile 128x128.
// mode 0: fp32 partials (split-K via z); mode 1: CL scatter via LUTs.
// ---------------------------------------------------------------------------
__global__ __launch_bounds__(256) void attn_pv_lds(
    const float* __restrict__ P, int lda, int Mrows,
    const u16* __restrict__ Bh, const u16* __restrict__ Bl, int ldb,
    int Nclamp, int Kpart, int Nvalid, int mode, float* outf, int ldo,
    long partstride, u16* __restrict__ Oh, u16* __restrict__ Ol,
    const int* __restrict__ rowbase, const int* __restrict__ doff) {
  __shared__ float Asf[128 * 32];              // 16KB fp32 A tile
  __shared__ u16 BsH[128 * 32], BsL[128 * 32]; // 8+8KB
  int t = threadIdx.x;
  int lane = t & 63;
  int w = t >> 6;
  int wc = w & 1, wr = w >> 1;
  int l15 = lane & 15, l16 = lane >> 4;
  int row0 = blockIdx.x * 128;
  int col0 = blockIdx.y * 128;
  int kbase = blockIdx.z * Kpart;
  if (outf) outf += (long)blockIdx.z * partstride;

  int arow = t >> 3;
  int acol = (t & 7) * 4;
  long abase[4];
#pragma unroll
  for (int j = 0; j < 4; ++j) {
    int r = row0 + arow + 32 * j;
    if (r >= Mrows) r = Mrows - 1;
    abase[j] = (long)r * lda + acol;
  }
  int rs = t >> 2;
  int cs = (t & 3) * 8;
  long bbase[2];
#pragma unroll
  for (int c = 0; c < 2; ++c) {
    int cc = col0 + rs + 64 * c;
    if (cc >= Nclamp) cc = Nclamp - 1;
    bbase[c] = (long)cc * ldb + cs;
  }
  int ldst = w * 512;

  f32x4 acc[4][4];
#pragma unroll
  for (int m = 0; m < 4; ++m)
#pragma unroll
    for (int n = 0; n < 4; ++n) acc[m][n] = (f32x4){0.f, 0.f, 0.f, 0.f};

  for (int k = kbase; k < kbase + Kpart; k += 32) {
#pragma unroll
    for (int j = 0; j < 4; ++j)
      gload16(P + abase[j] + k, Asf + (w * 64 + 256 * j) * 4);
#pragma unroll
    for (int c = 0; c < 2; ++c) {
      gload16(Bh + bbase[c] + k, BsH + c * 2048 + ldst);
      gload16(Bl + bbase[c] + k, BsL + c * 2048 + ldst);
    }
    __syncthreads();
    bf16x8 ah[4], al[4];
#pragma unroll
    for (int m = 0; m < 4; ++m) {
      int rrow = wr * 64 + m * 16 + l15;
      const float* ap = Asf + rrow * 32 + l16 * 8;
      f32x4 p0 = *(const f32x4*)(ap);
      f32x4 p1 = *(const f32x4*)(ap + 4);
#pragma unroll
      for (int e = 0; e < 4; ++e) {
        float f0 = p0[e], f1 = p1[e];
        u16 h0 = f2bf(f0), h1 = f2bf(f1);
        ah[m][e] = (short)h0;
        ah[m][4 + e] = (short)h1;
        al[m][e] = (short)f2bf(f0 - bf2f(h0));
        al[m][4 + e] = (short)f2bf(f1 - bf2f(h1));
      }
    }
#pragma unroll
    for (int n = 0; n < 4; ++n) {
      int rcol = wc * 64 + n * 16 + l15;
      bf16x8 bh = *(const bf16x8*)(BsH + rcol * 32 + l16 * 8);
      bf16x8 bl = *(const bf16x8*)(BsL + rcol * 32 + l16 * 8);
#pragma unroll
      for (int m = 0; m < 4; ++m) {
        acc[m][n] = MFMA(ah[m], bh, acc[m][n]);
        acc[m][n] = MFMA(ah[m], bl, acc[m][n]);
        acc[m][n] = MFMA(al[m], bh, acc[m][n]);
      }
    }
    __syncthreads();
  }

#pragma unroll
  for (int m = 0; m < 4; ++m) {
#pragma unroll
    for (int r = 0; r < 4; ++r) {
      int sr = row0 + wr * 64 + m * 16 + l16 * 4 + r;
      if (sr >= Mrows) continue;
#pragma unroll
      for (int n = 0; n < 4; ++n) {
        int c = col0 + wc * 64 + n * 16 + l15;
        if (c >= Nvalid) continue;
        float v = acc[m][n][r];
        if (mode == 0) {
          outf[(long)sr * ldo + c] = v;
        } else {
          long off = (long)rowbase[sr] + doff[c];
          splitw(v, &Oh[off], &Ol[off]);
        }
      }
    }
  }
}

// ---------------------------------------------------------------------------
__global__ __launch_bounds__(256) void reduce_scatter(
    const float* __restrict__ parts, int nparts, long pstride, int rows, int N,
    int mode, float* outf, u16* __restrict__ Oh, u16* __restrict__ Ol,
    const int* __restrict__ rowbase, const int* __restrict__ doff) {
  long gid = (long)blockIdx.x * 256 + threadIdx.x;
  long tot = (long)rows * N;
  if (gid >= tot) return;
  float s = 0.f;
  for (int p = 0; p < nparts; ++p) s += parts[p * pstride + gid];
  if (mode == 0) {
    outf[gid] = s;
  } else {
    int r = (int)(gid / N), c = (int)(gid % N);
    long off = (long)rowbase[r] + doff[c];
    splitw(s, &Oh[off], &Ol[off]);
  }
}

// ---------------------------------------------------------------------------
// In-place row softmax: row stride NtokPad, valid length Ntok. Writes fp32
// probabilities in place; zeroes pad columns [Ntok, NtokPad).
// ---------------------------------------------------------------------------
__global__ __launch_bounds__(256) void softmax_ip(float* __restrict__ S,
                                                  int Ntok, int NtokPad) {
  int row = blockIdx.x;
  float* p = S + (long)row * NtokPad;
  __shared__ float red[256];
  int t = threadIdx.x;
  float m = -1e30f;
  for (int i = t; i < Ntok; i += 256) m = fmaxf(m, p[i]);
  red[t] = m;
  __syncthreads();
  for (int s = 128; s > 0; s >>= 1) {
    if (t < s) red[t] = fmaxf(red[t], red[t + s]);
    __syncthreads();
  }
  m = red[0];
  __syncthreads();
  float sum = 0.f;
  for (int i = t; i < Ntok; i += 256) sum += __expf(p[i] - m);
  red[t] = sum;
  __syncthreads();
  for (int s = 128; s > 0; s >>= 1) {
    if (t < s) red[t] += red[t + s];
    __syncthreads();
  }
  float inv = 1.f / red[0];
  __syncthreads();
  for (int i = t; i < Ntok; i += 256) p[i] = __expf(p[i] - m) * inv;
  for (int i = Ntok + t; i < NtokPad; i += 256) p[i] = 0.f;
}

// ---------------------------------------------------------------------------
__global__ __launch_bounds__(256) void wt_build(const float* __restrict__ w,
                                                int Cout, int Cin, int taps,
                                                u16* __restrict__ Wh,
                                                u16* __restrict__ Wl) {
  long gid = (long)blockIdx.x * 256 + threadIdx.x;
  long tot = (long)taps * Cout * Cin;
  if (gid >= tot) return;
  int ic = (int)(gid % Cin);
  long r = gid / Cin;
  int oc = (int)(r % Cout);
  int tap = (int)(r / Cout);
  float v = w[((long)oc * Cin + ic) * taps + tap];
  splitw(v, &Wh[gid], &Wl[gid]);
}

// fused q/k/v 1x1 weight split build (one group of 64 out-channels)
__global__ __launch_bounds__(256) void wtqkv_build(
    const float* __restrict__ wq, const float* __restrict__ wk,
    const float* __restrict__ wv, int co, u16* __restrict__ qh,
    u16* __restrict__ ql, u16* __restrict__ kh, u16* __restrict__ kl,
    u16* __restrict__ vh, u16* __restrict__ vl) {
  int gid = blockIdx.x * 256 + threadIdx.x;
  if (gid >= 64 * 256) return;
  int ic = gid & 255, c = gid >> 8;
  long src = (long)(co + c) * 256 + ic;
  splitw(wq[src], &qh[gid], &ql[gid]);
  splitw(wk[src], &kh[gid], &kl[gid]);
  splitw(wv[src], &vh[gid], &vl[gid]);
}

// ---------------------------------------------------------------------------
__global__ __launch_bounds__(256) void maps_build(int ph, int pw, int ow,
                                                  int* __restrict__ nmap,
                                                  int* __restrict__ dmap) {
  int s = blockIdx.x * 256 + threadIdx.x;
  if (s >= 4800) return;
  int y = s / 160, x = s - y * 160;
  int i = y / ph, yy = y - i * ph;
  int j = x / pw, xx = x - j * pw;
  nmap[s] = i * ow + j;
  dmap[s] = yy * pw + xx;
}

__global__ __launch_bounds__(256) void luts_build(int ph, int pw, int ohow,
                                                  int ow, int pp, int Ntok,
                                                  int Dd, int gbase,
                                                  int* __restrict__ rowbase,
                                                  int* __restrict__ doff) {
  int gid = blockIdx.x * 256 + threadIdx.x;
  if (gid < Ntok) {
    int tt = gid / ohow, rem = gid - tt * ohow;
    int i = rem / ow, j = rem - i * ow;
    rowbase[gid] =
        tt * (32 * 162 * 256) + ((i * ph + 1) * 162 + (j * pw + 1)) * 256;
  }
  if (gid < Dd) {
    int c = gid / pp, rr = gid - c * pp;
    int yy = rr / pw, xx = rr - yy * pw;
    doff[gid] = (yy * 162 + xx) * 256 + gbase + c;
  }
}

// ---------------------------------------------------------------------------
// Bilinear x2 upsample (align_corners) CL hi/lo -> CL hi/lo. Writes the FULL
// padded output (zeros in halo) so overlaid buffers are re-cleaned per frame.
// ---------------------------------------------------------------------------
__global__ __launch_bounds__(256) void up_cl2cl_pad(
    const u16* __restrict__ sh, const u16* __restrict__ sl,
    u16* __restrict__ oh, u16* __restrict__ ol, int C, int H, int W, int Wps,
    int Poffs, int Hp, int Wpo, int Poffo) {
  int Ho = 2 * H, Wo = 2 * W;
  long tot = (long)Hp * Wpo * C;
  long gid = (long)blockIdx.x * 256 + threadIdx.x;
  if (gid >= tot) return;
  int c = (int)(gid % C);
  long r = gid / C;
  int xp = (int)(r % Wpo);
  int yp = (int)(r / Wpo);
  int x = xp - Poffo, y = yp - Poffo;
  float v = 0.f;
  if ((unsigned)x < (unsigned)Wo && (unsigned)y < (unsigned)Ho) {
    float fy = (float)(y * (H - 1)) / (float)(Ho - 1);
    float fx = (float)(x * (W - 1)) / (float)(Wo - 1);
    int y0 = (int)fy, x0 = (int)fx;
    int y1 = min(y0 + 1, H - 1), x1 = min(x0 + 1, W - 1);
    float wy = fy - y0, wx = fx - x0;
    auto rd = [&](int cy, int cx) {
      long o = ((long)(cy + Poffs) * Wps + (cx + Poffs)) * C + c;
      return bf2f(sh[o]) + bf2f(sl[o]);
    };
    float r0 = rd(y0, x0) * (1.f - wx) + rd(y0, x1) * wx;
    float r1 = rd(y1, x0) * (1.f - wx) + rd(y1, x1) * wx;
    v = r0 * (1.f - wy) + r1 * wy;
  }
  splitw(v, &oh[gid], &ol[gid]);
}

// ---------------------------------------------------------------------------
extern "C" void kernel_launch(void* const* d_in, const int* in_sizes, int n_in,
                              void* d_out, int out_size, void* d_ws,
                              size_t ws_size, hipStream_t stream) {
  const float* input = (const float*)d_in[0];
  const float* enc_w0 = (const float*)d_in[1];
  const float* enc_b0 = (const float*)d_in[2];
  const float* enc_w1 = (const float*)d_in[3];
  const float* enc_b1 = (const float*)d_in[4];
  const float* enc_w2 = (const float*)d_in[5];
  const float* enc_b2 = (const float*)d_in[6];
  const float* enc_w3 = (const float*)d_in[7];
  const float* enc_b3 = (const float*)d_in[8];
  const float* tq_w = (const float*)d_in[9];
  const float* tq_b = (const float*)d_in[10];
  const float* tk_w = (const float*)d_in[11];
  const float* tk_b = (const float*)d_in[12];
  const float* tv_w = (const float*)d_in[13];
  const float* tv_b = (const float*)d_in[14];
  const float* to_w = (const float*)d_in[15];
  const float* to_b = (const float*)d_in[16];
  const float* tf1_w = (const float*)d_in[17];
  const float* tf1_b = (const float*)d_in[18];
  const float* tf2_w = (const float*)d_in[19];
  const float* tf2_b = (const float*)d_in[20];
  const float* d0_w = (const float*)d_in[21];
  const float* d0_b = (const float*)d_in[22];
  const float* d1_w = (const float*)d_in[23];
  const float* d1_b = (const float*)d_in[24];
  const float* d2_w = (const float*)d_in[25];
  const float* d2_b = (const float*)d_in[26];
  const float* d3_w = (const float*)d_in[27];
  const float* d3_b = (const float*)d_in[28];
  float* out = (float*)d_out;

  // -------- workspace layout --------
  unsigned char* wsb = (unsigned char*)d_ws;
  size_t off = 0;
  auto alloc = [&](size_t bytes) {
    void* p = wsb + off;
    off = (off + bytes + 255) & ~(size_t)255;
    return p;
  };
  const long XCL_E = 22839296L;   // 16*34*164*256
  const long XCL2_E = 21233664L;  // 16*32*162*256
  const long QT_E = 4915200L;
  const long VT_E = 5111808L;
  u16* XCLh = (u16*)alloc(XCL_E * 2);
  u16* XCLl = (u16*)alloc(XCL_E * 2);
  u16* XCL2h = (u16*)alloc(XCL2_E * 2);
  u16* XCL2l = (u16*)alloc(XCL2_E * 2);
  u16* qth = (u16*)alloc(QT_E * 2);
  u16* qtl = (u16*)alloc(QT_E * 2);
  u16* kth = (u16*)alloc(QT_E * 2);
  u16* ktl = (u16*)alloc(QT_E * 2);
  u16* vth = (u16*)alloc(VT_E * 2);
  u16* vtl = (u16*)alloc(VT_E * 2);
  int* nmapA = (int*)alloc(4 * 4800 * 4);
  int* dmapA = (int*)alloc(4 * 4800 * 4);
  int* rowbaseA = (int*)alloc(7120 * 4);
  int* doffA = (int*)alloc(93248 * 4);
  u16* qwh = (u16*)alloc(16384 * 2);
  u16* qwl = (u16*)alloc(16384 * 2);
  u16* kwh = (u16*)alloc(16384 * 2);
  u16* kwl = (u16*)alloc(16384 * 2);
  u16* vwh = (u16*)alloc(16384 * 2);
  u16* vwl = (u16*)alloc(16384 * 2);
  // scores region (allocated LAST): holds fp32 scores/P in place (+ g3
  // split-K partials). P has no separate bf16 hi/lo buffers.
  size_t fixed_end = off;
  size_t avail = ws_size > fixed_end ? ws_size - fixed_end : 0;
  size_t SCB = avail > 4096 ? avail - 4096 : 0;
  if (SCB > 104857600UL) SCB = 104857600UL;
  float* scores = (float*)alloc(SCB);
  size_t need = off;
  if (ws_size < need) return;        // fail loud, not crash
  long SCAPf = (long)(SCB / 4);
  if (SCAPf < 1400000) return;       // ~5.6 MB minimum (weights + g0)

  // trunk conv weights overlay the scores region (disjoint lifetimes)
  u16* Wth = (u16*)scores;
  u16* Wtl = Wth + 589824;

  // ---- decoder buffers: overlay XCL2 + token region (dead in decoder) ----
  unsigned char* decbase = (unsigned char*)XCL2h;
  u16* dec0inH = (u16*)(decbase + 0);
  u16* dec0inL = (u16*)(decbase + 20443136);
  u16* dec0outH = (u16*)(decbase + 40886272);
  u16* dec0outL = (u16*)(decbase + 51107840);
  u16* dec1outH = (u16*)(decbase + 61329408);
  u16* dec1outL = (u16*)(decbase + 66440192);
  u16* dec2inH = (u16*)(decbase + 71550976);
  u16* dec2inL = (u16*)(decbase + 91601920);
  float* dec2out = (float*)(decbase + 0);
  u16* Wd0h = (u16*)(decbase + 111652864);
  u16* Wd0l = Wd0h + 294912;
  u16* W1h = Wd0l + 294912;
  u16* W1l = W1h + 73728;
  u16* W2h = W1l + 73728;
  u16* W2l = W2h + 36864;
  const long D0IN_FS = 5110784, D0OUT_FS = 2555392, D1OUT_FS = 1277696;
  const long D2IN_FS = 5012736, D2OUT_FS = 4915200;

  const long FS_TR = 1427456;  // 34*164*256
  const long FS_T2 = 1327104;  // 32*162*256 == 64*324*64
  const long FS_E2 = 713728;   // 34*164*128

  static const int PWa[4] = {80, 32, 10, 5};
  static const int PHa[4] = {15, 6, 5, 3};
  static const int rbOff[4] = {0, 64, 464, 2000};
  static const int doOff[4] = {0, 76800, 89088, 92288};

  // -------- encoder --------
  hipMemsetAsync(XCLh, 0, XCL_E * 2, stream);
  hipMemsetAsync(XCLl, 0, XCL_E * 2, stream);
  hipMemsetAsync(XCL2h, 0, XCL2_E * 2, stream);
  hipMemsetAsync(XCL2l, 0, XCL2_E * 2, stream);
  hipMemsetAsync(vth, 0, VT_E * 2, stream);  // pad-column zero guard
  hipMemsetAsync(vtl, 0, VT_E * 2, stream);
  {  // enc0: fp32 direct -> CL [64][324][64] Poff2 in XCL2 space
    long tot = 16L * 64 * 60 * 40;
    conv2d_k<3, 2, 1><<<cdivu(tot, 256), 256, 0, stream>>>(
        input, enc_w0, enc_b0, nullptr, XCL2h, XCL2l, 324, 2, FS_T2, 16, 3,
        120, 640, 64, 60, 320, 1, ACT_LEAKY);
  }
  {  // enc1: 64->64, 60x320 (tile 256x64)
    wt_build<<<cdivu(9L * 64 * 64, 256), 256, 0, stream>>>(enc_w1, 64, 64, 9,
                                                           Wth, Wtl);
    conv_gemm_lds<4, 1><<<dim3(75, 1, 16), 256, 0, stream>>>(
        XCL2h, XCL2l, Wth, Wtl, enc_b1, 64, 64, 60, 320, 324, 2, 1, 1, 1, 9,
        FS_T2, ACT_LEAKY, nullptr, 0, XCLh, XCLl, FS_T2, 324, 2, 0);
  }
  hipMemsetAsync(XCL2h, 0, XCL2_E * 2, stream);
  hipMemsetAsync(XCL2l, 0, XCL2_E * 2, stream);
  {  // enc2: 64->128 stride2 -> CL [34][164][128] in XCL2 space
    wt_build<<<cdivu(9L * 128 * 64, 256), 256, 0, stream>>>(enc_w2, 128, 64, 9,
                                                            Wth, Wtl);
    conv_gemm_lds<2, 2><<<dim3(38, 1, 16), 256, 0, stream>>>(
        XCLh, XCLl, Wth, Wtl, enc_b2, 64, 128, 30, 160, 324, 2, 2, 1, 1, 9,
        FS_T2, ACT_LEAKY, nullptr, 0, XCL2h, XCL2l, FS_E2, 164, 2, 0);
  }
  hipMemsetAsync(XCLh, 0, XCL_E * 2, stream);
  hipMemsetAsync(XCLl, 0, XCL_E * 2, stream);
  {  // enc3: 128->256 -> trunk XCL [34][164][256]
    wt_build<<<cdivu(9L * 256 * 128, 256), 256, 0, stream>>>(enc_w3, 256, 128,
                                                             9, Wth, Wtl);
    conv_gemm_lds<2, 2><<<dim3(38, 2, 16), 256, 0, stream>>>(
        XCL2h, XCL2l, Wth, Wtl, enc_b3, 128, 256, 30, 160, 164, 2, 1, 1, 1, 9,
        FS_E2, ACT_LEAKY, nullptr, 0, XCLh, XCLl, FS_TR, 164, 2, 0);
  }
  hipMemsetAsync(XCL2h, 0, XCL2_E * 2, stream);
  hipMemsetAsync(XCL2l, 0, XCL2_E * 2, stream);

  // -------- token maps / scatter LUTs --------
  for (int g = 0; g < 4; ++g) {
    int ph = PHa[g], pw = PWa[g];
    int ohh = 30 / ph, oww = 160 / pw;
    int Ntok = 16 * ohh * oww, Dd = 64 * ph * pw, pp = ph * pw;
    maps_build<<<19, 256, 0, stream>>>(ph, pw, oww, nmapA + g * 4800,
                                       dmapA + g * 4800);
    int mx = Ntok > Dd ? Ntok : Dd;
    luts_build<<<cdivu(mx, 256), 256, 0, stream>>>(
        ph, pw, ohh * oww, oww, pp, Ntok, Dd, g * 64, rowbaseA + rbOff[g],
        doffA + doOff[g]);
  }

  // -------- transformer stack --------
  for (int l = 0; l < 8; ++l) {
    for (int g = 0; g < 4; ++g) {
      int ph = PHa[g], pw = PWa[g];
      int ohh = 30 / ph, oww = 160 / pw;
      int ohow = ohh * oww;
      int Ntok = 16 * ohow, Dd = 64 * ph * pw, pp = ph * pw;
      int NtokPad = (Ntok + 31) & ~31;
      float scale = 1.0f / sqrtf((float)Dd);
      const int* nmap = nmapA + g * 4800;
      const int* dmap = dmapA + g * 4800;
      const int* rowbase = rowbaseA + rbOff[g];
      const int* doffp = doffA + doOff[g];

      wtqkv_build<<<64, 256, 0, stream>>>(
          tq_w + (long)l * 65536, tk_w + (long)l * 65536,
          tv_w + (long)l * 65536, g * 64, qwh, qwl, kwh, kwl, vwh, vwl);
      qkv_gemm_lds<<<dim3(19, 1, 16), 256, 0, stream>>>(
          XCLh, XCLl, FS_TR, 164, 2, qwh, qwl, tq_b + l * 256 + g * 64, nmap,
          dmap, ohow, Dd, pp, NtokPad, scale, 0, qth, qtl);
      qkv_gemm_lds<<<dim3(19, 1, 16), 256, 0, stream>>>(
          XCLh, XCLl, FS_TR, 164, 2, kwh, kwl, tk_b + l * 256 + g * 64, nmap,
          dmap, ohow, Dd, pp, NtokPad, 1.f, 1, kth, ktl);
      qkv_gemm_lds<<<dim3(19, 1, 16), 256, 0, stream>>>(
          XCLh, XCLl, FS_TR, 164, 2, vwh, vwl, tv_b + l * 256 + g * 64, nmap,
          dmap, ohow, Dd, pp, NtokPad, 1.f, 2, vth, vtl);

      if (g == 0) {
        // QK split-K: 32 parts of K=2400 -> partials -> reduce -> softmax
        float* scoresR = scores + 131072;
        attn_gemm_lds<<<dim3(1, 1, 32), 256, 0, stream>>>(
            qth, qtl, Dd, 64, kth, ktl, Dd, 64, 2400, 64, 0, scores, 64, 4096,
            nullptr, nullptr, nullptr, nullptr);
        reduce_scatter<<<16, 256, 0, stream>>>(scores, 32, 4096, 64, 64, 0,
                                               scoresR, nullptr, nullptr,
                                               nullptr, nullptr);
        softmax_ip<<<64, 256, 0, stream>>>(scoresR, 64, 64);
        attn_pv_lds<<<dim3(1, 600, 1), 256, 0, stream>>>(
            scoresR, 64, 64, vth, vtl, 64, Dd, 64, Dd, 1, nullptr, 0, 0,
            XCL2h, XCL2l, rowbase, doffp);
      } else {
        long denom = (long)NtokPad + (g == 3 ? 3840 : 0);
        long cap = (SCAPf / denom) & ~127L;
        int chunk = (int)(cap < 128 ? 128 : cap);
        if (chunk > Ntok) chunk = Ntok;
        float* partials = scores + (long)chunk * NtokPad;
        for (int r0 = 0; r0 < Ntok; r0 += chunk) {
          int rows = Ntok - r0 < chunk ? Ntok - r0 : chunk;
          attn_gemm_lds<<<dim3(cdivu(rows, 128), cdivu(Ntok, 128), 1), 256, 0,
                          stream>>>(qth + (long)r0 * Dd, qtl + (long)r0 * Dd,
                                    Dd, rows, kth, ktl, Dd, Ntok, Dd, Ntok, 0,
                                    scores, NtokPad, 0, nullptr, nullptr,
                                    nullptr, nullptr);
          softmax_ip<<<rows, 256, 0, stream>>>(scores, Ntok, NtokPad);
          if (g == 3) {
            attn_pv_lds<<<dim3(cdivu(rows, 128), 8, 4), 256, 0, stream>>>(
                scores, NtokPad, rows, vth, vtl, NtokPad, Dd, 1280, Dd, 0,
                partials, 960, (long)rows * 960, nullptr, nullptr, nullptr,
                nullptr);
            reduce_scatter<<<cdivu((long)rows * 960, 256), 256, 0, stream>>>(
                partials, 4, (long)rows * 960, rows, 960, 1, nullptr, XCL2h,
                XCL2l, rowbase + r0, doffp);
          } else {
            attn_pv_lds<<<dim3(cdivu(rows, 128), Dd / 128, 1), 256, 0,
                          stream>>>(scores, NtokPad, rows, vth, vtl, NtokPad,
                                    Dd, NtokPad, Dd, 1, nullptr, 0, 0, XCL2h,
                                    XCL2l, rowbase + r0, doffp);
          }
        }
      }
    }

    // out-conv 3x3 + leaky + residual (in-place on XCL)
    wt_build<<<cdivu(9L * 256 * 256, 256), 256, 0, stream>>>(
        to_w + (long)l * 589824, 256, 256, 9, Wth, Wtl);
    conv_gemm_lds<2, 2><<<dim3(38, 2, 16), 256, 0, stream>>>(
        XCL2h, XCL2l, Wth, Wtl, to_b + l * 256, 256, 256, 30, 160, 162, 1, 1,
        1, 1, 9, FS_T2, ACT_LEAKY, nullptr, 0, XCLh, XCLl, FS_TR, 164, 2, 1);
    // ff1: dil2 pad2
    wt_build<<<cdivu(9L * 256 * 256, 256), 256, 0, stream>>>(
        tf1_w + (long)l * 589824, 256, 256, 9, Wth, Wtl);
    conv_gemm_lds<2, 2><<<dim3(38, 2, 16), 256, 0, stream>>>(
        XCLh, XCLl, Wth, Wtl, tf1_b + l * 256, 256, 256, 30, 160, 164, 2, 1, 2,
        2, 9, FS_TR, ACT_LEAKY, nullptr, 0, XCL2h, XCL2l, FS_T2, 162, 1, 0);
    // ff2 + residual (in-place on XCL)
    wt_build<<<cdivu(9L * 256 * 256, 256), 256, 0, stream>>>(
        tf2_w + (long)l * 589824, 256, 256, 9, Wth, Wtl);
    conv_gemm_lds<2, 2><<<dim3(38, 2, 16), 256, 0, stream>>>(
        XCL2h, XCL2l, Wth, Wtl, tf2_b + l * 256, 256, 256, 30, 160, 162, 1, 1,
        1, 1, 9, FS_T2, ACT_LEAKY, nullptr, 0, XCLh, XCLl, FS_TR, 164, 2, 1);
  }

  // -------- decoder (2-frame groups; overlays XCL2+token region) --------
  hipMemsetAsync(decbase, 0, 111652864, stream);
  wt_build<<<cdivu(9L * 128 * 256, 256), 256, 0, stream>>>(d0_w, 128, 256, 9,
                                                           Wd0h, Wd0l);
  wt_build<<<cdivu(9L * 64 * 128, 256), 256, 0, stream>>>(d1_w, 64, 128, 9,
                                                          W1h, W1l);
  wt_build<<<cdivu(9L * 64 * 64, 256), 256, 0, stream>>>(d2_w, 64, 64, 9, W2h,
                                                         W2l);
  for (int f = 0; f < 16; f += 2) {
    for (int ff = 0; ff < 2; ++ff)
      up_cl2cl_pad<<<cdivu(62L * 322 * 256, 256), 256, 0, stream>>>(
          XCLh + (long)(f + ff) * FS_TR, XCLl + (long)(f + ff) * FS_TR,
          dec0inH + (long)ff * D0IN_FS, dec0inL + (long)ff * D0IN_FS, 256, 30,
          160, 164, 2, 62, 322, 1);
    conv_gemm_lds<2, 2><<<dim3(150, 1, 2), 256, 0, stream>>>(
        dec0inH, dec0inL, Wd0h, Wd0l, d0_b, 256, 128, 60, 320, 322, 1, 1, 1, 1,
        9, D0IN_FS, ACT_LEAKY, nullptr, 0, dec0outH, dec0outL, D0OUT_FS, 322,
        1, 0);
    conv_gemm_lds<4, 1><<<dim3(75, 1, 2), 256, 0, stream>>>(
        dec0outH, dec0outL, W1h, W1l, d1_b, 128, 64, 60, 320, 322, 1, 1, 1, 1,
        9, D0OUT_FS, ACT_LEAKY, nullptr, 0, dec1outH, dec1outL, D1OUT_FS, 322,
        1, 0);
    for (int ff = 0; ff < 2; ++ff)
      up_cl2cl_pad<<<cdivu(122L * 642 * 64, 256), 256, 0, stream>>>(
          dec1outH + (long)ff * D1OUT_FS, dec1outL + (long)ff * D1OUT_FS,
          dec2inH + (long)ff * D2IN_FS, dec2inL + (long)ff * D2IN_FS, 64, 60,
          320, 322, 1, 122, 642, 1);
    conv_gemm_lds<4, 1><<<dim3(300, 1, 2), 256, 0, stream>>>(
        dec2inH, dec2inL, W2h, W2l, d2_b, 64, 64, 120, 640, 642, 1, 1, 1, 1, 9,
        D2IN_FS, ACT_LEAKY, dec2out, D2OUT_FS, nullptr, nullptr, 0, 0, 0, 0);
    {
      long tot = 2L * 3 * 120 * 80;
      conv2d_k<3, 1, 1><<<cdivu(tot, 256), 256, 0, stream>>>(
          dec2out, d3_w, d3_b, out + (long)f * 230400, nullptr, nullptr, 0, 0,
          0, 2, 64, 120, 640, 3, 120, 640, 1, ACT_TANH);
    }
  }
}

// Round 11
// 37008.606 us; speedup vs baseline: 27.7153x; 1.0184x over previous
//
#include <hip/hip_runtime.h>
#include <hip/hip_bf16.h>
#include <math.h>

#define ACT_NONE 0
#define ACT_LEAKY 1
#define ACT_TANH 2

typedef __attribute__((ext_vector_type(8))) short bf16x8;
typedef __attribute__((ext_vector_type(4))) float f32x4;
typedef unsigned short u16;

#define MFMA(a, b, c) __builtin_amdgcn_mfma_f32_16x16x32_bf16((bf16x8)(a), (bf16x8)(b), (c), 0, 0, 0)

static inline unsigned cdivu(long a, long b) { return (unsigned)((a + b - 1) / b); }

__device__ __forceinline__ u16 f2bf(float x) {
  union { __hip_bfloat16 h; u16 u; } cv;
  cv.h = __float2bfloat16(x);
  return cv.u;
}
__device__ __forceinline__ float bf2f(u16 b) {
  union { u16 u; __hip_bfloat16 h; } cv;
  cv.u = b;
  return __bfloat162float(cv.h);
}
__device__ __forceinline__ void splitw(float v, u16* ph, u16* pl) {
  u16 h = f2bf(v);
  *ph = h;
  *pl = f2bf(v - bf2f(h));
}
// async global->LDS, 16B per lane; dest must be wave-uniform base (+lane*16)
__device__ __forceinline__ void gload16(const void* g, void* l) {
  __builtin_amdgcn_global_load_lds(
      (const __attribute__((address_space(1))) unsigned int*)g,
      (__attribute__((address_space(3))) unsigned int*)l, 16, 0, 0);
}

// ---------------------------------------------------------------------------
// Direct fp32 conv (enc0: Cin=3; d3: Cout=3+tanh). Optional CL hi/lo output.
// ---------------------------------------------------------------------------
template <int K, int S, int DIL>
__global__ __launch_bounds__(256) void conv2d_k(
    const float* __restrict__ x, const float* __restrict__ w,
    const float* __restrict__ bias, float* y, u16* clh, u16* cll, int WpO,
    int PoffO, long o_fstride, int N, int Cin, int Hin, int Win, int Cout,
    int Hout, int Wout, int pad, int act) {
  constexpr int TW = 8;
  constexpr int XL = (TW - 1) * S + (K - 1) * DIL + 1;
  int wq = (Wout + TW - 1) / TW;
  long gid = (long)blockIdx.x * 256 + threadIdx.x;
  long total = (long)N * Cout * Hout * wq;
  if (gid >= total) return;
  int xg = (int)(gid % wq);
  long r = gid / wq;
  int yo = (int)(r % Hout);
  r /= Hout;
  int oc = (int)(r % Cout);
  int n = (int)(r / Cout);

  float bv = bias[oc];
  float acc[TW];
#pragma unroll
  for (int j = 0; j < TW; ++j) acc[j] = bv;

  int xo0 = xg * TW;
  int xi0 = xo0 * S - pad;
  const float* xn = x + (long)n * Cin * Hin * Win;
  const float* wb = w + (long)oc * Cin * K * K;

  for (int ic = 0; ic < Cin; ++ic) {
    const float* xc = xn + (long)ic * Hin * Win;
    const float* wc = wb + ic * (K * K);
#pragma unroll
    for (int ky = 0; ky < K; ++ky) {
      int yi = yo * S - pad + ky * DIL;
      if ((unsigned)yi < (unsigned)Hin) {
        const float* row = xc + (long)yi * Win;
        float xr[XL];
#pragma unroll
        for (int i2 = 0; i2 < XL; ++i2) {
          int xi = xi0 + i2;
          xr[i2] = ((unsigned)xi < (unsigned)Win) ? row[xi] : 0.f;
        }
#pragma unroll
        for (int kx = 0; kx < K; ++kx) {
          float wv = wc[ky * K + kx];
#pragma unroll
          for (int j = 0; j < TW; ++j)
            acc[j] = fmaf(wv, xr[j * S + kx * DIL], acc[j]);
        }
      }
    }
  }

#pragma unroll
  for (int j = 0; j < TW; ++j) {
    if (xo0 + j < Wout) {
      float v = acc[j];
      if (act == ACT_LEAKY)
        v = v >= 0.f ? v : 0.2f * v;
      else if (act == ACT_TANH)
        v = tanhf(v);
      if (y) y[(((long)n * Cout + oc) * Hout + yo) * Wout + xo0 + j] = v;
      if (clh) {
        long off = (long)n * o_fstride +
                   ((long)(yo + PoffO) * WpO + (xo0 + j + PoffO)) * Cout + oc;
        splitw(v, &clh[off], &cll[off]);
      }
    }
  }
}

// ---------------------------------------------------------------------------
// LDS-staged MFMA implicit-GEMM conv (m97 2-barrier structure).
// ---------------------------------------------------------------------------
template <int WM, int WN>
__global__ __launch_bounds__(256) void conv_gemm_lds(
    const u16* __restrict__ Ah, const u16* __restrict__ Al,
    const u16* __restrict__ Bh, const u16* __restrict__ Bl,
    const float* __restrict__ bias, int Cin, int Cout, int Hout, int Wout,
    int Wp, int Poff, int S, int DIL, int pad, int taps, long a_fstride,
    int act, float* yout, long y_fstride, u16* Oh, u16* Ol, long o_fstride,
    int WpO, int PoffO, int useres) {
  constexpr int TM = WM * 64, TN = WN * 64;
  __shared__ u16 AsH[TM * 32], AsL[TM * 32], BsH[TN * 32], BsL[TN * 32];
  int t = threadIdx.x;
  int lane = t & 63;
  int w = t >> 6;
  int wr = w / WN, wc = w % WN;
  int l15 = lane & 15, l16 = lane >> 4;
  int HW = Hout * Wout;
  int row0 = blockIdx.x * TM;
  int col0 = blockIdx.y * TN;
  const u16* Afh = Ah + (long)blockIdx.z * a_fstride;
  const u16* Afl = Al + (long)blockIdx.z * a_fstride;

  int rs = t >> 2;
  int cs = (t & 3) * 8;
  long abase[WM];
#pragma unroll
  for (int c = 0; c < WM; ++c) {
    int s = row0 + rs + 64 * c;
    if (s >= HW) s = HW - 1;
    int yo = s / Wout, xo = s - yo * Wout;
    int yb = yo * S - pad + Poff, xb = xo * S - pad + Poff;
    abase[c] = ((long)yb * Wp + xb) * Cin + cs;
  }
  long bbase[WN];
#pragma unroll
  for (int c = 0; c < WN; ++c)
    bbase[c] = (long)(col0 + rs + 64 * c) * Cin + cs;
  int ldst = w * 512;

  f32x4 acc[4][4];
#pragma unroll
  for (int m = 0; m < 4; ++m)
#pragma unroll
    for (int n = 0; n < 4; ++n) acc[m][n] = (f32x4){0.f, 0.f, 0.f, 0.f};

  for (int tap = 0; tap < taps; ++tap) {
    int ky = tap / 3, kx = tap - ky * 3;
    long atap = ((long)ky * DIL * Wp + kx * DIL) * Cin;
    long btap = (long)tap * Cout * Cin;
    for (int ic0 = 0; ic0 < Cin; ic0 += 32) {
#pragma unroll
      for (int c = 0; c < WM; ++c) {
        gload16(Afh + abase[c] + atap + ic0, AsH + c * 2048 + ldst);
        gload16(Afl + abase[c] + atap + ic0, AsL + c * 2048 + ldst);
      }
#pragma unroll
      for (int c = 0; c < WN; ++c) {
        gload16(Bh + bbase[c] + btap + ic0, BsH + c * 2048 + ldst);
        gload16(Bl + bbase[c] + btap + ic0, BsL + c * 2048 + ldst);
      }
      __syncthreads();
      bf16x8 ah[4], al[4];
#pragma unroll
      for (int m = 0; m < 4; ++m) {
        int rrow = wr * 64 + m * 16 + l15;
        ah[m] = *(const bf16x8*)(AsH + rrow * 32 + l16 * 8);
        al[m] = *(const bf16x8*)(AsL + rrow * 32 + l16 * 8);
      }
#pragma unroll
      for (int n = 0; n < 4; ++n) {
        int rcol = wc * 64 + n * 16 + l15;
        bf16x8 bh = *(const bf16x8*)(BsH + rcol * 32 + l16 * 8);
        bf16x8 bl = *(const bf16x8*)(BsL + rcol * 32 + l16 * 8);
#pragma unroll
        for (int m = 0; m < 4; ++m) {
          acc[m][n] = MFMA(ah[m], bh, acc[m][n]);
          acc[m][n] = MFMA(ah[m], bl, acc[m][n]);
          acc[m][n] = MFMA(al[m], bh, acc[m][n]);
        }
      }
      __syncthreads();
    }
  }

  float* yf = yout ? yout + (long)blockIdx.z * y_fstride : nullptr;
  u16* Ofh = Oh ? Oh + (long)blockIdx.z * o_fstride : nullptr;
  u16* Ofl = Ol ? Ol + (long)blockIdx.z * o_fstride : nullptr;
#pragma unroll
  for (int m = 0; m < 4; ++m) {
#pragma unroll
    for (int r = 0; r < 4; ++r) {
      int s = row0 + wr * 64 + m * 16 + l16 * 4 + r;
      if (s >= HW) continue;
      int yo = s / Wout, xo = s - yo * Wout;
      long clbase = 0;
      if (Ofh) clbase = ((long)(yo + PoffO) * WpO + (xo + PoffO)) * Cout;
#pragma unroll
      for (int n = 0; n < 4; ++n) {
        int oc = col0 + wc * 64 + n * 16 + l15;
        float v = acc[m][n][r] + bias[oc];
        if (act == ACT_LEAKY) v = v >= 0.f ? v : 0.2f * v;
        if (Ofh) {
          long off = clbase + oc;
          if (useres) v += bf2f(Ofh[off]) + bf2f(Ofl[off]);
          splitw(v, &Ofh[off], &Ofl[off]);
        }
        if (yf) yf[((long)oc * Hout + yo) * Wout + xo] = v;
      }
    }
  }
}

// ---------------------------------------------------------------------------
// Fused QKV 1x1 GEMM: one dispatch computes Q,K,V sequentially per block
// (mat loop; per-mat arithmetic identical to the previous 3 dispatches).
// Tile 256x64, 4 waves. Token-layout scatter. mat: 0=Q(scaled),1=K,2=V(T).
// ---------------------------------------------------------------------------
__global__ __launch_bounds__(256) void qkv3_gemm_lds(
    const u16* __restrict__ Ah, const u16* __restrict__ Al, long a_fstride,
    int Wp, int Poff, const u16* __restrict__ qwh, const u16* __restrict__ qwl,
    const u16* __restrict__ kwh, const u16* __restrict__ kwl,
    const u16* __restrict__ vwh, const u16* __restrict__ vwl,
    const float* __restrict__ qbias, const float* __restrict__ kbias,
    const float* __restrict__ vbias, const int* __restrict__ nmap,
    const int* __restrict__ dmap, int ohow, int Dd, int pp, int NtokPad,
    float scale, u16* __restrict__ tqh, u16* __restrict__ tql,
    u16* __restrict__ tkh, u16* __restrict__ tkl, u16* __restrict__ tvh,
    u16* __restrict__ tvl) {
  __shared__ u16 AsH[256 * 32], AsL[256 * 32], BsH[64 * 32], BsL[64 * 32];
  int t = threadIdx.x;
  int lane = t & 63;
  int w = t >> 6;
  int l15 = lane & 15, l16 = lane >> 4;
  int row0 = blockIdx.x * 256;
  int frame = blockIdx.z;
  const u16* Afh = Ah + (long)frame * a_fstride;
  const u16* Afl = Al + (long)frame * a_fstride;

  int rs = t >> 2;
  int cs = (t & 3) * 8;
  long abase[4];
#pragma unroll
  for (int c = 0; c < 4; ++c) {
    int s = row0 + rs + 64 * c;
    if (s >= 4800) s = 4799;
    int yo = s / 160, xo = s - yo * 160;
    abase[c] = ((long)(yo + Poff) * Wp + (xo + Poff)) * 256 + cs;
  }
  long bbase = (long)rs * 256 + cs;
  int ldst = w * 512;

  for (int mat = 0; mat < 3; ++mat) {
    const u16* Bh = mat == 0 ? qwh : mat == 1 ? kwh : vwh;
    const u16* Bl = mat == 0 ? qwl : mat == 1 ? kwl : vwl;
    const float* bias = mat == 0 ? qbias : mat == 1 ? kbias : vbias;
    u16* tH = mat == 0 ? tqh : mat == 1 ? tkh : tvh;
    u16* tL = mat == 0 ? tql : mat == 1 ? tkl : tvl;

    f32x4 acc[4][4];
#pragma unroll
    for (int m = 0; m < 4; ++m)
#pragma unroll
      for (int n = 0; n < 4; ++n) acc[m][n] = (f32x4){0.f, 0.f, 0.f, 0.f};

    for (int ic0 = 0; ic0 < 256; ic0 += 32) {
#pragma unroll
      for (int c = 0; c < 4; ++c) {
        gload16(Afh + abase[c] + ic0, AsH + c * 2048 + ldst);
        gload16(Afl + abase[c] + ic0, AsL + c * 2048 + ldst);
      }
      gload16(Bh + bbase + ic0, BsH + ldst);
      gload16(Bl + bbase + ic0, BsL + ldst);
      __syncthreads();
      bf16x8 ah[4], al[4];
#pragma unroll
      for (int m = 0; m < 4; ++m) {
        int rrow = w * 64 + m * 16 + l15;
        ah[m] = *(const bf16x8*)(AsH + rrow * 32 + l16 * 8);
        al[m] = *(const bf16x8*)(AsL + rrow * 32 + l16 * 8);
      }
#pragma unroll
      for (int n = 0; n < 4; ++n) {
        int rcol = n * 16 + l15;
        bf16x8 bh = *(const bf16x8*)(BsH + rcol * 32 + l16 * 8);
        bf16x8 bl = *(const bf16x8*)(BsL + rcol * 32 + l16 * 8);
#pragma unroll
        for (int m = 0; m < 4; ++m) {
          acc[m][n] = MFMA(ah[m], bh, acc[m][n]);
          acc[m][n] = MFMA(ah[m], bl, acc[m][n]);
          acc[m][n] = MFMA(al[m], bh, acc[m][n]);
        }
      }
      __syncthreads();
    }

#pragma unroll
    for (int m = 0; m < 4; ++m) {
#pragma unroll
      for (int r = 0; r < 4; ++r) {
        int s = row0 + w * 64 + m * 16 + l16 * 4 + r;
        if (s >= 4800) continue;
        int nm = nmap[s], dm = dmap[s];
        int ntok = frame * ohow + nm;
#pragma unroll
        for (int n = 0; n < 4; ++n) {
          int c = n * 16 + l15;
          float v = acc[m][n][r] + bias[c];
          if (mat == 0) v *= scale;
          int d = c * pp + dm;
          long off = (mat == 2) ? ((long)d * NtokPad + ntok)
                                : ((long)ntok * Dd + d);
          splitw(v, &tH[off], &tL[off]);
        }
      }
    }
  }
}

// ---------------------------------------------------------------------------
// LDS-staged attention GEMM (tile 128x128, 256 thr). Used for QK. mode 0:
// fp32 out (split-K via z).
// ---------------------------------------------------------------------------
__global__ __launch_bounds__(256) void attn_gemm_lds(
    const u16* __restrict__ Ah, const u16* __restrict__ Al, int lda, int Mrows,
    const u16* __restrict__ Bh, const u16* __restrict__ Bl, int ldb,
    int Nclamp, int Kpart, int Nvalid, int mode, float* outf, int ldo,
    long partstride, u16* __restrict__ Oh, u16* __restrict__ Ol,
    const int* __restrict__ rowbase, const int* __restrict__ doff) {
  __shared__ u16 AsH[128 * 32], AsL[128 * 32], BsH[128 * 32], BsL[128 * 32];
  int t = threadIdx.x;
  int lane = t & 63;
  int w = t >> 6;
  int wc = w & 1, wr = w >> 1;
  int l15 = lane & 15, l16 = lane >> 4;
  int row0 = blockIdx.x * 128;
  int col0 = blockIdx.y * 128;
  int kbase = blockIdx.z * Kpart;
  if (outf) outf += (long)blockIdx.z * partstride;

  int rs = t >> 2;
  int cs = (t & 3) * 8;
  long abase[2], bbase[2];
#pragma unroll
  for (int c = 0; c < 2; ++c) {
    int sr = row0 + rs + 64 * c;
    if (sr >= Mrows) sr = Mrows - 1;
    abase[c] = (long)sr * lda + cs;
    int cc = col0 + rs + 64 * c;
    if (cc >= Nclamp) cc = Nclamp - 1;
    bbase[c] = (long)cc * ldb + cs;
  }
  int ldst = w * 512;

  f32x4 acc[4][4];
#pragma unroll
  for (int m = 0; m < 4; ++m)
#pragma unroll
    for (int n = 0; n < 4; ++n) acc[m][n] = (f32x4){0.f, 0.f, 0.f, 0.f};

  for (int k = kbase; k < kbase + Kpart; k += 32) {
#pragma unroll
    for (int c = 0; c < 2; ++c) {
      gload16(Ah + abase[c] + k, AsH + c * 2048 + ldst);
      gload16(Al + abase[c] + k, AsL + c * 2048 + ldst);
      gload16(Bh + bbase[c] + k, BsH + c * 2048 + ldst);
      gload16(Bl + bbase[c] + k, BsL + c * 2048 + ldst);
    }
    __syncthreads();
    bf16x8 ah[4], al[4];
#pragma unroll
    for (int m = 0; m < 4; ++m) {
      int rrow = wr * 64 + m * 16 + l15;
      ah[m] = *(const bf16x8*)(AsH + rrow * 32 + l16 * 8);
      al[m] = *(const bf16x8*)(AsL + rrow * 32 + l16 * 8);
    }
#pragma unroll
    for (int n = 0; n < 4; ++n) {
      int rcol = wc * 64 + n * 16 + l15;
      bf16x8 bh = *(const bf16x8*)(BsH + rcol * 32 + l16 * 8);
      bf16x8 bl = *(const bf16x8*)(BsL + rcol * 32 + l16 * 8);
#pragma unroll
      for (int m = 0; m < 4; ++m) {
        acc[m][n] = MFMA(ah[m], bh, acc[m][n]);
        acc[m][n] = MFMA(ah[m], bl, acc[m][n]);
        acc[m][n] = MFMA(al[m], bh, acc[m][n]);
      }
    }
    __syncthreads();
  }

#pragma unroll
  for (int m = 0; m < 4; ++m) {
#pragma unroll
    for (int r = 0; r < 4; ++r) {
      int sr = row0 + wr * 64 + m * 16 + l16 * 4 + r;
      if (sr >= Mrows) continue;
#pragma unroll
      for (int n = 0; n < 4; ++n) {
        int c = col0 + wc * 64 + n * 16 + l15;
        if (c >= Nvalid) continue;
        float v = acc[m][n][r];
        if (mode == 0) {
          outf[(long)sr * ldo + c] = v;
        } else {
          long off = (long)rowbase[sr] + doff[c];
          splitw(v, &Oh[off], &Ol[off]);
        }
      }
    }
  }
}

// ---------------------------------------------------------------------------
// PV GEMM: A = fp32 P rows (in-place softmax output), split to hi/lo bf16
// ON THE FLY (bit-identical to splitw). B = split V. Tile 128x128.
// mode 0: fp32 partials (split-K via z); mode 1: CL scatter via LUTs.
// ---------------------------------------------------------------------------
__global__ __launch_bounds__(256) void attn_pv_lds(
    const float* __restrict__ P, int lda, int Mrows,
    const u16* __restrict__ Bh, const u16* __restrict__ Bl, int ldb,
    int Nclamp, int Kpart, int Nvalid, int mode, float* outf, int ldo,
    long partstride, u16* __restrict__ Oh, u16* __restrict__ Ol,
    const int* __restrict__ rowbase, const int* __restrict__ doff) {
  __shared__ float Asf[128 * 32];              // 16KB fp32 A tile
  __shared__ u16 BsH[128 * 32], BsL[128 * 32]; // 8+8KB
  int t = threadIdx.x;
  int lane = t & 63;
  int w = t >> 6;
  int wc = w & 1, wr = w >> 1;
  int l15 = lane & 15, l16 = lane >> 4;
  int row0 = blockIdx.x * 128;
  int col0 = blockIdx.y * 128;
  int kbase = blockIdx.z * Kpart;
  if (outf) outf += (long)blockIdx.z * partstride;

  int arow = t >> 3;
  int acol = (t & 7) * 4;
  long abase[4];
#pragma unroll
  for (int j = 0; j < 4; ++j) {
    int r = row0 + arow + 32 * j;
    if (r >= Mrows) r = Mrows - 1;
    abase[j] = (long)r * lda + acol;
  }
  int rs = t >> 2;
  int cs = (t & 3) * 8;
  long bbase[2];
#pragma unroll
  for (int c = 0; c < 2; ++c) {
    int cc = col0 + rs + 64 * c;
    if (cc >= Nclamp) cc = Nclamp - 1;
    bbase[c] = (long)cc * ldb + cs;
  }
  int ldst = w * 512;

  f32x4 acc[4][4];
#pragma unroll
  for (int m = 0; m < 4; ++m)
#pragma unroll
    for (int n = 0; n < 4; ++n) acc[m][n] = (f32x4){0.f, 0.f, 0.f, 0.f};

  for (int k = kbase; k < kbase + Kpart; k += 32) {
#pragma unroll
    for (int j = 0; j < 4; ++j)
      gload16(P + abase[j] + k, Asf + (w * 64 + 256 * j) * 4);
#pragma unroll
    for (int c = 0; c < 2; ++c) {
      gload16(Bh + bbase[c] + k, BsH + c * 2048 + ldst);
      gload16(Bl + bbase[c] + k, BsL + c * 2048 + ldst);
    }
    __syncthreads();
    bf16x8 ah[4], al[4];
#pragma unroll
    for (int m = 0; m < 4; ++m) {
      int rrow = wr * 64 + m * 16 + l15;
      const float* ap = Asf + rrow * 32 + l16 * 8;
      f32x4 p0 = *(const f32x4*)(ap);
      f32x4 p1 = *(const f32x4*)(ap + 4);
#pragma unroll
      for (int e = 0; e < 4; ++e) {
        float f0 = p0[e], f1 = p1[e];
        u16 h0 = f2bf(f0), h1 = f2bf(f1);
        ah[m][e] = (short)h0;
        ah[m][4 + e] = (short)h1;
        al[m][e] = (short)f2bf(f0 - bf2f(h0));
        al[m][4 + e] = (short)f2bf(f1 - bf2f(h1));
      }
    }
#pragma unroll
    for (int n = 0; n < 4; ++n) {
      int rcol = wc * 64 + n * 16 + l15;
      bf16x8 bh = *(const bf16x8*)(BsH + rcol * 32 + l16 * 8);
      bf16x8 bl = *(const bf16x8*)(BsL + rcol * 32 + l16 * 8);
#pragma unroll
      for (int m = 0; m < 4; ++m) {
        acc[m][n] = MFMA(ah[m], bh, acc[m][n]);
        acc[m][n] = MFMA(ah[m], bl, acc[m][n]);
        acc[m][n] = MFMA(al[m], bh, acc[m][n]);
      }
    }
    __syncthreads();
  }

#pragma unroll
  for (int m = 0; m < 4; ++m) {
#pragma unroll
    for (int r = 0; r < 4; ++r) {
      int sr = row0 + wr * 64 + m * 16 + l16 * 4 + r;
      if (sr >= Mrows) continue;
#pragma unroll
      for (int n = 0; n < 4; ++n) {
        int c = col0 + wc * 64 + n * 16 + l15;
        if (c >= Nvalid) continue;
        float v = acc[m][n][r];
        if (mode == 0) {
          outf[(long)sr * ldo + c] = v;
        } else {
          long off = (long)rowbase[sr] + doff[c];
          splitw(v, &Oh[off], &Ol[off]);
        }
      }
    }
  }
}

// ---------------------------------------------------------------------------
__global__ __launch_bounds__(256) void reduce_scatter(
    const float* __restrict__ parts, int nparts, long pstride, int rows, int N,
    int mode, float* outf, u16* __restrict__ Oh, u16* __restrict__ Ol,
    const int* __restrict__ rowbase, const int* __restrict__ doff) {
  long gid = (long)blockIdx.x * 256 + threadIdx.x;
  long tot = (long)rows * N;
  if (gid >= tot) return;
  float s = 0.f;
  for (int p = 0; p < nparts; ++p) s += parts[p * pstride + gid];
  if (mode == 0) {
    outf[gid] = s;
  } else {
    int r = (int)(gid / N), c = (int)(gid % N);
    long off = (long)rowbase[r] + doff[c];
    splitw(s, &Oh[off], &Ol[off]);
  }
}

// ---------------------------------------------------------------------------
// In-place row softmax: row stride NtokPad, valid length Ntok. Writes fp32
// probabilities in place; zeroes pad columns [Ntok, NtokPad).
// ---------------------------------------------------------------------------
__global__ __launch_bounds__(256) void softmax_ip(float* __restrict__ S,
                                                  int Ntok, int NtokPad) {
  int row = blockIdx.x;
  float* p = S + (long)row * NtokPad;
  __shared__ float red[256];
  int t = threadIdx.x;
  float m = -1e30f;
  for (int i = t; i < Ntok; i += 256) m = fmaxf(m, p[i]);
  red[t] = m;
  __syncthreads();
  for (int s = 128; s > 0; s >>= 1) {
    if (t < s) red[t] = fmaxf(red[t], red[t + s]);
    __syncthreads();
  }
  m = red[0];
  __syncthreads();
  float sum = 0.f;
  for (int i = t; i < Ntok; i += 256) sum += __expf(p[i] - m);
  red[t] = sum;
  __syncthreads();
  for (int s = 128; s > 0; s >>= 1) {
    if (t < s) red[t] += red[t + s];
    __syncthreads();
  }
  float inv = 1.f / red[0];
  __syncthreads();
  for (int i = t; i < Ntok; i += 256) p[i] = __expf(p[i] - m) * inv;
  for (int i = Ntok + t; i < NtokPad; i += 256) p[i] = 0.f;
}

// ---------------------------------------------------------------------------
__global__ __launch_bounds__(256) void wt_build(const float* __restrict__ w,
                                                int Cout, int Cin, int taps,
                                                u16* __restrict__ Wh,
                                                u16* __restrict__ Wl) {
  long gid = (long)blockIdx.x * 256 + threadIdx.x;
  long tot = (long)taps * Cout * Cin;
  if (gid >= tot) return;
  int ic = (int)(gid % Cin);
  long r = gid / Cin;
  int oc = (int)(r % Cout);
  int tap = (int)(r / Cout);
  float v = w[((long)oc * Cin + ic) * taps + tap];
  splitw(v, &Wh[gid], &Wl[gid]);
}

// build to/ff1/ff2 weight splits (256x256x9 each) in one dispatch
__global__ __launch_bounds__(256) void wt3_build(const float* __restrict__ w0,
                                                 const float* __restrict__ w1,
                                                 const float* __restrict__ w2,
                                                 u16* __restrict__ base) {
  long gid = (long)blockIdx.x * 256 + threadIdx.x;
  if (gid >= 3L * 589824) return;
  int mat = (int)(gid / 589824);
  int idx = (int)(gid - (long)mat * 589824);
  const float* w = mat == 0 ? w0 : mat == 1 ? w1 : w2;
  int ic = idx & 255;
  int r = idx >> 8;
  int oc = r & 255;
  int tap = r >> 8;
  float v = w[((long)oc * 256 + ic) * 9 + tap];
  u16* dst = base + (long)mat * 1179648;
  splitw(v, &dst[idx], &dst[589824 + idx]);
}

// fused q/k/v 1x1 weight split build, ALL 4 groups in one dispatch.
// layout: g*16384 + c*256 + ic  (c = out-channel within group)
__global__ __launch_bounds__(256) void wtqkv_build_all(
    const float* __restrict__ wq, const float* __restrict__ wk,
    const float* __restrict__ wv, u16* __restrict__ qh, u16* __restrict__ ql,
    u16* __restrict__ kh, u16* __restrict__ kl, u16* __restrict__ vh,
    u16* __restrict__ vl) {
  int gid = blockIdx.x * 256 + threadIdx.x;
  if (gid >= 4 * 64 * 256) return;
  int ic = gid & 255;
  int c = (gid >> 8) & 63;
  int g = gid >> 14;
  long src = (long)(g * 64 + c) * 256 + ic;
  splitw(wq[src], &qh[gid], &ql[gid]);
  splitw(wk[src], &kh[gid], &kl[gid]);
  splitw(wv[src], &vh[gid], &vl[gid]);
}

// ---------------------------------------------------------------------------
__global__ __launch_bounds__(256) void maps_build(int ph, int pw, int ow,
                                                  int* __restrict__ nmap,
                                                  int* __restrict__ dmap) {
  int s = blockIdx.x * 256 + threadIdx.x;
  if (s >= 4800) return;
  int y = s / 160, x = s - y * 160;
  int i = y / ph, yy = y - i * ph;
  int j = x / pw, xx = x - j * pw;
  nmap[s] = i * ow + j;
  dmap[s] = yy * pw + xx;
}

__global__ __launch_bounds__(256) void luts_build(int ph, int pw, int ohow,
                                                  int ow, int pp, int Ntok,
                                                  int Dd, int gbase,
                                                  int* __restrict__ rowbase,
                                                  int* __restrict__ doff) {
  int gid = blockIdx.x * 256 + threadIdx.x;
  if (gid < Ntok) {
    int tt = gid / ohow, rem = gid - tt * ohow;
    int i = rem / ow, j = rem - i * ow;
    rowbase[gid] =
        tt * (32 * 162 * 256) + ((i * ph + 1) * 162 + (j * pw + 1)) * 256;
  }
  if (gid < Dd) {
    int c = gid / pp, rr = gid - c * pp;
    int yy = rr / pw, xx = rr - yy * pw;
    doff[gid] = (yy * 162 + xx) * 256 + gbase + c;
  }
}

// ---------------------------------------------------------------------------
// Bilinear x2 upsample (align_corners) CL hi/lo -> CL hi/lo. Writes the FULL
// padded output (zeros in halo) so overlaid buffers are re-cleaned per frame.
// ---------------------------------------------------------------------------
__global__ __launch_bounds__(256) void up_cl2cl_pad(
    const u16* __restrict__ sh, const u16* __restrict__ sl,
    u16* __restrict__ oh, u16* __restrict__ ol, int C, int H, int W, int Wps,
    int Poffs, int Hp, int Wpo, int Poffo) {
  int Ho = 2 * H, Wo = 2 * W;
  long tot = (long)Hp * Wpo * C;
  long gid = (long)blockIdx.x * 256 + threadIdx.x;
  if (gid >= tot) return;
  int c = (int)(gid % C);
  long r = gid / C;
  int xp = (int)(r % Wpo);
  int yp = (int)(r / Wpo);
  int x = xp - Poffo, y = yp - Poffo;
  float v = 0.f;
  if ((unsigned)x < (unsigned)Wo && (unsigned)y < (unsigned)Ho) {
    float fy = (float)(y * (H - 1)) / (float)(Ho - 1);
    float fx = (float)(x * (W - 1)) / (float)(Wo - 1);
    int y0 = (int)fy, x0 = (int)fx;
    int y1 = min(y0 + 1, H - 1), x1 = min(x0 + 1, W - 1);
    float wy = fy - y0, wx = fx - x0;
    auto rd = [&](int cy, int cx) {
      long o = ((long)(cy + Poffs) * Wps + (cx + Poffs)) * C + c;
      return bf2f(sh[o]) + bf2f(sl[o]);
    };
    float r0 = rd(y0, x0) * (1.f - wx) + rd(y0, x1) * wx;
    float r1 = rd(y1, x0) * (1.f - wx) + rd(y1, x1) * wx;
    v = r0 * (1.f - wy) + r1 * wy;
  }
  splitw(v, &oh[gid], &ol[gid]);
}

// ---------------------------------------------------------------------------
extern "C" void kernel_launch(void* const* d_in, const int* in_sizes, int n_in,
                              void* d_out, int out_size, void* d_ws,
                              size_t ws_size, hipStream_t stream) {
  const float* input = (const float*)d_in[0];
  const float* enc_w0 = (const float*)d_in[1];
  const float* enc_b0 = (const float*)d_in[2];
  const float* enc_w1 = (const float*)d_in[3];
  const float* enc_b1 = (const float*)d_in[4];
  const float* enc_w2 = (const float*)d_in[5];
  const float* enc_b2 = (const float*)d_in[6];
  const float* enc_w3 = (const float*)d_in[7];
  const float* enc_b3 = (const float*)d_in[8];
  const float* tq_w = (const float*)d_in[9];
  const float* tq_b = (const float*)d_in[10];
  const float* tk_w = (const float*)d_in[11];
  const float* tk_b = (const float*)d_in[12];
  const float* tv_w = (const float*)d_in[13];
  const float* tv_b = (const float*)d_in[14];
  const float* to_w = (const float*)d_in[15];
  const float* to_b = (const float*)d_in[16];
  const float* tf1_w = (const float*)d_in[17];
  const float* tf1_b = (const float*)d_in[18];
  const float* tf2_w = (const float*)d_in[19];
  const float* tf2_b = (const float*)d_in[20];
  const float* d0_w = (const float*)d_in[21];
  const float* d0_b = (const float*)d_in[22];
  const float* d1_w = (const float*)d_in[23];
  const float* d1_b = (const float*)d_in[24];
  const float* d2_w = (const float*)d_in[25];
  const float* d2_b = (const float*)d_in[26];
  const float* d3_w = (const float*)d_in[27];
  const float* d3_b = (const float*)d_in[28];
  float* out = (float*)d_out;

  // -------- workspace layout --------
  unsigned char* wsb = (unsigned char*)d_ws;
  size_t off = 0;
  auto alloc = [&](size_t bytes) {
    void* p = wsb + off;
    off = (off + bytes + 255) & ~(size_t)255;
    return p;
  };
  const long XCL_E = 22839296L;   // 16*34*164*256
  const long XCL2_E = 21233664L;  // 16*32*162*256
  const long QT_E = 4915200L;
  const long VT_E = 5111808L;
  u16* XCLh = (u16*)alloc(XCL_E * 2);
  u16* XCLl = (u16*)alloc(XCL_E * 2);
  u16* XCL2h = (u16*)alloc(XCL2_E * 2);
  u16* XCL2l = (u16*)alloc(XCL2_E * 2);
  u16* qth = (u16*)alloc(QT_E * 2);
  u16* qtl = (u16*)alloc(QT_E * 2);
  u16* kth = (u16*)alloc(QT_E * 2);
  u16* ktl = (u16*)alloc(QT_E * 2);
  u16* vth = (u16*)alloc(VT_E * 2);
  u16* vtl = (u16*)alloc(VT_E * 2);
  int* nmapA = (int*)alloc(4 * 4800 * 4);
  int* dmapA = (int*)alloc(4 * 4800 * 4);
  int* rowbaseA = (int*)alloc(7120 * 4);
  int* doffA = (int*)alloc(93248 * 4);
  u16* qwh = (u16*)alloc(65536 * 2);
  u16* qwl = (u16*)alloc(65536 * 2);
  u16* kwh = (u16*)alloc(65536 * 2);
  u16* kwl = (u16*)alloc(65536 * 2);
  u16* vwh = (u16*)alloc(65536 * 2);
  u16* vwl = (u16*)alloc(65536 * 2);
  // scores region (allocated LAST): fp32 scores/P in place + g3 partials;
  // also overlaid by trunk conv weight splits (wt3) between attn and convs.
  size_t fixed_end = off;
  size_t avail = ws_size > fixed_end ? ws_size - fixed_end : 0;
  size_t SCB = avail > 4096 ? avail - 4096 : 0;
  if (SCB > 104857600UL) SCB = 104857600UL;
  float* scores = (float*)alloc(SCB);
  size_t need = off;
  if (ws_size < need) return;        // fail loud, not crash
  long SCAPf = (long)(SCB / 4);
  if (SCAPf < 1800000) return;       // ~7.2 MB minimum (wt3 + g0)

  // encoder weight splits + trunk wt3 region overlay the scores region
  u16* Wth = (u16*)scores;
  u16* Wtl = Wth + 589824;
  u16* W3 = (u16*)scores;  // 3 mats x (589824 hi + 589824 lo)

  // ---- decoder buffers: overlay XCL2 + token region (dead in decoder) ----
  unsigned char* decbase = (unsigned char*)XCL2h;
  u16* dec0inH = (u16*)(decbase + 0);
  u16* dec0inL = (u16*)(decbase + 20443136);
  u16* dec0outH = (u16*)(decbase + 40886272);
  u16* dec0outL = (u16*)(decbase + 51107840);
  u16* dec1outH = (u16*)(decbase + 61329408);
  u16* dec1outL = (u16*)(decbase + 66440192);
  u16* dec2inH = (u16*)(decbase + 71550976);
  u16* dec2inL = (u16*)(decbase + 91601920);
  float* dec2out = (float*)(decbase + 0);
  u16* Wd0h = (u16*)(decbase + 111652864);
  u16* Wd0l = Wd0h + 294912;
  u16* W1h = Wd0l + 294912;
  u16* W1l = W1h + 73728;
  u16* W2h = W1l + 73728;
  u16* W2l = W2h + 36864;
  const long D0IN_FS = 5110784, D0OUT_FS = 2555392, D1OUT_FS = 1277696;
  const long D2IN_FS = 5012736, D2OUT_FS = 4915200;

  const long FS_TR = 1427456;  // 34*164*256
  const long FS_T2 = 1327104;  // 32*162*256 == 64*324*64
  const long FS_E2 = 713728;   // 34*164*128

  static const int PWa[4] = {80, 32, 10, 5};
  static const int PHa[4] = {15, 6, 5, 3};
  static const int rbOff[4] = {0, 64, 464, 2000};
  static const int doOff[4] = {0, 76800, 89088, 92288};

  // -------- encoder --------
  hipMemsetAsync(XCLh, 0, XCL_E * 2, stream);
  hipMemsetAsync(XCLl, 0, XCL_E * 2, stream);
  hipMemsetAsync(XCL2h, 0, XCL2_E * 2, stream);
  hipMemsetAsync(XCL2l, 0, XCL2_E * 2, stream);
  hipMemsetAsync(vth, 0, VT_E * 2, stream);  // pad-column zero guard
  hipMemsetAsync(vtl, 0, VT_E * 2, stream);
  {  // enc0: fp32 direct -> CL [64][324][64] Poff2 in XCL2 space
    long tot = 16L * 64 * 60 * 40;
    conv2d_k<3, 2, 1><<<cdivu(tot, 256), 256, 0, stream>>>(
        input, enc_w0, enc_b0, nullptr, XCL2h, XCL2l, 324, 2, FS_T2, 16, 3,
        120, 640, 64, 60, 320, 1, ACT_LEAKY);
  }
  {  // enc1: 64->64, 60x320 (tile 256x64)
    wt_build<<<cdivu(9L * 64 * 64, 256), 256, 0, stream>>>(enc_w1, 64, 64, 9,
                                                           Wth, Wtl);
    conv_gemm_lds<4, 1><<<dim3(75, 1, 16), 256, 0, stream>>>(
        XCL2h, XCL2l, Wth, Wtl, enc_b1, 64, 64, 60, 320, 324, 2, 1, 1, 1, 9,
        FS_T2, ACT_LEAKY, nullptr, 0, XCLh, XCLl, FS_T2, 324, 2, 0);
  }
  hipMemsetAsync(XCL2h, 0, XCL2_E * 2, stream);
  hipMemsetAsync(XCL2l, 0, XCL2_E * 2, stream);
  {  // enc2: 64->128 stride2 -> CL [34][164][128] in XCL2 space
    wt_build<<<cdivu(9L * 128 * 64, 256), 256, 0, stream>>>(enc_w2, 128, 64, 9,
                                                            Wth, Wtl);
    conv_gemm_lds<2, 2><<<dim3(38, 1, 16), 256, 0, stream>>>(
        XCLh, XCLl, Wth, Wtl, enc_b2, 64, 128, 30, 160, 324, 2, 2, 1, 1, 9,
        FS_T2, ACT_LEAKY, nullptr, 0, XCL2h, XCL2l, FS_E2, 164, 2, 0);
  }
  hipMemsetAsync(XCLh, 0, XCL_E * 2, stream);
  hipMemsetAsync(XCLl, 0, XCL_E * 2, stream);
  {  // enc3: 128->256 -> trunk XCL [34][164][256]
    wt_build<<<cdivu(9L * 256 * 128, 256), 256, 0, stream>>>(enc_w3, 256, 128,
                                                             9, Wth, Wtl);
    conv_gemm_lds<2, 2><<<dim3(38, 2, 16), 256, 0, stream>>>(
        XCL2h, XCL2l, Wth, Wtl, enc_b3, 128, 256, 30, 160, 164, 2, 1, 1, 1, 9,
        FS_E2, ACT_LEAKY, nullptr, 0, XCLh, XCLl, FS_TR, 164, 2, 0);
  }
  hipMemsetAsync(XCL2h, 0, XCL2_E * 2, stream);
  hipMemsetAsync(XCL2l, 0, XCL2_E * 2, stream);

  // -------- token maps / scatter LUTs --------
  for (int g = 0; g < 4; ++g) {
    int ph = PHa[g], pw = PWa[g];
    int ohh = 30 / ph, oww = 160 / pw;
    int Ntok = 16 * ohh * oww, Dd = 64 * ph * pw, pp = ph * pw;
    maps_build<<<19, 256, 0, stream>>>(ph, pw, oww, nmapA + g * 4800,
                                       dmapA + g * 4800);
    int mx = Ntok > Dd ? Ntok : Dd;
    luts_build<<<cdivu(mx, 256), 256, 0, stream>>>(
        ph, pw, ohh * oww, oww, pp, Ntok, Dd, g * 64, rowbaseA + rbOff[g],
        doffA + doOff[g]);
  }

  // -------- transformer stack --------
  for (int l = 0; l < 8; ++l) {
    // all 4 groups' q/k/v weight splits in one dispatch
    wtqkv_build_all<<<256, 256, 0, stream>>>(
        tq_w + (long)l * 65536, tk_w + (long)l * 65536,
        tv_w + (long)l * 65536, qwh, qwl, kwh, kwl, vwh, vwl);

    for (int g = 0; g < 4; ++g) {
      int ph = PHa[g], pw = PWa[g];
      int ohh = 30 / ph, oww = 160 / pw;
      int ohow = ohh * oww;
      int Ntok = 16 * ohow, Dd = 64 * ph * pw, pp = ph * pw;
      int NtokPad = (Ntok + 31) & ~31;
      float scale = 1.0f / sqrtf((float)Dd);
      const int* nmap = nmapA + g * 4800;
      const int* dmap = dmapA + g * 4800;
      const int* rowbase = rowbaseA + rbOff[g];
      const int* doffp = doffA + doOff[g];

      // fused Q,K,V (one dispatch; per-mat arithmetic identical to before)
      qkv3_gemm_lds<<<dim3(19, 1, 16), 256, 0, stream>>>(
          XCLh, XCLl, FS_TR, 164, 2, qwh + g * 16384, qwl + g * 16384,
          kwh + g * 16384, kwl + g * 16384, vwh + g * 16384, vwl + g * 16384,
          tq_b + l * 256 + g * 64, tk_b + l * 256 + g * 64,
          tv_b + l * 256 + g * 64, nmap, dmap, ohow, Dd, pp, NtokPad, scale,
          qth, qtl, kth, ktl, vth, vtl);

      if (g == 0) {
        // QK split-K: 32 parts of K=2400 -> partials -> reduce -> softmax
        float* scoresR = scores + 131072;
        attn_gemm_lds<<<dim3(1, 1, 32), 256, 0, stream>>>(
            qth, qtl, Dd, 64, kth, ktl, Dd, 64, 2400, 64, 0, scores, 64, 4096,
            nullptr, nullptr, nullptr, nullptr);
        reduce_scatter<<<16, 256, 0, stream>>>(scores, 32, 4096, 64, 64, 0,
                                               scoresR, nullptr, nullptr,
                                               nullptr, nullptr);
        softmax_ip<<<64, 256, 0, stream>>>(scoresR, 64, 64);
        attn_pv_lds<<<dim3(1, 600, 1), 256, 0, stream>>>(
            scoresR, 64, 64, vth, vtl, 64, Dd, 64, Dd, 1, nullptr, 0, 0,
            XCL2h, XCL2l, rowbase, doffp);
      } else {
        long denom = (long)NtokPad + (g == 3 ? 3840 : 0);
        long cap = (SCAPf / denom) & ~127L;
        int chunk = (int)(cap < 128 ? 128 : cap);
        if (chunk > Ntok) chunk = Ntok;
        float* partials = scores + (long)chunk * NtokPad;
        for (int r0 = 0; r0 < Ntok; r0 += chunk) {
          int rows = Ntok - r0 < chunk ? Ntok - r0 : chunk;
          attn_gemm_lds<<<dim3(cdivu(rows, 128), cdivu(Ntok, 128), 1), 256, 0,
                          stream>>>(qth + (long)r0 * Dd, qtl + (long)r0 * Dd,
                                    Dd, rows, kth, ktl, Dd, Ntok, Dd, Ntok, 0,
                                    scores, NtokPad, 0, nullptr, nullptr,
                                    nullptr, nullptr);
          softmax_ip<<<rows, 256, 0, stream>>>(scores, Ntok, NtokPad);
          if (g == 3) {
            attn_pv_lds<<<dim3(cdivu(rows, 128), 8, 4), 256, 0, stream>>>(
                scores, NtokPad, rows, vth, vtl, NtokPad, Dd, 1280, Dd, 0,
                partials, 960, (long)rows * 960, nullptr, nullptr, nullptr,
                nullptr);
            reduce_scatter<<<cdivu((long)rows * 960, 256), 256, 0, stream>>>(
                partials, 4, (long)rows * 960, rows, 960, 1, nullptr, XCL2h,
                XCL2l, rowbase + r0, doffp);
          } else {
            attn_pv_lds<<<dim3(cdivu(rows, 128), Dd / 128, 1), 256, 0,
                          stream>>>(scores, NtokPad, rows, vth, vtl, NtokPad,
                                    Dd, NtokPad, Dd, 1, nullptr, 0, 0, XCL2h,
                                    XCL2l, rowbase + r0, doffp);
          }
        }
      }
    }

    // build to/ff1/ff2 weight splits in ONE dispatch (scores region is free)
    wt3_build<<<6912, 256, 0, stream>>>(to_w + (long)l * 589824,
                                        tf1_w + (long)l * 589824,
                                        tf2_w + (long)l * 589824, W3);
    // out-conv 3x3 + leaky + residual (in-place on XCL)
    conv_gemm_lds<2, 2><<<dim3(38, 2, 16), 256, 0, stream>>>(
        XCL2h, XCL2l, W3, W3 + 589824, to_b + l * 256, 256, 256, 30, 160, 162,
        1, 1, 1, 1, 9, FS_T2, ACT_LEAKY, nullptr, 0, XCLh, XCLl, FS_TR, 164, 2,
        1);
    // ff1: dil2 pad2
    conv_gemm_lds<2, 2><<<dim3(38, 2, 16), 256, 0, stream>>>(
        XCLh, XCLl, W3 + 1179648, W3 + 1769472, tf1_b + l * 256, 256, 256, 30,
        160, 164, 2, 1, 2, 2, 9, FS_TR, ACT_LEAKY, nullptr, 0, XCL2h, XCL2l,
        FS_T2, 162, 1, 0);
    // ff2 + residual (in-place on XCL)
    conv_gemm_lds<2, 2><<<dim3(38, 2, 16), 256, 0, stream>>>(
        XCL2h, XCL2l, W3 + 2359296, W3 + 2949120, tf2_b + l * 256, 256, 256,
        30, 160, 162, 1, 1, 1, 1, 9, FS_T2, ACT_LEAKY, nullptr, 0, XCLh, XCLl,
        FS_TR, 164, 2, 1);
  }

  // -------- decoder (2-frame groups; overlays XCL2+token region) --------
  hipMemsetAsync(decbase, 0, 111652864, stream);
  wt_build<<<cdivu(9L * 128 * 256, 256), 256, 0, stream>>>(d0_w, 128, 256, 9,
                                                           Wd0h, Wd0l);
  wt_build<<<cdivu(9L * 64 * 128, 256), 256, 0, stream>>>(d1_w, 64, 128, 9,
                                                          W1h, W1l);
  wt_build<<<cdivu(9L * 64 * 64, 256), 256, 0, stream>>>(d2_w, 64, 64, 9, W2h,
                                                         W2l);
  for (int f = 0; f < 16; f += 2) {
    for (int ff = 0; ff < 2; ++ff)
      up_cl2cl_pad<<<cdivu(62L * 322 * 256, 256), 256, 0, stream>>>(
          XCLh + (long)(f + ff) * FS_TR, XCLl + (long)(f + ff) * FS_TR,
          dec0inH + (long)ff * D0IN_FS, dec0inL + (long)ff * D0IN_FS, 256, 30,
          160, 164, 2, 62, 322, 1);
    conv_gemm_lds<2, 2><<<dim3(150, 1, 2), 256, 0, stream>>>(
        dec0inH, dec0inL, Wd0h, Wd0l, d0_b, 256, 128, 60, 320, 322, 1, 1, 1, 1,
        9, D0IN_FS, ACT_LEAKY, nullptr, 0, dec0outH, dec0outL, D0OUT_FS, 322,
        1, 0);
    conv_gemm_lds<4, 1><<<dim3(75, 1, 2), 256, 0, stream>>>(
        dec0outH, dec0outL, W1h, W1l, d1_b, 128, 64, 60, 320, 322, 1, 1, 1, 1,
        9, D0OUT_FS, ACT_LEAKY, nullptr, 0, dec1outH, dec1outL, D1OUT_FS, 322,
        1, 0);
    for (int ff = 0; ff < 2; ++ff)
      up_cl2cl_pad<<<cdivu(122L * 642 * 64, 256), 256, 0, stream>>>(
          dec1outH + (long)ff * D1OUT_FS, dec1outL + (long)ff * D1OUT_FS,
          dec2inH + (long)ff * D2IN_FS, dec2inL + (long)ff * D2IN_FS, 64, 60,
          320, 322, 1, 122, 642, 1);
    conv_gemm_lds<4, 1><<<dim3(300, 1, 2), 256, 0, stream>>>(
        dec2inH, dec2inL, W2h, W2l, d2_b, 64, 64, 120, 640, 642, 1, 1, 1, 1, 9,
        D2IN_FS, ACT_LEAKY, dec2out, D2OUT_FS, nullptr, nullptr, 0, 0, 0, 0);
    {
      long tot = 2L * 3 * 120 * 80;
      conv2d_k<3, 1, 1><<<cdivu(tot, 256), 256, 0, stream>>>(
          dec2out, d3_w, d3_b, out + (long)f * 230400, nullptr, nullptr, 0, 0,
          0, 2, 64, 120, 640, 3, 120, 640, 1, ACT_TANH);
    }
  }
}

// Round 12
// 33061.404 us; speedup vs baseline: 31.0242x; 1.1194x over previous
//
#include <hip/hip_runtime.h>
#include <hip/hip_bf16.h>
#include <math.h>

#define ACT_NONE 0
#define ACT_LEAKY 1
#define ACT_TANH 2

typedef __attribute__((ext_vector_type(8))) short bf16x8;
typedef __attribute__((ext_vector_type(4))) float f32x4;
typedef unsigned short u16;

#define MFMA(a, b, c) __builtin_amdgcn_mfma_f32_16x16x32_bf16((bf16x8)(a), (bf16x8)(b), (c), 0, 0, 0)

static inline unsigned cdivu(long a, long b) { return (unsigned)((a + b - 1) / b); }

__device__ __forceinline__ u16 f2bf(float x) {
  union { __hip_bfloat16 h; u16 u; } cv;
  cv.h = __float2bfloat16(x);
  return cv.u;
}
__device__ __forceinline__ float bf2f(u16 b) {
  union { u16 u; __hip_bfloat16 h; } cv;
  cv.u = b;
  return __bfloat162float(cv.h);
}
__device__ __forceinline__ void splitw(float v, u16* ph, u16* pl) {
  u16 h = f2bf(v);
  *ph = h;
  *pl = f2bf(v - bf2f(h));
}
// async global->LDS, 16B per lane; dest must be wave-uniform base (+lane*16)
__device__ __forceinline__ void gload16(const void* g, void* l) {
  __builtin_amdgcn_global_load_lds(
      (const __attribute__((address_space(1))) unsigned int*)g,
      (__attribute__((address_space(3))) unsigned int*)l, 16, 0, 0);
}

// ---------------------------------------------------------------------------
// Direct fp32 conv (enc0: Cin=3; d3: Cout=3+tanh). Optional CL hi/lo output.
// ---------------------------------------------------------------------------
template <int K, int S, int DIL>
__global__ __launch_bounds__(256) void conv2d_k(
    const float* __restrict__ x, const float* __restrict__ w,
    const float* __restrict__ bias, float* y, u16* clh, u16* cll, int WpO,
    int PoffO, long o_fstride, int N, int Cin, int Hin, int Win, int Cout,
    int Hout, int Wout, int pad, int act) {
  constexpr int TW = 8;
  constexpr int XL = (TW - 1) * S + (K - 1) * DIL + 1;
  int wq = (Wout + TW - 1) / TW;
  long gid = (long)blockIdx.x * 256 + threadIdx.x;
  long total = (long)N * Cout * Hout * wq;
  if (gid >= total) return;
  int xg = (int)(gid % wq);
  long r = gid / wq;
  int yo = (int)(r % Hout);
  r /= Hout;
  int oc = (int)(r % Cout);
  int n = (int)(r / Cout);

  float bv = bias[oc];
  float acc[TW];
#pragma unroll
  for (int j = 0; j < TW; ++j) acc[j] = bv;

  int xo0 = xg * TW;
  int xi0 = xo0 * S - pad;
  const float* xn = x + (long)n * Cin * Hin * Win;
  const float* wb = w + (long)oc * Cin * K * K;

  for (int ic = 0; ic < Cin; ++ic) {
    const float* xc = xn + (long)ic * Hin * Win;
    const float* wc = wb + ic * (K * K);
#pragma unroll
    for (int ky = 0; ky < K; ++ky) {
      int yi = yo * S - pad + ky * DIL;
      if ((unsigned)yi < (unsigned)Hin) {
        const float* row = xc + (long)yi * Win;
        float xr[XL];
#pragma unroll
        for (int i2 = 0; i2 < XL; ++i2) {
          int xi = xi0 + i2;
          xr[i2] = ((unsigned)xi < (unsigned)Win) ? row[xi] : 0.f;
        }
#pragma unroll
        for (int kx = 0; kx < K; ++kx) {
          float wv = wc[ky * K + kx];
#pragma unroll
          for (int j = 0; j < TW; ++j)
            acc[j] = fmaf(wv, xr[j * S + kx * DIL], acc[j]);
        }
      }
    }
  }

#pragma unroll
  for (int j = 0; j < TW; ++j) {
    if (xo0 + j < Wout) {
      float v = acc[j];
      if (act == ACT_LEAKY)
        v = v >= 0.f ? v : 0.2f * v;
      else if (act == ACT_TANH)
        v = tanhf(v);
      if (y) y[(((long)n * Cout + oc) * Hout + yo) * Wout + xo0 + j] = v;
      if (clh) {
        long off = (long)n * o_fstride +
                   ((long)(yo + PoffO) * WpO + (xo0 + j + PoffO)) * Cout + oc;
        splitw(v, &clh[off], &cll[off]);
      }
    }
  }
}

// ---------------------------------------------------------------------------
// LDS-staged MFMA implicit-GEMM conv (m97 2-barrier structure).
// ---------------------------------------------------------------------------
template <int WM, int WN>
__global__ __launch_bounds__(256) void conv_gemm_lds(
    const u16* __restrict__ Ah, const u16* __restrict__ Al,
    const u16* __restrict__ Bh, const u16* __restrict__ Bl,
    const float* __restrict__ bias, int Cin, int Cout, int Hout, int Wout,
    int Wp, int Poff, int S, int DIL, int pad, int taps, long a_fstride,
    int act, float* yout, long y_fstride, u16* Oh, u16* Ol, long o_fstride,
    int WpO, int PoffO, int useres) {
  constexpr int TM = WM * 64, TN = WN * 64;
  __shared__ u16 AsH[TM * 32], AsL[TM * 32], BsH[TN * 32], BsL[TN * 32];
  int t = threadIdx.x;
  int lane = t & 63;
  int w = t >> 6;
  int wr = w / WN, wc = w % WN;
  int l15 = lane & 15, l16 = lane >> 4;
  int HW = Hout * Wout;
  int row0 = blockIdx.x * TM;
  int col0 = blockIdx.y * TN;
  const u16* Afh = Ah + (long)blockIdx.z * a_fstride;
  const u16* Afl = Al + (long)blockIdx.z * a_fstride;

  int rs = t >> 2;
  int cs = (t & 3) * 8;
  long abase[WM];
#pragma unroll
  for (int c = 0; c < WM; ++c) {
    int s = row0 + rs + 64 * c;
    if (s >= HW) s = HW - 1;
    int yo = s / Wout, xo = s - yo * Wout;
    int yb = yo * S - pad + Poff, xb = xo * S - pad + Poff;
    abase[c] = ((long)yb * Wp + xb) * Cin + cs;
  }
  long bbase[WN];
#pragma unroll
  for (int c = 0; c < WN; ++c)
    bbase[c] = (long)(col0 + rs + 64 * c) * Cin + cs;
  int ldst = w * 512;

  f32x4 acc[4][4];
#pragma unroll
  for (int m = 0; m < 4; ++m)
#pragma unroll
    for (int n = 0; n < 4; ++n) acc[m][n] = (f32x4){0.f, 0.f, 0.f, 0.f};

  for (int tap = 0; tap < taps; ++tap) {
    int ky = tap / 3, kx = tap - ky * 3;
    long atap = ((long)ky * DIL * Wp + kx * DIL) * Cin;
    long btap = (long)tap * Cout * Cin;
    for (int ic0 = 0; ic0 < Cin; ic0 += 32) {
#pragma unroll
      for (int c = 0; c < WM; ++c) {
        gload16(Afh + abase[c] + atap + ic0, AsH + c * 2048 + ldst);
        gload16(Afl + abase[c] + atap + ic0, AsL + c * 2048 + ldst);
      }
#pragma unroll
      for (int c = 0; c < WN; ++c) {
        gload16(Bh + bbase[c] + btap + ic0, BsH + c * 2048 + ldst);
        gload16(Bl + bbase[c] + btap + ic0, BsL + c * 2048 + ldst);
      }
      __syncthreads();
      bf16x8 ah[4], al[4];
#pragma unroll
      for (int m = 0; m < 4; ++m) {
        int rrow = wr * 64 + m * 16 + l15;
        ah[m] = *(const bf16x8*)(AsH + rrow * 32 + l16 * 8);
        al[m] = *(const bf16x8*)(AsL + rrow * 32 + l16 * 8);
      }
#pragma unroll
      for (int n = 0; n < 4; ++n) {
        int rcol = wc * 64 + n * 16 + l15;
        bf16x8 bh = *(const bf16x8*)(BsH + rcol * 32 + l16 * 8);
        bf16x8 bl = *(const bf16x8*)(BsL + rcol * 32 + l16 * 8);
#pragma unroll
        for (int m = 0; m < 4; ++m) {
          acc[m][n] = MFMA(ah[m], bh, acc[m][n]);
          acc[m][n] = MFMA(ah[m], bl, acc[m][n]);
          acc[m][n] = MFMA(al[m], bh, acc[m][n]);
        }
      }
      __syncthreads();
    }
  }

  float* yf = yout ? yout + (long)blockIdx.z * y_fstride : nullptr;
  u16* Ofh = Oh ? Oh + (long)blockIdx.z * o_fstride : nullptr;
  u16* Ofl = Ol ? Ol + (long)blockIdx.z * o_fstride : nullptr;
#pragma unroll
  for (int m = 0; m < 4; ++m) {
#pragma unroll
    for (int r = 0; r < 4; ++r) {
      int s = row0 + wr * 64 + m * 16 + l16 * 4 + r;
      if (s >= HW) continue;
      int yo = s / Wout, xo = s - yo * Wout;
      long clbase = 0;
      if (Ofh) clbase = ((long)(yo + PoffO) * WpO + (xo + PoffO)) * Cout;
#pragma unroll
      for (int n = 0; n < 4; ++n) {
        int oc = col0 + wc * 64 + n * 16 + l15;
        float v = acc[m][n][r] + bias[oc];
        if (act == ACT_LEAKY) v = v >= 0.f ? v : 0.2f * v;
        if (Ofh) {
          long off = clbase + oc;
          if (useres) v += bf2f(Ofh[off]) + bf2f(Ofl[off]);
          splitw(v, &Ofh[off], &Ofl[off]);
        }
        if (yf) yf[((long)oc * Hout + yo) * Wout + xo] = v;
      }
    }
  }
}

// ---------------------------------------------------------------------------
// Fused QKV 1x1 GEMM (one dispatch computes Q,K,V). Tile 256x64, 4 waves.
// Token feature layout d = dm*64 + c  (channels innermost -> coalesced
// token writes for Q,K; PV scatter also coalesced via matching LUT).
// ---------------------------------------------------------------------------
__global__ __launch_bounds__(256) void qkv3_gemm_lds(
    const u16* __restrict__ Ah, const u16* __restrict__ Al, long a_fstride,
    int Wp, int Poff, const u16* __restrict__ qwh, const u16* __restrict__ qwl,
    const u16* __restrict__ kwh, const u16* __restrict__ kwl,
    const u16* __restrict__ vwh, const u16* __restrict__ vwl,
    const float* __restrict__ qbias, const float* __restrict__ kbias,
    const float* __restrict__ vbias, const int* __restrict__ nmap,
    const int* __restrict__ dmap, int ohow, int Dd, int pp, int NtokPad,
    float scale, u16* __restrict__ tqh, u16* __restrict__ tql,
    u16* __restrict__ tkh, u16* __restrict__ tkl, u16* __restrict__ tvh,
    u16* __restrict__ tvl) {
  __shared__ u16 AsH[256 * 32], AsL[256 * 32], BsH[64 * 32], BsL[64 * 32];
  int t = threadIdx.x;
  int lane = t & 63;
  int w = t >> 6;
  int l15 = lane & 15, l16 = lane >> 4;
  int row0 = blockIdx.x * 256;
  int frame = blockIdx.z;
  const u16* Afh = Ah + (long)frame * a_fstride;
  const u16* Afl = Al + (long)frame * a_fstride;

  int rs = t >> 2;
  int cs = (t & 3) * 8;
  long abase[4];
#pragma unroll
  for (int c = 0; c < 4; ++c) {
    int s = row0 + rs + 64 * c;
    if (s >= 4800) s = 4799;
    int yo = s / 160, xo = s - yo * 160;
    abase[c] = ((long)(yo + Poff) * Wp + (xo + Poff)) * 256 + cs;
  }
  long bbase = (long)rs * 256 + cs;
  int ldst = w * 512;

  for (int mat = 0; mat < 3; ++mat) {
    const u16* Bh = mat == 0 ? qwh : mat == 1 ? kwh : vwh;
    const u16* Bl = mat == 0 ? qwl : mat == 1 ? kwl : vwl;
    const float* bias = mat == 0 ? qbias : mat == 1 ? kbias : vbias;
    u16* tH = mat == 0 ? tqh : mat == 1 ? tkh : tvh;
    u16* tL = mat == 0 ? tql : mat == 1 ? tkl : tvl;

    f32x4 acc[4][4];
#pragma unroll
    for (int m = 0; m < 4; ++m)
#pragma unroll
      for (int n = 0; n < 4; ++n) acc[m][n] = (f32x4){0.f, 0.f, 0.f, 0.f};

    for (int ic0 = 0; ic0 < 256; ic0 += 32) {
#pragma unroll
      for (int c = 0; c < 4; ++c) {
        gload16(Afh + abase[c] + ic0, AsH + c * 2048 + ldst);
        gload16(Afl + abase[c] + ic0, AsL + c * 2048 + ldst);
      }
      gload16(Bh + bbase + ic0, BsH + ldst);
      gload16(Bl + bbase + ic0, BsL + ldst);
      __syncthreads();
      bf16x8 ah[4], al[4];
#pragma unroll
      for (int m = 0; m < 4; ++m) {
        int rrow = w * 64 + m * 16 + l15;
        ah[m] = *(const bf16x8*)(AsH + rrow * 32 + l16 * 8);
        al[m] = *(const bf16x8*)(AsL + rrow * 32 + l16 * 8);
      }
#pragma unroll
      for (int n = 0; n < 4; ++n) {
        int rcol = n * 16 + l15;
        bf16x8 bh = *(const bf16x8*)(BsH + rcol * 32 + l16 * 8);
        bf16x8 bl = *(const bf16x8*)(BsL + rcol * 32 + l16 * 8);
#pragma unroll
        for (int m = 0; m < 4; ++m) {
          acc[m][n] = MFMA(ah[m], bh, acc[m][n]);
          acc[m][n] = MFMA(ah[m], bl, acc[m][n]);
          acc[m][n] = MFMA(al[m], bh, acc[m][n]);
        }
      }
      __syncthreads();
    }

#pragma unroll
    for (int m = 0; m < 4; ++m) {
#pragma unroll
      for (int r = 0; r < 4; ++r) {
        int s = row0 + w * 64 + m * 16 + l16 * 4 + r;
        if (s >= 4800) continue;
        int nm = nmap[s], dm = dmap[s];
        int ntok = frame * ohow + nm;
#pragma unroll
        for (int n = 0; n < 4; ++n) {
          int c = n * 16 + l15;
          float v = acc[m][n][r] + bias[c];
          if (mat == 0) v *= scale;
          int d = dm * 64 + c;  // channels innermost
          long off = (mat == 2) ? ((long)d * NtokPad + ntok)
                                : ((long)ntok * Dd + d);
          splitw(v, &tH[off], &tL[off]);
        }
      }
    }
  }
}

// ---------------------------------------------------------------------------
// LDS-staged attention GEMM (tile 128x128, 256 thr). Used for QK. mode 0:
// fp32 out (split-K via z).
// ---------------------------------------------------------------------------
__global__ __launch_bounds__(256) void attn_gemm_lds(
    const u16* __restrict__ Ah, const u16* __restrict__ Al, int lda, int Mrows,
    const u16* __restrict__ Bh, const u16* __restrict__ Bl, int ldb,
    int Nclamp, int Kpart, int Nvalid, int mode, float* outf, int ldo,
    long partstride, u16* __restrict__ Oh, u16* __restrict__ Ol,
    const int* __restrict__ rowbase, const int* __restrict__ doff) {
  __shared__ u16 AsH[128 * 32], AsL[128 * 32], BsH[128 * 32], BsL[128 * 32];
  int t = threadIdx.x;
  int lane = t & 63;
  int w = t >> 6;
  int wc = w & 1, wr = w >> 1;
  int l15 = lane & 15, l16 = lane >> 4;
  int row0 = blockIdx.x * 128;
  int col0 = blockIdx.y * 128;
  int kbase = blockIdx.z * Kpart;
  if (outf) outf += (long)blockIdx.z * partstride;

  int rs = t >> 2;
  int cs = (t & 3) * 8;
  long abase[2], bbase[2];
#pragma unroll
  for (int c = 0; c < 2; ++c) {
    int sr = row0 + rs + 64 * c;
    if (sr >= Mrows) sr = Mrows - 1;
    abase[c] = (long)sr * lda + cs;
    int cc = col0 + rs + 64 * c;
    if (cc >= Nclamp) cc = Nclamp - 1;
    bbase[c] = (long)cc * ldb + cs;
  }
  int ldst = w * 512;

  f32x4 acc[4][4];
#pragma unroll
  for (int m = 0; m < 4; ++m)
#pragma unroll
    for (int n = 0; n < 4; ++n) acc[m][n] = (f32x4){0.f, 0.f, 0.f, 0.f};

  for (int k = kbase; k < kbase + Kpart; k += 32) {
#pragma unroll
    for (int c = 0; c < 2; ++c) {
      gload16(Ah + abase[c] + k, AsH + c * 2048 + ldst);
      gload16(Al + abase[c] + k, AsL + c * 2048 + ldst);
      gload16(Bh + bbase[c] + k, BsH + c * 2048 + ldst);
      gload16(Bl + bbase[c] + k, BsL + c * 2048 + ldst);
    }
    __syncthreads();
    bf16x8 ah[4], al[4];
#pragma unroll
    for (int m = 0; m < 4; ++m) {
      int rrow = wr * 64 + m * 16 + l15;
      ah[m] = *(const bf16x8*)(AsH + rrow * 32 + l16 * 8);
      al[m] = *(const bf16x8*)(AsL + rrow * 32 + l16 * 8);
    }
#pragma unroll
    for (int n = 0; n < 4; ++n) {
      int rcol = wc * 64 + n * 16 + l15;
      bf16x8 bh = *(const bf16x8*)(BsH + rcol * 32 + l16 * 8);
      bf16x8 bl = *(const bf16x8*)(BsL + rcol * 32 + l16 * 8);
#pragma unroll
      for (int m = 0; m < 4; ++m) {
        acc[m][n] = MFMA(ah[m], bh, acc[m][n]);
        acc[m][n] = MFMA(ah[m], bl, acc[m][n]);
        acc[m][n] = MFMA(al[m], bh, acc[m][n]);
      }
    }
    __syncthreads();
  }

#pragma unroll
  for (int m = 0; m < 4; ++m) {
#pragma unroll
    for (int r = 0; r < 4; ++r) {
      int sr = row0 + wr * 64 + m * 16 + l16 * 4 + r;
      if (sr >= Mrows) continue;
#pragma unroll
      for (int n = 0; n < 4; ++n) {
        int c = col0 + wc * 64 + n * 16 + l15;
        if (c >= Nvalid) continue;
        float v = acc[m][n][r];
        if (mode == 0) {
          outf[(long)sr * ldo + c] = v;
        } else {
          long off = (long)rowbase[sr] + doff[c];
          splitw(v, &Oh[off], &Ol[off]);
        }
      }
    }
  }
}

// ---------------------------------------------------------------------------
// PV GEMM: A = fp32 P rows, split to hi/lo bf16 on the fly. B = split V.
// Tile 128x128. mode 0: fp32 partials; mode 1: CL scatter (coalesced: the
// d-layout has channels innermost so doff[c] is contiguous in c).
// ---------------------------------------------------------------------------
__global__ __launch_bounds__(256) void attn_pv_lds(
    const float* __restrict__ P, int lda, int Mrows,
    const u16* __restrict__ Bh, const u16* __restrict__ Bl, int ldb,
    int Nclamp, int Kpart, int Nvalid, int mode, float* outf, int ldo,
    long partstride, u16* __restrict__ Oh, u16* __restrict__ Ol,
    const int* __restrict__ rowbase, const int* __restrict__ doff) {
  __shared__ float Asf[128 * 32];
  __shared__ u16 BsH[128 * 32], BsL[128 * 32];
  int t = threadIdx.x;
  int lane = t & 63;
  int w = t >> 6;
  int wc = w & 1, wr = w >> 1;
  int l15 = lane & 15, l16 = lane >> 4;
  int row0 = blockIdx.x * 128;
  int col0 = blockIdx.y * 128;
  int kbase = blockIdx.z * Kpart;
  if (outf) outf += (long)blockIdx.z * partstride;

  int arow = t >> 3;
  int acol = (t & 7) * 4;
  long abase[4];
#pragma unroll
  for (int j = 0; j < 4; ++j) {
    int r = row0 + arow + 32 * j;
    if (r >= Mrows) r = Mrows - 1;
    abase[j] = (long)r * lda + acol;
  }
  int rs = t >> 2;
  int cs = (t & 3) * 8;
  long bbase[2];
#pragma unroll
  for (int c = 0; c < 2; ++c) {
    int cc = col0 + rs + 64 * c;
    if (cc >= Nclamp) cc = Nclamp - 1;
    bbase[c] = (long)cc * ldb + cs;
  }
  int ldst = w * 512;

  f32x4 acc[4][4];
#pragma unroll
  for (int m = 0; m < 4; ++m)
#pragma unroll
    for (int n = 0; n < 4; ++n) acc[m][n] = (f32x4){0.f, 0.f, 0.f, 0.f};

  for (int k = kbase; k < kbase + Kpart; k += 32) {
#pragma unroll
    for (int j = 0; j < 4; ++j)
      gload16(P + abase[j] + k, Asf + (w * 64 + 256 * j) * 4);
#pragma unroll
    for (int c = 0; c < 2; ++c) {
      gload16(Bh + bbase[c] + k, BsH + c * 2048 + ldst);
      gload16(Bl + bbase[c] + k, BsL + c * 2048 + ldst);
    }
    __syncthreads();
    bf16x8 ah[4], al[4];
#pragma unroll
    for (int m = 0; m < 4; ++m) {
      int rrow = wr * 64 + m * 16 + l15;
      const float* ap = Asf + rrow * 32 + l16 * 8;
      f32x4 p0 = *(const f32x4*)(ap);
      f32x4 p1 = *(const f32x4*)(ap + 4);
#pragma unroll
      for (int e = 0; e < 4; ++e) {
        float f0 = p0[e], f1 = p1[e];
        u16 h0 = f2bf(f0), h1 = f2bf(f1);
        ah[m][e] = (short)h0;
        ah[m][4 + e] = (short)h1;
        al[m][e] = (short)f2bf(f0 - bf2f(h0));
        al[m][4 + e] = (short)f2bf(f1 - bf2f(h1));
      }
    }
#pragma unroll
    for (int n = 0; n < 4; ++n) {
      int rcol = wc * 64 + n * 16 + l15;
      bf16x8 bh = *(const bf16x8*)(BsH + rcol * 32 + l16 * 8);
      bf16x8 bl = *(const bf16x8*)(BsL + rcol * 32 + l16 * 8);
#pragma unroll
      for (int m = 0; m < 4; ++m) {
        acc[m][n] = MFMA(ah[m], bh, acc[m][n]);
        acc[m][n] = MFMA(ah[m], bl, acc[m][n]);
        acc[m][n] = MFMA(al[m], bh, acc[m][n]);
      }
    }
    __syncthreads();
  }

#pragma unroll
  for (int m = 0; m < 4; ++m) {
#pragma unroll
    for (int r = 0; r < 4; ++r) {
      int sr = row0 + wr * 64 + m * 16 + l16 * 4 + r;
      if (sr >= Mrows) continue;
#pragma unroll
      for (int n = 0; n < 4; ++n) {
        int c = col0 + wc * 64 + n * 16 + l15;
        if (c >= Nvalid) continue;
        float v = acc[m][n][r];
        if (mode == 0) {
          outf[(long)sr * ldo + c] = v;
        } else {
          long off = (long)rowbase[sr] + doff[c];
          splitw(v, &Oh[off], &Ol[off]);
        }
      }
    }
  }
}

// ---------------------------------------------------------------------------
__global__ __launch_bounds__(256) void reduce_scatter(
    const float* __restrict__ parts, int nparts, long pstride, int rows, int N,
    int mode, float* outf, u16* __restrict__ Oh, u16* __restrict__ Ol,
    const int* __restrict__ rowbase, const int* __restrict__ doff) {
  long gid = (long)blockIdx.x * 256 + threadIdx.x;
  long tot = (long)rows * N;
  if (gid >= tot) return;
  float s = 0.f;
  for (int p = 0; p < nparts; ++p) s += parts[p * pstride + gid];
  if (mode == 0) {
    outf[gid] = s;
  } else {
    int r = (int)(gid / N), c = (int)(gid % N);
    long off = (long)rowbase[r] + doff[c];
    splitw(s, &Oh[off], &Ol[off]);
  }
}

// ---------------------------------------------------------------------------
// In-place row softmax: row stride NtokPad, valid length Ntok.
// ---------------------------------------------------------------------------
__global__ __launch_bounds__(256) void softmax_ip(float* __restrict__ S,
                                                  int Ntok, int NtokPad) {
  int row = blockIdx.x;
  float* p = S + (long)row * NtokPad;
  __shared__ float red[256];
  int t = threadIdx.x;
  float m = -1e30f;
  for (int i = t; i < Ntok; i += 256) m = fmaxf(m, p[i]);
  red[t] = m;
  __syncthreads();
  for (int s = 128; s > 0; s >>= 1) {
    if (t < s) red[t] = fmaxf(red[t], red[t + s]);
    __syncthreads();
  }
  m = red[0];
  __syncthreads();
  float sum = 0.f;
  for (int i = t; i < Ntok; i += 256) sum += __expf(p[i] - m);
  red[t] = sum;
  __syncthreads();
  for (int s = 128; s > 0; s >>= 1) {
    if (t < s) red[t] += red[t + s];
    __syncthreads();
  }
  float inv = 1.f / red[0];
  __syncthreads();
  for (int i = t; i < Ntok; i += 256) p[i] = __expf(p[i] - m) * inv;
  for (int i = Ntok + t; i < NtokPad; i += 256) p[i] = 0.f;
}

// ---------------------------------------------------------------------------
__global__ __launch_bounds__(256) void wt_build(const float* __restrict__ w,
                                                int Cout, int Cin, int taps,
                                                u16* __restrict__ Wh,
                                                u16* __restrict__ Wl) {
  long gid = (long)blockIdx.x * 256 + threadIdx.x;
  long tot = (long)taps * Cout * Cin;
  if (gid >= tot) return;
  int ic = (int)(gid % Cin);
  long r = gid / Cin;
  int oc = (int)(r % Cout);
  int tap = (int)(r / Cout);
  float v = w[((long)oc * Cin + ic) * taps + tap];
  splitw(v, &Wh[gid], &Wl[gid]);
}

// build to/ff1/ff2 weight splits (256x256x9 each) in one dispatch
__global__ __launch_bounds__(256) void wt3_build(const float* __restrict__ w0,
                                                 const float* __restrict__ w1,
                                                 const float* __restrict__ w2,
                                                 u16* __restrict__ base) {
  long gid = (long)blockIdx.x * 256 + threadIdx.x;
  if (gid >= 3L * 589824) return;
  int mat = (int)(gid / 589824);
  int idx = (int)(gid - (long)mat * 589824);
  const float* w = mat == 0 ? w0 : mat == 1 ? w1 : w2;
  int ic = idx & 255;
  int r = idx >> 8;
  int oc = r & 255;
  int tap = r >> 8;
  float v = w[((long)oc * 256 + ic) * 9 + tap];
  u16* dst = base + (long)mat * 1179648;
  splitw(v, &dst[idx], &dst[589824 + idx]);
}

// fused q/k/v 1x1 weight split build, ALL 4 groups in one dispatch.
__global__ __launch_bounds__(256) void wtqkv_build_all(
    const float* __restrict__ wq, const float* __restrict__ wk,
    const float* __restrict__ wv, u16* __restrict__ qh, u16* __restrict__ ql,
    u16* __restrict__ kh, u16* __restrict__ kl, u16* __restrict__ vh,
    u16* __restrict__ vl) {
  int gid = blockIdx.x * 256 + threadIdx.x;
  if (gid >= 4 * 64 * 256) return;
  int ic = gid & 255;
  int c = (gid >> 8) & 63;
  int g = gid >> 14;
  long src = (long)(g * 64 + c) * 256 + ic;
  splitw(wq[src], &qh[gid], &ql[gid]);
  splitw(wk[src], &kh[gid], &kl[gid]);
  splitw(wv[src], &vh[gid], &vl[gid]);
}

// ---------------------------------------------------------------------------
__global__ __launch_bounds__(256) void maps_build(int ph, int pw, int ow,
                                                  int* __restrict__ nmap,
                                                  int* __restrict__ dmap) {
  int s = blockIdx.x * 256 + threadIdx.x;
  if (s >= 4800) return;
  int y = s / 160, x = s - y * 160;
  int i = y / ph, yy = y - i * ph;
  int j = x / pw, xx = x - j * pw;
  nmap[s] = i * ow + j;
  dmap[s] = yy * pw + xx;
}

// d = dm*64 + ch  (channels innermost). doff[d] contiguous in ch.
__global__ __launch_bounds__(256) void luts_build(int ph, int pw, int ohow,
                                                  int ow, int pp, int Ntok,
                                                  int Dd, int gbase,
                                                  int* __restrict__ rowbase,
                                                  int* __restrict__ doff) {
  int gid = blockIdx.x * 256 + threadIdx.x;
  if (gid < Ntok) {
    int tt = gid / ohow, rem = gid - tt * ohow;
    int i = rem / ow, j = rem - i * ow;
    rowbase[gid] =
        tt * (32 * 162 * 256) + ((i * ph + 1) * 162 + (j * pw + 1)) * 256;
  }
  if (gid < Dd) {
    int ch = gid & 63;
    int dm = gid >> 6;
    int yy = dm / pw, xx = dm - yy * pw;
    doff[gid] = (yy * 162 + xx) * 256 + gbase + ch;
  }
}

// ---------------------------------------------------------------------------
// Bilinear x2 upsample (align_corners) CL hi/lo -> CL hi/lo, full padded
// write. blockIdx.z = frame; s_fs/o_fs are per-frame element strides.
// ---------------------------------------------------------------------------
__global__ __launch_bounds__(256) void up_cl2cl_pad(
    const u16* __restrict__ sh, const u16* __restrict__ sl,
    u16* __restrict__ oh, u16* __restrict__ ol, long s_fs, long o_fs, int C,
    int H, int W, int Wps, int Poffs, int Hp, int Wpo, int Poffo) {
  sh += (long)blockIdx.z * s_fs;
  sl += (long)blockIdx.z * s_fs;
  oh += (long)blockIdx.z * o_fs;
  ol += (long)blockIdx.z * o_fs;
  int Ho = 2 * H, Wo = 2 * W;
  long tot = (long)Hp * Wpo * C;
  long gid = (long)blockIdx.x * 256 + threadIdx.x;
  if (gid >= tot) return;
  int c = (int)(gid % C);
  long r = gid / C;
  int xp = (int)(r % Wpo);
  int yp = (int)(r / Wpo);
  int x = xp - Poffo, y = yp - Poffo;
  float v = 0.f;
  if ((unsigned)x < (unsigned)Wo && (unsigned)y < (unsigned)Ho) {
    float fy = (float)(y * (H - 1)) / (float)(Ho - 1);
    float fx = (float)(x * (W - 1)) / (float)(Wo - 1);
    int y0 = (int)fy, x0 = (int)fx;
    int y1 = min(y0 + 1, H - 1), x1 = min(x0 + 1, W - 1);
    float wy = fy - y0, wx = fx - x0;
    auto rd = [&](int cy, int cx) {
      long o = ((long)(cy + Poffs) * Wps + (cx + Poffs)) * C + c;
      return bf2f(sh[o]) + bf2f(sl[o]);
    };
    float r0 = rd(y0, x0) * (1.f - wx) + rd(y0, x1) * wx;
    float r1 = rd(y1, x0) * (1.f - wx) + rd(y1, x1) * wx;
    v = r0 * (1.f - wy) + r1 * wy;
  }
  splitw(v, &oh[gid], &ol[gid]);
}

// ---------------------------------------------------------------------------
extern "C" void kernel_launch(void* const* d_in, const int* in_sizes, int n_in,
                              void* d_out, int out_size, void* d_ws,
                              size_t ws_size, hipStream_t stream) {
  const float* input = (const float*)d_in[0];
  const float* enc_w0 = (const float*)d_in[1];
  const float* enc_b0 = (const float*)d_in[2];
  const float* enc_w1 = (const float*)d_in[3];
  const float* enc_b1 = (const float*)d_in[4];
  const float* enc_w2 = (const float*)d_in[5];
  const float* enc_b2 = (const float*)d_in[6];
  const float* enc_w3 = (const float*)d_in[7];
  const float* enc_b3 = (const float*)d_in[8];
  const float* tq_w = (const float*)d_in[9];
  const float* tq_b = (const float*)d_in[10];
  const float* tk_w = (const float*)d_in[11];
  const float* tk_b = (const float*)d_in[12];
  const float* tv_w = (const float*)d_in[13];
  const float* tv_b = (const float*)d_in[14];
  const float* to_w = (const float*)d_in[15];
  const float* to_b = (const float*)d_in[16];
  const float* tf1_w = (const float*)d_in[17];
  const float* tf1_b = (const float*)d_in[18];
  const float* tf2_w = (const float*)d_in[19];
  const float* tf2_b = (const float*)d_in[20];
  const float* d0_w = (const float*)d_in[21];
  const float* d0_b = (const float*)d_in[22];
  const float* d1_w = (const float*)d_in[23];
  const float* d1_b = (const float*)d_in[24];
  const float* d2_w = (const float*)d_in[25];
  const float* d2_b = (const float*)d_in[26];
  const float* d3_w = (const float*)d_in[27];
  const float* d3_b = (const float*)d_in[28];
  float* out = (float*)d_out;

  // -------- workspace layout --------
  unsigned char* wsb = (unsigned char*)d_ws;
  size_t off = 0;
  auto alloc = [&](size_t bytes) {
    void* p = wsb + off;
    off = (off + bytes + 255) & ~(size_t)255;
    return p;
  };
  const long XCL_E = 22839296L;   // 16*34*164*256
  const long XCL2_E = 21233664L;  // 16*32*162*256
  const long QT_E = 4915200L;
  const long VT_E = 5111808L;
  u16* XCLh = (u16*)alloc(XCL_E * 2);
  u16* XCLl = (u16*)alloc(XCL_E * 2);
  u16* XCL2h = (u16*)alloc(XCL2_E * 2);
  u16* XCL2l = (u16*)alloc(XCL2_E * 2);
  u16* qth = (u16*)alloc(QT_E * 2);
  u16* qtl = (u16*)alloc(QT_E * 2);
  u16* kth = (u16*)alloc(QT_E * 2);
  u16* ktl = (u16*)alloc(QT_E * 2);
  u16* vth = (u16*)alloc(VT_E * 2);
  u16* vtl = (u16*)alloc(VT_E * 2);
  int* nmapA = (int*)alloc(4 * 4800 * 4);
  int* dmapA = (int*)alloc(4 * 4800 * 4);
  int* rowbaseA = (int*)alloc(7120 * 4);
  int* doffA = (int*)alloc(93248 * 4);
  u16* qwh = (u16*)alloc(65536 * 2);
  u16* qwl = (u16*)alloc(65536 * 2);
  u16* kwh = (u16*)alloc(65536 * 2);
  u16* kwl = (u16*)alloc(65536 * 2);
  u16* vwh = (u16*)alloc(65536 * 2);
  u16* vwl = (u16*)alloc(65536 * 2);
  size_t fixed_end = off;
  size_t avail = ws_size > fixed_end ? ws_size - fixed_end : 0;
  size_t SCB = avail > 4096 ? avail - 4096 : 0;
  if (SCB > 104857600UL) SCB = 104857600UL;
  float* scores = (float*)alloc(SCB);
  size_t need = off;
  if (ws_size < need) return;  // fail loud, not crash
  long SCAPf = (long)(SCB / 4);
  if (SCAPf < 1800000) return;

  // encoder weight splits + trunk wt3 region overlay the scores region
  u16* Wth = (u16*)scores;
  u16* Wtl = Wth + 589824;
  u16* W3 = (u16*)scores;

  // ---- decoder buffers: overlay XCL2+token+scores region ----
  // 4-frame front half (up0/d0/d1), 2-frame back half (up2/d2/d3).
  // Region after XCL trunk state: ws - 91.36MB >= 152.8MB; peak use 144.7MB.
  unsigned char* decbase = (unsigned char*)XCL2h;
  u16* dec0inH = (u16*)(decbase + 0);           // 4 x 10,221,568
  u16* dec0inL = (u16*)(decbase + 40886272);    // 4 x 10,221,568
  u16* dec0outH = (u16*)(decbase + 81772544);   // 4 x 5,110,784
  u16* dec0outL = (u16*)(decbase + 102215680);  // 4 x 5,110,784
  u16* dec1outH = (u16*)(decbase + 122658816);  // 4 x 2,555,392
  u16* dec1outL = (u16*)(decbase + 132880384);  // 4 x 2,555,392
  u16* dec2inH = (u16*)(decbase + 0);           // 2 x 10,025,472 (dec0in dead)
  u16* dec2inL = (u16*)(decbase + 20050944);
  float* dec2out = (float*)(decbase + 40101888);  // 2 x 19,660,800
  u16* Wd0h = (u16*)(decbase + 143101952);
  u16* Wd0l = Wd0h + 294912;
  u16* W1h = Wd0l + 294912;
  u16* W1l = W1h + 73728;
  u16* W2h = W1l + 73728;
  u16* W2l = W2h + 36864;
  const long D0IN_FS = 5110784, D0OUT_FS = 2555392, D1OUT_FS = 1277696;
  const long D2IN_FS = 5012736, D2OUT_FS = 4915200;

  const long FS_TR = 1427456;  // 34*164*256
  const long FS_T2 = 1327104;  // 32*162*256 == 64*324*64
  const long FS_E2 = 713728;   // 34*164*128

  static const int PWa[4] = {80, 32, 10, 5};
  static const int PHa[4] = {15, 6, 5, 3};
  static const int rbOff[4] = {0, 64, 464, 2000};
  static const int doOff[4] = {0, 76800, 89088, 92288};

  // -------- encoder --------
  hipMemsetAsync(XCLh, 0, XCL_E * 2, stream);
  hipMemsetAsync(XCLl, 0, XCL_E * 2, stream);
  hipMemsetAsync(XCL2h, 0, XCL2_E * 2, stream);
  hipMemsetAsync(XCL2l, 0, XCL2_E * 2, stream);
  hipMemsetAsync(vth, 0, VT_E * 2, stream);
  hipMemsetAsync(vtl, 0, VT_E * 2, stream);
  {  // enc0: fp32 direct -> CL [64][324][64] Poff2 in XCL2 space
    long tot = 16L * 64 * 60 * 40;
    conv2d_k<3, 2, 1><<<cdivu(tot, 256), 256, 0, stream>>>(
        input, enc_w0, enc_b0, nullptr, XCL2h, XCL2l, 324, 2, FS_T2, 16, 3,
        120, 640, 64, 60, 320, 1, ACT_LEAKY);
  }
  {  // enc1
    wt_build<<<cdivu(9L * 64 * 64, 256), 256, 0, stream>>>(enc_w1, 64, 64, 9,
                                                           Wth, Wtl);
    conv_gemm_lds<4, 1><<<dim3(75, 1, 16), 256, 0, stream>>>(
        XCL2h, XCL2l, Wth, Wtl, enc_b1, 64, 64, 60, 320, 324, 2, 1, 1, 1, 9,
        FS_T2, ACT_LEAKY, nullptr, 0, XCLh, XCLl, FS_T2, 324, 2, 0);
  }
  hipMemsetAsync(XCL2h, 0, XCL2_E * 2, stream);
  hipMemsetAsync(XCL2l, 0, XCL2_E * 2, stream);
  {  // enc2
    wt_build<<<cdivu(9L * 128 * 64, 256), 256, 0, stream>>>(enc_w2, 128, 64, 9,
                                                            Wth, Wtl);
    conv_gemm_lds<2, 2><<<dim3(38, 1, 16), 256, 0, stream>>>(
        XCLh, XCLl, Wth, Wtl, enc_b2, 64, 128, 30, 160, 324, 2, 2, 1, 1, 9,
        FS_T2, ACT_LEAKY, nullptr, 0, XCL2h, XCL2l, FS_E2, 164, 2, 0);
  }
  hipMemsetAsync(XCLh, 0, XCL_E * 2, stream);
  hipMemsetAsync(XCLl, 0, XCL_E * 2, stream);
  {  // enc3
    wt_build<<<cdivu(9L * 256 * 128, 256), 256, 0, stream>>>(enc_w3, 256, 128,
                                                             9, Wth, Wtl);
    conv_gemm_lds<2, 2><<<dim3(38, 2, 16), 256, 0, stream>>>(
        XCL2h, XCL2l, Wth, Wtl, enc_b3, 128, 256, 30, 160, 164, 2, 1, 1, 1, 9,
        FS_E2, ACT_LEAKY, nullptr, 0, XCLh, XCLl, FS_TR, 164, 2, 0);
  }
  hipMemsetAsync(XCL2h, 0, XCL2_E * 2, stream);
  hipMemsetAsync(XCL2l, 0, XCL2_E * 2, stream);

  // -------- token maps / scatter LUTs --------
  for (int g = 0; g < 4; ++g) {
    int ph = PHa[g], pw = PWa[g];
    int ohh = 30 / ph, oww = 160 / pw;
    int Ntok = 16 * ohh * oww, Dd = 64 * ph * pw, pp = ph * pw;
    maps_build<<<19, 256, 0, stream>>>(ph, pw, oww, nmapA + g * 4800,
                                       dmapA + g * 4800);
    int mx = Ntok > Dd ? Ntok : Dd;
    luts_build<<<cdivu(mx, 256), 256, 0, stream>>>(
        ph, pw, ohh * oww, oww, pp, Ntok, Dd, g * 64, rowbaseA + rbOff[g],
        doffA + doOff[g]);
  }

  // -------- transformer stack --------
  for (int l = 0; l < 8; ++l) {
    wtqkv_build_all<<<256, 256, 0, stream>>>(
        tq_w + (long)l * 65536, tk_w + (long)l * 65536,
        tv_w + (long)l * 65536, qwh, qwl, kwh, kwl, vwh, vwl);

    for (int g = 0; g < 4; ++g) {
      int ph = PHa[g], pw = PWa[g];
      int ohh = 30 / ph, oww = 160 / pw;
      int ohow = ohh * oww;
      int Ntok = 16 * ohow, Dd = 64 * ph * pw, pp = ph * pw;
      int NtokPad = (Ntok + 31) & ~31;
      float scale = 1.0f / sqrtf((float)Dd);
      const int* nmap = nmapA + g * 4800;
      const int* dmap = dmapA + g * 4800;
      const int* rowbase = rowbaseA + rbOff[g];
      const int* doffp = doffA + doOff[g];

      qkv3_gemm_lds<<<dim3(19, 1, 16), 256, 0, stream>>>(
          XCLh, XCLl, FS_TR, 164, 2, qwh + g * 16384, qwl + g * 16384,
          kwh + g * 16384, kwl + g * 16384, vwh + g * 16384, vwl + g * 16384,
          tq_b + l * 256 + g * 64, tk_b + l * 256 + g * 64,
          tv_b + l * 256 + g * 64, nmap, dmap, ohow, Dd, pp, NtokPad, scale,
          qth, qtl, kth, ktl, vth, vtl);

      if (g == 0) {
        float* scoresR = scores + 131072;
        attn_gemm_lds<<<dim3(1, 1, 32), 256, 0, stream>>>(
            qth, qtl, Dd, 64, kth, ktl, Dd, 64, 2400, 64, 0, scores, 64, 4096,
            nullptr, nullptr, nullptr, nullptr);
        reduce_scatter<<<16, 256, 0, stream>>>(scores, 32, 4096, 64, 64, 0,
                                               scoresR, nullptr, nullptr,
                                               nullptr, nullptr);
        softmax_ip<<<64, 256, 0, stream>>>(scoresR, 64, 64);
        attn_pv_lds<<<dim3(1, 600, 1), 256, 0, stream>>>(
            scoresR, 64, 64, vth, vtl, 64, Dd, 64, Dd, 1, nullptr, 0, 0,
            XCL2h, XCL2l, rowbase, doffp);
      } else {
        long denom = (long)NtokPad + (g == 3 ? 3840 : 0);
        long cap = (SCAPf / denom) & ~127L;
        int chunk = (int)(cap < 128 ? 128 : cap);
        if (chunk > Ntok) chunk = Ntok;
        float* partials = scores + (long)chunk * NtokPad;
        for (int r0 = 0; r0 < Ntok; r0 += chunk) {
          int rows = Ntok - r0 < chunk ? Ntok - r0 : chunk;
          attn_gemm_lds<<<dim3(cdivu(rows, 128), cdivu(Ntok, 128), 1), 256, 0,
                          stream>>>(qth + (long)r0 * Dd, qtl + (long)r0 * Dd,
                                    Dd, rows, kth, ktl, Dd, Ntok, Dd, Ntok, 0,
                                    scores, NtokPad, 0, nullptr, nullptr,
                                    nullptr, nullptr);
          softmax_ip<<<rows, 256, 0, stream>>>(scores, Ntok, NtokPad);
          if (g == 3) {
            attn_pv_lds<<<dim3(cdivu(rows, 128), 8, 4), 256, 0, stream>>>(
                scores, NtokPad, rows, vth, vtl, NtokPad, Dd, 1280, Dd, 0,
                partials, 960, (long)rows * 960, nullptr, nullptr, nullptr,
                nullptr);
            reduce_scatter<<<cdivu((long)rows * 960, 256), 256, 0, stream>>>(
                partials, 4, (long)rows * 960, rows, 960, 1, nullptr, XCL2h,
                XCL2l, rowbase + r0, doffp);
          } else {
            attn_pv_lds<<<dim3(cdivu(rows, 128), Dd / 128, 1), 256, 0,
                          stream>>>(scores, NtokPad, rows, vth, vtl, NtokPad,
                                    Dd, NtokPad, Dd, 1, nullptr, 0, 0, XCL2h,
                                    XCL2l, rowbase + r0, doffp);
          }
        }
      }
    }

    wt3_build<<<6912, 256, 0, stream>>>(to_w + (long)l * 589824,
                                        tf1_w + (long)l * 589824,
                                        tf2_w + (long)l * 589824, W3);
    conv_gemm_lds<2, 2><<<dim3(38, 2, 16), 256, 0, stream>>>(
        XCL2h, XCL2l, W3, W3 + 589824, to_b + l * 256, 256, 256, 30, 160, 162,
        1, 1, 1, 1, 9, FS_T2, ACT_LEAKY, nullptr, 0, XCLh, XCLl, FS_TR, 164, 2,
        1);
    conv_gemm_lds<2, 2><<<dim3(38, 2, 16), 256, 0, stream>>>(
        XCLh, XCLl, W3 + 1179648, W3 + 1769472, tf1_b + l * 256, 256, 256, 30,
        160, 164, 2, 1, 2, 2, 9, FS_TR, ACT_LEAKY, nullptr, 0, XCL2h, XCL2l,
        FS_T2, 162, 1, 0);
    conv_gemm_lds<2, 2><<<dim3(38, 2, 16), 256, 0, stream>>>(
        XCL2h, XCL2l, W3 + 2359296, W3 + 2949120, tf2_b + l * 256, 256, 256,
        30, 160, 162, 1, 1, 1, 1, 9, FS_T2, ACT_LEAKY, nullptr, 0, XCLh, XCLl,
        FS_TR, 164, 2, 1);
  }

  // -------- decoder: 4-frame front half, 2-frame back half --------
  hipMemsetAsync(decbase, 0, 144723968, stream);
  wt_build<<<cdivu(9L * 128 * 256, 256), 256, 0, stream>>>(d0_w, 128, 256, 9,
                                                           Wd0h, Wd0l);
  wt_build<<<cdivu(9L * 64 * 128, 256), 256, 0, stream>>>(d1_w, 64, 128, 9,
                                                          W1h, W1l);
  wt_build<<<cdivu(9L * 64 * 64, 256), 256, 0, stream>>>(d2_w, 64, 64, 9, W2h,
                                                         W2l);
  for (int f = 0; f < 16; f += 4) {
    // up0 x4 frames: trunk 30x160 -> 60x320 CL [62][322][256]
    up_cl2cl_pad<<<dim3(cdivu(62L * 322 * 256, 256), 1, 4), 256, 0, stream>>>(
        XCLh + (long)f * FS_TR, XCLl + (long)f * FS_TR, dec0inH, dec0inL,
        FS_TR, D0IN_FS, 256, 30, 160, 164, 2, 62, 322, 1);
    // d0: 256->128, 60x320, z=4
    conv_gemm_lds<2, 2><<<dim3(150, 1, 4), 256, 0, stream>>>(
        dec0inH, dec0inL, Wd0h, Wd0l, d0_b, 256, 128, 60, 320, 322, 1, 1, 1, 1,
        9, D0IN_FS, ACT_LEAKY, nullptr, 0, dec0outH, dec0outL, D0OUT_FS, 322,
        1, 0);
    // d1: 128->64, 60x320, z=4
    conv_gemm_lds<4, 1><<<dim3(75, 1, 4), 256, 0, stream>>>(
        dec0outH, dec0outL, W1h, W1l, d1_b, 128, 64, 60, 320, 322, 1, 1, 1, 1,
        9, D0OUT_FS, ACT_LEAKY, nullptr, 0, dec1outH, dec1outL, D1OUT_FS, 322,
        1, 0);
    for (int ff = 0; ff < 4; ff += 2) {
      // up2 x2 frames: 60x320 -> 120x640 CL [122][642][64]
      up_cl2cl_pad<<<dim3(cdivu(122L * 642 * 64, 256), 1, 2), 256, 0,
                     stream>>>(dec1outH + (long)ff * D1OUT_FS,
                               dec1outL + (long)ff * D1OUT_FS, dec2inH,
                               dec2inL, D1OUT_FS, D2IN_FS, 64, 60, 320, 322, 1,
                               122, 642, 1);
      // d2: 64->64, 120x640, fp32 NCHW out, z=2
      conv_gemm_lds<4, 1><<<dim3(300, 1, 2), 256, 0, stream>>>(
          dec2inH, dec2inL, W2h, W2l, d2_b, 64, 64, 120, 640, 642, 1, 1, 1, 1,
          9, D2IN_FS, ACT_LEAKY, dec2out, D2OUT_FS, nullptr, nullptr, 0, 0, 0,
          0);
      // d3: 64->3 + tanh, fp32 direct, 2 frames
      long tot = 2L * 3 * 120 * 80;
      conv2d_k<3, 1, 1><<<cdivu(tot, 256), 256, 0, stream>>>(
          dec2out, d3_w, d3_b, out + (long)(f + ff) * 230400, nullptr, nullptr,
          0, 0, 0, 2, 64, 120, 640, 3, 120, 640, 1, ACT_TANH);
    }
  }
}

// Round 13
// 30722.476 us; speedup vs baseline: 33.3861x; 1.0761x over previous
//
#include <hip/hip_runtime.h>
#include <hip/hip_bf16.h>
#include <math.h>

#define ACT_NONE 0
#define ACT_LEAKY 1
#define ACT_TANH 2

typedef __attribute__((ext_vector_type(8))) short bf16x8;
typedef __attribute__((ext_vector_type(4))) float f32x4;
typedef unsigned short u16;

#define MFMA(a, b, c) __builtin_amdgcn_mfma_f32_16x16x32_bf16((bf16x8)(a), (bf16x8)(b), (c), 0, 0, 0)

static inline unsigned cdivu(long a, long b) { return (unsigned)((a + b - 1) / b); }

__device__ __forceinline__ u16 f2bf(float x) {
  union { __hip_bfloat16 h; u16 u; } cv;
  cv.h = __float2bfloat16(x);
  return cv.u;
}
__device__ __forceinline__ float bf2f(u16 b) {
  union { u16 u; __hip_bfloat16 h; } cv;
  cv.u = b;
  return __bfloat162float(cv.h);
}
__device__ __forceinline__ void splitw(float v, u16* ph, u16* pl) {
  u16 h = f2bf(v);
  *ph = h;
  *pl = f2bf(v - bf2f(h));
}
// async global->LDS, 16B per lane; dest must be wave-uniform base (+lane*16)
__device__ __forceinline__ void gload16(const void* g, void* l) {
  __builtin_amdgcn_global_load_lds(
      (const __attribute__((address_space(1))) unsigned int*)g,
      (__attribute__((address_space(3))) unsigned int*)l, 16, 0, 0);
}

// ---------------------------------------------------------------------------
// Direct fp32 conv (d3: Cout=3+tanh). Optional CL hi/lo output.
// ---------------------------------------------------------------------------
template <int K, int S, int DIL>
__global__ __launch_bounds__(256) void conv2d_k(
    const float* __restrict__ x, const float* __restrict__ w,
    const float* __restrict__ bias, float* y, u16* clh, u16* cll, int WpO,
    int PoffO, long o_fstride, int N, int Cin, int Hin, int Win, int Cout,
    int Hout, int Wout, int pad, int act) {
  constexpr int TW = 8;
  constexpr int XL = (TW - 1) * S + (K - 1) * DIL + 1;
  int wq = (Wout + TW - 1) / TW;
  long gid = (long)blockIdx.x * 256 + threadIdx.x;
  long total = (long)N * Cout * Hout * wq;
  if (gid >= total) return;
  int xg = (int)(gid % wq);
  long r = gid / wq;
  int yo = (int)(r % Hout);
  r /= Hout;
  int oc = (int)(r % Cout);
  int n = (int)(r / Cout);

  float bv = bias[oc];
  float acc[TW];
#pragma unroll
  for (int j = 0; j < TW; ++j) acc[j] = bv;

  int xo0 = xg * TW;
  int xi0 = xo0 * S - pad;
  const float* xn = x + (long)n * Cin * Hin * Win;
  const float* wb = w + (long)oc * Cin * K * K;

  for (int ic = 0; ic < Cin; ++ic) {
    const float* xc = xn + (long)ic * Hin * Win;
    const float* wc = wb + ic * (K * K);
#pragma unroll
    for (int ky = 0; ky < K; ++ky) {
      int yi = yo * S - pad + ky * DIL;
      if ((unsigned)yi < (unsigned)Hin) {
        const float* row = xc + (long)yi * Win;
        float xr[XL];
#pragma unroll
        for (int i2 = 0; i2 < XL; ++i2) {
          int xi = xi0 + i2;
          xr[i2] = ((unsigned)xi < (unsigned)Win) ? row[xi] : 0.f;
        }
#pragma unroll
        for (int kx = 0; kx < K; ++kx) {
          float wv = wc[ky * K + kx];
#pragma unroll
          for (int j = 0; j < TW; ++j)
            acc[j] = fmaf(wv, xr[j * S + kx * DIL], acc[j]);
        }
      }
    }
  }

#pragma unroll
  for (int j = 0; j < TW; ++j) {
    if (xo0 + j < Wout) {
      float v = acc[j];
      if (act == ACT_LEAKY)
        v = v >= 0.f ? v : 0.2f * v;
      else if (act == ACT_TANH)
        v = tanhf(v);
      if (y) y[(((long)n * Cout + oc) * Hout + yo) * Wout + xo0 + j] = v;
      if (clh) {
        long off = (long)n * o_fstride +
                   ((long)(yo + PoffO) * WpO + (xo0 + j + PoffO)) * Cout + oc;
        splitw(v, &clh[off], &cll[off]);
      }
    }
  }
}

// ---------------------------------------------------------------------------
// enc0 (3->64, stride2) with oc-innermost lanes -> coalesced CL writes.
// Same FMA order as conv2d_k (ic,ky,kx) -> bit-identical values.
// ---------------------------------------------------------------------------
__global__ __launch_bounds__(256) void conv_enc0_cl(
    const float* __restrict__ x, const float* __restrict__ w,
    const float* __restrict__ bias, u16* __restrict__ clh,
    u16* __restrict__ cll) {
  __shared__ float ws[64][29];  // stride 29: conflict-free column reads
  int t = threadIdx.x;
  for (int i = t; i < 64 * 27; i += 256) ws[i / 27][i % 27] = w[i];
  __syncthreads();
  int oc = t & 63;
  float bv = bias[oc];
  long s0 = (long)blockIdx.x * 32 + (t >> 6);
#pragma unroll
  for (int step = 0; step < 8; ++step) {
    long s = s0 + step * 4;
    int xo = (int)(s % 320);
    long r = s / 320;
    int yo = (int)(r % 60);
    int n = (int)(r / 60);
    float acc = bv;
    for (int ic = 0; ic < 3; ++ic) {
      const float* xp = x + ((long)n * 3 + ic) * 76800;
      const float* wp = ws[oc] + ic * 9;
#pragma unroll
      for (int ky = 0; ky < 3; ++ky) {
        int yi = yo * 2 - 1 + ky;
        if ((unsigned)yi < 120u) {
#pragma unroll
          for (int kx = 0; kx < 3; ++kx) {
            int xi = xo * 2 - 1 + kx;
            if ((unsigned)xi < 640u)
              acc = fmaf(wp[ky * 3 + kx], xp[yi * 640 + xi], acc);
          }
        }
      }
    }
    float v = acc >= 0.f ? acc : 0.2f * acc;
    long off = (long)n * 1327104 + ((long)(yo + 2) * 324 + (xo + 2)) * 64 + oc;
    splitw(v, &clh[off], &cll[off]);
  }
}

// ---------------------------------------------------------------------------
// LDS-staged MFMA implicit-GEMM conv (m97 2-barrier structure).
// ---------------------------------------------------------------------------
template <int WM, int WN>
__global__ __launch_bounds__(256) void conv_gemm_lds(
    const u16* __restrict__ Ah, const u16* __restrict__ Al,
    const u16* __restrict__ Bh, const u16* __restrict__ Bl,
    const float* __restrict__ bias, int Cin, int Cout, int Hout, int Wout,
    int Wp, int Poff, int S, int DIL, int pad, int taps, long a_fstride,
    int act, float* yout, long y_fstride, u16* Oh, u16* Ol, long o_fstride,
    int WpO, int PoffO, int useres) {
  constexpr int TM = WM * 64, TN = WN * 64;
  __shared__ u16 AsH[TM * 32], AsL[TM * 32], BsH[TN * 32], BsL[TN * 32];
  int t = threadIdx.x;
  int lane = t & 63;
  int w = t >> 6;
  int wr = w / WN, wc = w % WN;
  int l15 = lane & 15, l16 = lane >> 4;
  int HW = Hout * Wout;
  int row0 = blockIdx.x * TM;
  int col0 = blockIdx.y * TN;
  const u16* Afh = Ah + (long)blockIdx.z * a_fstride;
  const u16* Afl = Al + (long)blockIdx.z * a_fstride;

  int rs = t >> 2;
  int cs = (t & 3) * 8;
  long abase[WM];
#pragma unroll
  for (int c = 0; c < WM; ++c) {
    int s = row0 + rs + 64 * c;
    if (s >= HW) s = HW - 1;
    int yo = s / Wout, xo = s - yo * Wout;
    int yb = yo * S - pad + Poff, xb = xo * S - pad + Poff;
    abase[c] = ((long)yb * Wp + xb) * Cin + cs;
  }
  long bbase[WN];
#pragma unroll
  for (int c = 0; c < WN; ++c)
    bbase[c] = (long)(col0 + rs + 64 * c) * Cin + cs;
  int ldst = w * 512;

  f32x4 acc[4][4];
#pragma unroll
  for (int m = 0; m < 4; ++m)
#pragma unroll
    for (int n = 0; n < 4; ++n) acc[m][n] = (f32x4){0.f, 0.f, 0.f, 0.f};

  for (int tap = 0; tap < taps; ++tap) {
    int ky = tap / 3, kx = tap - ky * 3;
    long atap = ((long)ky * DIL * Wp + kx * DIL) * Cin;
    long btap = (long)tap * Cout * Cin;
    for (int ic0 = 0; ic0 < Cin; ic0 += 32) {
#pragma unroll
      for (int c = 0; c < WM; ++c) {
        gload16(Afh + abase[c] + atap + ic0, AsH + c * 2048 + ldst);
        gload16(Afl + abase[c] + atap + ic0, AsL + c * 2048 + ldst);
      }
#pragma unroll
      for (int c = 0; c < WN; ++c) {
        gload16(Bh + bbase[c] + btap + ic0, BsH + c * 2048 + ldst);
        gload16(Bl + bbase[c] + btap + ic0, BsL + c * 2048 + ldst);
      }
      __syncthreads();
      bf16x8 ah[4], al[4];
#pragma unroll
      for (int m = 0; m < 4; ++m) {
        int rrow = wr * 64 + m * 16 + l15;
        ah[m] = *(const bf16x8*)(AsH + rrow * 32 + l16 * 8);
        al[m] = *(const bf16x8*)(AsL + rrow * 32 + l16 * 8);
      }
#pragma unroll
      for (int n = 0; n < 4; ++n) {
        int rcol = wc * 64 + n * 16 + l15;
        bf16x8 bh = *(const bf16x8*)(BsH + rcol * 32 + l16 * 8);
        bf16x8 bl = *(const bf16x8*)(BsL + rcol * 32 + l16 * 8);
#pragma unroll
        for (int m = 0; m < 4; ++m) {
          acc[m][n] = MFMA(ah[m], bh, acc[m][n]);
          acc[m][n] = MFMA(ah[m], bl, acc[m][n]);
          acc[m][n] = MFMA(al[m], bh, acc[m][n]);
        }
      }
      __syncthreads();
    }
  }

  float* yf = yout ? yout + (long)blockIdx.z * y_fstride : nullptr;
  u16* Ofh = Oh ? Oh + (long)blockIdx.z * o_fstride : nullptr;
  u16* Ofl = Ol ? Ol + (long)blockIdx.z * o_fstride : nullptr;
#pragma unroll
  for (int m = 0; m < 4; ++m) {
#pragma unroll
    for (int r = 0; r < 4; ++r) {
      int s = row0 + wr * 64 + m * 16 + l16 * 4 + r;
      if (s >= HW) continue;
      int yo = s / Wout, xo = s - yo * Wout;
      long clbase = 0;
      if (Ofh) clbase = ((long)(yo + PoffO) * WpO + (xo + PoffO)) * Cout;
#pragma unroll
      for (int n = 0; n < 4; ++n) {
        int oc = col0 + wc * 64 + n * 16 + l15;
        float v = acc[m][n][r] + bias[oc];
        if (act == ACT_LEAKY) v = v >= 0.f ? v : 0.2f * v;
        if (Ofh) {
          long off = clbase + oc;
          if (useres) v += bf2f(Ofh[off]) + bf2f(Ofl[off]);
          splitw(v, &Ofh[off], &Ofl[off]);
        }
        if (yf) yf[((long)oc * Hout + yo) * Wout + xo] = v;
      }
    }
  }
}

// ---------------------------------------------------------------------------
// Fused QKV 1x1 GEMM (one dispatch computes Q,K,V). Tile 256x64, 4 waves.
// Token feature layout d = dm*64 + c (channels innermost -> coalesced).
// Q (mat 0) stores HI ONLY (QK uses 2-term Qh*(Kh+Kl)).
// ---------------------------------------------------------------------------
__global__ __launch_bounds__(256) void qkv3_gemm_lds(
    const u16* __restrict__ Ah, const u16* __restrict__ Al, long a_fstride,
    int Wp, int Poff, const u16* __restrict__ qwh, const u16* __restrict__ qwl,
    const u16* __restrict__ kwh, const u16* __restrict__ kwl,
    const u16* __restrict__ vwh, const u16* __restrict__ vwl,
    const float* __restrict__ qbias, const float* __restrict__ kbias,
    const float* __restrict__ vbias, const int* __restrict__ nmap,
    const int* __restrict__ dmap, int ohow, int Dd, int pp, int NtokPad,
    float scale, u16* __restrict__ tqh, u16* __restrict__ tql,
    u16* __restrict__ tkh, u16* __restrict__ tkl, u16* __restrict__ tvh,
    u16* __restrict__ tvl) {
  __shared__ u16 AsH[256 * 32], AsL[256 * 32], BsH[64 * 32], BsL[64 * 32];
  int t = threadIdx.x;
  int lane = t & 63;
  int w = t >> 6;
  int l15 = lane & 15, l16 = lane >> 4;
  int row0 = blockIdx.x * 256;
  int frame = blockIdx.z;
  const u16* Afh = Ah + (long)frame * a_fstride;
  const u16* Afl = Al + (long)frame * a_fstride;

  int rs = t >> 2;
  int cs = (t & 3) * 8;
  long abase[4];
#pragma unroll
  for (int c = 0; c < 4; ++c) {
    int s = row0 + rs + 64 * c;
    if (s >= 4800) s = 4799;
    int yo = s / 160, xo = s - yo * 160;
    abase[c] = ((long)(yo + Poff) * Wp + (xo + Poff)) * 256 + cs;
  }
  long bbase = (long)rs * 256 + cs;
  int ldst = w * 512;

  for (int mat = 0; mat < 3; ++mat) {
    const u16* Bh = mat == 0 ? qwh : mat == 1 ? kwh : vwh;
    const u16* Bl = mat == 0 ? qwl : mat == 1 ? kwl : vwl;
    const float* bias = mat == 0 ? qbias : mat == 1 ? kbias : vbias;
    u16* tH = mat == 0 ? tqh : mat == 1 ? tkh : tvh;
    u16* tL = mat == 0 ? tql : mat == 1 ? tkl : tvl;

    f32x4 acc[4][4];
#pragma unroll
    for (int m = 0; m < 4; ++m)
#pragma unroll
      for (int n = 0; n < 4; ++n) acc[m][n] = (f32x4){0.f, 0.f, 0.f, 0.f};

    for (int ic0 = 0; ic0 < 256; ic0 += 32) {
#pragma unroll
      for (int c = 0; c < 4; ++c) {
        gload16(Afh + abase[c] + ic0, AsH + c * 2048 + ldst);
        gload16(Afl + abase[c] + ic0, AsL + c * 2048 + ldst);
      }
      gload16(Bh + bbase + ic0, BsH + ldst);
      gload16(Bl + bbase + ic0, BsL + ldst);
      __syncthreads();
      bf16x8 ah[4], al[4];
#pragma unroll
      for (int m = 0; m < 4; ++m) {
        int rrow = w * 64 + m * 16 + l15;
        ah[m] = *(const bf16x8*)(AsH + rrow * 32 + l16 * 8);
        al[m] = *(const bf16x8*)(AsL + rrow * 32 + l16 * 8);
      }
#pragma unroll
      for (int n = 0; n < 4; ++n) {
        int rcol = n * 16 + l15;
        bf16x8 bh = *(const bf16x8*)(BsH + rcol * 32 + l16 * 8);
        bf16x8 bl = *(const bf16x8*)(BsL + rcol * 32 + l16 * 8);
#pragma unroll
        for (int m = 0; m < 4; ++m) {
          acc[m][n] = MFMA(ah[m], bh, acc[m][n]);
          acc[m][n] = MFMA(ah[m], bl, acc[m][n]);
          acc[m][n] = MFMA(al[m], bh, acc[m][n]);
        }
      }
      __syncthreads();
    }

#pragma unroll
    for (int m = 0; m < 4; ++m) {
#pragma unroll
      for (int r = 0; r < 4; ++r) {
        int s = row0 + w * 64 + m * 16 + l16 * 4 + r;
        if (s >= 4800) continue;
        int nm = nmap[s], dm = dmap[s];
        int ntok = frame * ohow + nm;
#pragma unroll
        for (int n = 0; n < 4; ++n) {
          int c = n * 16 + l15;
          float v = acc[m][n][r] + bias[c];
          if (mat == 0) v *= scale;
          int d = dm * 64 + c;
          long off = (mat == 2) ? ((long)d * NtokPad + ntok)
                                : ((long)ntok * Dd + d);
          u16 h = f2bf(v);
          tH[off] = h;
          if (mat != 0) tL[off] = f2bf(v - bf2f(h));
        }
      }
    }
  }
}

// ---------------------------------------------------------------------------
// QK GEMM, 2-term: S = Qh*(Kh+Kl). A-low not staged. LDS 24KB.
// ---------------------------------------------------------------------------
__global__ __launch_bounds__(256) void attn_gemm_lds(
    const u16* __restrict__ Ah, const u16* __restrict__ Al, int lda, int Mrows,
    const u16* __restrict__ Bh, const u16* __restrict__ Bl, int ldb,
    int Nclamp, int Kpart, int Nvalid, int mode, float* outf, int ldo,
    long partstride, u16* __restrict__ Oh, u16* __restrict__ Ol,
    const int* __restrict__ rowbase, const int* __restrict__ doff) {
  __shared__ u16 AsH[128 * 32], BsH[128 * 32], BsL[128 * 32];
  int t = threadIdx.x;
  int lane = t & 63;
  int w = t >> 6;
  int wc = w & 1, wr = w >> 1;
  int l15 = lane & 15, l16 = lane >> 4;
  int row0 = blockIdx.x * 128;
  int col0 = blockIdx.y * 128;
  int kbase = blockIdx.z * Kpart;
  if (outf) outf += (long)blockIdx.z * partstride;

  int rs = t >> 2;
  int cs = (t & 3) * 8;
  long abase[2], bbase[2];
#pragma unroll
  for (int c = 0; c < 2; ++c) {
    int sr = row0 + rs + 64 * c;
    if (sr >= Mrows) sr = Mrows - 1;
    abase[c] = (long)sr * lda + cs;
    int cc = col0 + rs + 64 * c;
    if (cc >= Nclamp) cc = Nclamp - 1;
    bbase[c] = (long)cc * ldb + cs;
  }
  int ldst = w * 512;

  f32x4 acc[4][4];
#pragma unroll
  for (int m = 0; m < 4; ++m)
#pragma unroll
    for (int n = 0; n < 4; ++n) acc[m][n] = (f32x4){0.f, 0.f, 0.f, 0.f};

  for (int k = kbase; k < kbase + Kpart; k += 32) {
#pragma unroll
    for (int c = 0; c < 2; ++c) {
      gload16(Ah + abase[c] + k, AsH + c * 2048 + ldst);
      gload16(Bh + bbase[c] + k, BsH + c * 2048 + ldst);
      gload16(Bl + bbase[c] + k, BsL + c * 2048 + ldst);
    }
    __syncthreads();
    bf16x8 ah[4];
#pragma unroll
    for (int m = 0; m < 4; ++m) {
      int rrow = wr * 64 + m * 16 + l15;
      ah[m] = *(const bf16x8*)(AsH + rrow * 32 + l16 * 8);
    }
#pragma unroll
    for (int n = 0; n < 4; ++n) {
      int rcol = wc * 64 + n * 16 + l15;
      bf16x8 bh = *(const bf16x8*)(BsH + rcol * 32 + l16 * 8);
      bf16x8 bl = *(const bf16x8*)(BsL + rcol * 32 + l16 * 8);
#pragma unroll
      for (int m = 0; m < 4; ++m) {
        acc[m][n] = MFMA(ah[m], bh, acc[m][n]);
        acc[m][n] = MFMA(ah[m], bl, acc[m][n]);
      }
    }
    __syncthreads();
  }

#pragma unroll
  for (int m = 0; m < 4; ++m) {
#pragma unroll
    for (int r = 0; r < 4; ++r) {
      int sr = row0 + wr * 64 + m * 16 + l16 * 4 + r;
      if (sr >= Mrows) continue;
#pragma unroll
      for (int n = 0; n < 4; ++n) {
        int c = col0 + wc * 64 + n * 16 + l15;
        if (c >= Nvalid) continue;
        float v = acc[m][n][r];
        if (mode == 0) {
          outf[(long)sr * ldo + c] = v;
        } else {
          long off = (long)rowbase[sr] + doff[c];
          splitw(v, &Oh[off], &Ol[off]);
        }
      }
    }
  }
}

// ---------------------------------------------------------------------------
// PV GEMM, 2-term: O = Ph*(Vh+Vl). A = fp32 P rows (hi split on the fly).
// ---------------------------------------------------------------------------
__global__ __launch_bounds__(256) void attn_pv_lds(
    const float* __restrict__ P, int lda, int Mrows,
    const u16* __restrict__ Bh, const u16* __restrict__ Bl, int ldb,
    int Nclamp, int Kpart, int Nvalid, int mode, float* outf, int ldo,
    long partstride, u16* __restrict__ Oh, u16* __restrict__ Ol,
    const int* __restrict__ rowbase, const int* __restrict__ doff) {
  __shared__ float Asf[128 * 32];
  __shared__ u16 BsH[128 * 32], BsL[128 * 32];
  int t = threadIdx.x;
  int lane = t & 63;
  int w = t >> 6;
  int wc = w & 1, wr = w >> 1;
  int l15 = lane & 15, l16 = lane >> 4;
  int row0 = blockIdx.x * 128;
  int col0 = blockIdx.y * 128;
  int kbase = blockIdx.z * Kpart;
  if (outf) outf += (long)blockIdx.z * partstride;

  int arow = t >> 3;
  int acol = (t & 7) * 4;
  long abase[4];
#pragma unroll
  for (int j = 0; j < 4; ++j) {
    int r = row0 + arow + 32 * j;
    if (r >= Mrows) r = Mrows - 1;
    abase[j] = (long)r * lda + acol;
  }
  int rs = t >> 2;
  int cs = (t & 3) * 8;
  long bbase[2];
#pragma unroll
  for (int c = 0; c < 2; ++c) {
    int cc = col0 + rs + 64 * c;
    if (cc >= Nclamp) cc = Nclamp - 1;
    bbase[c] = (long)cc * ldb + cs;
  }
  int ldst = w * 512;

  f32x4 acc[4][4];
#pragma unroll
  for (int m = 0; m < 4; ++m)
#pragma unroll
    for (int n = 0; n < 4; ++n) acc[m][n] = (f32x4){0.f, 0.f, 0.f, 0.f};

  for (int k = kbase; k < kbase + Kpart; k += 32) {
#pragma unroll
    for (int j = 0; j < 4; ++j)
      gload16(P + abase[j] + k, Asf + (w * 64 + 256 * j) * 4);
#pragma unroll
    for (int c = 0; c < 2; ++c) {
      gload16(Bh + bbase[c] + k, BsH + c * 2048 + ldst);
      gload16(Bl + bbase[c] + k, BsL + c * 2048 + ldst);
    }
    __syncthreads();
    bf16x8 ah[4];
#pragma unroll
    for (int m = 0; m < 4; ++m) {
      int rrow = wr * 64 + m * 16 + l15;
      const float* ap = Asf + rrow * 32 + l16 * 8;
      f32x4 p0 = *(const f32x4*)(ap);
      f32x4 p1 = *(const f32x4*)(ap + 4);
#pragma unroll
      for (int e = 0; e < 4; ++e) {
        ah[m][e] = (short)f2bf(p0[e]);
        ah[m][4 + e] = (short)f2bf(p1[e]);
      }
    }
#pragma unroll
    for (int n = 0; n < 4; ++n) {
      int rcol = wc * 64 + n * 16 + l15;
      bf16x8 bh = *(const bf16x8*)(BsH + rcol * 32 + l16 * 8);
      bf16x8 bl = *(const bf16x8*)(BsL + rcol * 32 + l16 * 8);
#pragma unroll
      for (int m = 0; m < 4; ++m) {
        acc[m][n] = MFMA(ah[m], bh, acc[m][n]);
        acc[m][n] = MFMA(ah[m], bl, acc[m][n]);
      }
    }
    __syncthreads();
  }

#pragma unroll
  for (int m = 0; m < 4; ++m) {
#pragma unroll
    for (int r = 0; r < 4; ++r) {
      int sr = row0 + wr * 64 + m * 16 + l16 * 4 + r;
      if (sr >= Mrows) continue;
#pragma unroll
      for (int n = 0; n < 4; ++n) {
        int c = col0 + wc * 64 + n * 16 + l15;
        if (c >= Nvalid) continue;
        float v = acc[m][n][r];
        if (mode == 0) {
          outf[(long)sr * ldo + c] = v;
        } else {
          long off = (long)rowbase[sr] + doff[c];
          splitw(v, &Oh[off], &Ol[off]);
        }
      }
    }
  }
}

// ---------------------------------------------------------------------------
__global__ __launch_bounds__(256) void reduce_scatter(
    const float* __restrict__ parts, int nparts, long pstride, int rows, int N,
    int mode, float* outf, u16* __restrict__ Oh, u16* __restrict__ Ol,
    const int* __restrict__ rowbase, const int* __restrict__ doff) {
  long gid = (long)blockIdx.x * 256 + threadIdx.x;
  long tot = (long)rows * N;
  if (gid >= tot) return;
  float s = 0.f;
  for (int p = 0; p < nparts; ++p) s += parts[p * pstride + gid];
  if (mode == 0) {
    outf[gid] = s;
  } else {
    int r = (int)(gid / N), c = (int)(gid % N);
    long off = (long)rowbase[r] + doff[c];
    splitw(s, &Oh[off], &Ol[off]);
  }
}

// ---------------------------------------------------------------------------
__global__ __launch_bounds__(256) void softmax_ip(float* __restrict__ S,
                                                  int Ntok, int NtokPad) {
  int row = blockIdx.x;
  float* p = S + (long)row * NtokPad;
  __shared__ float red[256];
  int t = threadIdx.x;
  float m = -1e30f;
  for (int i = t; i < Ntok; i += 256) m = fmaxf(m, p[i]);
  red[t] = m;
  __syncthreads();
  for (int s = 128; s > 0; s >>= 1) {
    if (t < s) red[t] = fmaxf(red[t], red[t + s]);
    __syncthreads();
  }
  m = red[0];
  __syncthreads();
  float sum = 0.f;
  for (int i = t; i < Ntok; i += 256) sum += __expf(p[i] - m);
  red[t] = sum;
  __syncthreads();
  for (int s = 128; s > 0; s >>= 1) {
    if (t < s) red[t] += red[t + s];
    __syncthreads();
  }
  float inv = 1.f / red[0];
  __syncthreads();
  for (int i = t; i < Ntok; i += 256) p[i] = __expf(p[i] - m) * inv;
  for (int i = Ntok + t; i < NtokPad; i += 256) p[i] = 0.f;
}

// ---------------------------------------------------------------------------
__global__ __launch_bounds__(256) void wt_build(const float* __restrict__ w,
                                                int Cout, int Cin, int taps,
                                                u16* __restrict__ Wh,
                                                u16* __restrict__ Wl) {
  long gid = (long)blockIdx.x * 256 + threadIdx.x;
  long tot = (long)taps * Cout * Cin;
  if (gid >= tot) return;
  int ic = (int)(gid % Cin);
  long r = gid / Cin;
  int oc = (int)(r % Cout);
  int tap = (int)(r / Cout);
  float v = w[((long)oc * Cin + ic) * taps + tap];
  splitw(v, &Wh[gid], &Wl[gid]);
}

// build to/ff1/ff2 weight splits (256x256x9 each) in one dispatch
__global__ __launch_bounds__(256) void wt3_build(const float* __restrict__ w0,
                                                 const float* __restrict__ w1,
                                                 const float* __restrict__ w2,
                                                 u16* __restrict__ base) {
  long gid = (long)blockIdx.x * 256 + threadIdx.x;
  if (gid >= 3L * 589824) return;
  int mat = (int)(gid / 589824);
  int idx = (int)(gid - (long)mat * 589824);
  const float* w = mat == 0 ? w0 : mat == 1 ? w1 : w2;
  int ic = idx & 255;
  int r = idx >> 8;
  int oc = r & 255;
  int tap = r >> 8;
  float v = w[((long)oc * 256 + ic) * 9 + tap];
  u16* dst = base + (long)mat * 1179648;
  splitw(v, &dst[idx], &dst[589824 + idx]);
}

// fused q/k/v 1x1 weight split build, ALL 4 groups in one dispatch.
__global__ __launch_bounds__(256) void wtqkv_build_all(
    const float* __restrict__ wq, const float* __restrict__ wk,
    const float* __restrict__ wv, u16* __restrict__ qh, u16* __restrict__ ql,
    u16* __restrict__ kh, u16* __restrict__ kl, u16* __restrict__ vh,
    u16* __restrict__ vl) {
  int gid = blockIdx.x * 256 + threadIdx.x;
  if (gid >= 4 * 64 * 256) return;
  int ic = gid & 255;
  int c = (gid >> 8) & 63;
  int g = gid >> 14;
  long src = (long)(g * 64 + c) * 256 + ic;
  splitw(wq[src], &qh[gid], &ql[gid]);
  splitw(wk[src], &kh[gid], &kl[gid]);
  splitw(wv[src], &vh[gid], &vl[gid]);
}

// ---------------------------------------------------------------------------
__global__ __launch_bounds__(256) void maps_build(int ph, int pw, int ow,
                                                  int* __restrict__ nmap,
                                                  int* __restrict__ dmap) {
  int s = blockIdx.x * 256 + threadIdx.x;
  if (s >= 4800) return;
  int y = s / 160, x = s - y * 160;
  int i = y / ph, yy = y - i * ph;
  int j = x / pw, xx = x - j * pw;
  nmap[s] = i * ow + j;
  dmap[s] = yy * pw + xx;
}

// d = dm*64 + ch (channels innermost). doff[d] contiguous in ch.
__global__ __launch_bounds__(256) void luts_build(int ph, int pw, int ohow,
                                                  int ow, int pp, int Ntok,
                                                  int Dd, int gbase,
                                                  int* __restrict__ rowbase,
                                                  int* __restrict__ doff) {
  int gid = blockIdx.x * 256 + threadIdx.x;
  if (gid < Ntok) {
    int tt = gid / ohow, rem = gid - tt * ohow;
    int i = rem / ow, j = rem - i * ow;
    rowbase[gid] =
        tt * (32 * 162 * 256) + ((i * ph + 1) * 162 + (j * pw + 1)) * 256;
  }
  if (gid < Dd) {
    int ch = gid & 63;
    int dm = gid >> 6;
    int yy = dm / pw, xx = dm - yy * pw;
    doff[gid] = (yy * 162 + xx) * 256 + gbase + ch;
  }
}

// ---------------------------------------------------------------------------
// Bilinear x2 upsample (align_corners) CL hi/lo -> CL hi/lo, full padded
// write. blockIdx.z = frame; s_fs/o_fs are per-frame element strides.
// ---------------------------------------------------------------------------
__global__ __launch_bounds__(256) void up_cl2cl_pad(
    const u16* __restrict__ sh, const u16* __restrict__ sl,
    u16* __restrict__ oh, u16* __restrict__ ol, long s_fs, long o_fs, int C,
    int H, int W, int Wps, int Poffs, int Hp, int Wpo, int Poffo) {
  sh += (long)blockIdx.z * s_fs;
  sl += (long)blockIdx.z * s_fs;
  oh += (long)blockIdx.z * o_fs;
  ol += (long)blockIdx.z * o_fs;
  int Ho = 2 * H, Wo = 2 * W;
  long tot = (long)Hp * Wpo * C;
  long gid = (long)blockIdx.x * 256 + threadIdx.x;
  if (gid >= tot) return;
  int c = (int)(gid % C);
  long r = gid / C;
  int xp = (int)(r % Wpo);
  int yp = (int)(r / Wpo);
  int x = xp - Poffo, y = yp - Poffo;
  float v = 0.f;
  if ((unsigned)x < (unsigned)Wo && (unsigned)y < (unsigned)Ho) {
    float fy = (float)(y * (H - 1)) / (float)(Ho - 1);
    float fx = (float)(x * (W - 1)) / (float)(Wo - 1);
    int y0 = (int)fy, x0 = (int)fx;
    int y1 = min(y0 + 1, H - 1), x1 = min(x0 + 1, W - 1);
    float wy = fy - y0, wx = fx - x0;
    auto rd = [&](int cy, int cx) {
      long o = ((long)(cy + Poffs) * Wps + (cx + Poffs)) * C + c;
      return bf2f(sh[o]) + bf2f(sl[o]);
    };
    float r0 = rd(y0, x0) * (1.f - wx) + rd(y0, x1) * wx;
    float r1 = rd(y1, x0) * (1.f - wx) + rd(y1, x1) * wx;
    v = r0 * (1.f - wy) + r1 * wy;
  }
  splitw(v, &oh[gid], &ol[gid]);
}

// ---------------------------------------------------------------------------
extern "C" void kernel_launch(void* const* d_in, const int* in_sizes, int n_in,
                              void* d_out, int out_size, void* d_ws,
                              size_t ws_size, hipStream_t stream) {
  const float* input = (const float*)d_in[0];
  const float* enc_w0 = (const float*)d_in[1];
  const float* enc_b0 = (const float*)d_in[2];
  const float* enc_w1 = (const float*)d_in[3];
  const float* enc_b1 = (const float*)d_in[4];
  const float* enc_w2 = (const float*)d_in[5];
  const float* enc_b2 = (const float*)d_in[6];
  const float* enc_w3 = (const float*)d_in[7];
  const float* enc_b3 = (const float*)d_in[8];
  const float* tq_w = (const float*)d_in[9];
  const float* tq_b = (const float*)d_in[10];
  const float* tk_w = (const float*)d_in[11];
  const float* tk_b = (const float*)d_in[12];
  const float* tv_w = (const float*)d_in[13];
  const float* tv_b = (const float*)d_in[14];
  const float* to_w = (const float*)d_in[15];
  const float* to_b = (const float*)d_in[16];
  const float* tf1_w = (const float*)d_in[17];
  const float* tf1_b = (const float*)d_in[18];
  const float* tf2_w = (const float*)d_in[19];
  const float* tf2_b = (const float*)d_in[20];
  const float* d0_w = (const float*)d_in[21];
  const float* d0_b = (const float*)d_in[22];
  const float* d1_w = (const float*)d_in[23];
  const float* d1_b = (const float*)d_in[24];
  const float* d2_w = (const float*)d_in[25];
  const float* d2_b = (const float*)d_in[26];
  const float* d3_w = (const float*)d_in[27];
  const float* d3_b = (const float*)d_in[28];
  float* out = (float*)d_out;

  // -------- workspace layout --------
  unsigned char* wsb = (unsigned char*)d_ws;
  size_t off = 0;
  auto alloc = [&](size_t bytes) {
    void* p = wsb + off;
    off = (off + bytes + 255) & ~(size_t)255;
    return p;
  };
  const long XCL_E = 22839296L;   // 16*34*164*256
  const long XCL2_E = 21233664L;  // 16*32*162*256
  const long QT_E = 4915200L;
  const long VT_E = 5111808L;
  u16* XCLh = (u16*)alloc(XCL_E * 2);
  u16* XCLl = (u16*)alloc(XCL_E * 2);
  u16* XCL2h = (u16*)alloc(XCL2_E * 2);
  u16* XCL2l = (u16*)alloc(XCL2_E * 2);
  u16* qth = (u16*)alloc(QT_E * 2);
  u16* qtl = (u16*)alloc(QT_E * 2);
  u16* kth = (u16*)alloc(QT_E * 2);
  u16* ktl = (u16*)alloc(QT_E * 2);
  u16* vth = (u16*)alloc(VT_E * 2);
  u16* vtl = (u16*)alloc(VT_E * 2);
  int* nmapA = (int*)alloc(4 * 4800 * 4);
  int* dmapA = (int*)alloc(4 * 4800 * 4);
  int* rowbaseA = (int*)alloc(7120 * 4);
  int* doffA = (int*)alloc(93248 * 4);
  u16* qwh = (u16*)alloc(65536 * 2);
  u16* qwl = (u16*)alloc(65536 * 2);
  u16* kwh = (u16*)alloc(65536 * 2);
  u16* kwl = (u16*)alloc(65536 * 2);
  u16* vwh = (u16*)alloc(65536 * 2);
  u16* vwl = (u16*)alloc(65536 * 2);
  size_t fixed_end = off;
  size_t avail = ws_size > fixed_end ? ws_size - fixed_end : 0;
  size_t SCB = avail > 4096 ? avail - 4096 : 0;
  if (SCB > 104857600UL) SCB = 104857600UL;
  float* scores = (float*)alloc(SCB);
  size_t need = off;
  if (ws_size < need) return;  // fail loud, not crash
  long SCAPf = (long)(SCB / 4);
  if (SCAPf < 1800000) return;

  // encoder weight splits + trunk wt3 region overlay the scores region
  u16* Wth = (u16*)scores;
  u16* Wtl = Wth + 589824;
  u16* W3 = (u16*)scores;

  // ---- decoder buffers: overlay XCL2+token+scores region ----
  unsigned char* decbase = (unsigned char*)XCL2h;
  u16* dec0inH = (u16*)(decbase + 0);
  u16* dec0inL = (u16*)(decbase + 40886272);
  u16* dec0outH = (u16*)(decbase + 81772544);
  u16* dec0outL = (u16*)(decbase + 102215680);
  u16* dec1outH = (u16*)(decbase + 122658816);
  u16* dec1outL = (u16*)(decbase + 132880384);
  u16* dec2inH = (u16*)(decbase + 0);
  u16* dec2inL = (u16*)(decbase + 20050944);
  float* dec2out = (float*)(decbase + 40101888);
  u16* Wd0h = (u16*)(decbase + 143101952);
  u16* Wd0l = Wd0h + 294912;
  u16* W1h = Wd0l + 294912;
  u16* W1l = W1h + 73728;
  u16* W2h = W1l + 73728;
  u16* W2l = W2h + 36864;
  const long D0IN_FS = 5110784, D0OUT_FS = 2555392, D1OUT_FS = 1277696;
  const long D2IN_FS = 5012736, D2OUT_FS = 4915200;

  const long FS_TR = 1427456;  // 34*164*256
  const long FS_T2 = 1327104;  // 32*162*256 == 64*324*64
  const long FS_E2 = 713728;   // 34*164*128

  static const int PWa[4] = {80, 32, 10, 5};
  static const int PHa[4] = {15, 6, 5, 3};
  static const int rbOff[4] = {0, 64, 464, 2000};
  static const int doOff[4] = {0, 76800, 89088, 92288};

  // -------- encoder --------
  hipMemsetAsync(XCLh, 0, XCL_E * 2, stream);
  hipMemsetAsync(XCLl, 0, XCL_E * 2, stream);
  hipMemsetAsync(XCL2h, 0, XCL2_E * 2, stream);
  hipMemsetAsync(XCL2l, 0, XCL2_E * 2, stream);
  hipMemsetAsync(vth, 0, VT_E * 2, stream);
  hipMemsetAsync(vtl, 0, VT_E * 2, stream);
  // enc0: coalesced CL writes (oc-innermost lanes)
  conv_enc0_cl<<<9600, 256, 0, stream>>>(input, enc_w0, enc_b0, XCL2h, XCL2l);
  {  // enc1
    wt_build<<<cdivu(9L * 64 * 64, 256), 256, 0, stream>>>(enc_w1, 64, 64, 9,
                                                           Wth, Wtl);
    conv_gemm_lds<4, 1><<<dim3(75, 1, 16), 256, 0, stream>>>(
        XCL2h, XCL2l, Wth, Wtl, enc_b1, 64, 64, 60, 320, 324, 2, 1, 1, 1, 9,
        FS_T2, ACT_LEAKY, nullptr, 0, XCLh, XCLl, FS_T2, 324, 2, 0);
  }
  hipMemsetAsync(XCL2h, 0, XCL2_E * 2, stream);
  hipMemsetAsync(XCL2l, 0, XCL2_E * 2, stream);
  {  // enc2
    wt_build<<<cdivu(9L * 128 * 64, 256), 256, 0, stream>>>(enc_w2, 128, 64, 9,
                                                            Wth, Wtl);
    conv_gemm_lds<2, 2><<<dim3(38, 1, 16), 256, 0, stream>>>(
        XCLh, XCLl, Wth, Wtl, enc_b2, 64, 128, 30, 160, 324, 2, 2, 1, 1, 9,
        FS_T2, ACT_LEAKY, nullptr, 0, XCL2h, XCL2l, FS_E2, 164, 2, 0);
  }
  hipMemsetAsync(XCLh, 0, XCL_E * 2, stream);
  hipMemsetAsync(XCLl, 0, XCL_E * 2, stream);
  {  // enc3
    wt_build<<<cdivu(9L * 256 * 128, 256), 256, 0, stream>>>(enc_w3, 256, 128,
                                                             9, Wth, Wtl);
    conv_gemm_lds<2, 2><<<dim3(38, 2, 16), 256, 0, stream>>>(
        XCL2h, XCL2l, Wth, Wtl, enc_b3, 128, 256, 30, 160, 164, 2, 1, 1, 1, 9,
        FS_E2, ACT_LEAKY, nullptr, 0, XCLh, XCLl, FS_TR, 164, 2, 0);
  }
  hipMemsetAsync(XCL2h, 0, XCL2_E * 2, stream);
  hipMemsetAsync(XCL2l, 0, XCL2_E * 2, stream);

  // -------- token maps / scatter LUTs --------
  for (int g = 0; g < 4; ++g) {
    int ph = PHa[g], pw = PWa[g];
    int ohh = 30 / ph, oww = 160 / pw;
    int Ntok = 16 * ohh * oww, Dd = 64 * ph * pw, pp = ph * pw;
    maps_build<<<19, 256, 0, stream>>>(ph, pw, oww, nmapA + g * 4800,
                                       dmapA + g * 4800);
    int mx = Ntok > Dd ? Ntok : Dd;
    luts_build<<<cdivu(mx, 256), 256, 0, stream>>>(
        ph, pw, ohh * oww, oww, pp, Ntok, Dd, g * 64, rowbaseA + rbOff[g],
        doffA + doOff[g]);
  }

  // -------- transformer stack --------
  for (int l = 0; l < 8; ++l) {
    wtqkv_build_all<<<256, 256, 0, stream>>>(
        tq_w + (long)l * 65536, tk_w + (long)l * 65536,
        tv_w + (long)l * 65536, qwh, qwl, kwh, kwl, vwh, vwl);

    for (int g = 0; g < 4; ++g) {
      int ph = PHa[g], pw = PWa[g];
      int ohh = 30 / ph, oww = 160 / pw;
      int ohow = ohh * oww;
      int Ntok = 16 * ohow, Dd = 64 * ph * pw, pp = ph * pw;
      int NtokPad = (Ntok + 31) & ~31;
      float scale = 1.0f / sqrtf((float)Dd);
      const int* nmap = nmapA + g * 4800;
      const int* dmap = dmapA + g * 4800;
      const int* rowbase = rowbaseA + rbOff[g];
      const int* doffp = doffA + doOff[g];

      qkv3_gemm_lds<<<dim3(19, 1, 16), 256, 0, stream>>>(
          XCLh, XCLl, FS_TR, 164, 2, qwh + g * 16384, qwl + g * 16384,
          kwh + g * 16384, kwl + g * 16384, vwh + g * 16384, vwl + g * 16384,
          tq_b + l * 256 + g * 64, tk_b + l * 256 + g * 64,
          tv_b + l * 256 + g * 64, nmap, dmap, ohow, Dd, pp, NtokPad, scale,
          qth, qtl, kth, ktl, vth, vtl);

      if (g == 0) {
        float* scoresR = scores + 131072;
        attn_gemm_lds<<<dim3(1, 1, 32), 256, 0, stream>>>(
            qth, qtl, Dd, 64, kth, ktl, Dd, 64, 2400, 64, 0, scores, 64, 4096,
            nullptr, nullptr, nullptr, nullptr);
        reduce_scatter<<<16, 256, 0, stream>>>(scores, 32, 4096, 64, 64, 0,
                                               scoresR, nullptr, nullptr,
                                               nullptr, nullptr);
        softmax_ip<<<64, 256, 0, stream>>>(scoresR, 64, 64);
        attn_pv_lds<<<dim3(1, 600, 1), 256, 0, stream>>>(
            scoresR, 64, 64, vth, vtl, 64, Dd, 64, Dd, 1, nullptr, 0, 0,
            XCL2h, XCL2l, rowbase, doffp);
      } else {
        long denom = (long)NtokPad + (g == 3 ? 3840 : 0);
        long cap = (SCAPf / denom) & ~127L;
        int chunk = (int)(cap < 128 ? 128 : cap);
        if (chunk > Ntok) chunk = Ntok;
        float* partials = scores + (long)chunk * NtokPad;
        for (int r0 = 0; r0 < Ntok; r0 += chunk) {
          int rows = Ntok - r0 < chunk ? Ntok - r0 : chunk;
          attn_gemm_lds<<<dim3(cdivu(rows, 128), cdivu(Ntok, 128), 1), 256, 0,
                          stream>>>(qth + (long)r0 * Dd, qtl + (long)r0 * Dd,
                                    Dd, rows, kth, ktl, Dd, Ntok, Dd, Ntok, 0,
                                    scores, NtokPad, 0, nullptr, nullptr,
                                    nullptr, nullptr);
          softmax_ip<<<rows, 256, 0, stream>>>(scores, Ntok, NtokPad);
          if (g == 3) {
            attn_pv_lds<<<dim3(cdivu(rows, 128), 8, 4), 256, 0, stream>>>(
                scores, NtokPad, rows, vth, vtl, NtokPad, Dd, 1280, Dd, 0,
                partials, 960, (long)rows * 960, nullptr, nullptr, nullptr,
                nullptr);
            reduce_scatter<<<cdivu((long)rows * 960, 256), 256, 0, stream>>>(
                partials, 4, (long)rows * 960, rows, 960, 1, nullptr, XCL2h,
                XCL2l, rowbase + r0, doffp);
          } else {
            attn_pv_lds<<<dim3(cdivu(rows, 128), Dd / 128, 1), 256, 0,
                          stream>>>(scores, NtokPad, rows, vth, vtl, NtokPad,
                                    Dd, NtokPad, Dd, 1, nullptr, 0, 0, XCL2h,
                                    XCL2l, rowbase + r0, doffp);
          }
        }
      }
    }

    wt3_build<<<6912, 256, 0, stream>>>(to_w + (long)l * 589824,
                                        tf1_w + (long)l * 589824,
                                        tf2_w + (long)l * 589824, W3);
    conv_gemm_lds<2, 2><<<dim3(38, 2, 16), 256, 0, stream>>>(
        XCL2h, XCL2l, W3, W3 + 589824, to_b + l * 256, 256, 256, 30, 160, 162,
        1, 1, 1, 1, 9, FS_T2, ACT_LEAKY, nullptr, 0, XCLh, XCLl, FS_TR, 164, 2,
        1);
    conv_gemm_lds<2, 2><<<dim3(38, 2, 16), 256, 0, stream>>>(
        XCLh, XCLl, W3 + 1179648, W3 + 1769472, tf1_b + l * 256, 256, 256, 30,
        160, 164, 2, 1, 2, 2, 9, FS_TR, ACT_LEAKY, nullptr, 0, XCL2h, XCL2l,
        FS_T2, 162, 1, 0);
    conv_gemm_lds<2, 2><<<dim3(38, 2, 16), 256, 0, stream>>>(
        XCL2h, XCL2l, W3 + 2359296, W3 + 2949120, tf2_b + l * 256, 256, 256,
        30, 160, 162, 1, 1, 1, 1, 9, FS_T2, ACT_LEAKY, nullptr, 0, XCLh, XCLl,
        FS_TR, 164, 2, 1);
  }

  // -------- decoder: 4-frame front half, 2-frame back half --------
  hipMemsetAsync(decbase, 0, 144723968, stream);
  wt_build<<<cdivu(9L * 128 * 256, 256), 256, 0, stream>>>(d0_w, 128, 256, 9,
                                                           Wd0h, Wd0l);
  wt_build<<<cdivu(9L * 64 * 128, 256), 256, 0, stream>>>(d1_w, 64, 128, 9,
                                                          W1h, W1l);
  wt_build<<<cdivu(9L * 64 * 64, 256), 256, 0, stream>>>(d2_w, 64, 64, 9, W2h,
                                                         W2l);
  for (int f = 0; f < 16; f += 4) {
    up_cl2cl_pad<<<dim3(cdivu(62L * 322 * 256, 256), 1, 4), 256, 0, stream>>>(
        XCLh + (long)f * FS_TR, XCLl + (long)f * FS_TR, dec0inH, dec0inL,
        FS_TR, D0IN_FS, 256, 30, 160, 164, 2, 62, 322, 1);
    conv_gemm_lds<2, 2><<<dim3(150, 1, 4), 256, 0, stream>>>(
        dec0inH, dec0inL, Wd0h, Wd0l, d0_b, 256, 128, 60, 320, 322, 1, 1, 1, 1,
        9, D0IN_FS, ACT_LEAKY, nullptr, 0, dec0outH, dec0outL, D0OUT_FS, 322,
        1, 0);
    conv_gemm_lds<4, 1><<<dim3(75, 1, 4), 256, 0, stream>>>(
        dec0outH, dec0outL, W1h, W1l, d1_b, 128, 64, 60, 320, 322, 1, 1, 1, 1,
        9, D0OUT_FS, ACT_LEAKY, nullptr, 0, dec1outH, dec1outL, D1OUT_FS, 322,
        1, 0);
    for (int ff = 0; ff < 4; ff += 2) {
      up_cl2cl_pad<<<dim3(cdivu(122L * 642 * 64, 256), 1, 2), 256, 0,
                     stream>>>(dec1outH + (long)ff * D1OUT_FS,
                               dec1outL + (long)ff * D1OUT_FS, dec2inH,
                               dec2inL, D1OUT_FS, D2IN_FS, 64, 60, 320, 322, 1,
                               122, 642, 1);
      conv_gemm_lds<4, 1><<<dim3(300, 1, 2), 256, 0, stream>>>(
          dec2inH, dec2inL, W2h, W2l, d2_b, 64, 64, 120, 640, 642, 1, 1, 1, 1,
          9, D2IN_FS, ACT_LEAKY, dec2out, D2OUT_FS, nullptr, nullptr, 0, 0, 0,
          0);
      long tot = 2L * 3 * 120 * 80;
      conv2d_k<3, 1, 1><<<cdivu(tot, 256), 256, 0, stream>>>(
          dec2out, d3_w, d3_b, out + (long)(f + ff) * 230400, nullptr, nullptr,
          0, 0, 0, 2, 64, 120, 640, 3, 120, 640, 1, ACT_TANH);
    }
  }
}

// Round 14
// 27674.060 us; speedup vs baseline: 37.0638x; 1.1102x over previous
//
#include <hip/hip_runtime.h>
#include <hip/hip_bf16.h>
#include <math.h>

#define ACT_NONE 0
#define ACT_LEAKY 1
#define ACT_TANH 2

typedef __attribute__((ext_vector_type(8))) short bf16x8;
typedef __attribute__((ext_vector_type(4))) float f32x4;
typedef unsigned short u16;

#define MFMA(a, b, c) __builtin_amdgcn_mfma_f32_16x16x32_bf16((bf16x8)(a), (bf16x8)(b), (c), 0, 0, 0)

static inline unsigned cdivu(long a, long b) { return (unsigned)((a + b - 1) / b); }

__device__ __forceinline__ u16 f2bf(float x) {
  union { __hip_bfloat16 h; u16 u; } cv;
  cv.h = __float2bfloat16(x);
  return cv.u;
}
__device__ __forceinline__ float bf2f(u16 b) {
  union { u16 u; __hip_bfloat16 h; } cv;
  cv.u = b;
  return __bfloat162float(cv.h);
}
__device__ __forceinline__ void splitw(float v, u16* ph, u16* pl) {
  u16 h = f2bf(v);
  *ph = h;
  *pl = f2bf(v - bf2f(h));
}
// async global->LDS, 16B per lane; dest must be wave-uniform base (+lane*16)
__device__ __forceinline__ void gload16(const void* g, void* l) {
  __builtin_amdgcn_global_load_lds(
      (const __attribute__((address_space(1))) unsigned int*)g,
      (__attribute__((address_space(3))) unsigned int*)l, 16, 0, 0);
}

// ---------------------------------------------------------------------------
// Direct fp32 conv (d3: Cout=3+tanh). Optional CL hi/lo output.
// ---------------------------------------------------------------------------
template <int K, int S, int DIL>
__global__ __launch_bounds__(256) void conv2d_k(
    const float* __restrict__ x, const float* __restrict__ w,
    const float* __restrict__ bias, float* y, u16* clh, u16* cll, int WpO,
    int PoffO, long o_fstride, int N, int Cin, int Hin, int Win, int Cout,
    int Hout, int Wout, int pad, int act) {
  constexpr int TW = 8;
  constexpr int XL = (TW - 1) * S + (K - 1) * DIL + 1;
  int wq = (Wout + TW - 1) / TW;
  long gid = (long)blockIdx.x * 256 + threadIdx.x;
  long total = (long)N * Cout * Hout * wq;
  if (gid >= total) return;
  int xg = (int)(gid % wq);
  long r = gid / wq;
  int yo = (int)(r % Hout);
  r /= Hout;
  int oc = (int)(r % Cout);
  int n = (int)(r / Cout);

  float bv = bias[oc];
  float acc[TW];
#pragma unroll
  for (int j = 0; j < TW; ++j) acc[j] = bv;

  int xo0 = xg * TW;
  int xi0 = xo0 * S - pad;
  const float* xn = x + (long)n * Cin * Hin * Win;
  const float* wb = w + (long)oc * Cin * K * K;

  for (int ic = 0; ic < Cin; ++ic) {
    const float* xc = xn + (long)ic * Hin * Win;
    const float* wc = wb + ic * (K * K);
#pragma unroll
    for (int ky = 0; ky < K; ++ky) {
      int yi = yo * S - pad + ky * DIL;
      if ((unsigned)yi < (unsigned)Hin) {
        const float* row = xc + (long)yi * Win;
        float xr[XL];
#pragma unroll
        for (int i2 = 0; i2 < XL; ++i2) {
          int xi = xi0 + i2;
          xr[i2] = ((unsigned)xi < (unsigned)Win) ? row[xi] : 0.f;
        }
#pragma unroll
        for (int kx = 0; kx < K; ++kx) {
          float wv = wc[ky * K + kx];
#pragma unroll
          for (int j = 0; j < TW; ++j)
            acc[j] = fmaf(wv, xr[j * S + kx * DIL], acc[j]);
        }
      }
    }
  }

#pragma unroll
  for (int j = 0; j < TW; ++j) {
    if (xo0 + j < Wout) {
      float v = acc[j];
      if (act == ACT_LEAKY)
        v = v >= 0.f ? v : 0.2f * v;
      else if (act == ACT_TANH)
        v = tanhf(v);
      if (y) y[(((long)n * Cout + oc) * Hout + yo) * Wout + xo0 + j] = v;
      if (clh) {
        long off = (long)n * o_fstride +
                   ((long)(yo + PoffO) * WpO + (xo0 + j + PoffO)) * Cout + oc;
        splitw(v, &clh[off], &cll[off]);
      }
    }
  }
}

// ---------------------------------------------------------------------------
// enc0 (3->64, stride2) with oc-innermost lanes -> coalesced CL writes.
// ---------------------------------------------------------------------------
__global__ __launch_bounds__(256) void conv_enc0_cl(
    const float* __restrict__ x, const float* __restrict__ w,
    const float* __restrict__ bias, u16* __restrict__ clh,
    u16* __restrict__ cll) {
  __shared__ float ws[64][29];
  int t = threadIdx.x;
  for (int i = t; i < 64 * 27; i += 256) ws[i / 27][i % 27] = w[i];
  __syncthreads();
  int oc = t & 63;
  float bv = bias[oc];
  long s0 = (long)blockIdx.x * 32 + (t >> 6);
#pragma unroll
  for (int step = 0; step < 8; ++step) {
    long s = s0 + step * 4;
    int xo = (int)(s % 320);
    long r = s / 320;
    int yo = (int)(r % 60);
    int n = (int)(r / 60);
    float acc = bv;
    for (int ic = 0; ic < 3; ++ic) {
      const float* xp = x + ((long)n * 3 + ic) * 76800;
      const float* wp = ws[oc] + ic * 9;
#pragma unroll
      for (int ky = 0; ky < 3; ++ky) {
        int yi = yo * 2 - 1 + ky;
        if ((unsigned)yi < 120u) {
#pragma unroll
          for (int kx = 0; kx < 3; ++kx) {
            int xi = xo * 2 - 1 + kx;
            if ((unsigned)xi < 640u)
              acc = fmaf(wp[ky * 3 + kx], xp[yi * 640 + xi], acc);
          }
        }
      }
    }
    float v = acc >= 0.f ? acc : 0.2f * acc;
    long off = (long)n * 1327104 + ((long)(yo + 2) * 324 + (xo + 2)) * 64 + oc;
    splitw(v, &clh[off], &cll[off]);
  }
}

// ---------------------------------------------------------------------------
// LDS-staged MFMA implicit-GEMM conv, 2-term: Ah*(Bh+Bl). Activations (A)
// quantize to bf16 at MFMA input; fp32-master hi/lo stream kept in storage.
// ---------------------------------------------------------------------------
template <int WM, int WN>
__global__ __launch_bounds__(256) void conv_gemm_lds(
    const u16* __restrict__ Ah, const u16* __restrict__ Al,
    const u16* __restrict__ Bh, const u16* __restrict__ Bl,
    const float* __restrict__ bias, int Cin, int Cout, int Hout, int Wout,
    int Wp, int Poff, int S, int DIL, int pad, int taps, long a_fstride,
    int act, float* yout, long y_fstride, u16* Oh, u16* Ol, long o_fstride,
    int WpO, int PoffO, int useres) {
  constexpr int TM = WM * 64, TN = WN * 64;
  __shared__ u16 AsH[TM * 32], BsH[TN * 32], BsL[TN * 32];
  int t = threadIdx.x;
  int lane = t & 63;
  int w = t >> 6;
  int wr = w / WN, wc = w % WN;
  int l15 = lane & 15, l16 = lane >> 4;
  int HW = Hout * Wout;
  int row0 = blockIdx.x * TM;
  int col0 = blockIdx.y * TN;
  const u16* Afh = Ah + (long)blockIdx.z * a_fstride;

  int rs = t >> 2;
  int cs = (t & 3) * 8;
  long abase[WM];
#pragma unroll
  for (int c = 0; c < WM; ++c) {
    int s = row0 + rs + 64 * c;
    if (s >= HW) s = HW - 1;
    int yo = s / Wout, xo = s - yo * Wout;
    int yb = yo * S - pad + Poff, xb = xo * S - pad + Poff;
    abase[c] = ((long)yb * Wp + xb) * Cin + cs;
  }
  long bbase[WN];
#pragma unroll
  for (int c = 0; c < WN; ++c)
    bbase[c] = (long)(col0 + rs + 64 * c) * Cin + cs;
  int ldst = w * 512;

  f32x4 acc[4][4];
#pragma unroll
  for (int m = 0; m < 4; ++m)
#pragma unroll
    for (int n = 0; n < 4; ++n) acc[m][n] = (f32x4){0.f, 0.f, 0.f, 0.f};

  for (int tap = 0; tap < taps; ++tap) {
    int ky = tap / 3, kx = tap - ky * 3;
    long atap = ((long)ky * DIL * Wp + kx * DIL) * Cin;
    long btap = (long)tap * Cout * Cin;
    for (int ic0 = 0; ic0 < Cin; ic0 += 32) {
#pragma unroll
      for (int c = 0; c < WM; ++c)
        gload16(Afh + abase[c] + atap + ic0, AsH + c * 2048 + ldst);
#pragma unroll
      for (int c = 0; c < WN; ++c) {
        gload16(Bh + bbase[c] + btap + ic0, BsH + c * 2048 + ldst);
        gload16(Bl + bbase[c] + btap + ic0, BsL + c * 2048 + ldst);
      }
      __syncthreads();
      bf16x8 ah[4];
#pragma unroll
      for (int m = 0; m < 4; ++m) {
        int rrow = wr * 64 + m * 16 + l15;
        ah[m] = *(const bf16x8*)(AsH + rrow * 32 + l16 * 8);
      }
#pragma unroll
      for (int n = 0; n < 4; ++n) {
        int rcol = wc * 64 + n * 16 + l15;
        bf16x8 bh = *(const bf16x8*)(BsH + rcol * 32 + l16 * 8);
        bf16x8 bl = *(const bf16x8*)(BsL + rcol * 32 + l16 * 8);
#pragma unroll
        for (int m = 0; m < 4; ++m) {
          acc[m][n] = MFMA(ah[m], bh, acc[m][n]);
          acc[m][n] = MFMA(ah[m], bl, acc[m][n]);
        }
      }
      __syncthreads();
    }
  }

  float* yf = yout ? yout + (long)blockIdx.z * y_fstride : nullptr;
  u16* Ofh = Oh ? Oh + (long)blockIdx.z * o_fstride : nullptr;
  u16* Ofl = Ol ? Ol + (long)blockIdx.z * o_fstride : nullptr;
#pragma unroll
  for (int m = 0; m < 4; ++m) {
#pragma unroll
    for (int r = 0; r < 4; ++r) {
      int s = row0 + wr * 64 + m * 16 + l16 * 4 + r;
      if (s >= HW) continue;
      int yo = s / Wout, xo = s - yo * Wout;
      long clbase = 0;
      if (Ofh) clbase = ((long)(yo + PoffO) * WpO + (xo + PoffO)) * Cout;
#pragma unroll
      for (int n = 0; n < 4; ++n) {
        int oc = col0 + wc * 64 + n * 16 + l15;
        float v = acc[m][n][r] + bias[oc];
        if (act == ACT_LEAKY) v = v >= 0.f ? v : 0.2f * v;
        if (Ofh) {
          long off = clbase + oc;
          if (useres) v += bf2f(Ofh[off]) + bf2f(Ofl[off]);
          splitw(v, &Ofh[off], &Ofl[off]);
        }
        if (yf) yf[((long)oc * Hout + yo) * Wout + xo] = v;
      }
    }
  }
}

// ---------------------------------------------------------------------------
// Fused QKV 1x1 GEMM, 2-term Ah*(Bh+Bl). Tile 256x64, 4 waves.
// Token layout d = dm*64 + c (channels innermost). Q stores HI only.
// ---------------------------------------------------------------------------
__global__ __launch_bounds__(256) void qkv3_gemm_lds(
    const u16* __restrict__ Ah, const u16* __restrict__ Al, long a_fstride,
    int Wp, int Poff, const u16* __restrict__ qwh, const u16* __restrict__ qwl,
    const u16* __restrict__ kwh, const u16* __restrict__ kwl,
    const u16* __restrict__ vwh, const u16* __restrict__ vwl,
    const float* __restrict__ qbias, const float* __restrict__ kbias,
    const float* __restrict__ vbias, const int* __restrict__ nmap,
    const int* __restrict__ dmap, int ohow, int Dd, int pp, int NtokPad,
    float scale, u16* __restrict__ tqh, u16* __restrict__ tql,
    u16* __restrict__ tkh, u16* __restrict__ tkl, u16* __restrict__ tvh,
    u16* __restrict__ tvl) {
  __shared__ u16 AsH[256 * 32], BsH[64 * 32], BsL[64 * 32];
  int t = threadIdx.x;
  int lane = t & 63;
  int w = t >> 6;
  int l15 = lane & 15, l16 = lane >> 4;
  int row0 = blockIdx.x * 256;
  int frame = blockIdx.z;
  const u16* Afh = Ah + (long)frame * a_fstride;

  int rs = t >> 2;
  int cs = (t & 3) * 8;
  long abase[4];
#pragma unroll
  for (int c = 0; c < 4; ++c) {
    int s = row0 + rs + 64 * c;
    if (s >= 4800) s = 4799;
    int yo = s / 160, xo = s - yo * 160;
    abase[c] = ((long)(yo + Poff) * Wp + (xo + Poff)) * 256 + cs;
  }
  long bbase = (long)rs * 256 + cs;
  int ldst = w * 512;

  for (int mat = 0; mat < 3; ++mat) {
    const u16* Bh = mat == 0 ? qwh : mat == 1 ? kwh : vwh;
    const u16* Bl = mat == 0 ? qwl : mat == 1 ? kwl : vwl;
    const float* bias = mat == 0 ? qbias : mat == 1 ? kbias : vbias;
    u16* tH = mat == 0 ? tqh : mat == 1 ? tkh : tvh;
    u16* tL = mat == 0 ? tql : mat == 1 ? tkl : tvl;

    f32x4 acc[4][4];
#pragma unroll
    for (int m = 0; m < 4; ++m)
#pragma unroll
      for (int n = 0; n < 4; ++n) acc[m][n] = (f32x4){0.f, 0.f, 0.f, 0.f};

    for (int ic0 = 0; ic0 < 256; ic0 += 32) {
#pragma unroll
      for (int c = 0; c < 4; ++c)
        gload16(Afh + abase[c] + ic0, AsH + c * 2048 + ldst);
      gload16(Bh + bbase + ic0, BsH + ldst);
      gload16(Bl + bbase + ic0, BsL + ldst);
      __syncthreads();
      bf16x8 ah[4];
#pragma unroll
      for (int m = 0; m < 4; ++m) {
        int rrow = w * 64 + m * 16 + l15;
        ah[m] = *(const bf16x8*)(AsH + rrow * 32 + l16 * 8);
      }
#pragma unroll
      for (int n = 0; n < 4; ++n) {
        int rcol = n * 16 + l15;
        bf16x8 bh = *(const bf16x8*)(BsH + rcol * 32 + l16 * 8);
        bf16x8 bl = *(const bf16x8*)(BsL + rcol * 32 + l16 * 8);
#pragma unroll
        for (int m = 0; m < 4; ++m) {
          acc[m][n] = MFMA(ah[m], bh, acc[m][n]);
          acc[m][n] = MFMA(ah[m], bl, acc[m][n]);
        }
      }
      __syncthreads();
    }

#pragma unroll
    for (int m = 0; m < 4; ++m) {
#pragma unroll
      for (int r = 0; r < 4; ++r) {
        int s = row0 + w * 64 + m * 16 + l16 * 4 + r;
        if (s >= 4800) continue;
        int nm = nmap[s], dm = dmap[s];
        int ntok = frame * ohow + nm;
#pragma unroll
        for (int n = 0; n < 4; ++n) {
          int c = n * 16 + l15;
          float v = acc[m][n][r] + bias[c];
          if (mat == 0) v *= scale;
          int d = dm * 64 + c;
          long off = (mat == 2) ? ((long)d * NtokPad + ntok)
                                : ((long)ntok * Dd + d);
          u16 h = f2bf(v);
          tH[off] = h;
          if (mat != 0) tL[off] = f2bf(v - bf2f(h));
        }
      }
    }
  }
}

// ---------------------------------------------------------------------------
// QK GEMM, 2-term: S = Qh*(Kh+Kl).
// ---------------------------------------------------------------------------
__global__ __launch_bounds__(256) void attn_gemm_lds(
    const u16* __restrict__ Ah, const u16* __restrict__ Al, int lda, int Mrows,
    const u16* __restrict__ Bh, const u16* __restrict__ Bl, int ldb,
    int Nclamp, int Kpart, int Nvalid, int mode, float* outf, int ldo,
    long partstride, u16* __restrict__ Oh, u16* __restrict__ Ol,
    const int* __restrict__ rowbase, const int* __restrict__ doff) {
  __shared__ u16 AsH[128 * 32], BsH[128 * 32], BsL[128 * 32];
  int t = threadIdx.x;
  int lane = t & 63;
  int w = t >> 6;
  int wc = w & 1, wr = w >> 1;
  int l15 = lane & 15, l16 = lane >> 4;
  int row0 = blockIdx.x * 128;
  int col0 = blockIdx.y * 128;
  int kbase = blockIdx.z * Kpart;
  if (outf) outf += (long)blockIdx.z * partstride;

  int rs = t >> 2;
  int cs = (t & 3) * 8;
  long abase[2], bbase[2];
#pragma unroll
  for (int c = 0; c < 2; ++c) {
    int sr = row0 + rs + 64 * c;
    if (sr >= Mrows) sr = Mrows - 1;
    abase[c] = (long)sr * lda + cs;
    int cc = col0 + rs + 64 * c;
    if (cc >= Nclamp) cc = Nclamp - 1;
    bbase[c] = (long)cc * ldb + cs;
  }
  int ldst = w * 512;

  f32x4 acc[4][4];
#pragma unroll
  for (int m = 0; m < 4; ++m)
#pragma unroll
    for (int n = 0; n < 4; ++n) acc[m][n] = (f32x4){0.f, 0.f, 0.f, 0.f};

  for (int k = kbase; k < kbase + Kpart; k += 32) {
#pragma unroll
    for (int c = 0; c < 2; ++c) {
      gload16(Ah + abase[c] + k, AsH + c * 2048 + ldst);
      gload16(Bh + bbase[c] + k, BsH + c * 2048 + ldst);
      gload16(Bl + bbase[c] + k, BsL + c * 2048 + ldst);
    }
    __syncthreads();
    bf16x8 ah[4];
#pragma unroll
    for (int m = 0; m < 4; ++m) {
      int rrow = wr * 64 + m * 16 + l15;
      ah[m] = *(const bf16x8*)(AsH + rrow * 32 + l16 * 8);
    }
#pragma unroll
    for (int n = 0; n < 4; ++n) {
      int rcol = wc * 64 + n * 16 + l15;
      bf16x8 bh = *(const bf16x8*)(BsH + rcol * 32 + l16 * 8);
      bf16x8 bl = *(const bf16x8*)(BsL + rcol * 32 + l16 * 8);
#pragma unroll
      for (int m = 0; m < 4; ++m) {
        acc[m][n] = MFMA(ah[m], bh, acc[m][n]);
        acc[m][n] = MFMA(ah[m], bl, acc[m][n]);
      }
    }
    __syncthreads();
  }

#pragma unroll
  for (int m = 0; m < 4; ++m) {
#pragma unroll
    for (int r = 0; r < 4; ++r) {
      int sr = row0 + wr * 64 + m * 16 + l16 * 4 + r;
      if (sr >= Mrows) continue;
#pragma unroll
      for (int n = 0; n < 4; ++n) {
        int c = col0 + wc * 64 + n * 16 + l15;
        if (c >= Nvalid) continue;
        float v = acc[m][n][r];
        if (mode == 0) {
          outf[(long)sr * ldo + c] = v;
        } else {
          long off = (long)rowbase[sr] + doff[c];
          splitw(v, &Oh[off], &Ol[off]);
        }
      }
    }
  }
}

// ---------------------------------------------------------------------------
// PV GEMM, 2-term: O = Ph*(Vh+Vl). A = fp32 P rows (hi split on the fly).
// ---------------------------------------------------------------------------
__global__ __launch_bounds__(256) void attn_pv_lds(
    const float* __restrict__ P, int lda, int Mrows,
    const u16* __restrict__ Bh, const u16* __restrict__ Bl, int ldb,
    int Nclamp, int Kpart, int Nvalid, int mode, float* outf, int ldo,
    long partstride, u16* __restrict__ Oh, u16* __restrict__ Ol,
    const int* __restrict__ rowbase, const int* __restrict__ doff) {
  __shared__ float Asf[128 * 32];
  __shared__ u16 BsH[128 * 32], BsL[128 * 32];
  int t = threadIdx.x;
  int lane = t & 63;
  int w = t >> 6;
  int wc = w & 1, wr = w >> 1;
  int l15 = lane & 15, l16 = lane >> 4;
  int row0 = blockIdx.x * 128;
  int col0 = blockIdx.y * 128;
  int kbase = blockIdx.z * Kpart;
  if (outf) outf += (long)blockIdx.z * partstride;

  int arow = t >> 3;
  int acol = (t & 7) * 4;
  long abase[4];
#pragma unroll
  for (int j = 0; j < 4; ++j) {
    int r = row0 + arow + 32 * j;
    if (r >= Mrows) r = Mrows - 1;
    abase[j] = (long)r * lda + acol;
  }
  int rs = t >> 2;
  int cs = (t & 3) * 8;
  long bbase[2];
#pragma unroll
  for (int c = 0; c < 2; ++c) {
    int cc = col0 + rs + 64 * c;
    if (cc >= Nclamp) cc = Nclamp - 1;
    bbase[c] = (long)cc * ldb + cs;
  }
  int ldst = w * 512;

  f32x4 acc[4][4];
#pragma unroll
  for (int m = 0; m < 4; ++m)
#pragma unroll
    for (int n = 0; n < 4; ++n) acc[m][n] = (f32x4){0.f, 0.f, 0.f, 0.f};

  for (int k = kbase; k < kbase + Kpart; k += 32) {
#pragma unroll
    for (int j = 0; j < 4; ++j)
      gload16(P + abase[j] + k, Asf + (w * 64 + 256 * j) * 4);
#pragma unroll
    for (int c = 0; c < 2; ++c) {
      gload16(Bh + bbase[c] + k, BsH + c * 2048 + ldst);
      gload16(Bl + bbase[c] + k, BsL + c * 2048 + ldst);
    }
    __syncthreads();
    bf16x8 ah[4];
#pragma unroll
    for (int m = 0; m < 4; ++m) {
      int rrow = wr * 64 + m * 16 + l15;
      const float* ap = Asf + rrow * 32 + l16 * 8;
      f32x4 p0 = *(const f32x4*)(ap);
      f32x4 p1 = *(const f32x4*)(ap + 4);
#pragma unroll
      for (int e = 0; e < 4; ++e) {
        ah[m][e] = (short)f2bf(p0[e]);
        ah[m][4 + e] = (short)f2bf(p1[e]);
      }
    }
#pragma unroll
    for (int n = 0; n < 4; ++n) {
      int rcol = wc * 64 + n * 16 + l15;
      bf16x8 bh = *(const bf16x8*)(BsH + rcol * 32 + l16 * 8);
      bf16x8 bl = *(const bf16x8*)(BsL + rcol * 32 + l16 * 8);
#pragma unroll
      for (int m = 0; m < 4; ++m) {
        acc[m][n] = MFMA(ah[m], bh, acc[m][n]);
        acc[m][n] = MFMA(ah[m], bl, acc[m][n]);
      }
    }
    __syncthreads();
  }

#pragma unroll
  for (int m = 0; m < 4; ++m) {
#pragma unroll
    for (int r = 0; r < 4; ++r) {
      int sr = row0 + wr * 64 + m * 16 + l16 * 4 + r;
      if (sr >= Mrows) continue;
#pragma unroll
      for (int n = 0; n < 4; ++n) {
        int c = col0 + wc * 64 + n * 16 + l15;
        if (c >= Nvalid) continue;
        float v = acc[m][n][r];
        if (mode == 0) {
          outf[(long)sr * ldo + c] = v;
        } else {
          long off = (long)rowbase[sr] + doff[c];
          splitw(v, &Oh[off], &Ol[off]);
        }
      }
    }
  }
}

// ---------------------------------------------------------------------------
__global__ __launch_bounds__(256) void reduce_scatter(
    const float* __restrict__ parts, int nparts, long pstride, int rows, int N,
    int mode, float* outf, u16* __restrict__ Oh, u16* __restrict__ Ol,
    const int* __restrict__ rowbase, const int* __restrict__ doff) {
  long gid = (long)blockIdx.x * 256 + threadIdx.x;
  long tot = (long)rows * N;
  if (gid >= tot) return;
  float s = 0.f;
  for (int p = 0; p < nparts; ++p) s += parts[p * pstride + gid];
  if (mode == 0) {
    outf[gid] = s;
  } else {
    int r = (int)(gid / N), c = (int)(gid % N);
    long off = (long)rowbase[r] + doff[c];
    splitw(s, &Oh[off], &Ol[off]);
  }
}

// ---------------------------------------------------------------------------
__global__ __launch_bounds__(256) void softmax_ip(float* __restrict__ S,
                                                  int Ntok, int NtokPad) {
  int row = blockIdx.x;
  float* p = S + (long)row * NtokPad;
  __shared__ float red[256];
  int t = threadIdx.x;
  float m = -1e30f;
  for (int i = t; i < Ntok; i += 256) m = fmaxf(m, p[i]);
  red[t] = m;
  __syncthreads();
  for (int s = 128; s > 0; s >>= 1) {
    if (t < s) red[t] = fmaxf(red[t], red[t + s]);
    __syncthreads();
  }
  m = red[0];
  __syncthreads();
  float sum = 0.f;
  for (int i = t; i < Ntok; i += 256) sum += __expf(p[i] - m);
  red[t] = sum;
  __syncthreads();
  for (int s = 128; s > 0; s >>= 1) {
    if (t < s) red[t] += red[t + s];
    __syncthreads();
  }
  float inv = 1.f / red[0];
  __syncthreads();
  for (int i = t; i < Ntok; i += 256) p[i] = __expf(p[i] - m) * inv;
  for (int i = Ntok + t; i < NtokPad; i += 256) p[i] = 0.f;
}

// ---------------------------------------------------------------------------
__global__ __launch_bounds__(256) void wt_build(const float* __restrict__ w,
                                                int Cout, int Cin, int taps,
                                                u16* __restrict__ Wh,
                                                u16* __restrict__ Wl) {
  long gid = (long)blockIdx.x * 256 + threadIdx.x;
  long tot = (long)taps * Cout * Cin;
  if (gid >= tot) return;
  int ic = (int)(gid % Cin);
  long r = gid / Cin;
  int oc = (int)(r % Cout);
  int tap = (int)(r / Cout);
  float v = w[((long)oc * Cin + ic) * taps + tap];
  splitw(v, &Wh[gid], &Wl[gid]);
}

// build to/ff1/ff2 weight splits (256x256x9 each) in one dispatch
__global__ __launch_bounds__(256) void wt3_build(const float* __restrict__ w0,
                                                 const float* __restrict__ w1,
                                                 const float* __restrict__ w2,
                                                 u16* __restrict__ base) {
  long gid = (long)blockIdx.x * 256 + threadIdx.x;
  if (gid >= 3L * 589824) return;
  int mat = (int)(gid / 589824);
  int idx = (int)(gid - (long)mat * 589824);
  const float* w = mat == 0 ? w0 : mat == 1 ? w1 : w2;
  int ic = idx & 255;
  int r = idx >> 8;
  int oc = r & 255;
  int tap = r >> 8;
  float v = w[((long)oc * 256 + ic) * 9 + tap];
  u16* dst = base + (long)mat * 1179648;
  splitw(v, &dst[idx], &dst[589824 + idx]);
}

// fused q/k/v 1x1 weight split build, ALL 4 groups in one dispatch.
__global__ __launch_bounds__(256) void wtqkv_build_all(
    const float* __restrict__ wq, const float* __restrict__ wk,
    const float* __restrict__ wv, u16* __restrict__ qh, u16* __restrict__ ql,
    u16* __restrict__ kh, u16* __restrict__ kl, u16* __restrict__ vh,
    u16* __restrict__ vl) {
  int gid = blockIdx.x * 256 + threadIdx.x;
  if (gid >= 4 * 64 * 256) return;
  int ic = gid & 255;
  int c = (gid >> 8) & 63;
  int g = gid >> 14;
  long src = (long)(g * 64 + c) * 256 + ic;
  splitw(wq[src], &qh[gid], &ql[gid]);
  splitw(wk[src], &kh[gid], &kl[gid]);
  splitw(wv[src], &vh[gid], &vl[gid]);
}

// ---------------------------------------------------------------------------
__global__ __launch_bounds__(256) void maps_build(int ph, int pw, int ow,
                                                  int* __restrict__ nmap,
                                                  int* __restrict__ dmap) {
  int s = blockIdx.x * 256 + threadIdx.x;
  if (s >= 4800) return;
  int y = s / 160, x = s - y * 160;
  int i = y / ph, yy = y - i * ph;
  int j = x / pw, xx = x - j * pw;
  nmap[s] = i * ow + j;
  dmap[s] = yy * pw + xx;
}

// d = dm*64 + ch (channels innermost). doff[d] contiguous in ch.
__global__ __launch_bounds__(256) void luts_build(int ph, int pw, int ohow,
                                                  int ow, int pp, int Ntok,
                                                  int Dd, int gbase,
                                                  int* __restrict__ rowbase,
                                                  int* __restrict__ doff) {
  int gid = blockIdx.x * 256 + threadIdx.x;
  if (gid < Ntok) {
    int tt = gid / ohow, rem = gid - tt * ohow;
    int i = rem / ow, j = rem - i * ow;
    rowbase[gid] =
        tt * (32 * 162 * 256) + ((i * ph + 1) * 162 + (j * pw + 1)) * 256;
  }
  if (gid < Dd) {
    int ch = gid & 63;
    int dm = gid >> 6;
    int yy = dm / pw, xx = dm - yy * pw;
    doff[gid] = (yy * 162 + xx) * 256 + gbase + ch;
  }
}

// ---------------------------------------------------------------------------
// Bilinear x2 upsample (align_corners) CL hi/lo -> CL hi/lo, full padded
// write. blockIdx.z = frame; s_fs/o_fs are per-frame element strides.
// ---------------------------------------------------------------------------
__global__ __launch_bounds__(256) void up_cl2cl_pad(
    const u16* __restrict__ sh, const u16* __restrict__ sl,
    u16* __restrict__ oh, u16* __restrict__ ol, long s_fs, long o_fs, int C,
    int H, int W, int Wps, int Poffs, int Hp, int Wpo, int Poffo) {
  sh += (long)blockIdx.z * s_fs;
  sl += (long)blockIdx.z * s_fs;
  oh += (long)blockIdx.z * o_fs;
  ol += (long)blockIdx.z * o_fs;
  int Ho = 2 * H, Wo = 2 * W;
  long tot = (long)Hp * Wpo * C;
  long gid = (long)blockIdx.x * 256 + threadIdx.x;
  if (gid >= tot) return;
  int c = (int)(gid % C);
  long r = gid / C;
  int xp = (int)(r % Wpo);
  int yp = (int)(r / Wpo);
  int x = xp - Poffo, y = yp - Poffo;
  float v = 0.f;
  if ((unsigned)x < (unsigned)Wo && (unsigned)y < (unsigned)Ho) {
    float fy = (float)(y * (H - 1)) / (float)(Ho - 1);
    float fx = (float)(x * (W - 1)) / (float)(Wo - 1);
    int y0 = (int)fy, x0 = (int)fx;
    int y1 = min(y0 + 1, H - 1), x1 = min(x0 + 1, W - 1);
    float wy = fy - y0, wx = fx - x0;
    auto rd = [&](int cy, int cx) {
      long o = ((long)(cy + Poffs) * Wps + (cx + Poffs)) * C + c;
      return bf2f(sh[o]) + bf2f(sl[o]);
    };
    float r0 = rd(y0, x0) * (1.f - wx) + rd(y0, x1) * wx;
    float r1 = rd(y1, x0) * (1.f - wx) + rd(y1, x1) * wx;
    v = r0 * (1.f - wy) + r1 * wy;
  }
  splitw(v, &oh[gid], &ol[gid]);
}

// ---------------------------------------------------------------------------
extern "C" void kernel_launch(void* const* d_in, const int* in_sizes, int n_in,
                              void* d_out, int out_size, void* d_ws,
                              size_t ws_size, hipStream_t stream) {
  const float* input = (const float*)d_in[0];
  const float* enc_w0 = (const float*)d_in[1];
  const float* enc_b0 = (const float*)d_in[2];
  const float* enc_w1 = (const float*)d_in[3];
  const float* enc_b1 = (const float*)d_in[4];
  const float* enc_w2 = (const float*)d_in[5];
  const float* enc_b2 = (const float*)d_in[6];
  const float* enc_w3 = (const float*)d_in[7];
  const float* enc_b3 = (const float*)d_in[8];
  const float* tq_w = (const float*)d_in[9];
  const float* tq_b = (const float*)d_in[10];
  const float* tk_w = (const float*)d_in[11];
  const float* tk_b = (const float*)d_in[12];
  const float* tv_w = (const float*)d_in[13];
  const float* tv_b = (const float*)d_in[14];
  const float* to_w = (const float*)d_in[15];
  const float* to_b = (const float*)d_in[16];
  const float* tf1_w = (const float*)d_in[17];
  const float* tf1_b = (const float*)d_in[18];
  const float* tf2_w = (const float*)d_in[19];
  const float* tf2_b = (const float*)d_in[20];
  const float* d0_w = (const float*)d_in[21];
  const float* d0_b = (const float*)d_in[22];
  const float* d1_w = (const float*)d_in[23];
  const float* d1_b = (const float*)d_in[24];
  const float* d2_w = (const float*)d_in[25];
  const float* d2_b = (const float*)d_in[26];
  const float* d3_w = (const float*)d_in[27];
  const float* d3_b = (const float*)d_in[28];
  float* out = (float*)d_out;

  // -------- workspace layout --------
  unsigned char* wsb = (unsigned char*)d_ws;
  size_t off = 0;
  auto alloc = [&](size_t bytes) {
    void* p = wsb + off;
    off = (off + bytes + 255) & ~(size_t)255;
    return p;
  };
  const long XCL_E = 22839296L;   // 16*34*164*256
  const long XCL2_E = 21233664L;  // 16*32*162*256
  const long QT_E = 4915200L;
  const long VT_E = 5111808L;
  u16* XCLh = (u16*)alloc(XCL_E * 2);
  u16* XCLl = (u16*)alloc(XCL_E * 2);
  u16* XCL2h = (u16*)alloc(XCL2_E * 2);
  u16* XCL2l = (u16*)alloc(XCL2_E * 2);
  u16* qth = (u16*)alloc(QT_E * 2);
  u16* qtl = (u16*)alloc(QT_E * 2);
  u16* kth = (u16*)alloc(QT_E * 2);
  u16* ktl = (u16*)alloc(QT_E * 2);
  u16* vth = (u16*)alloc(VT_E * 2);
  u16* vtl = (u16*)alloc(VT_E * 2);
  int* nmapA = (int*)alloc(4 * 4800 * 4);
  int* dmapA = (int*)alloc(4 * 4800 * 4);
  int* rowbaseA = (int*)alloc(7120 * 4);
  int* doffA = (int*)alloc(93248 * 4);
  u16* qwh = (u16*)alloc(65536 * 2);
  u16* qwl = (u16*)alloc(65536 * 2);
  u16* kwh = (u16*)alloc(65536 * 2);
  u16* kwl = (u16*)alloc(65536 * 2);
  u16* vwh = (u16*)alloc(65536 * 2);
  u16* vwl = (u16*)alloc(65536 * 2);
  size_t fixed_end = off;
  size_t avail = ws_size > fixed_end ? ws_size - fixed_end : 0;
  size_t SCB = avail > 4096 ? avail - 4096 : 0;
  if (SCB > 104857600UL) SCB = 104857600UL;
  float* scores = (float*)alloc(SCB);
  size_t need = off;
  if (ws_size < need) return;  // fail loud, not crash
  long SCAPf = (long)(SCB / 4);
  if (SCAPf < 1800000) return;

  // encoder weight splits + trunk wt3 region overlay the scores region
  u16* Wth = (u16*)scores;
  u16* Wtl = Wth + 589824;
  u16* W3 = (u16*)scores;

  // ---- decoder buffers: overlay XCL2+token+scores region ----
  unsigned char* decbase = (unsigned char*)XCL2h;
  u16* dec0inH = (u16*)(decbase + 0);
  u16* dec0inL = (u16*)(decbase + 40886272);
  u16* dec0outH = (u16*)(decbase + 81772544);
  u16* dec0outL = (u16*)(decbase + 102215680);
  u16* dec1outH = (u16*)(decbase + 122658816);
  u16* dec1outL = (u16*)(decbase + 132880384);
  u16* dec2inH = (u16*)(decbase + 0);
  u16* dec2inL = (u16*)(decbase + 20050944);
  float* dec2out = (float*)(decbase + 40101888);
  u16* Wd0h = (u16*)(decbase + 143101952);
  u16* Wd0l = Wd0h + 294912;
  u16* W1h = Wd0l + 294912;
  u16* W1l = W1h + 73728;
  u16* W2h = W1l + 73728;
  u16* W2l = W2h + 36864;
  const long D0IN_FS = 5110784, D0OUT_FS = 2555392, D1OUT_FS = 1277696;
  const long D2IN_FS = 5012736, D2OUT_FS = 4915200;

  const long FS_TR = 1427456;  // 34*164*256
  const long FS_T2 = 1327104;  // 32*162*256 == 64*324*64
  const long FS_E2 = 713728;   // 34*164*128

  static const int PWa[4] = {80, 32, 10, 5};
  static const int PHa[4] = {15, 6, 5, 3};
  static const int rbOff[4] = {0, 64, 464, 2000};
  static const int doOff[4] = {0, 76800, 89088, 92288};

  // -------- encoder --------
  hipMemsetAsync(XCLh, 0, XCL_E * 2, stream);
  hipMemsetAsync(XCLl, 0, XCL_E * 2, stream);
  hipMemsetAsync(XCL2h, 0, XCL2_E * 2, stream);
  hipMemsetAsync(XCL2l, 0, XCL2_E * 2, stream);
  hipMemsetAsync(vth, 0, VT_E * 2, stream);
  hipMemsetAsync(vtl, 0, VT_E * 2, stream);
  conv_enc0_cl<<<9600, 256, 0, stream>>>(input, enc_w0, enc_b0, XCL2h, XCL2l);
  {  // enc1
    wt_build<<<cdivu(9L * 64 * 64, 256), 256, 0, stream>>>(enc_w1, 64, 64, 9,
                                                           Wth, Wtl);
    conv_gemm_lds<4, 1><<<dim3(75, 1, 16), 256, 0, stream>>>(
        XCL2h, XCL2l, Wth, Wtl, enc_b1, 64, 64, 60, 320, 324, 2, 1, 1, 1, 9,
        FS_T2, ACT_LEAKY, nullptr, 0, XCLh, XCLl, FS_T2, 324, 2, 0);
  }
  hipMemsetAsync(XCL2h, 0, XCL2_E * 2, stream);
  hipMemsetAsync(XCL2l, 0, XCL2_E * 2, stream);
  {  // enc2
    wt_build<<<cdivu(9L * 128 * 64, 256), 256, 0, stream>>>(enc_w2, 128, 64, 9,
                                                            Wth, Wtl);
    conv_gemm_lds<2, 2><<<dim3(38, 1, 16), 256, 0, stream>>>(
        XCLh, XCLl, Wth, Wtl, enc_b2, 64, 128, 30, 160, 324, 2, 2, 1, 1, 9,
        FS_T2, ACT_LEAKY, nullptr, 0, XCL2h, XCL2l, FS_E2, 164, 2, 0);
  }
  hipMemsetAsync(XCLh, 0, XCL_E * 2, stream);
  hipMemsetAsync(XCLl, 0, XCL_E * 2, stream);
  {  // enc3
    wt_build<<<cdivu(9L * 256 * 128, 256), 256, 0, stream>>>(enc_w3, 256, 128,
                                                             9, Wth, Wtl);
    conv_gemm_lds<2, 2><<<dim3(38, 2, 16), 256, 0, stream>>>(
        XCL2h, XCL2l, Wth, Wtl, enc_b3, 128, 256, 30, 160, 164, 2, 1, 1, 1, 9,
        FS_E2, ACT_LEAKY, nullptr, 0, XCLh, XCLl, FS_TR, 164, 2, 0);
  }
  hipMemsetAsync(XCL2h, 0, XCL2_E * 2, stream);
  hipMemsetAsync(XCL2l, 0, XCL2_E * 2, stream);

  // -------- token maps / scatter LUTs --------
  for (int g = 0; g < 4; ++g) {
    int ph = PHa[g], pw = PWa[g];
    int ohh = 30 / ph, oww = 160 / pw;
    int Ntok = 16 * ohh * oww, Dd = 64 * ph * pw, pp = ph * pw;
    maps_build<<<19, 256, 0, stream>>>(ph, pw, oww, nmapA + g * 4800,
                                       dmapA + g * 4800);
    int mx = Ntok > Dd ? Ntok : Dd;
    luts_build<<<cdivu(mx, 256), 256, 0, stream>>>(
        ph, pw, ohh * oww, oww, pp, Ntok, Dd, g * 64, rowbaseA + rbOff[g],
        doffA + doOff[g]);
  }

  // -------- transformer stack --------
  for (int l = 0; l < 8; ++l) {
    wtqkv_build_all<<<256, 256, 0, stream>>>(
        tq_w + (long)l * 65536, tk_w + (long)l * 65536,
        tv_w + (long)l * 65536, qwh, qwl, kwh, kwl, vwh, vwl);

    for (int g = 0; g < 4; ++g) {
      int ph = PHa[g], pw = PWa[g];
      int ohh = 30 / ph, oww = 160 / pw;
      int ohow = ohh * oww;
      int Ntok = 16 * ohow, Dd = 64 * ph * pw, pp = ph * pw;
      int NtokPad = (Ntok + 31) & ~31;
      float scale = 1.0f / sqrtf((float)Dd);
      const int* nmap = nmapA + g * 4800;
      const int* dmap = dmapA + g * 4800;
      const int* rowbase = rowbaseA + rbOff[g];
      const int* doffp = doffA + doOff[g];

      qkv3_gemm_lds<<<dim3(19, 1, 16), 256, 0, stream>>>(
          XCLh, XCLl, FS_TR, 164, 2, qwh + g * 16384, qwl + g * 16384,
          kwh + g * 16384, kwl + g * 16384, vwh + g * 16384, vwl + g * 16384,
          tq_b + l * 256 + g * 64, tk_b + l * 256 + g * 64,
          tv_b + l * 256 + g * 64, nmap, dmap, ohow, Dd, pp, NtokPad, scale,
          qth, qtl, kth, ktl, vth, vtl);

      if (g == 0) {
        float* scoresR = scores + 131072;
        attn_gemm_lds<<<dim3(1, 1, 32), 256, 0, stream>>>(
            qth, qtl, Dd, 64, kth, ktl, Dd, 64, 2400, 64, 0, scores, 64, 4096,
            nullptr, nullptr, nullptr, nullptr);
        reduce_scatter<<<16, 256, 0, stream>>>(scores, 32, 4096, 64, 64, 0,
                                               scoresR, nullptr, nullptr,
                                               nullptr, nullptr);
        softmax_ip<<<64, 256, 0, stream>>>(scoresR, 64, 64);
        attn_pv_lds<<<dim3(1, 600, 1), 256, 0, stream>>>(
            scoresR, 64, 64, vth, vtl, 64, Dd, 64, Dd, 1, nullptr, 0, 0,
            XCL2h, XCL2l, rowbase, doffp);
      } else {
        long denom = (long)NtokPad + (g == 3 ? 3840 : 0);
        long cap = (SCAPf / denom) & ~127L;
        int chunk = (int)(cap < 128 ? 128 : cap);
        if (chunk > Ntok) chunk = Ntok;
        float* partials = scores + (long)chunk * NtokPad;
        for (int r0 = 0; r0 < Ntok; r0 += chunk) {
          int rows = Ntok - r0 < chunk ? Ntok - r0 : chunk;
          attn_gemm_lds<<<dim3(cdivu(rows, 128), cdivu(Ntok, 128), 1), 256, 0,
                          stream>>>(qth + (long)r0 * Dd, qtl + (long)r0 * Dd,
                                    Dd, rows, kth, ktl, Dd, Ntok, Dd, Ntok, 0,
                                    scores, NtokPad, 0, nullptr, nullptr,
                                    nullptr, nullptr);
          softmax_ip<<<rows, 256, 0, stream>>>(scores, Ntok, NtokPad);
          if (g == 3) {
            attn_pv_lds<<<dim3(cdivu(rows, 128), 8, 4), 256, 0, stream>>>(
                scores, NtokPad, rows, vth, vtl, NtokPad, Dd, 1280, Dd, 0,
                partials, 960, (long)rows * 960, nullptr, nullptr, nullptr,
                nullptr);
            reduce_scatter<<<cdivu((long)rows * 960, 256), 256, 0, stream>>>(
                partials, 4, (long)rows * 960, rows, 960, 1, nullptr, XCL2h,
                XCL2l, rowbase + r0, doffp);
          } else {
            attn_pv_lds<<<dim3(cdivu(rows, 128), Dd / 128, 1), 256, 0,
                          stream>>>(scores, NtokPad, rows, vth, vtl, NtokPad,
                                    Dd, NtokPad, Dd, 1, nullptr, 0, 0, XCL2h,
                                    XCL2l, rowbase + r0, doffp);
          }
        }
      }
    }

    wt3_build<<<6912, 256, 0, stream>>>(to_w + (long)l * 589824,
                                        tf1_w + (long)l * 589824,
                                        tf2_w + (long)l * 589824, W3);
    conv_gemm_lds<2, 2><<<dim3(38, 2, 16), 256, 0, stream>>>(
        XCL2h, XCL2l, W3, W3 + 589824, to_b + l * 256, 256, 256, 30, 160, 162,
        1, 1, 1, 1, 9, FS_T2, ACT_LEAKY, nullptr, 0, XCLh, XCLl, FS_TR, 164, 2,
        1);
    conv_gemm_lds<2, 2><<<dim3(38, 2, 16), 256, 0, stream>>>(
        XCLh, XCLl, W3 + 1179648, W3 + 1769472, tf1_b + l * 256, 256, 256, 30,
        160, 164, 2, 1, 2, 2, 9, FS_TR, ACT_LEAKY, nullptr, 0, XCL2h, XCL2l,
        FS_T2, 162, 1, 0);
    conv_gemm_lds<2, 2><<<dim3(38, 2, 16), 256, 0, stream>>>(
        XCL2h, XCL2l, W3 + 2359296, W3 + 2949120, tf2_b + l * 256, 256, 256,
        30, 160, 162, 1, 1, 1, 1, 9, FS_T2, ACT_LEAKY, nullptr, 0, XCLh, XCLl,
        FS_TR, 164, 2, 1);
  }

  // -------- decoder: 4-frame front half, 2-frame back half --------
  hipMemsetAsync(decbase, 0, 144723968, stream);
  wt_build<<<cdivu(9L * 128 * 256, 256), 256, 0, stream>>>(d0_w, 128, 256, 9,
                                                           Wd0h, Wd0l);
  wt_build<<<cdivu(9L * 64 * 128, 256), 256, 0, stream>>>(d1_w, 64, 128, 9,
                                                          W1h, W1l);
  wt_build<<<cdivu(9L * 64 * 64, 256), 256, 0, stream>>>(d2_w, 64, 64, 9, W2h,
                                                         W2l);
  for (int f = 0; f < 16; f += 4) {
    up_cl2cl_pad<<<dim3(cdivu(62L * 322 * 256, 256), 1, 4), 256, 0, stream>>>(
        XCLh + (long)f * FS_TR, XCLl + (long)f * FS_TR, dec0inH, dec0inL,
        FS_TR, D0IN_FS, 256, 30, 160, 164, 2, 62, 322, 1);
    conv_gemm_lds<2, 2><<<dim3(150, 1, 4), 256, 0, stream>>>(
        dec0inH, dec0inL, Wd0h, Wd0l, d0_b, 256, 128, 60, 320, 322, 1, 1, 1, 1,
        9, D0IN_FS, ACT_LEAKY, nullptr, 0, dec0outH, dec0outL, D0OUT_FS, 322,
        1, 0);
    conv_gemm_lds<4, 1><<<dim3(75, 1, 4), 256, 0, stream>>>(
        dec0outH, dec0outL, W1h, W1l, d1_b, 128, 64, 60, 320, 322, 1, 1, 1, 1,
        9, D0OUT_FS, ACT_LEAKY, nullptr, 0, dec1outH, dec1outL, D1OUT_FS, 322,
        1, 0);
    for (int ff = 0; ff < 4; ff += 2) {
      up_cl2cl_pad<<<dim3(cdivu(122L * 642 * 64, 256), 1, 2), 256, 0,
                     stream>>>(dec1outH + (long)ff * D1OUT_FS,
                               dec1outL + (long)ff * D1OUT_FS, dec2inH,
                               dec2inL, D1OUT_FS, D2IN_FS, 64, 60, 320, 322, 1,
                               122, 642, 1);
      conv_gemm_lds<4, 1><<<dim3(300, 1, 2), 256, 0, stream>>>(
          dec2inH, dec2inL, W2h, W2l, d2_b, 64, 64, 120, 640, 642, 1, 1, 1, 1,
          9, D2IN_FS, ACT_LEAKY, dec2out, D2OUT_FS, nullptr, nullptr, 0, 0, 0,
          0);
      long tot = 2L * 3 * 120 * 80;
      conv2d_k<3, 1, 1><<<cdivu(tot, 256), 256, 0, stream>>>(
          dec2out, d3_w, d3_b, out + (long)(f + ff) * 230400, nullptr, nullptr,
          0, 0, 0, 2, 64, 120, 640, 3, 120, 640, 1, ACT_TANH);
    }
  }
}